// Round 2
// baseline (890.553 us; speedup 1.0000x reference)
//
#include <hip/hip_runtime.h>
#include <cstdint>
#include <cstddef>

// Round 1: identical to round 0 — previous bench failed on infra
// (UnresponsiveContainer), no signal received. Resubmitting for a real run.

#define BB 64      // batch
#define CH 256     // channels
#define NP 128     // points
#define DQ 64      // q/k dim
#define NLAYERS 4

#define ANG_FACTOR 3.8197186342054885f   // 180/(pi*15) = 12/pi
#define DIV_STEP   0.28782313662425575f  // ln(10000)/32

// ---------------------------------------------------------------------------
// E2[b][m][o] = sum_d p2w[o][d]*emb2[b][m][d] + p2b[o]
// emb2[.,2j]=sin(idx*div_j), emb2[.,2j+1]=cos(idx*div_j), idx=angle_cross*FACTOR
__global__ __launch_bounds__(256) void k_e2(
    const float* __restrict__ ac, const float* __restrict__ p2w,
    const float* __restrict__ p2b, float* __restrict__ E2)
{
  __shared__ float pw[DQ][65];
  __shared__ float emb[4][DQ];
  __shared__ float pb[DQ];
  int tid = threadIdx.x;
  int bm0 = blockIdx.x * 4;
#pragma unroll
  for (int i = 0; i < 16; i++) {
    int idx = tid + i * 256;
    pw[idx >> 6][idx & 63] = p2w[idx];
  }
  if (tid < DQ) pb[tid] = p2b[tid];
  if (tid < 128) {
    int ml = tid >> 5, j = tid & 31;
    float a = ac[bm0 + ml];
    float s, c;
    __sincosf(a * ANG_FACTOR * __expf(-(float)j * DIV_STEP), &s, &c);
    emb[ml][2 * j] = s;
    emb[ml][2 * j + 1] = c;
  }
  __syncthreads();
  int mloc = tid >> 6, o = tid & 63;
  float acc = pb[o];
#pragma unroll
  for (int d = 0; d < DQ; d++) acc = fmaf(pw[o][d], emb[mloc][d], acc);
  E2[(size_t)(bm0 + mloc) * DQ + o] = acc;
}

// ---------------------------------------------------------------------------
// kind0: XQ[b][n][d]  = sum_c Wq[d][c] x[b][c][n]      (stored n-major)
// kind1: KLT[b][m][o] = sum_c Wk[o][c] x[b][c][m]      (transposed store)
// kind2: KP2T[b][m][o]= sum_c Wq[o][c] pca[b][c][m] + E2[b][m][o]
__global__ __launch_bounds__(256) void k_qk(
    const float* __restrict__ xsrc, int xbs, const float* __restrict__ pca,
    const float* __restrict__ Wq, const float* __restrict__ Wk,
    const float* __restrict__ E2,
    float* __restrict__ XQ, float* __restrict__ KLT, float* __restrict__ KP2T)
{
  int b = blockIdx.x, kind = blockIdx.y;
  const float* W = (kind == 1) ? Wk : Wq;
  const float* X = (kind == 2) ? (pca + (size_t)b * CH * NP) : (xsrc + (size_t)b * xbs);
  __shared__ __align__(16) float WT[32][68];
  __shared__ __align__(16) float XT[32][NP];
  int tid = threadIdx.x;
  int tn = tid & 15, td = tid >> 4;
  float acc[4][8] = {};
  for (int c0 = 0; c0 < CH; c0 += 32) {
    __syncthreads();
#pragma unroll
    for (int i = 0; i < 8; i++) {
      int idx = tid + i * 256;
      WT[idx & 31][idx >> 5] = W[(size_t)(idx >> 5) * CH + c0 + (idx & 31)];
    }
#pragma unroll
    for (int i = 0; i < 16; i++) {
      int idx = tid + i * 256;
      XT[idx >> 7][idx & 127] = X[(size_t)(c0 + (idx >> 7)) * NP + (idx & 127)];
    }
    __syncthreads();
#pragma unroll
    for (int cc = 0; cc < 32; cc++) {
      float4 w4 = *(const float4*)&WT[cc][td * 4];
      float4 xa = *(const float4*)&XT[cc][tn * 8];
      float4 xb = *(const float4*)&XT[cc][tn * 8 + 4];
      float w[4] = {w4.x, w4.y, w4.z, w4.w};
      float xv[8] = {xa.x, xa.y, xa.z, xa.w, xb.x, xb.y, xb.z, xb.w};
#pragma unroll
      for (int i = 0; i < 4; i++)
#pragma unroll
        for (int j = 0; j < 8; j++) acc[i][j] = fmaf(w[i], xv[j], acc[i][j]);
    }
  }
  int d0 = td * 4, n0 = tn * 8;
  if (kind == 0) {
#pragma unroll
    for (int j = 0; j < 8; j++) {
      float4 v = {acc[0][j], acc[1][j], acc[2][j], acc[3][j]};
      *(float4*)&XQ[((size_t)b * NP + n0 + j) * DQ + d0] = v;
    }
  } else if (kind == 1) {
#pragma unroll
    for (int j = 0; j < 8; j++) {
      float4 v = {acc[0][j], acc[1][j], acc[2][j], acc[3][j]};
      *(float4*)&KLT[((size_t)b * NP + n0 + j) * DQ + d0] = v;
    }
  } else {
#pragma unroll
    for (int j = 0; j < 8; j++) {
      float4 e = *(const float4*)&E2[((size_t)b * NP + n0 + j) * DQ + d0];
      float4 v = {acc[0][j] + e.x, acc[1][j] + e.y, acc[2][j] + e.z, acc[3][j] + e.w};
      *(float4*)&KP2T[((size_t)b * NP + n0 + j) * DQ + d0] = v;
    }
  }
}

// ---------------------------------------------------------------------------
// Q1[b][n][d] = sum_o XQ[b][n][o] p1w[o][d];  C1[b][n] = sum_o XQ[b][n][o] p1b[o]
__global__ __launch_bounds__(256) void k_q1c1(
    const float* __restrict__ XQ, const float* __restrict__ p1w,
    const float* __restrict__ p1b, float* __restrict__ Q1, float* __restrict__ C1)
{
  int b = blockIdx.x, tid = threadIdx.x;
  __shared__ float xqs[NP][65];
  __shared__ float pw[DQ][65];
  __shared__ float pb[DQ];
#pragma unroll
  for (int i = 0; i < 32; i++) {
    int idx = tid + i * 256;
    xqs[idx >> 6][idx & 63] = XQ[(size_t)b * NP * DQ + idx];
  }
#pragma unroll
  for (int i = 0; i < 16; i++) {
    int idx = tid + i * 256;
    pw[idx >> 6][idx & 63] = p1w[idx];
  }
  if (tid < DQ) pb[tid] = p1b[tid];
  __syncthreads();
  int n = tid >> 1, d0 = (tid & 1) * 32;
  float acc[32] = {};
  float cacc = 0.0f;
  for (int o = 0; o < DQ; o++) {
    float xv = xqs[n][o];
    cacc = fmaf(pb[o], xv, cacc);
#pragma unroll
    for (int dd = 0; dd < 32; dd++) acc[dd] = fmaf(pw[o][d0 + dd], xv, acc[dd]);
  }
#pragma unroll
  for (int dd = 0; dd < 32; dd += 4) {
    float4 v = {acc[dd], acc[dd + 1], acc[dd + 2], acc[dd + 3]};
    *(float4*)&Q1[((size_t)b * NP + n) * DQ + d0 + dd] = v;
  }
  if ((tid & 1) == 0) C1[b * NP + n] = cacc;
}

// ---------------------------------------------------------------------------
// EN[b][n][m] = bw * sum_o xq[n][o] KLT[m][o] + (1-bw) * sum_o xq[n][o] KP2T[m][o]
__global__ __launch_bounds__(256) void k_energyA(
    const float* __restrict__ XQ, const float* __restrict__ KLT,
    const float* __restrict__ KP2T, const float* __restrict__ beta_w, int layer,
    float* __restrict__ EN)
{
  int nh = blockIdx.x, b = blockIdx.y;
  int n0 = nh * 64;
  float bw = beta_w[layer];
  __shared__ __align__(16) float WT[32][68];
  __shared__ __align__(16) float BT[32][132];
  int tid = threadIdx.x, tn = tid & 15, td = tid >> 4;
  float acc[4][8] = {};
#pragma unroll
  for (int kt = 0; kt < 4; kt++) {
    int k0 = (kt & 1) * 32;
    const float* Bsrc = (kt < 2) ? KLT : KP2T;
    float as = (kt < 2) ? bw : (1.0f - bw);
    __syncthreads();
#pragma unroll
    for (int i = 0; i < 8; i++) {
      int idx = tid + i * 256;
      WT[idx & 31][idx >> 5] =
          as * XQ[((size_t)b * NP + n0 + (idx >> 5)) * DQ + k0 + (idx & 31)];
    }
#pragma unroll
    for (int i = 0; i < 16; i++) {
      int idx = tid + i * 256;
      BT[idx & 31][idx >> 5] = Bsrc[((size_t)b * NP + (idx >> 5)) * DQ + k0 + (idx & 31)];
    }
    __syncthreads();
#pragma unroll
    for (int kk = 0; kk < 32; kk++) {
      float4 w4 = *(const float4*)&WT[kk][td * 4];
      float4 xa = *(const float4*)&BT[kk][tn * 8];
      float4 xb = *(const float4*)&BT[kk][tn * 8 + 4];
      float w[4] = {w4.x, w4.y, w4.z, w4.w};
      float xv[8] = {xa.x, xa.y, xa.z, xa.w, xb.x, xb.y, xb.z, xb.w};
#pragma unroll
      for (int i = 0; i < 4; i++)
#pragma unroll
        for (int j = 0; j < 8; j++) acc[i][j] = fmaf(w[i], xv[j], acc[i][j]);
    }
  }
#pragma unroll
  for (int i = 0; i < 4; i++) {
    float4 va = {acc[i][0], acc[i][1], acc[i][2], acc[i][3]};
    float4 vb = {acc[i][4], acc[i][5], acc[i][6], acc[i][7]};
    size_t off = ((size_t)b * NP + n0 + td * 4 + i) * NP + tn * 8;
    *(float4*)&EN[off] = va;
    *(float4*)&EN[off + 4] = vb;
  }
}

// ---------------------------------------------------------------------------
// EN += bw*(q1 . emb1(angle_self) + c1), then softmax over m (in place)
__global__ __launch_bounds__(128) void k_bias(
    float* __restrict__ EN, const float* __restrict__ Q1,
    const float* __restrict__ C1, const float* __restrict__ AS,
    const float* __restrict__ beta_w, int layer)
{
  int blk = blockIdx.x;
  int b = blk >> 7, n = blk & 127;
  int m = threadIdx.x;
  __shared__ float q1s[DQ];
  __shared__ float divs[32];
  __shared__ float red[128];
  if (m < DQ) q1s[m] = Q1[((size_t)b * NP + n) * DQ + m];
  if (m >= 96) divs[m - 96] = __expf(-(float)(m - 96) * DIV_STEP);
  __syncthreads();
  float bw = beta_w[layer];
  size_t row = ((size_t)b * NP + n) * NP;
  float E = EN[row + m];
  float bias = C1[b * NP + n];
  float idxv = AS[row + m] * ANG_FACTOR;
#pragma unroll
  for (int j = 0; j < 32; j++) {
    float s, c;
    __sincosf(idxv * divs[j], &s, &c);
    bias = fmaf(q1s[2 * j], s, bias);
    bias = fmaf(q1s[2 * j + 1], c, bias);
  }
  E += bw * bias;
  red[m] = E;
  __syncthreads();
#pragma unroll
  for (int st = 64; st > 0; st >>= 1) {
    if (m < st) red[m] = fmaxf(red[m], red[m + st]);
    __syncthreads();
  }
  float mx = red[0];
  __syncthreads();
  float p = __expf(E - mx);
  red[m] = p;
  __syncthreads();
#pragma unroll
  for (int st = 64; st > 0; st >>= 1) {
    if (m < st) red[m] += red[m + st];
    __syncthreads();
  }
  EN[row + m] = p / red[0];
}

// ---------------------------------------------------------------------------
// SCL[b][m] = 1 / (1e-12 + sum_n EN[b][n][m])
__global__ __launch_bounds__(128) void k_colsum(const float* __restrict__ EN,
                                                float* __restrict__ SCL)
{
  int b = blockIdx.x, m = threadIdx.x;
  float s = 1e-12f;
  for (int n = 0; n < NP; n++) s += EN[((size_t)b * NP + n) * NP + m];
  SCL[b * NP + m] = 1.0f / s;
}

// ---------------------------------------------------------------------------
// U[b][c][n] = bx*sum_k Wv[c][k] x[b][k][n] + (1-bx)*sum_k Wvp[c][k] pca[b][k][n]
__global__ __launch_bounds__(256) void k_u(
    const float* __restrict__ xsrc, int xbs, const float* __restrict__ pca,
    const float* __restrict__ Wv, const float* __restrict__ Wvp,
    const float* __restrict__ beta_x, int layer, float* __restrict__ U)
{
  int cq = blockIdx.x, b = blockIdx.y;
  int c0 = cq * 64;
  float bx = beta_x[layer];
  __shared__ __align__(16) float WT[32][68];
  __shared__ __align__(16) float XT[32][NP];
  int tid = threadIdx.x, tn = tid & 15, tc = tid >> 4;
  float acc[4][8] = {};
  for (int half = 0; half < 2; half++) {
    const float* X = half ? (pca + (size_t)b * CH * NP) : (xsrc + (size_t)b * xbs);
    const float* W = half ? Wvp : Wv;
    float sc = half ? (1.0f - bx) : bx;
    for (int k0 = 0; k0 < CH; k0 += 32) {
      __syncthreads();
#pragma unroll
      for (int i = 0; i < 8; i++) {
        int idx = tid + i * 256;
        WT[idx & 31][idx >> 5] = sc * W[(size_t)(c0 + (idx >> 5)) * CH + k0 + (idx & 31)];
      }
#pragma unroll
      for (int i = 0; i < 16; i++) {
        int idx = tid + i * 256;
        XT[idx >> 7][idx & 127] = X[(size_t)(k0 + (idx >> 7)) * NP + (idx & 127)];
      }
      __syncthreads();
#pragma unroll
      for (int kk = 0; kk < 32; kk++) {
        float4 w4 = *(const float4*)&WT[kk][tc * 4];
        float4 xa = *(const float4*)&XT[kk][tn * 8];
        float4 xb = *(const float4*)&XT[kk][tn * 8 + 4];
        float w[4] = {w4.x, w4.y, w4.z, w4.w};
        float xv[8] = {xa.x, xa.y, xa.z, xa.w, xb.x, xb.y, xb.z, xb.w};
#pragma unroll
        for (int i = 0; i < 4; i++)
#pragma unroll
          for (int j = 0; j < 8; j++) acc[i][j] = fmaf(w[i], xv[j], acc[i][j]);
      }
    }
  }
#pragma unroll
  for (int i = 0; i < 4; i++) {
    float4 va = {acc[i][0], acc[i][1], acc[i][2], acc[i][3]};
    float4 vb = {acc[i][4], acc[i][5], acc[i][6], acc[i][7]};
    size_t off = ((size_t)b * CH + c0 + tc * 4 + i) * NP + tn * 8;
    *(float4*)&U[off] = va;
    *(float4*)&U[off + 4] = vb;
  }
}

// ---------------------------------------------------------------------------
// T[b][c][m] = x[b][c][m] - (sum_n U[b][c][n] EN[b][n][m]) * SCL[b][m]
__global__ __launch_bounds__(256) void k_t(
    const float* __restrict__ U, const float* __restrict__ EN,
    const float* __restrict__ SCL, const float* __restrict__ xsrc, int xbs,
    float* __restrict__ T)
{
  int cq = blockIdx.x, b = blockIdx.y;
  int c0 = cq * 64;
  __shared__ __align__(16) float UT[32][68];
  __shared__ __align__(16) float ET[32][NP];
  int tid = threadIdx.x, tm = tid & 15, tc = tid >> 4;
  float acc[4][8] = {};
  for (int n0 = 0; n0 < NP; n0 += 32) {
    __syncthreads();
#pragma unroll
    for (int i = 0; i < 8; i++) {
      int idx = tid + i * 256;
      UT[idx & 31][idx >> 5] = U[((size_t)b * CH + c0 + (idx >> 5)) * NP + n0 + (idx & 31)];
    }
#pragma unroll
    for (int i = 0; i < 16; i++) {
      int idx = tid + i * 256;
      ET[idx >> 7][idx & 127] = EN[((size_t)b * NP + n0 + (idx >> 7)) * NP + (idx & 127)];
    }
    __syncthreads();
#pragma unroll
    for (int nn = 0; nn < 32; nn++) {
      float4 u4 = *(const float4*)&UT[nn][tc * 4];
      float4 ea = *(const float4*)&ET[nn][tm * 8];
      float4 eb = *(const float4*)&ET[nn][tm * 8 + 4];
      float w[4] = {u4.x, u4.y, u4.z, u4.w};
      float ev[8] = {ea.x, ea.y, ea.z, ea.w, eb.x, eb.y, eb.z, eb.w};
#pragma unroll
      for (int i = 0; i < 4; i++)
#pragma unroll
        for (int j = 0; j < 8; j++) acc[i][j] = fmaf(w[i], ev[j], acc[i][j]);
    }
  }
  int m0 = tm * 8;
  float4 sa = *(const float4*)&SCL[b * NP + m0];
  float4 sb = *(const float4*)&SCL[b * NP + m0 + 4];
  float sc[8] = {sa.x, sa.y, sa.z, sa.w, sb.x, sb.y, sb.z, sb.w};
#pragma unroll
  for (int i = 0; i < 4; i++) {
    int c = c0 + tc * 4 + i;
    float4 xa = *(const float4*)&xsrc[(size_t)b * xbs + (size_t)c * NP + m0];
    float4 xb = *(const float4*)&xsrc[(size_t)b * xbs + (size_t)c * NP + m0 + 4];
    float xv[8] = {xa.x, xa.y, xa.z, xa.w, xb.x, xb.y, xb.z, xb.w};
    float t[8];
#pragma unroll
    for (int j = 0; j < 8; j++) t[j] = xv[j] - acc[i][j] * sc[j];
    float4 ta = {t[0], t[1], t[2], t[3]}, tb = {t[4], t[5], t[6], t[7]};
    size_t off = ((size_t)b * CH + c) * NP + m0;
    *(float4*)&T[off] = ta;
    *(float4*)&T[off + 4] = tb;
  }
}

// ---------------------------------------------------------------------------
// out[b][l*CH+c][n] = x[b][c][n] + gelu(BN(sum_k Wl[c][k] T[b][k][n] + bl[c]))
__global__ __launch_bounds__(256) void k_h(
    const float* __restrict__ T, const float* __restrict__ Wl,
    const float* __restrict__ bl, const float* __restrict__ bng,
    const float* __restrict__ bnb, const float* __restrict__ xsrc, int xbs,
    float* __restrict__ out, int layer)
{
  int cq = blockIdx.x, b = blockIdx.y;
  int c0 = cq * 64;
  __shared__ __align__(16) float WT[32][68];
  __shared__ __align__(16) float TT[32][NP];
  int tid = threadIdx.x, tn = tid & 15, tc = tid >> 4;
  float acc[4][8] = {};
  for (int k0 = 0; k0 < CH; k0 += 32) {
    __syncthreads();
#pragma unroll
    for (int i = 0; i < 8; i++) {
      int idx = tid + i * 256;
      WT[idx & 31][idx >> 5] = Wl[(size_t)(c0 + (idx >> 5)) * CH + k0 + (idx & 31)];
    }
#pragma unroll
    for (int i = 0; i < 16; i++) {
      int idx = tid + i * 256;
      TT[idx >> 7][idx & 127] = T[((size_t)b * CH + k0 + (idx >> 7)) * NP + (idx & 127)];
    }
    __syncthreads();
#pragma unroll
    for (int kk = 0; kk < 32; kk++) {
      float4 w4 = *(const float4*)&WT[kk][tc * 4];
      float4 xa = *(const float4*)&TT[kk][tn * 8];
      float4 xb = *(const float4*)&TT[kk][tn * 8 + 4];
      float w[4] = {w4.x, w4.y, w4.z, w4.w};
      float xv[8] = {xa.x, xa.y, xa.z, xa.w, xb.x, xb.y, xb.z, xb.w};
#pragma unroll
      for (int i = 0; i < 4; i++)
#pragma unroll
        for (int j = 0; j < 8; j++) acc[i][j] = fmaf(w[i], xv[j], acc[i][j]);
    }
  }
  const float rbn = 1.0f / sqrtf(1.0f + 1e-5f);
  int n0 = tn * 8;
#pragma unroll
  for (int i = 0; i < 4; i++) {
    int c = c0 + tc * 4 + i;
    float blv = bl[c], gv = bng[c], bv = bnb[c];
    float4 xa = *(const float4*)&xsrc[(size_t)b * xbs + (size_t)c * NP + n0];
    float4 xb = *(const float4*)&xsrc[(size_t)b * xbs + (size_t)c * NP + n0 + 4];
    float xv[8] = {xa.x, xa.y, xa.z, xa.w, xb.x, xb.y, xb.z, xb.w};
    float o[8];
#pragma unroll
    for (int j = 0; j < 8; j++) {
      float h = acc[i][j] + blv;
      h = h * rbn * gv + bv;
      float g = 0.5f * h * (1.0f + erff(h * 0.70710678118654752440f));
      o[j] = xv[j] + g;
    }
    float4 oa = {o[0], o[1], o[2], o[3]}, ob = {o[4], o[5], o[6], o[7]};
    size_t off = ((size_t)b * 4 * CH + (size_t)layer * CH + c) * NP + n0;
    *(float4*)&out[off] = oa;
    *(float4*)&out[off + 4] = ob;
  }
}

// ---------------------------------------------------------------------------
extern "C" void kernel_launch(void* const* d_in, const int* in_sizes, int n_in,
                              void* d_out, int out_size, void* d_ws, size_t ws_size,
                              hipStream_t stream)
{
  (void)in_sizes; (void)n_in; (void)out_size; (void)ws_size;
  const float* lrf     = (const float*)d_in[0];
  const float* pca     = (const float*)d_in[1];
  const float* a_self  = (const float*)d_in[2];
  const float* a_cross = (const float*)d_in[3];
  const float* Wq  = (const float*)d_in[4];
  const float* Wk  = (const float*)d_in[5];
  const float* Wv  = (const float*)d_in[6];
  const float* Wvp = (const float*)d_in[7];
  const float* Wl  = (const float*)d_in[8];
  const float* bl  = (const float*)d_in[9];
  const float* bng = (const float*)d_in[10];
  const float* bnb = (const float*)d_in[11];
  const float* p1w = (const float*)d_in[12];
  const float* p1b = (const float*)d_in[13];
  const float* p2w = (const float*)d_in[14];
  const float* p2b = (const float*)d_in[15];
  const float* beta_x = (const float*)d_in[16];
  const float* beta_w = (const float*)d_in[17];
  float* out = (float*)d_out;
  float* ws  = (float*)d_ws;

  // workspace carve (floats): total 7,880,704 floats = 31.5 MB
  float* XQ   = ws;
  float* Q1   = XQ + (size_t)BB * NP * DQ;
  float* C1   = Q1 + (size_t)BB * NP * DQ;
  float* KLT  = C1 + (size_t)BB * NP;
  float* KP2T = KLT + (size_t)BB * NP * DQ;
  float* E2   = KP2T + (size_t)BB * NP * DQ;
  float* EN   = E2 + (size_t)BB * NP * DQ;
  float* SCL  = EN + (size_t)BB * NP * NP;
  float* U    = SCL + (size_t)BB * NP;
  float* T    = U + (size_t)BB * CH * NP;

  for (int l = 0; l < NLAYERS; l++) {
    const float* xsrc = (l == 0) ? lrf : (out + (size_t)(l - 1) * CH * NP);
    int xbs = (l == 0) ? CH * NP : 4 * CH * NP;
    k_e2<<<dim3(BB * NP / 4), 256, 0, stream>>>(
        a_cross, p2w + (size_t)l * DQ * DQ, p2b + (size_t)l * DQ, E2);
    k_qk<<<dim3(BB, 3), 256, 0, stream>>>(
        xsrc, xbs, pca, Wq + (size_t)l * DQ * CH, Wk + (size_t)l * DQ * CH, E2,
        XQ, KLT, KP2T);
    k_q1c1<<<dim3(BB), 256, 0, stream>>>(
        XQ, p1w + (size_t)l * DQ * DQ, p1b + (size_t)l * DQ, Q1, C1);
    k_energyA<<<dim3(2, BB), 256, 0, stream>>>(XQ, KLT, KP2T, beta_w, l, EN);
    k_bias<<<dim3(BB * NP), 128, 0, stream>>>(EN, Q1, C1, a_self, beta_w, l);
    k_colsum<<<dim3(BB), 128, 0, stream>>>(EN, SCL);
    k_u<<<dim3(4, BB), 256, 0, stream>>>(
        xsrc, xbs, pca, Wv + (size_t)l * CH * CH, Wvp + (size_t)l * CH * CH,
        beta_x, l, U);
    k_t<<<dim3(4, BB), 256, 0, stream>>>(U, EN, SCL, xsrc, xbs, T);
    k_h<<<dim3(4, BB), 256, 0, stream>>>(
        T, Wl + (size_t)l * CH * CH, bl + (size_t)l * CH, bng + (size_t)l * CH,
        bnb + (size_t)l * CH, xsrc, xbs, out, l);
  }
}

// Round 3
// 717.248 us; speedup vs baseline: 1.2416x; 1.2416x over previous
//
#include <hip/hip_runtime.h>
#include <cstdint>
#include <cstddef>

// Round 2: occupancy fix. All GEMM-shaped kernels move from 64-wide to
// 32-wide output tiles; k_u splits x/pca halves into separate blocks
// (U1/U2, summed in k_t staging); k_energy splits lrf/pca sources into
// ENa/ENb (summed in k_bias). Grids go 256 -> 384..1024 blocks.
// T aliases the dead XQ/KLT/KP2T/E2 region to keep ws ~34MB.

#define BB 64      // batch
#define CH 256     // channels
#define NP 128     // points
#define DQ 64      // q/k dim
#define NLAYERS 4

#define ANG_FACTOR 3.8197186342054885f   // 180/(pi*15) = 12/pi
#define DIV_STEP   0.28782313662425575f  // ln(10000)/32

// ---------------------------------------------------------------------------
// E2[b][m][o] = sum_d p2w[o][d]*emb2[b][m][d] + p2b[o]
__global__ __launch_bounds__(256) void k_e2(
    const float* __restrict__ ac, const float* __restrict__ p2w,
    const float* __restrict__ p2b, float* __restrict__ E2)
{
  __shared__ float pw[DQ][65];
  __shared__ float emb[4][DQ];
  __shared__ float pb[DQ];
  int tid = threadIdx.x;
  int bm0 = blockIdx.x * 4;
#pragma unroll
  for (int i = 0; i < 16; i++) {
    int idx = tid + i * 256;
    pw[idx >> 6][idx & 63] = p2w[idx];
  }
  if (tid < DQ) pb[tid] = p2b[tid];
  if (tid < 128) {
    int ml = tid >> 5, j = tid & 31;
    float a = ac[bm0 + ml];
    float s, c;
    __sincosf(a * ANG_FACTOR * __expf(-(float)j * DIV_STEP), &s, &c);
    emb[ml][2 * j] = s;
    emb[ml][2 * j + 1] = c;
  }
  __syncthreads();
  int mloc = tid >> 6, o = tid & 63;
  float acc = pb[o];
#pragma unroll
  for (int d = 0; d < DQ; d++) acc = fmaf(pw[o][d], emb[mloc][d], acc);
  E2[(size_t)(bm0 + mloc) * DQ + o] = acc;
}

// ---------------------------------------------------------------------------
// 32-d tile per block. kind0: XQ = Wq@x (n-major); kind1: KLT = Wk@x (m-major
// rows of DQ); kind2: KP2T = Wq@pca + E2.
__global__ __launch_bounds__(256) void k_qk(
    const float* __restrict__ xsrc, int xbs, const float* __restrict__ pca,
    const float* __restrict__ Wq, const float* __restrict__ Wk,
    const float* __restrict__ E2,
    float* __restrict__ XQ, float* __restrict__ KLT, float* __restrict__ KP2T)
{
  int dtile = blockIdx.x, kind = blockIdx.y, b = blockIdx.z;
  const float* W = (kind == 1) ? Wk : Wq;
  const float* X = (kind == 2) ? (pca + (size_t)b * CH * NP) : (xsrc + (size_t)b * xbs);
  __shared__ __align__(16) float WT[32][34];   // [c][d]
  __shared__ __align__(16) float XT[32][NP];   // [c][n]
  int tid = threadIdx.x;
  int tn = tid & 15, td = tid >> 4;
  float acc[2][8] = {};
  for (int c0 = 0; c0 < CH; c0 += 32) {
    __syncthreads();
#pragma unroll
    for (int i = 0; i < 4; i++) {
      int idx = tid + i * 256;
      WT[idx & 31][idx >> 5] = W[(size_t)(dtile * 32 + (idx >> 5)) * CH + c0 + (idx & 31)];
    }
#pragma unroll
    for (int i = 0; i < 16; i++) {
      int idx = tid + i * 256;
      XT[idx >> 7][idx & 127] = X[(size_t)(c0 + (idx >> 7)) * NP + (idx & 127)];
    }
    __syncthreads();
#pragma unroll
    for (int cc = 0; cc < 32; cc++) {
      float2 w2 = *(const float2*)&WT[cc][td * 2];
      float4 xa = *(const float4*)&XT[cc][tn * 8];
      float4 xb = *(const float4*)&XT[cc][tn * 8 + 4];
      float w[2] = {w2.x, w2.y};
      float xv[8] = {xa.x, xa.y, xa.z, xa.w, xb.x, xb.y, xb.z, xb.w};
#pragma unroll
      for (int i = 0; i < 2; i++)
#pragma unroll
        for (int j = 0; j < 8; j++) acc[i][j] = fmaf(w[i], xv[j], acc[i][j]);
    }
  }
  int d0 = dtile * 32 + td * 2, n0 = tn * 8;
  if (kind == 0) {
#pragma unroll
    for (int j = 0; j < 8; j++) {
      float2 v = {acc[0][j], acc[1][j]};
      *(float2*)&XQ[((size_t)b * NP + n0 + j) * DQ + d0] = v;
    }
  } else if (kind == 1) {
#pragma unroll
    for (int j = 0; j < 8; j++) {
      float2 v = {acc[0][j], acc[1][j]};
      *(float2*)&KLT[((size_t)b * NP + n0 + j) * DQ + d0] = v;
    }
  } else {
#pragma unroll
    for (int j = 0; j < 8; j++) {
      float2 e = *(const float2*)&E2[((size_t)b * NP + n0 + j) * DQ + d0];
      float2 v = {acc[0][j] + e.x, acc[1][j] + e.y};
      *(float2*)&KP2T[((size_t)b * NP + n0 + j) * DQ + d0] = v;
    }
  }
}

// ---------------------------------------------------------------------------
// Q1[b][n][d] = sum_o XQ[b][n][o] p1w[o][d];  C1[b][n] = sum_o XQ[b][n][o] p1b[o]
__global__ __launch_bounds__(256) void k_q1c1(
    const float* __restrict__ XQ, const float* __restrict__ p1w,
    const float* __restrict__ p1b, float* __restrict__ Q1, float* __restrict__ C1)
{
  int b = blockIdx.x, tid = threadIdx.x;
  __shared__ float xqs[NP][65];
  __shared__ float pw[DQ][65];
  __shared__ float pb[DQ];
#pragma unroll
  for (int i = 0; i < 32; i++) {
    int idx = tid + i * 256;
    xqs[idx >> 6][idx & 63] = XQ[(size_t)b * NP * DQ + idx];
  }
#pragma unroll
  for (int i = 0; i < 16; i++) {
    int idx = tid + i * 256;
    pw[idx >> 6][idx & 63] = p1w[idx];
  }
  if (tid < DQ) pb[tid] = p1b[tid];
  __syncthreads();
  int n = tid >> 1, d0 = (tid & 1) * 32;
  float acc[32] = {};
  float cacc = 0.0f;
  for (int o = 0; o < DQ; o++) {
    float xv = xqs[n][o];
    cacc = fmaf(pb[o], xv, cacc);
#pragma unroll
    for (int dd = 0; dd < 32; dd++) acc[dd] = fmaf(pw[o][d0 + dd], xv, acc[dd]);
  }
#pragma unroll
  for (int dd = 0; dd < 32; dd += 4) {
    float4 v = {acc[dd], acc[dd + 1], acc[dd + 2], acc[dd + 3]};
    *(float4*)&Q1[((size_t)b * NP + n) * DQ + d0 + dd] = v;
  }
  if ((tid & 1) == 0) C1[b * NP + n] = cacc;
}

// ---------------------------------------------------------------------------
// src=0: ENa = bw * xq @ KLT^T ; src=1: ENb = (1-bw) * xq @ KP2T^T
// 32-n tile per block.
__global__ __launch_bounds__(256) void k_energy(
    const float* __restrict__ XQ, const float* __restrict__ KLT,
    const float* __restrict__ KP2T, const float* __restrict__ beta_w, int layer,
    float* __restrict__ ENa, float* __restrict__ ENb)
{
  int ntile = blockIdx.x, b = blockIdx.y, src = blockIdx.z;
  float bw = beta_w[layer];
  const float* Bsrc = src ? KP2T : KLT;
  float as = src ? (1.0f - bw) : bw;
  float* OUT = src ? ENb : ENa;
  __shared__ __align__(16) float WT[32][34];    // [k][n]
  __shared__ __align__(16) float BT[32][132];   // [k][m]
  int tid = threadIdx.x, tn = tid & 15, tc = tid >> 4;
  float acc[2][8] = {};
#pragma unroll
  for (int k0 = 0; k0 < DQ; k0 += 32) {
    __syncthreads();
#pragma unroll
    for (int i = 0; i < 4; i++) {
      int idx = tid + i * 256;
      WT[idx & 31][idx >> 5] =
          as * XQ[((size_t)b * NP + ntile * 32 + (idx >> 5)) * DQ + k0 + (idx & 31)];
    }
#pragma unroll
    for (int i = 0; i < 16; i++) {
      int idx = tid + i * 256;
      BT[idx & 31][idx >> 5] = Bsrc[((size_t)b * NP + (idx >> 5)) * DQ + k0 + (idx & 31)];
    }
    __syncthreads();
#pragma unroll
    for (int kk = 0; kk < 32; kk++) {
      float2 w2 = *(const float2*)&WT[kk][tc * 2];
      float4 xa = *(const float4*)&BT[kk][tn * 8];
      float4 xb = *(const float4*)&BT[kk][tn * 8 + 4];
      float w[2] = {w2.x, w2.y};
      float xv[8] = {xa.x, xa.y, xa.z, xa.w, xb.x, xb.y, xb.z, xb.w};
#pragma unroll
      for (int i = 0; i < 2; i++)
#pragma unroll
        for (int j = 0; j < 8; j++) acc[i][j] = fmaf(w[i], xv[j], acc[i][j]);
    }
  }
#pragma unroll
  for (int i = 0; i < 2; i++) {
    int n = ntile * 32 + tc * 2 + i;
    float4 va = {acc[i][0], acc[i][1], acc[i][2], acc[i][3]};
    float4 vb = {acc[i][4], acc[i][5], acc[i][6], acc[i][7]};
    size_t off = ((size_t)b * NP + n) * NP + tn * 8;
    *(float4*)&OUT[off] = va;
    *(float4*)&OUT[off + 4] = vb;
  }
}

// ---------------------------------------------------------------------------
// P = softmax_m(ENa + ENb + bw*(q1.emb1 + c1)); write P into ENa.
__global__ __launch_bounds__(128) void k_bias(
    float* __restrict__ ENa, const float* __restrict__ ENb,
    const float* __restrict__ Q1, const float* __restrict__ C1,
    const float* __restrict__ AS, const float* __restrict__ beta_w, int layer)
{
  int blk = blockIdx.x;
  int b = blk >> 7, n = blk & 127;
  int m = threadIdx.x;
  __shared__ float q1s[DQ];
  __shared__ float divs[32];
  __shared__ float xred[2];
  __shared__ float sred[2];
  if (m < DQ) q1s[m] = Q1[((size_t)b * NP + n) * DQ + m];
  if (m >= 96) divs[m - 96] = __expf(-(float)(m - 96) * DIV_STEP);
  __syncthreads();
  float bw = beta_w[layer];
  size_t row = ((size_t)b * NP + n) * NP;
  float E = ENa[row + m] + ENb[row + m];
  float bias = C1[b * NP + n];
  float idxv = AS[row + m] * ANG_FACTOR;
#pragma unroll
  for (int j = 0; j < 32; j++) {
    float s, c;
    __sincosf(idxv * divs[j], &s, &c);
    bias = fmaf(q1s[2 * j], s, bias);
    bias = fmaf(q1s[2 * j + 1], c, bias);
  }
  E += bw * bias;
  float v = E;
#pragma unroll
  for (int off = 32; off; off >>= 1) v = fmaxf(v, __shfl_xor(v, off));
  if ((m & 63) == 0) xred[m >> 6] = v;
  __syncthreads();
  float mx = fmaxf(xred[0], xred[1]);
  float p = __expf(E - mx);
  v = p;
#pragma unroll
  for (int off = 32; off; off >>= 1) v += __shfl_xor(v, off);
  if ((m & 63) == 0) sred[m >> 6] = v;
  __syncthreads();
  float s = sred[0] + sred[1];
  ENa[row + m] = p / s;
}

// ---------------------------------------------------------------------------
// SCL[b][m] = 1 / (1e-12 + sum_n P[b][n][m])
__global__ __launch_bounds__(256) void k_colsum(const float* __restrict__ EN,
                                                float* __restrict__ SCL)
{
  int b = blockIdx.x;
  int m = threadIdx.x & 127, h = threadIdx.x >> 7;
  __shared__ float part[2][128];
  float s = 0.0f;
  for (int n = h * 64; n < h * 64 + 64; n++) s += EN[((size_t)b * NP + n) * NP + m];
  part[h][m] = s;
  __syncthreads();
  if (h == 0) SCL[b * NP + m] = 1.0f / (1e-12f + part[0][m] + part[1][m]);
}

// ---------------------------------------------------------------------------
// half=0: U1 = bx * Wv @ x ; half=1: U2 = (1-bx) * Wvp @ pca.  32-c tiles.
__global__ __launch_bounds__(256) void k_u(
    const float* __restrict__ xsrc, int xbs, const float* __restrict__ pca,
    const float* __restrict__ Wv, const float* __restrict__ Wvp,
    const float* __restrict__ beta_x, int layer,
    float* __restrict__ U1, float* __restrict__ U2)
{
  int ctile = blockIdx.x, b = blockIdx.y, half = blockIdx.z;
  float bx = beta_x[layer];
  const float* X = half ? (pca + (size_t)b * CH * NP) : (xsrc + (size_t)b * xbs);
  const float* W = half ? Wvp : Wv;
  float sc = half ? (1.0f - bx) : bx;
  float* OUT = half ? U2 : U1;
  __shared__ __align__(16) float WT[32][34];   // [k][c]
  __shared__ __align__(16) float XT[32][NP];   // [k][n]
  int tid = threadIdx.x, tn = tid & 15, tc = tid >> 4;
  float acc[2][8] = {};
  for (int k0 = 0; k0 < CH; k0 += 32) {
    __syncthreads();
#pragma unroll
    for (int i = 0; i < 4; i++) {
      int idx = tid + i * 256;
      WT[idx & 31][idx >> 5] = sc * W[(size_t)(ctile * 32 + (idx >> 5)) * CH + k0 + (idx & 31)];
    }
#pragma unroll
    for (int i = 0; i < 16; i++) {
      int idx = tid + i * 256;
      XT[idx >> 7][idx & 127] = X[(size_t)(k0 + (idx >> 7)) * NP + (idx & 127)];
    }
    __syncthreads();
#pragma unroll
    for (int kk = 0; kk < 32; kk++) {
      float2 w2 = *(const float2*)&WT[kk][tc * 2];
      float4 xa = *(const float4*)&XT[kk][tn * 8];
      float4 xb = *(const float4*)&XT[kk][tn * 8 + 4];
      float w[2] = {w2.x, w2.y};
      float xv[8] = {xa.x, xa.y, xa.z, xa.w, xb.x, xb.y, xb.z, xb.w};
#pragma unroll
      for (int i = 0; i < 2; i++)
#pragma unroll
        for (int j = 0; j < 8; j++) acc[i][j] = fmaf(w[i], xv[j], acc[i][j]);
    }
  }
#pragma unroll
  for (int i = 0; i < 2; i++) {
    int c = ctile * 32 + tc * 2 + i;
    float4 va = {acc[i][0], acc[i][1], acc[i][2], acc[i][3]};
    float4 vb = {acc[i][4], acc[i][5], acc[i][6], acc[i][7]};
    size_t off = ((size_t)b * CH + c) * NP + tn * 8;
    *(float4*)&OUT[off] = va;
    *(float4*)&OUT[off + 4] = vb;
  }
}

// ---------------------------------------------------------------------------
// T[b][c][m] = x[b][c][m] - (sum_n (U1+U2)[b][c][n] P[b][n][m]) * SCL[b][m]
__global__ __launch_bounds__(256) void k_t(
    const float* __restrict__ U1, const float* __restrict__ U2,
    const float* __restrict__ EN, const float* __restrict__ SCL,
    const float* __restrict__ xsrc, int xbs, float* __restrict__ T)
{
  int ctile = blockIdx.x, b = blockIdx.y;
  __shared__ __align__(16) float UT[32][34];    // [n][c]
  __shared__ __align__(16) float ET[32][132];   // [n][m]
  int tid = threadIdx.x, tm = tid & 15, tc = tid >> 4;
  float acc[2][8] = {};
  for (int n0 = 0; n0 < NP; n0 += 32) {
    __syncthreads();
#pragma unroll
    for (int i = 0; i < 4; i++) {
      int idx = tid + i * 256;
      size_t off = ((size_t)b * CH + ctile * 32 + (idx >> 5)) * NP + n0 + (idx & 31);
      UT[idx & 31][idx >> 5] = U1[off] + U2[off];
    }
#pragma unroll
    for (int i = 0; i < 16; i++) {
      int idx = tid + i * 256;
      ET[idx >> 7][idx & 127] = EN[((size_t)b * NP + n0 + (idx >> 7)) * NP + (idx & 127)];
    }
    __syncthreads();
#pragma unroll
    for (int nn = 0; nn < 32; nn++) {
      float2 u2v = *(const float2*)&UT[nn][tc * 2];
      float4 ea = *(const float4*)&ET[nn][tm * 8];
      float4 eb = *(const float4*)&ET[nn][tm * 8 + 4];
      float w[2] = {u2v.x, u2v.y};
      float ev[8] = {ea.x, ea.y, ea.z, ea.w, eb.x, eb.y, eb.z, eb.w};
#pragma unroll
      for (int i = 0; i < 2; i++)
#pragma unroll
        for (int j = 0; j < 8; j++) acc[i][j] = fmaf(w[i], ev[j], acc[i][j]);
    }
  }
  int m0 = tm * 8;
  float4 sa = *(const float4*)&SCL[b * NP + m0];
  float4 sb = *(const float4*)&SCL[b * NP + m0 + 4];
  float sc[8] = {sa.x, sa.y, sa.z, sa.w, sb.x, sb.y, sb.z, sb.w};
#pragma unroll
  for (int i = 0; i < 2; i++) {
    int c = ctile * 32 + tc * 2 + i;
    float4 xa = *(const float4*)&xsrc[(size_t)b * xbs + (size_t)c * NP + m0];
    float4 xb = *(const float4*)&xsrc[(size_t)b * xbs + (size_t)c * NP + m0 + 4];
    float xv[8] = {xa.x, xa.y, xa.z, xa.w, xb.x, xb.y, xb.z, xb.w};
    float t[8];
#pragma unroll
    for (int j = 0; j < 8; j++) t[j] = xv[j] - acc[i][j] * sc[j];
    float4 ta = {t[0], t[1], t[2], t[3]}, tb = {t[4], t[5], t[6], t[7]};
    size_t off = ((size_t)b * CH + c) * NP + m0;
    *(float4*)&T[off] = ta;
    *(float4*)&T[off + 4] = tb;
  }
}

// ---------------------------------------------------------------------------
// out[b][l*CH+c][n] = x[b][c][n] + gelu(BN(Wl @ T + bl)).  32-c tiles.
__global__ __launch_bounds__(256) void k_h(
    const float* __restrict__ T, const float* __restrict__ Wl,
    const float* __restrict__ bl, const float* __restrict__ bng,
    const float* __restrict__ bnb, const float* __restrict__ xsrc, int xbs,
    float* __restrict__ out, int layer)
{
  int ctile = blockIdx.x, b = blockIdx.y;
  __shared__ __align__(16) float WT[32][34];   // [k][c]
  __shared__ __align__(16) float TT[32][NP];   // [k][n]
  int tid = threadIdx.x, tn = tid & 15, tc = tid >> 4;
  float acc[2][8] = {};
  for (int k0 = 0; k0 < CH; k0 += 32) {
    __syncthreads();
#pragma unroll
    for (int i = 0; i < 4; i++) {
      int idx = tid + i * 256;
      WT[idx & 31][idx >> 5] = Wl[(size_t)(ctile * 32 + (idx >> 5)) * CH + k0 + (idx & 31)];
    }
#pragma unroll
    for (int i = 0; i < 16; i++) {
      int idx = tid + i * 256;
      TT[idx >> 7][idx & 127] = T[((size_t)b * CH + k0 + (idx >> 7)) * NP + (idx & 127)];
    }
    __syncthreads();
#pragma unroll
    for (int kk = 0; kk < 32; kk++) {
      float2 w2 = *(const float2*)&WT[kk][tc * 2];
      float4 xa = *(const float4*)&TT[kk][tn * 8];
      float4 xb = *(const float4*)&TT[kk][tn * 8 + 4];
      float w[2] = {w2.x, w2.y};
      float xv[8] = {xa.x, xa.y, xa.z, xa.w, xb.x, xb.y, xb.z, xb.w};
#pragma unroll
      for (int i = 0; i < 2; i++)
#pragma unroll
        for (int j = 0; j < 8; j++) acc[i][j] = fmaf(w[i], xv[j], acc[i][j]);
    }
  }
  const float rbn = 1.0f / sqrtf(1.0f + 1e-5f);
  int n0 = tn * 8;
#pragma unroll
  for (int i = 0; i < 2; i++) {
    int c = ctile * 32 + tc * 2 + i;
    float blv = bl[c], gv = bng[c], bv = bnb[c];
    float4 xa = *(const float4*)&xsrc[(size_t)b * xbs + (size_t)c * NP + n0];
    float4 xb = *(const float4*)&xsrc[(size_t)b * xbs + (size_t)c * NP + n0 + 4];
    float xv[8] = {xa.x, xa.y, xa.z, xa.w, xb.x, xb.y, xb.z, xb.w};
    float o[8];
#pragma unroll
    for (int j = 0; j < 8; j++) {
      float h = acc[i][j] + blv;
      h = h * rbn * gv + bv;
      float g = 0.5f * h * (1.0f + erff(h * 0.70710678118654752440f));
      o[j] = xv[j] + g;
    }
    float4 oa = {o[0], o[1], o[2], o[3]}, ob = {o[4], o[5], o[6], o[7]};
    size_t off = ((size_t)b * 4 * CH + (size_t)layer * CH + c) * NP + n0;
    *(float4*)&out[off] = oa;
    *(float4*)&out[off + 4] = ob;
  }
}

// ---------------------------------------------------------------------------
extern "C" void kernel_launch(void* const* d_in, const int* in_sizes, int n_in,
                              void* d_out, int out_size, void* d_ws, size_t ws_size,
                              hipStream_t stream)
{
  (void)in_sizes; (void)n_in; (void)out_size; (void)ws_size;
  const float* lrf     = (const float*)d_in[0];
  const float* pca     = (const float*)d_in[1];
  const float* a_self  = (const float*)d_in[2];
  const float* a_cross = (const float*)d_in[3];
  const float* Wq  = (const float*)d_in[4];
  const float* Wk  = (const float*)d_in[5];
  const float* Wv  = (const float*)d_in[6];
  const float* Wvp = (const float*)d_in[7];
  const float* Wl  = (const float*)d_in[8];
  const float* bl  = (const float*)d_in[9];
  const float* bng = (const float*)d_in[10];
  const float* bnb = (const float*)d_in[11];
  const float* p1w = (const float*)d_in[12];
  const float* p1b = (const float*)d_in[13];
  const float* p2w = (const float*)d_in[14];
  const float* p2b = (const float*)d_in[15];
  const float* beta_x = (const float*)d_in[16];
  const float* beta_w = (const float*)d_in[17];
  float* out = (float*)d_out;
  float* ws  = (float*)d_ws;

  // workspace carve (floats), total ~8.55M floats = 34.2MB.
  // Region A (2M floats): XQ|KLT|KP2T|E2, later aliased as T.
  const size_t QKN = (size_t)BB * NP * DQ;   // 512K
  float* XQ   = ws;
  float* KLT  = XQ + QKN;
  float* KP2T = KLT + QKN;
  float* E2   = KP2T + QKN;
  float* T    = ws;                           // alias over region A (2M floats)
  float* Q1   = ws + 4 * QKN;
  float* C1   = Q1 + QKN;
  float* ENa  = C1 + (size_t)BB * NP;
  float* ENb  = ENa + (size_t)BB * NP * NP;
  float* SCL  = ENb + (size_t)BB * NP * NP;
  float* U1   = SCL + (size_t)BB * NP;
  float* U2   = U1 + (size_t)BB * CH * NP;

  for (int l = 0; l < NLAYERS; l++) {
    const float* xsrc = (l == 0) ? lrf : (out + (size_t)(l - 1) * CH * NP);
    int xbs = (l == 0) ? CH * NP : 4 * CH * NP;
    k_e2<<<dim3(BB * NP / 4), 256, 0, stream>>>(
        a_cross, p2w + (size_t)l * DQ * DQ, p2b + (size_t)l * DQ, E2);
    k_qk<<<dim3(2, 3, BB), 256, 0, stream>>>(
        xsrc, xbs, pca, Wq + (size_t)l * DQ * CH, Wk + (size_t)l * DQ * CH, E2,
        XQ, KLT, KP2T);
    k_q1c1<<<dim3(BB), 256, 0, stream>>>(
        XQ, p1w + (size_t)l * DQ * DQ, p1b + (size_t)l * DQ, Q1, C1);
    k_energy<<<dim3(4, BB, 2), 256, 0, stream>>>(XQ, KLT, KP2T, beta_w, l, ENa, ENb);
    k_bias<<<dim3(BB * NP), 128, 0, stream>>>(ENa, ENb, Q1, C1, a_self, beta_w, l);
    k_colsum<<<dim3(BB), 256, 0, stream>>>(ENa, SCL);
    k_u<<<dim3(8, BB, 2), 256, 0, stream>>>(
        xsrc, xbs, pca, Wv + (size_t)l * CH * CH, Wvp + (size_t)l * CH * CH,
        beta_x, l, U1, U2);
    k_t<<<dim3(8, BB), 256, 0, stream>>>(U1, U2, ENa, SCL, xsrc, xbs, T);
    k_h<<<dim3(8, BB), 256, 0, stream>>>(
        T, Wl + (size_t)l * CH * CH, bl + (size_t)l * CH, bng + (size_t)l * CH,
        bnb + (size_t)l * CH, xsrc, xbs, out, l);
  }
}

// Round 4
// 508.086 us; speedup vs baseline: 1.7528x; 1.4117x over previous
//
#include <hip/hip_runtime.h>
#include <cstdint>
#include <cstddef>

// Round 4: bf16 MFMA for the value-side GEMMs (k_u/k_t/k_h), fp32 kept for
// the energy/softmax path. No-LDS MFMA: all operands stored k-contiguous so
// A/B fragments are single global_load_dwordx4 (16 rows x 64B cachelines).
// k_colsum folded into new k_pt (P transpose->bf16 + column-sum reciprocal).

#define BB 64      // batch
#define CH 256     // channels
#define NP 128     // points
#define DQ 64      // q/k dim
#define NLAYERS 4

#define ANG_FACTOR 3.8197186342054885f   // 180/(pi*15) = 12/pi
#define DIV_STEP   0.28782313662425575f  // ln(10000)/32

typedef unsigned short u16;
typedef __attribute__((ext_vector_type(8))) short sh8;   // 8 bf16 = 4 VGPR
typedef __attribute__((ext_vector_type(4))) float f32x4; // MFMA C/D
#define MFMA(a, b, c) __builtin_amdgcn_mfma_f32_16x16x32_bf16(a, b, c, 0, 0, 0)

static __device__ __forceinline__ u16 f2bf(float x) {
  unsigned u = __float_as_uint(x);
  return (u16)((u + 0x7FFFu + ((u >> 16) & 1u)) >> 16);
}
static __device__ __forceinline__ float bf2f(u16 h) {
  return __uint_as_float(((unsigned)h) << 16);
}

// ---------------------------------------------------------------------------
// fp32 -> bf16 flat convert (weights, once per session)
__global__ __launch_bounds__(256) void k_cvt(const float* __restrict__ s,
                                             u16* __restrict__ d, int n)
{
  int i = (blockIdx.x * 256 + threadIdx.x) * 4;
  if (i < n) {
    float4 v = *(const float4*)(s + i);
    u16 o[4] = {f2bf(v.x), f2bf(v.y), f2bf(v.z), f2bf(v.w)};
    *(uint2*)(d + i) = *(const uint2*)o;
  }
}

// ---------------------------------------------------------------------------
// transpose + cvt: src fp32 [b][CH][NP] (batch stride xbs) -> dst bf16 [b][NP][CH]
__global__ __launch_bounds__(256) void k_xt(const float* __restrict__ x, int xbs,
                                            u16* __restrict__ xT)
{
  int nt = blockIdx.x, ct = blockIdx.y, b = blockIdx.z;
  __shared__ float tl[64][65];   // [n_loc][c_loc]
  int tid = threadIdx.x;
  {
    int col = tid & 63, rq = tid >> 6;   // col = n_loc
    const float* src = x + (size_t)b * xbs + (size_t)(ct * 64) * NP + nt * 64;
#pragma unroll
    for (int i = 0; i < 16; i++) {
      int c = rq + i * 4;
      tl[col][c] = src[(size_t)c * NP + col];
    }
  }
  __syncthreads();
  {
    int cloc = tid & 63, nq = tid >> 6;
    u16* dst = xT + ((size_t)b * NP + nt * 64) * CH + ct * 64;
#pragma unroll
    for (int i = 0; i < 16; i++) {
      int n = nq + i * 4;
      dst[(size_t)n * CH + cloc] = f2bf(tl[n][cloc]);
    }
  }
}

// ---------------------------------------------------------------------------
// E2[b][m][o] = sum_d p2w[o][d]*emb2[b][m][d] + p2b[o]
__global__ __launch_bounds__(256) void k_e2(
    const float* __restrict__ ac, const float* __restrict__ p2w,
    const float* __restrict__ p2b, float* __restrict__ E2)
{
  __shared__ float pw[DQ][65];
  __shared__ float emb[4][DQ];
  __shared__ float pb[DQ];
  int tid = threadIdx.x;
  int bm0 = blockIdx.x * 4;
#pragma unroll
  for (int i = 0; i < 16; i++) {
    int idx = tid + i * 256;
    pw[idx >> 6][idx & 63] = p2w[idx];
  }
  if (tid < DQ) pb[tid] = p2b[tid];
  if (tid < 128) {
    int ml = tid >> 5, j = tid & 31;
    float a = ac[bm0 + ml];
    float s, c;
    __sincosf(a * ANG_FACTOR * __expf(-(float)j * DIV_STEP), &s, &c);
    emb[ml][2 * j] = s;
    emb[ml][2 * j + 1] = c;
  }
  __syncthreads();
  int mloc = tid >> 6, o = tid & 63;
  float acc = pb[o];
#pragma unroll
  for (int d = 0; d < DQ; d++) acc = fmaf(pw[o][d], emb[mloc][d], acc);
  E2[(size_t)(bm0 + mloc) * DQ + o] = acc;
}

// ---------------------------------------------------------------------------
// fp32, 32-d tiles. kind0: XQ = Wq@x (n-major); kind1: KLT = Wk@x; kind2:
// KP2T = Wq@pca + E2.
__global__ __launch_bounds__(256) void k_qk(
    const float* __restrict__ xsrc, int xbs, const float* __restrict__ pca,
    const float* __restrict__ Wq, const float* __restrict__ Wk,
    const float* __restrict__ E2,
    float* __restrict__ XQ, float* __restrict__ KLT, float* __restrict__ KP2T)
{
  int dtile = blockIdx.x, kind = blockIdx.y, b = blockIdx.z;
  const float* W = (kind == 1) ? Wk : Wq;
  const float* X = (kind == 2) ? (pca + (size_t)b * CH * NP) : (xsrc + (size_t)b * xbs);
  __shared__ __align__(16) float WT[32][34];
  __shared__ __align__(16) float XT[32][NP];
  int tid = threadIdx.x;
  int tn = tid & 15, td = tid >> 4;
  float acc[2][8] = {};
  for (int c0 = 0; c0 < CH; c0 += 32) {
    __syncthreads();
#pragma unroll
    for (int i = 0; i < 4; i++) {
      int idx = tid + i * 256;
      WT[idx & 31][idx >> 5] = W[(size_t)(dtile * 32 + (idx >> 5)) * CH + c0 + (idx & 31)];
    }
#pragma unroll
    for (int i = 0; i < 16; i++) {
      int idx = tid + i * 256;
      XT[idx >> 7][idx & 127] = X[(size_t)(c0 + (idx >> 7)) * NP + (idx & 127)];
    }
    __syncthreads();
#pragma unroll
    for (int cc = 0; cc < 32; cc++) {
      float2 w2 = *(const float2*)&WT[cc][td * 2];
      float4 xa = *(const float4*)&XT[cc][tn * 8];
      float4 xb = *(const float4*)&XT[cc][tn * 8 + 4];
      float w[2] = {w2.x, w2.y};
      float xv[8] = {xa.x, xa.y, xa.z, xa.w, xb.x, xb.y, xb.z, xb.w};
#pragma unroll
      for (int i = 0; i < 2; i++)
#pragma unroll
        for (int j = 0; j < 8; j++) acc[i][j] = fmaf(w[i], xv[j], acc[i][j]);
    }
  }
  int d0 = dtile * 32 + td * 2, n0 = tn * 8;
  if (kind == 0) {
#pragma unroll
    for (int j = 0; j < 8; j++) {
      float2 v = {acc[0][j], acc[1][j]};
      *(float2*)&XQ[((size_t)b * NP + n0 + j) * DQ + d0] = v;
    }
  } else if (kind == 1) {
#pragma unroll
    for (int j = 0; j < 8; j++) {
      float2 v = {acc[0][j], acc[1][j]};
      *(float2*)&KLT[((size_t)b * NP + n0 + j) * DQ + d0] = v;
    }
  } else {
#pragma unroll
    for (int j = 0; j < 8; j++) {
      float2 e = *(const float2*)&E2[((size_t)b * NP + n0 + j) * DQ + d0];
      float2 v = {acc[0][j] + e.x, acc[1][j] + e.y};
      *(float2*)&KP2T[((size_t)b * NP + n0 + j) * DQ + d0] = v;
    }
  }
}

// ---------------------------------------------------------------------------
// Q1[b][n][d] = sum_o XQ[b][n][o] p1w[o][d];  C1[b][n] = sum_o XQ[b][n][o] p1b[o]
__global__ __launch_bounds__(256) void k_q1c1(
    const float* __restrict__ XQ, const float* __restrict__ p1w,
    const float* __restrict__ p1b, float* __restrict__ Q1, float* __restrict__ C1)
{
  int b = blockIdx.x, tid = threadIdx.x;
  __shared__ float xqs[NP][65];
  __shared__ float pw[DQ][65];
  __shared__ float pb[DQ];
#pragma unroll
  for (int i = 0; i < 32; i++) {
    int idx = tid + i * 256;
    xqs[idx >> 6][idx & 63] = XQ[(size_t)b * NP * DQ + idx];
  }
#pragma unroll
  for (int i = 0; i < 16; i++) {
    int idx = tid + i * 256;
    pw[idx >> 6][idx & 63] = p1w[idx];
  }
  if (tid < DQ) pb[tid] = p1b[tid];
  __syncthreads();
  int n = tid >> 1, d0 = (tid & 1) * 32;
  float acc[32] = {};
  float cacc = 0.0f;
  for (int o = 0; o < DQ; o++) {
    float xv = xqs[n][o];
    cacc = fmaf(pb[o], xv, cacc);
#pragma unroll
    for (int dd = 0; dd < 32; dd++) acc[dd] = fmaf(pw[o][d0 + dd], xv, acc[dd]);
  }
#pragma unroll
  for (int dd = 0; dd < 32; dd += 4) {
    float4 v = {acc[dd], acc[dd + 1], acc[dd + 2], acc[dd + 3]};
    *(float4*)&Q1[((size_t)b * NP + n) * DQ + d0 + dd] = v;
  }
  if ((tid & 1) == 0) C1[b * NP + n] = cacc;
}

// ---------------------------------------------------------------------------
// fp32 energy: src=0: ENa = bw * xq @ KLT^T ; src=1: ENb = (1-bw) * xq @ KP2T^T
__global__ __launch_bounds__(256) void k_energy(
    const float* __restrict__ XQ, const float* __restrict__ KLT,
    const float* __restrict__ KP2T, const float* __restrict__ beta_w, int layer,
    float* __restrict__ ENa, float* __restrict__ ENb)
{
  int ntile = blockIdx.x, b = blockIdx.y, src = blockIdx.z;
  float bw = beta_w[layer];
  const float* Bsrc = src ? KP2T : KLT;
  float as = src ? (1.0f - bw) : bw;
  float* OUT = src ? ENb : ENa;
  __shared__ __align__(16) float WT[32][34];
  __shared__ __align__(16) float BT[32][132];
  int tid = threadIdx.x, tn = tid & 15, tc = tid >> 4;
  float acc[2][8] = {};
#pragma unroll
  for (int k0 = 0; k0 < DQ; k0 += 32) {
    __syncthreads();
#pragma unroll
    for (int i = 0; i < 4; i++) {
      int idx = tid + i * 256;
      WT[idx & 31][idx >> 5] =
          as * XQ[((size_t)b * NP + ntile * 32 + (idx >> 5)) * DQ + k0 + (idx & 31)];
    }
#pragma unroll
    for (int i = 0; i < 16; i++) {
      int idx = tid + i * 256;
      BT[idx & 31][idx >> 5] = Bsrc[((size_t)b * NP + (idx >> 5)) * DQ + k0 + (idx & 31)];
    }
    __syncthreads();
#pragma unroll
    for (int kk = 0; kk < 32; kk++) {
      float2 w2 = *(const float2*)&WT[kk][tc * 2];
      float4 xa = *(const float4*)&BT[kk][tn * 8];
      float4 xb = *(const float4*)&BT[kk][tn * 8 + 4];
      float w[2] = {w2.x, w2.y};
      float xv[8] = {xa.x, xa.y, xa.z, xa.w, xb.x, xb.y, xb.z, xb.w};
#pragma unroll
      for (int i = 0; i < 2; i++)
#pragma unroll
        for (int j = 0; j < 8; j++) acc[i][j] = fmaf(w[i], xv[j], acc[i][j]);
    }
  }
#pragma unroll
  for (int i = 0; i < 2; i++) {
    int n = ntile * 32 + tc * 2 + i;
    float4 va = {acc[i][0], acc[i][1], acc[i][2], acc[i][3]};
    float4 vb = {acc[i][4], acc[i][5], acc[i][6], acc[i][7]};
    size_t off = ((size_t)b * NP + n) * NP + tn * 8;
    *(float4*)&OUT[off] = va;
    *(float4*)&OUT[off + 4] = vb;
  }
}

// ---------------------------------------------------------------------------
// P = softmax_m(ENa + ENb + bw*(q1.emb1 + c1)); write P into ENa.
__global__ __launch_bounds__(128) void k_bias(
    float* __restrict__ ENa, const float* __restrict__ ENb,
    const float* __restrict__ Q1, const float* __restrict__ C1,
    const float* __restrict__ AS, const float* __restrict__ beta_w, int layer)
{
  int blk = blockIdx.x;
  int b = blk >> 7, n = blk & 127;
  int m = threadIdx.x;
  __shared__ float q1s[DQ];
  __shared__ float divs[32];
  __shared__ float xred[2];
  __shared__ float sred[2];
  if (m < DQ) q1s[m] = Q1[((size_t)b * NP + n) * DQ + m];
  if (m >= 96) divs[m - 96] = __expf(-(float)(m - 96) * DIV_STEP);
  __syncthreads();
  float bw = beta_w[layer];
  size_t row = ((size_t)b * NP + n) * NP;
  float E = ENa[row + m] + ENb[row + m];
  float bias = C1[b * NP + n];
  float idxv = AS[row + m] * ANG_FACTOR;
#pragma unroll
  for (int j = 0; j < 32; j++) {
    float s, c;
    __sincosf(idxv * divs[j], &s, &c);
    bias = fmaf(q1s[2 * j], s, bias);
    bias = fmaf(q1s[2 * j + 1], c, bias);
  }
  E += bw * bias;
  float v = E;
#pragma unroll
  for (int off = 32; off; off >>= 1) v = fmaxf(v, __shfl_xor(v, off));
  if ((m & 63) == 0) xred[m >> 6] = v;
  __syncthreads();
  float mx = fmaxf(xred[0], xred[1]);
  float p = __expf(E - mx);
  v = p;
#pragma unroll
  for (int off = 32; off; off >>= 1) v += __shfl_xor(v, off);
  if ((m & 63) == 0) sred[m >> 6] = v;
  __syncthreads();
  float s = sred[0] + sred[1];
  ENa[row + m] = p / s;
}

// ---------------------------------------------------------------------------
// P fp32 [b][n][m] -> PT bf16 [b][m][n]; SCL[b][m] = 1/(1e-12 + sum_n P[n][m])
__global__ __launch_bounds__(256) void k_pt(const float* __restrict__ EN,
                                            u16* __restrict__ PT,
                                            float* __restrict__ SCL)
{
  int mt = blockIdx.x, b = blockIdx.y;
  __shared__ float tl[128][33];   // [n][m_loc]
  int tid = threadIdx.x;
  {
    int ml = tid & 31, nr = tid >> 5;
    const float* src = EN + (size_t)b * NP * NP + mt * 32;
#pragma unroll
    for (int i = 0; i < 16; i++) {
      int n = nr + i * 8;
      tl[n][ml] = src[(size_t)n * NP + ml];
    }
  }
  __syncthreads();
  int m = tid >> 3, nc = (tid & 7) * 16;
  float s = 0.0f;
  u16 tmp[16];
#pragma unroll
  for (int k = 0; k < 16; k++) {
    float v = tl[nc + k][m];
    s += v;
    tmp[k] = f2bf(v);
  }
  u16* dst = PT + ((size_t)b * NP + mt * 32 + m) * NP + nc;
  *(uint4*)&dst[0] = *(const uint4*)&tmp[0];
  *(uint4*)&dst[8] = *(const uint4*)&tmp[8];
  s += __shfl_xor(s, 1);
  s += __shfl_xor(s, 2);
  s += __shfl_xor(s, 4);
  if ((tid & 7) == 0) SCL[b * NP + mt * 32 + m] = 1.0f / (1e-12f + s);
}

// ---------------------------------------------------------------------------
// MFMA: U[b][c][n] = bx*(x^T @ Wv^T)^T + (1-bx)*(pca^T @ Wvp^T)^T
// A = xT/pT bf16 [n][k=c'], B = Wv/Wvp bf16 [c][k=c'].  C[row=n][col=c].
// Store U bf16 [c][n] (lane: 4 consecutive n).
__global__ __launch_bounds__(256) void k_u_m(
    const u16* __restrict__ xT, const u16* __restrict__ pT,
    const u16* __restrict__ Wv, const u16* __restrict__ Wvp,
    const float* __restrict__ beta_x, int layer, u16* __restrict__ U)
{
  int wid = blockIdx.x * 4 + (threadIdx.x >> 6);
  int lane = threadIdx.x & 63;
  int b = wid >> 5, q = wid & 31;
  int nt = q >> 3, ct = q & 7;
  int lm = lane & 15, lk = lane >> 4;
  const u16* Ax0 = xT + ((size_t)b * NP + nt * 32 + lm) * CH + lk * 8;
  const u16* Ax1 = Ax0 + 16 * CH;
  const u16* Ap0 = pT + ((size_t)b * NP + nt * 32 + lm) * CH + lk * 8;
  const u16* Ap1 = Ap0 + 16 * CH;
  const u16* Bx0 = Wv + ((size_t)(ct * 32) + lm) * CH + lk * 8;
  const u16* Bx1 = Bx0 + 16 * CH;
  const u16* Bp0 = Wvp + ((size_t)(ct * 32) + lm) * CH + lk * 8;
  const u16* Bp1 = Bp0 + 16 * CH;
  f32x4 ax00 = {}, ax01 = {}, ax10 = {}, ax11 = {};
  f32x4 ap00 = {}, ap01 = {}, ap10 = {}, ap11 = {};
#pragma unroll
  for (int ks = 0; ks < 8; ks++) {
    int o = ks * 32;
    sh8 a0 = *(const sh8*)(Ax0 + o), a1 = *(const sh8*)(Ax1 + o);
    sh8 w0 = *(const sh8*)(Bx0 + o), w1 = *(const sh8*)(Bx1 + o);
    ax00 = MFMA(a0, w0, ax00);
    ax01 = MFMA(a0, w1, ax01);
    ax10 = MFMA(a1, w0, ax10);
    ax11 = MFMA(a1, w1, ax11);
    sh8 p0 = *(const sh8*)(Ap0 + o), p1 = *(const sh8*)(Ap1 + o);
    sh8 v0 = *(const sh8*)(Bp0 + o), v1 = *(const sh8*)(Bp1 + o);
    ap00 = MFMA(p0, v0, ap00);
    ap01 = MFMA(p0, v1, ap01);
    ap10 = MFMA(p1, v0, ap10);
    ap11 = MFMA(p1, v1, ap11);
  }
  float bx = beta_x[layer], obx = 1.0f - bx;
  f32x4 accs[2][2] = {{ax00, ax01}, {ax10, ax11}};
  f32x4 accp[2][2] = {{ap00, ap01}, {ap10, ap11}};
#pragma unroll
  for (int i = 0; i < 2; i++)
#pragma unroll
    for (int j = 0; j < 2; j++) {
      int c = ct * 32 + j * 16 + lm;
      int n0 = nt * 32 + i * 16 + lk * 4;
      u16 ov[4];
#pragma unroll
      for (int r = 0; r < 4; r++)
        ov[r] = f2bf(bx * accs[i][j][r] + obx * accp[i][j][r]);
      *(uint2*)&U[((size_t)b * CH + c) * NP + n0] = *(const uint2*)ov;
    }
}

// ---------------------------------------------------------------------------
// MFMA: T^T[b][m][c] = bf(x^T[m][c]) - (sum_n U[c][n] PT[m][n]) * SCL[m]
// A = U bf16 [c][n] (M=c), B = PT bf16 [m][n] (N=m), K=128.
__global__ __launch_bounds__(256) void k_t_m(
    const u16* __restrict__ U, const u16* __restrict__ PT,
    const float* __restrict__ SCL, const u16* __restrict__ xT,
    u16* __restrict__ TT)
{
  int wid = blockIdx.x * 4 + (threadIdx.x >> 6);
  int lane = threadIdx.x & 63;
  int b = wid >> 5, q = wid & 31;
  int ct = q >> 2, mt = q & 3;
  int lm = lane & 15, lk = lane >> 4;
  const u16* A0 = U + ((size_t)b * CH + ct * 32 + lm) * NP + lk * 8;
  const u16* A1 = A0 + 16 * NP;
  const u16* B0 = PT + ((size_t)b * NP + mt * 32 + lm) * NP + lk * 8;
  const u16* B1 = B0 + 16 * NP;
  f32x4 a00 = {}, a01 = {}, a10 = {}, a11 = {};
#pragma unroll
  for (int ks = 0; ks < 4; ks++) {
    int o = ks * 32;
    sh8 a0 = *(const sh8*)(A0 + o), a1 = *(const sh8*)(A1 + o);
    sh8 b0 = *(const sh8*)(B0 + o), b1 = *(const sh8*)(B1 + o);
    a00 = MFMA(a0, b0, a00);
    a01 = MFMA(a0, b1, a01);
    a10 = MFMA(a1, b0, a10);
    a11 = MFMA(a1, b1, a11);
  }
  f32x4 acc[2][2] = {{a00, a01}, {a10, a11}};
#pragma unroll
  for (int i = 0; i < 2; i++)
#pragma unroll
    for (int j = 0; j < 2; j++) {
      int m = mt * 32 + j * 16 + lm;
      int c0 = ct * 32 + i * 16 + lk * 4;
      float scl = SCL[b * NP + m];
      uint2 xv = *(const uint2*)(xT + ((size_t)b * NP + m) * CH + c0);
      const u16* xh = (const u16*)&xv;
      u16 ov[4];
#pragma unroll
      for (int r = 0; r < 4; r++)
        ov[r] = f2bf(bf2f(xh[r]) - acc[i][j][r] * scl);
      *(uint2*)&TT[((size_t)b * NP + m) * CH + c0] = *(const uint2*)ov;
    }
}

// ---------------------------------------------------------------------------
// MFMA: out[b][l*CH+c][n] = x[b][c][n] + gelu(BN(sum_k Wl[c][k] T[k][n] + bl))
// A = Wl bf16 [c][k], B = TT bf16 [n][k], K=256.  C[row=c][col=n].
__global__ __launch_bounds__(256) void k_h_m(
    const u16* __restrict__ Wl, const u16* __restrict__ TT,
    const float* __restrict__ bl, const float* __restrict__ bng,
    const float* __restrict__ bnb, const float* __restrict__ xsrc, int xbs,
    float* __restrict__ out, int layer)
{
  int wid = blockIdx.x * 4 + (threadIdx.x >> 6);
  int lane = threadIdx.x & 63;
  int b = wid >> 5, q = wid & 31;
  int ct = q >> 2, nt = q & 3;
  int lm = lane & 15, lk = lane >> 4;
  const u16* A0 = Wl + ((size_t)(ct * 32) + lm) * CH + lk * 8;
  const u16* A1 = A0 + 16 * CH;
  const u16* B0 = TT + ((size_t)b * NP + nt * 32 + lm) * CH + lk * 8;
  const u16* B1 = B0 + 16 * CH;
  f32x4 a00 = {}, a01 = {}, a10 = {}, a11 = {};
#pragma unroll
  for (int ks = 0; ks < 8; ks++) {
    int o = ks * 32;
    sh8 a0 = *(const sh8*)(A0 + o), a1 = *(const sh8*)(A1 + o);
    sh8 b0 = *(const sh8*)(B0 + o), b1 = *(const sh8*)(B1 + o);
    a00 = MFMA(a0, b0, a00);
    a01 = MFMA(a0, b1, a01);
    a10 = MFMA(a1, b0, a10);
    a11 = MFMA(a1, b1, a11);
  }
  f32x4 acc[2][2] = {{a00, a01}, {a10, a11}};
  const float rbn = 0.999995000037499687f;  // 1/sqrt(1+1e-5)
#pragma unroll
  for (int i = 0; i < 2; i++)
#pragma unroll
    for (int j = 0; j < 2; j++) {
      int n = nt * 32 + j * 16 + lm;
      int cb = ct * 32 + i * 16 + lk * 4;
#pragma unroll
      for (int r = 0; r < 4; r++) {
        int c = cb + r;
        float h = acc[i][j][r] + bl[c];
        h = h * rbn * bng[c] + bnb[c];
        float g = 0.5f * h * (1.0f + erff(h * 0.70710678118654752440f));
        out[((size_t)b * 4 * CH + (size_t)layer * CH + c) * NP + n] =
            xsrc[(size_t)b * xbs + (size_t)c * NP + n] + g;
      }
    }
}

// ---------------------------------------------------------------------------
extern "C" void kernel_launch(void* const* d_in, const int* in_sizes, int n_in,
                              void* d_out, int out_size, void* d_ws, size_t ws_size,
                              hipStream_t stream)
{
  (void)in_sizes; (void)n_in; (void)out_size; (void)ws_size;
  const float* lrf     = (const float*)d_in[0];
  const float* pca     = (const float*)d_in[1];
  const float* a_self  = (const float*)d_in[2];
  const float* a_cross = (const float*)d_in[3];
  const float* Wq  = (const float*)d_in[4];
  const float* Wk  = (const float*)d_in[5];
  const float* Wv  = (const float*)d_in[6];
  const float* Wvp = (const float*)d_in[7];
  const float* Wl  = (const float*)d_in[8];
  const float* bl  = (const float*)d_in[9];
  const float* bng = (const float*)d_in[10];
  const float* bnb = (const float*)d_in[11];
  const float* p1w = (const float*)d_in[12];
  const float* p1b = (const float*)d_in[13];
  const float* p2w = (const float*)d_in[14];
  const float* p2b = (const float*)d_in[15];
  const float* beta_x = (const float*)d_in[16];
  const float* beta_w = (const float*)d_in[17];
  float* out = (float*)d_out;
  float* ws  = (float*)d_ws;

  // ---- workspace carve (float units) ----
  const size_t QKN = (size_t)BB * NP * DQ;        // 524288
  const size_t ENN = (size_t)BB * NP * NP;        // 1048576
  const size_t XTN = (size_t)BB * NP * CH / 2;    // bf16 x^T: 1048576 fl-eq
  const size_t UN  = (size_t)BB * CH * NP / 2;    // bf16 U:   1048576 fl-eq
  const size_t PTN = (size_t)BB * NP * NP / 2;    // bf16 P^T: 524288 fl-eq
  const size_t WBN = (size_t)NLAYERS * CH * CH / 2; // bf16 W: 131072 fl-eq

  float* XQ   = ws;                 // 512K
  float* KLT  = XQ + QKN;           // 512K ┐ aliased by TT after k_energy
  float* KP2T = KLT + QKN;          // 512K ┘
  float* E2   = KP2T + QKN;         // 512K
  float* Q1   = E2 + QKN;           // 512K
  float* C1   = Q1 + QKN;           // 8K
  float* ENa  = C1 + (size_t)BB * NP;   // 1M
  float* ENb  = ENa + ENN;              // 1M, aliased by Ubf after k_bias
  float* SCL  = ENb + ENN;              // 8K
  u16*   xbfT = (u16*)(SCL + (size_t)BB * NP);  // 1M fl-eq
  u16*   pbfT = (u16*)((float*)xbfT + XTN);     // 1M fl-eq
  u16*   PTbf = (u16*)((float*)pbfT + XTN);     // 512K fl-eq
  u16*   Wvbf  = (u16*)((float*)PTbf + PTN);    // 128K fl-eq
  u16*   Wvpbf = (u16*)((float*)Wvbf + WBN);
  u16*   Wlbf  = (u16*)((float*)Wvpbf + WBN);
  u16*   TbfT  = (u16*)KLT;         // alias: KLT+KP2T dead after k_energy
  u16*   Ubf   = (u16*)ENb;         // alias: ENb dead after k_bias

  // one-time: weight conversion + pca transpose
  const int wn = NLAYERS * CH * CH;
  k_cvt<<<dim3(wn / 1024), 256, 0, stream>>>(Wv, Wvbf, wn);
  k_cvt<<<dim3(wn / 1024), 256, 0, stream>>>(Wvp, Wvpbf, wn);
  k_cvt<<<dim3(wn / 1024), 256, 0, stream>>>(Wl, Wlbf, wn);
  k_xt<<<dim3(2, 4, BB), 256, 0, stream>>>(pca, CH * NP, pbfT);

  for (int l = 0; l < NLAYERS; l++) {
    const float* xsrc = (l == 0) ? lrf : (out + (size_t)(l - 1) * CH * NP);
    int xbs = (l == 0) ? CH * NP : 4 * CH * NP;
    k_xt<<<dim3(2, 4, BB), 256, 0, stream>>>(xsrc, xbs, xbfT);
    k_e2<<<dim3(BB * NP / 4), 256, 0, stream>>>(
        a_cross, p2w + (size_t)l * DQ * DQ, p2b + (size_t)l * DQ, E2);
    k_qk<<<dim3(2, 3, BB), 256, 0, stream>>>(
        xsrc, xbs, pca, Wq + (size_t)l * DQ * CH, Wk + (size_t)l * DQ * CH, E2,
        XQ, KLT, KP2T);
    k_q1c1<<<dim3(BB), 256, 0, stream>>>(
        XQ, p1w + (size_t)l * DQ * DQ, p1b + (size_t)l * DQ, Q1, C1);
    k_energy<<<dim3(4, BB, 2), 256, 0, stream>>>(XQ, KLT, KP2T, beta_w, l, ENa, ENb);
    k_bias<<<dim3(BB * NP), 128, 0, stream>>>(ENa, ENb, Q1, C1, a_self, beta_w, l);
    k_pt<<<dim3(4, BB), 256, 0, stream>>>(ENa, PTbf, SCL);
    k_u_m<<<dim3(512), 256, 0, stream>>>(
        xbfT, pbfT, Wvbf + (size_t)l * CH * CH, Wvpbf + (size_t)l * CH * CH,
        beta_x, l, Ubf);
    k_t_m<<<dim3(512), 256, 0, stream>>>(Ubf, PTbf, SCL, xbfT, TbfT);
    k_h_m<<<dim3(512), 256, 0, stream>>>(
        Wlbf + (size_t)l * CH * CH, TbfT, bl + (size_t)l * CH,
        bng + (size_t)l * CH, bnb + (size_t)l * CH, xsrc, xbs, out, l);
  }
}

// Round 5
// 453.195 us; speedup vs baseline: 1.9651x; 1.1211x over previous
//
#include <hip/hip_runtime.h>
#include <cstdint>
#include <cstddef>

// Round 5: split-bf16 (hi/lo) MFMA for the Q/K/energy path. W@x computed as
// Whi*xhi + Whi*xlo + Wlo*xhi on matrix cores -> fp32-equivalent accuracy at
// MFMA rate. k_energy fuses both sources into one EN write. Value path
// (k_u_m/k_t_m/k_h_m) unchanged from round 4.

#define BB 64      // batch
#define CH 256     // channels
#define NP 128     // points
#define DQ 64      // q/k dim
#define NLAYERS 4

#define ANG_FACTOR 3.8197186342054885f   // 180/(pi*15) = 12/pi
#define DIV_STEP   0.28782313662425575f  // ln(10000)/32

typedef unsigned short u16;
typedef __attribute__((ext_vector_type(8))) short sh8;   // 8 bf16 = 4 VGPR
typedef __attribute__((ext_vector_type(4))) float f32x4; // MFMA C/D
#define MFMA(a, b, c) __builtin_amdgcn_mfma_f32_16x16x32_bf16(a, b, c, 0, 0, 0)

static __device__ __forceinline__ u16 f2bf(float x) {
  unsigned u = __float_as_uint(x);
  return (u16)((u + 0x7FFFu + ((u >> 16) & 1u)) >> 16);
}
static __device__ __forceinline__ float bf2f(u16 h) {
  return __uint_as_float(((unsigned)h) << 16);
}

// ---------------------------------------------------------------------------
// fp32 -> bf16 flat convert (value weights, once)
__global__ __launch_bounds__(256) void k_cvt(const float* __restrict__ s,
                                             u16* __restrict__ d, int n)
{
  int i = (blockIdx.x * 256 + threadIdx.x) * 4;
  if (i < n) {
    float4 v = *(const float4*)(s + i);
    u16 o[4] = {f2bf(v.x), f2bf(v.y), f2bf(v.z), f2bf(v.w)};
    *(uint2*)(d + i) = *(const uint2*)o;
  }
}

// fp32 -> bf16 hi + lo flat convert (Wq/Wk, once)
__global__ __launch_bounds__(256) void k_cvt2(const float* __restrict__ s,
                                              u16* __restrict__ dh,
                                              u16* __restrict__ dl, int n)
{
  int i = (blockIdx.x * 256 + threadIdx.x) * 4;
  if (i < n) {
    float4 v = *(const float4*)(s + i);
    float vv[4] = {v.x, v.y, v.z, v.w};
    u16 h[4], l[4];
#pragma unroll
    for (int r = 0; r < 4; r++) {
      h[r] = f2bf(vv[r]);
      l[r] = f2bf(vv[r] - bf2f(h[r]));
    }
    *(uint2*)(dh + i) = *(const uint2*)h;
    *(uint2*)(dl + i) = *(const uint2*)l;
  }
}

// ---------------------------------------------------------------------------
// transpose + split: fp32 [b][CH][NP] (batch stride xbs) -> bf16 hi/lo [b][NP][CH]
__global__ __launch_bounds__(256) void k_xt2(const float* __restrict__ x, int xbs,
                                             u16* __restrict__ hiT,
                                             u16* __restrict__ loT)
{
  int nt = blockIdx.x, ct = blockIdx.y, b = blockIdx.z;
  __shared__ float tl[64][65];   // [n_loc][c_loc]
  int tid = threadIdx.x;
  {
    int col = tid & 63, rq = tid >> 6;
    const float* src = x + (size_t)b * xbs + (size_t)(ct * 64) * NP + nt * 64;
#pragma unroll
    for (int i = 0; i < 16; i++) {
      int c = rq + i * 4;
      tl[col][c] = src[(size_t)c * NP + col];
    }
  }
  __syncthreads();
  {
    int cloc = tid & 63, nq = tid >> 6;
#pragma unroll
    for (int i = 0; i < 16; i++) {
      int n = nq + i * 4;
      float v = tl[n][cloc];
      u16 h = f2bf(v);
      u16 l = f2bf(v - bf2f(h));
      size_t off = ((size_t)b * NP + nt * 64 + n) * CH + ct * 64 + cloc;
      hiT[off] = h;
      loT[off] = l;
    }
  }
}

// ---------------------------------------------------------------------------
// E2[b][m][o] = sum_d p2w[o][d]*emb2[b][m][d] + p2b[o]
__global__ __launch_bounds__(256) void k_e2(
    const float* __restrict__ ac, const float* __restrict__ p2w,
    const float* __restrict__ p2b, float* __restrict__ E2)
{
  __shared__ float pw[DQ][65];
  __shared__ float emb[4][DQ];
  __shared__ float pb[DQ];
  int tid = threadIdx.x;
  int bm0 = blockIdx.x * 4;
#pragma unroll
  for (int i = 0; i < 16; i++) {
    int idx = tid + i * 256;
    pw[idx >> 6][idx & 63] = p2w[idx];
  }
  if (tid < DQ) pb[tid] = p2b[tid];
  if (tid < 128) {
    int ml = tid >> 5, j = tid & 31;
    float a = ac[bm0 + ml];
    float s, c;
    __sincosf(a * ANG_FACTOR * __expf(-(float)j * DIV_STEP), &s, &c);
    emb[ml][2 * j] = s;
    emb[ml][2 * j + 1] = c;
  }
  __syncthreads();
  int mloc = tid >> 6, o = tid & 63;
  float acc = pb[o];
#pragma unroll
  for (int d = 0; d < DQ; d++) acc = fmaf(pw[o][d], emb[mloc][d], acc);
  E2[(size_t)(bm0 + mloc) * DQ + o] = acc;
}

// ---------------------------------------------------------------------------
// Split-bf16 MFMA QK projections. Per b, 24 wave-tiles:
//   mat0: XQ[n][d]  = Wq @ x   (fp32 + hi/lo out)
//   mat1: KLT[m][o] = Wk @ x   (hi/lo out)
//   mat2: KP2[m][o] = Wq @ pca + E2 (hi/lo out)
// D rows = W-rows (d), D cols = xT-rows (n). Wave tile 32x32.
__global__ __launch_bounds__(256) void k_qk_m(
    const u16* __restrict__ xThi, const u16* __restrict__ xTlo,
    const u16* __restrict__ pThi, const u16* __restrict__ pTlo,
    const u16* __restrict__ Wqhi, const u16* __restrict__ Wqlo,
    const u16* __restrict__ Wkhi, const u16* __restrict__ Wklo,
    const float* __restrict__ E2, float* __restrict__ XQ,
    u16* __restrict__ XQhi, u16* __restrict__ XQlo,
    u16* __restrict__ KLThi, u16* __restrict__ KLTlo,
    u16* __restrict__ KP2hi, u16* __restrict__ KP2lo)
{
  int wid = blockIdx.x * 4 + (threadIdx.x >> 6);
  int lane = threadIdx.x & 63;
  int b = wid / 24, q = wid % 24;
  int mat = q >> 3, t = q & 7;
  int nt = t >> 1, dt = t & 1;
  int lm = lane & 15, lk = lane >> 4;
  const u16* Ah = (mat == 1) ? Wkhi : Wqhi;
  const u16* Al = (mat == 1) ? Wklo : Wqlo;
  const u16* Bh = ((mat == 2) ? pThi : xThi) + (size_t)b * NP * CH;
  const u16* Bl = ((mat == 2) ? pTlo : xTlo) + (size_t)b * NP * CH;
  const u16* A0h = Ah + ((size_t)(dt * 32) + lm) * CH + lk * 8;
  const u16* A1h = A0h + 16 * CH;
  const u16* A0l = Al + ((size_t)(dt * 32) + lm) * CH + lk * 8;
  const u16* A1l = A0l + 16 * CH;
  const u16* B0h = Bh + ((size_t)(nt * 32) + lm) * CH + lk * 8;
  const u16* B1h = B0h + 16 * CH;
  const u16* B0l = Bl + ((size_t)(nt * 32) + lm) * CH + lk * 8;
  const u16* B1l = B0l + 16 * CH;
  f32x4 acc[2][2] = {};
#pragma unroll
  for (int ks = 0; ks < 8; ks++) {
    int o = ks * 32;
    sh8 a0h = *(const sh8*)(A0h + o), a1h = *(const sh8*)(A1h + o);
    sh8 a0l = *(const sh8*)(A0l + o), a1l = *(const sh8*)(A1l + o);
    sh8 b0h = *(const sh8*)(B0h + o), b1h = *(const sh8*)(B1h + o);
    sh8 b0l = *(const sh8*)(B0l + o), b1l = *(const sh8*)(B1l + o);
    acc[0][0] = MFMA(a0h, b0h, acc[0][0]);
    acc[0][0] = MFMA(a0h, b0l, acc[0][0]);
    acc[0][0] = MFMA(a0l, b0h, acc[0][0]);
    acc[0][1] = MFMA(a0h, b1h, acc[0][1]);
    acc[0][1] = MFMA(a0h, b1l, acc[0][1]);
    acc[0][1] = MFMA(a0l, b1h, acc[0][1]);
    acc[1][0] = MFMA(a1h, b0h, acc[1][0]);
    acc[1][0] = MFMA(a1h, b0l, acc[1][0]);
    acc[1][0] = MFMA(a1l, b0h, acc[1][0]);
    acc[1][1] = MFMA(a1h, b1h, acc[1][1]);
    acc[1][1] = MFMA(a1h, b1l, acc[1][1]);
    acc[1][1] = MFMA(a1l, b1h, acc[1][1]);
  }
#pragma unroll
  for (int i = 0; i < 2; i++)
#pragma unroll
    for (int j = 0; j < 2; j++) {
      int n = nt * 32 + j * 16 + lm;
      int d0 = dt * 32 + i * 16 + lk * 4;
      size_t off = ((size_t)b * NP + n) * DQ + d0;
      f32x4 v = acc[i][j];
      if (mat == 2) {
        float4 e = *(const float4*)&E2[off];
        v[0] += e.x; v[1] += e.y; v[2] += e.z; v[3] += e.w;
      }
      u16 h[4], l[4];
#pragma unroll
      for (int r = 0; r < 4; r++) {
        h[r] = f2bf(v[r]);
        l[r] = f2bf(v[r] - bf2f(h[r]));
      }
      if (mat == 0) {
        float4 vo = {v[0], v[1], v[2], v[3]};
        *(float4*)&XQ[off] = vo;
        *(uint2*)&XQhi[off] = *(const uint2*)h;
        *(uint2*)&XQlo[off] = *(const uint2*)l;
      } else if (mat == 1) {
        *(uint2*)&KLThi[off] = *(const uint2*)h;
        *(uint2*)&KLTlo[off] = *(const uint2*)l;
      } else {
        *(uint2*)&KP2hi[off] = *(const uint2*)h;
        *(uint2*)&KP2lo[off] = *(const uint2*)l;
      }
    }
}

// ---------------------------------------------------------------------------
// Q1[b][n][d] = sum_o XQ[b][n][o] p1w[o][d];  C1[b][n] = sum_o XQ[b][n][o] p1b[o]
__global__ __launch_bounds__(256) void k_q1c1(
    const float* __restrict__ XQ, const float* __restrict__ p1w,
    const float* __restrict__ p1b, float* __restrict__ Q1, float* __restrict__ C1)
{
  int b = blockIdx.x, tid = threadIdx.x;
  __shared__ float xqs[NP][65];
  __shared__ float pw[DQ][65];
  __shared__ float pb[DQ];
#pragma unroll
  for (int i = 0; i < 32; i++) {
    int idx = tid + i * 256;
    xqs[idx >> 6][idx & 63] = XQ[(size_t)b * NP * DQ + idx];
  }
#pragma unroll
  for (int i = 0; i < 16; i++) {
    int idx = tid + i * 256;
    pw[idx >> 6][idx & 63] = p1w[idx];
  }
  if (tid < DQ) pb[tid] = p1b[tid];
  __syncthreads();
  int n = tid >> 1, d0 = (tid & 1) * 32;
  float acc[32] = {};
  float cacc = 0.0f;
  for (int o = 0; o < DQ; o++) {
    float xv = xqs[n][o];
    cacc = fmaf(pb[o], xv, cacc);
#pragma unroll
    for (int dd = 0; dd < 32; dd++) acc[dd] = fmaf(pw[o][d0 + dd], xv, acc[dd]);
  }
#pragma unroll
  for (int dd = 0; dd < 32; dd += 4) {
    float4 v = {acc[dd], acc[dd + 1], acc[dd + 2], acc[dd + 3]};
    *(float4*)&Q1[((size_t)b * NP + n) * DQ + d0 + dd] = v;
  }
  if ((tid & 1) == 0) C1[b * NP + n] = cacc;
}

// ---------------------------------------------------------------------------
// Split-bf16 MFMA energy, both sources fused:
// EN[b][n][m] = bw * (xq[n].KLT[m]) + (1-bw) * (xq[n].KP2[m])
// D rows = K-rows (m), D cols = XQ-rows (n). Wave tile 32x32, K=64.
__global__ __launch_bounds__(256) void k_energy_m(
    const u16* __restrict__ XQhi, const u16* __restrict__ XQlo,
    const u16* __restrict__ KLThi, const u16* __restrict__ KLTlo,
    const u16* __restrict__ KP2hi, const u16* __restrict__ KP2lo,
    const float* __restrict__ beta_w, int layer, float* __restrict__ EN)
{
  int wid = blockIdx.x * 4 + (threadIdx.x >> 6);
  int lane = threadIdx.x & 63;
  int b = wid >> 4, q = wid & 15;
  int mt = q >> 2, ntl = q & 3;
  int lm = lane & 15, lk = lane >> 4;
  size_t arow = ((size_t)b * NP + mt * 32 + lm) * DQ + lk * 8;
  size_t brow = ((size_t)b * NP + ntl * 32 + lm) * DQ + lk * 8;
  const u16* L0h = KLThi + arow; const u16* L1h = L0h + 16 * DQ;
  const u16* L0l = KLTlo + arow; const u16* L1l = L0l + 16 * DQ;
  const u16* P0h = KP2hi + arow; const u16* P1h = P0h + 16 * DQ;
  const u16* P0l = KP2lo + arow; const u16* P1l = P0l + 16 * DQ;
  const u16* X0h = XQhi + brow;  const u16* X1h = X0h + 16 * DQ;
  const u16* X0l = XQlo + brow;  const u16* X1l = X0l + 16 * DQ;
  f32x4 aL[2][2] = {};
  f32x4 aP[2][2] = {};
#pragma unroll
  for (int ks = 0; ks < 2; ks++) {
    int o = ks * 32;
    sh8 x0h = *(const sh8*)(X0h + o), x1h = *(const sh8*)(X1h + o);
    sh8 x0l = *(const sh8*)(X0l + o), x1l = *(const sh8*)(X1l + o);
    {
      sh8 k0h = *(const sh8*)(L0h + o), k1h = *(const sh8*)(L1h + o);
      sh8 k0l = *(const sh8*)(L0l + o), k1l = *(const sh8*)(L1l + o);
      aL[0][0] = MFMA(k0h, x0h, aL[0][0]);
      aL[0][0] = MFMA(k0h, x0l, aL[0][0]);
      aL[0][0] = MFMA(k0l, x0h, aL[0][0]);
      aL[0][1] = MFMA(k0h, x1h, aL[0][1]);
      aL[0][1] = MFMA(k0h, x1l, aL[0][1]);
      aL[0][1] = MFMA(k0l, x1h, aL[0][1]);
      aL[1][0] = MFMA(k1h, x0h, aL[1][0]);
      aL[1][0] = MFMA(k1h, x0l, aL[1][0]);
      aL[1][0] = MFMA(k1l, x0h, aL[1][0]);
      aL[1][1] = MFMA(k1h, x1h, aL[1][1]);
      aL[1][1] = MFMA(k1h, x1l, aL[1][1]);
      aL[1][1] = MFMA(k1l, x1h, aL[1][1]);
    }
    {
      sh8 k0h = *(const sh8*)(P0h + o), k1h = *(const sh8*)(P1h + o);
      sh8 k0l = *(const sh8*)(P0l + o), k1l = *(const sh8*)(P1l + o);
      aP[0][0] = MFMA(k0h, x0h, aP[0][0]);
      aP[0][0] = MFMA(k0h, x0l, aP[0][0]);
      aP[0][0] = MFMA(k0l, x0h, aP[0][0]);
      aP[0][1] = MFMA(k0h, x1h, aP[0][1]);
      aP[0][1] = MFMA(k0h, x1l, aP[0][1]);
      aP[0][1] = MFMA(k0l, x1h, aP[0][1]);
      aP[1][0] = MFMA(k1h, x0h, aP[1][0]);
      aP[1][0] = MFMA(k1h, x0l, aP[1][0]);
      aP[1][0] = MFMA(k1l, x0h, aP[1][0]);
      aP[1][1] = MFMA(k1h, x1h, aP[1][1]);
      aP[1][1] = MFMA(k1h, x1l, aP[1][1]);
      aP[1][1] = MFMA(k1l, x1h, aP[1][1]);
    }
  }
  float bw = beta_w[layer], obw = 1.0f - bw;
#pragma unroll
  for (int i = 0; i < 2; i++)
#pragma unroll
    for (int j = 0; j < 2; j++) {
      int n = ntl * 32 + j * 16 + lm;
      int m0 = mt * 32 + i * 16 + lk * 4;
      float4 v;
      v.x = bw * aL[i][j][0] + obw * aP[i][j][0];
      v.y = bw * aL[i][j][1] + obw * aP[i][j][1];
      v.z = bw * aL[i][j][2] + obw * aP[i][j][2];
      v.w = bw * aL[i][j][3] + obw * aP[i][j][3];
      *(float4*)&EN[((size_t)b * NP + n) * NP + m0] = v;
    }
}

// ---------------------------------------------------------------------------
// P = softmax_m(EN + bw*(q1.emb1 + c1)); in place into EN.
__global__ __launch_bounds__(128) void k_bias(
    float* __restrict__ EN, const float* __restrict__ Q1,
    const float* __restrict__ C1, const float* __restrict__ AS,
    const float* __restrict__ beta_w, int layer)
{
  int blk = blockIdx.x;
  int b = blk >> 7, n = blk & 127;
  int m = threadIdx.x;
  __shared__ float q1s[DQ];
  __shared__ float divs[32];
  __shared__ float xred[2];
  __shared__ float sred[2];
  if (m < DQ) q1s[m] = Q1[((size_t)b * NP + n) * DQ + m];
  if (m >= 96) divs[m - 96] = __expf(-(float)(m - 96) * DIV_STEP);
  __syncthreads();
  float bw = beta_w[layer];
  size_t row = ((size_t)b * NP + n) * NP;
  float E = EN[row + m];
  float bias = C1[b * NP + n];
  float idxv = AS[row + m] * ANG_FACTOR;
#pragma unroll
  for (int j = 0; j < 32; j++) {
    float s, c;
    __sincosf(idxv * divs[j], &s, &c);
    bias = fmaf(q1s[2 * j], s, bias);
    bias = fmaf(q1s[2 * j + 1], c, bias);
  }
  E += bw * bias;
  float v = E;
#pragma unroll
  for (int off = 32; off; off >>= 1) v = fmaxf(v, __shfl_xor(v, off));
  if ((m & 63) == 0) xred[m >> 6] = v;
  __syncthreads();
  float mx = fmaxf(xred[0], xred[1]);
  float p = __expf(E - mx);
  v = p;
#pragma unroll
  for (int off = 32; off; off >>= 1) v += __shfl_xor(v, off);
  if ((m & 63) == 0) sred[m >> 6] = v;
  __syncthreads();
  float s = sred[0] + sred[1];
  EN[row + m] = p / s;
}

// ---------------------------------------------------------------------------
// P fp32 [b][n][m] -> PT bf16 [b][m][n]; SCL[b][m] = 1/(1e-12 + sum_n P[n][m])
__global__ __launch_bounds__(256) void k_pt(const float* __restrict__ EN,
                                            u16* __restrict__ PT,
                                            float* __restrict__ SCL)
{
  int mt = blockIdx.x, b = blockIdx.y;
  __shared__ float tl[128][33];
  int tid = threadIdx.x;
  {
    int ml = tid & 31, nr = tid >> 5;
    const float* src = EN + (size_t)b * NP * NP + mt * 32;
#pragma unroll
    for (int i = 0; i < 16; i++) {
      int n = nr + i * 8;
      tl[n][ml] = src[(size_t)n * NP + ml];
    }
  }
  __syncthreads();
  int m = tid >> 3, nc = (tid & 7) * 16;
  float s = 0.0f;
  u16 tmp[16];
#pragma unroll
  for (int k = 0; k < 16; k++) {
    float v = tl[nc + k][m];
    s += v;
    tmp[k] = f2bf(v);
  }
  u16* dst = PT + ((size_t)b * NP + mt * 32 + m) * NP + nc;
  *(uint4*)&dst[0] = *(const uint4*)&tmp[0];
  *(uint4*)&dst[8] = *(const uint4*)&tmp[8];
  s += __shfl_xor(s, 1);
  s += __shfl_xor(s, 2);
  s += __shfl_xor(s, 4);
  if ((tid & 7) == 0) SCL[b * NP + mt * 32 + m] = 1.0f / (1e-12f + s);
}

// ---------------------------------------------------------------------------
// MFMA: U[b][c][n] = bx*(x^T @ Wv^T)^T + (1-bx)*(pca^T @ Wvp^T)^T  (bf16 out)
__global__ __launch_bounds__(256) void k_u_m(
    const u16* __restrict__ xT, const u16* __restrict__ pT,
    const u16* __restrict__ Wv, const u16* __restrict__ Wvp,
    const float* __restrict__ beta_x, int layer, u16* __restrict__ U)
{
  int wid = blockIdx.x * 4 + (threadIdx.x >> 6);
  int lane = threadIdx.x & 63;
  int b = wid >> 5, q = wid & 31;
  int nt = q >> 3, ct = q & 7;
  int lm = lane & 15, lk = lane >> 4;
  const u16* Ax0 = xT + ((size_t)b * NP + nt * 32 + lm) * CH + lk * 8;
  const u16* Ax1 = Ax0 + 16 * CH;
  const u16* Ap0 = pT + ((size_t)b * NP + nt * 32 + lm) * CH + lk * 8;
  const u16* Ap1 = Ap0 + 16 * CH;
  const u16* Bx0 = Wv + ((size_t)(ct * 32) + lm) * CH + lk * 8;
  const u16* Bx1 = Bx0 + 16 * CH;
  const u16* Bp0 = Wvp + ((size_t)(ct * 32) + lm) * CH + lk * 8;
  const u16* Bp1 = Bp0 + 16 * CH;
  f32x4 ax00 = {}, ax01 = {}, ax10 = {}, ax11 = {};
  f32x4 ap00 = {}, ap01 = {}, ap10 = {}, ap11 = {};
#pragma unroll
  for (int ks = 0; ks < 8; ks++) {
    int o = ks * 32;
    sh8 a0 = *(const sh8*)(Ax0 + o), a1 = *(const sh8*)(Ax1 + o);
    sh8 w0 = *(const sh8*)(Bx0 + o), w1 = *(const sh8*)(Bx1 + o);
    ax00 = MFMA(a0, w0, ax00);
    ax01 = MFMA(a0, w1, ax01);
    ax10 = MFMA(a1, w0, ax10);
    ax11 = MFMA(a1, w1, ax11);
    sh8 p0 = *(const sh8*)(Ap0 + o), p1 = *(const sh8*)(Ap1 + o);
    sh8 v0 = *(const sh8*)(Bp0 + o), v1 = *(const sh8*)(Bp1 + o);
    ap00 = MFMA(p0, v0, ap00);
    ap01 = MFMA(p0, v1, ap01);
    ap10 = MFMA(p1, v0, ap10);
    ap11 = MFMA(p1, v1, ap11);
  }
  float bx = beta_x[layer], obx = 1.0f - bx;
  f32x4 accs[2][2] = {{ax00, ax01}, {ax10, ax11}};
  f32x4 accp[2][2] = {{ap00, ap01}, {ap10, ap11}};
#pragma unroll
  for (int i = 0; i < 2; i++)
#pragma unroll
    for (int j = 0; j < 2; j++) {
      int c = ct * 32 + j * 16 + lm;
      int n0 = nt * 32 + i * 16 + lk * 4;
      u16 ov[4];
#pragma unroll
      for (int r = 0; r < 4; r++)
        ov[r] = f2bf(bx * accs[i][j][r] + obx * accp[i][j][r]);
      *(uint2*)&U[((size_t)b * CH + c) * NP + n0] = *(const uint2*)ov;
    }
}

// ---------------------------------------------------------------------------
// MFMA: T^T[b][m][c] = bf(x^T[m][c]) - (sum_n U[c][n] PT[m][n]) * SCL[m]
__global__ __launch_bounds__(256) void k_t_m(
    const u16* __restrict__ U, const u16* __restrict__ PT,
    const float* __restrict__ SCL, const u16* __restrict__ xT,
    u16* __restrict__ TT)
{
  int wid = blockIdx.x * 4 + (threadIdx.x >> 6);
  int lane = threadIdx.x & 63;
  int b = wid >> 5, q = wid & 31;
  int ct = q >> 2, mt = q & 3;
  int lm = lane & 15, lk = lane >> 4;
  const u16* A0 = U + ((size_t)b * CH + ct * 32 + lm) * NP + lk * 8;
  const u16* A1 = A0 + 16 * NP;
  const u16* B0 = PT + ((size_t)b * NP + mt * 32 + lm) * NP + lk * 8;
  const u16* B1 = B0 + 16 * NP;
  f32x4 a00 = {}, a01 = {}, a10 = {}, a11 = {};
#pragma unroll
  for (int ks = 0; ks < 4; ks++) {
    int o = ks * 32;
    sh8 a0 = *(const sh8*)(A0 + o), a1 = *(const sh8*)(A1 + o);
    sh8 b0 = *(const sh8*)(B0 + o), b1 = *(const sh8*)(B1 + o);
    a00 = MFMA(a0, b0, a00);
    a01 = MFMA(a0, b1, a01);
    a10 = MFMA(a1, b0, a10);
    a11 = MFMA(a1, b1, a11);
  }
  f32x4 acc[2][2] = {{a00, a01}, {a10, a11}};
#pragma unroll
  for (int i = 0; i < 2; i++)
#pragma unroll
    for (int j = 0; j < 2; j++) {
      int m = mt * 32 + j * 16 + lm;
      int c0 = ct * 32 + i * 16 + lk * 4;
      float scl = SCL[b * NP + m];
      uint2 xv = *(const uint2*)(xT + ((size_t)b * NP + m) * CH + c0);
      const u16* xh = (const u16*)&xv;
      u16 ov[4];
#pragma unroll
      for (int r = 0; r < 4; r++)
        ov[r] = f2bf(bf2f(xh[r]) - acc[i][j][r] * scl);
      *(uint2*)&TT[((size_t)b * NP + m) * CH + c0] = *(const uint2*)ov;
    }
}

// ---------------------------------------------------------------------------
// MFMA: out[b][l*CH+c][n] = x[b][c][n] + gelu(BN(sum_k Wl[c][k] T[k][n] + bl))
__global__ __launch_bounds__(256) void k_h_m(
    const u16* __restrict__ Wl, const u16* __restrict__ TT,
    const float* __restrict__ bl, const float* __restrict__ bng,
    const float* __restrict__ bnb, const float* __restrict__ xsrc, int xbs,
    float* __restrict__ out, int layer)
{
  int wid = blockIdx.x * 4 + (threadIdx.x >> 6);
  int lane = threadIdx.x & 63;
  int b = wid >> 5, q = wid & 31;
  int ct = q >> 2, nt = q & 3;
  int lm = lane & 15, lk = lane >> 4;
  const u16* A0 = Wl + ((size_t)(ct * 32) + lm) * CH + lk * 8;
  const u16* A1 = A0 + 16 * CH;
  const u16* B0 = TT + ((size_t)b * NP + nt * 32 + lm) * CH + lk * 8;
  const u16* B1 = B0 + 16 * CH;
  f32x4 a00 = {}, a01 = {}, a10 = {}, a11 = {};
#pragma unroll
  for (int ks = 0; ks < 8; ks++) {
    int o = ks * 32;
    sh8 a0 = *(const sh8*)(A0 + o), a1 = *(const sh8*)(A1 + o);
    sh8 b0 = *(const sh8*)(B0 + o), b1 = *(const sh8*)(B1 + o);
    a00 = MFMA(a0, b0, a00);
    a01 = MFMA(a0, b1, a01);
    a10 = MFMA(a1, b0, a10);
    a11 = MFMA(a1, b1, a11);
  }
  f32x4 acc[2][2] = {{a00, a01}, {a10, a11}};
  const float rbn = 0.999995000037499687f;  // 1/sqrt(1+1e-5)
#pragma unroll
  for (int i = 0; i < 2; i++)
#pragma unroll
    for (int j = 0; j < 2; j++) {
      int n = nt * 32 + j * 16 + lm;
      int cb = ct * 32 + i * 16 + lk * 4;
#pragma unroll
      for (int r = 0; r < 4; r++) {
        int c = cb + r;
        float h = acc[i][j][r] + bl[c];
        h = h * rbn * bng[c] + bnb[c];
        float g = 0.5f * h * (1.0f + erff(h * 0.70710678118654752440f));
        out[((size_t)b * 4 * CH + (size_t)layer * CH + c) * NP + n] =
            xsrc[(size_t)b * xbs + (size_t)c * NP + n] + g;
      }
    }
}

// ---------------------------------------------------------------------------
extern "C" void kernel_launch(void* const* d_in, const int* in_sizes, int n_in,
                              void* d_out, int out_size, void* d_ws, size_t ws_size,
                              hipStream_t stream)
{
  (void)in_sizes; (void)n_in; (void)out_size; (void)ws_size;
  const float* lrf     = (const float*)d_in[0];
  const float* pca     = (const float*)d_in[1];
  const float* a_self  = (const float*)d_in[2];
  const float* a_cross = (const float*)d_in[3];
  const float* Wq  = (const float*)d_in[4];
  const float* Wk  = (const float*)d_in[5];
  const float* Wv  = (const float*)d_in[6];
  const float* Wvp = (const float*)d_in[7];
  const float* Wl  = (const float*)d_in[8];
  const float* bl  = (const float*)d_in[9];
  const float* bng = (const float*)d_in[10];
  const float* bnb = (const float*)d_in[11];
  const float* p1w = (const float*)d_in[12];
  const float* p1b = (const float*)d_in[13];
  const float* p2w = (const float*)d_in[14];
  const float* p2b = (const float*)d_in[15];
  const float* beta_x = (const float*)d_in[16];
  const float* beta_w = (const float*)d_in[17];
  float* out = (float*)d_out;
  float* ws  = (float*)d_ws;

  // ---- workspace carve (float units), ~11.6M floats = 46 MB ----
  const size_t QKN = (size_t)BB * NP * DQ;          // 524288
  const size_t ENN = (size_t)BB * NP * NP;          // 1048576
  const size_t XTN = (size_t)BB * NP * CH / 2;      // bf16 plane, fl-eq
  const size_t UNN = (size_t)BB * CH * NP / 2;
  const size_t WBN = (size_t)NLAYERS * CH * CH / 2;
  const size_t WQN = (size_t)NLAYERS * DQ * CH / 2;

  float* XQ  = ws;
  float* E2  = XQ + QKN;
  float* Q1  = E2 + QKN;
  float* C1  = Q1 + QKN;
  float* EN  = C1 + (size_t)BB * NP;
  float* SCL = EN + ENN;
  float* fp  = SCL + (size_t)BB * NP;
  u16* xThi = (u16*)fp;            fp += XTN;
  u16* xTlo = (u16*)fp;            fp += XTN;
  u16* pThi = (u16*)fp;            fp += XTN;
  u16* pTlo = (u16*)fp;            fp += XTN;
  u16* XQhi = (u16*)fp;            fp += QKN / 2;
  u16* XQlo = (u16*)fp;            fp += QKN / 2;
  u16* KLThi = (u16*)fp;           fp += QKN / 2;
  u16* KLTlo = (u16*)fp;           fp += QKN / 2;
  u16* KP2hi = (u16*)fp;           fp += QKN / 2;
  u16* KP2lo = (u16*)fp;           fp += QKN / 2;
  u16* PTbf = (u16*)fp;            fp += ENN / 2;
  u16* Ubf  = (u16*)fp;            fp += UNN;
  u16* TbfT = (u16*)fp;            fp += UNN;
  u16* Wvbf  = (u16*)fp;           fp += WBN;
  u16* Wvpbf = (u16*)fp;           fp += WBN;
  u16* Wlbf  = (u16*)fp;           fp += WBN;
  u16* Wqhi = (u16*)fp;            fp += WQN;
  u16* Wqlo = (u16*)fp;            fp += WQN;
  u16* Wkhi = (u16*)fp;            fp += WQN;
  u16* Wklo = (u16*)fp;            fp += WQN;

  // one-time: weight conversions + pca transpose/split
  const int wn = NLAYERS * CH * CH;    // 262144
  const int qn = NLAYERS * DQ * CH;    // 65536
  k_cvt<<<dim3(wn / 1024), 256, 0, stream>>>(Wv, Wvbf, wn);
  k_cvt<<<dim3(wn / 1024), 256, 0, stream>>>(Wvp, Wvpbf, wn);
  k_cvt<<<dim3(wn / 1024), 256, 0, stream>>>(Wl, Wlbf, wn);
  k_cvt2<<<dim3(qn / 1024), 256, 0, stream>>>(Wq, Wqhi, Wqlo, qn);
  k_cvt2<<<dim3(qn / 1024), 256, 0, stream>>>(Wk, Wkhi, Wklo, qn);
  k_xt2<<<dim3(2, 4, BB), 256, 0, stream>>>(pca, CH * NP, pThi, pTlo);

  for (int l = 0; l < NLAYERS; l++) {
    const float* xsrc = (l == 0) ? lrf : (out + (size_t)(l - 1) * CH * NP);
    int xbs = (l == 0) ? CH * NP : 4 * CH * NP;
    k_xt2<<<dim3(2, 4, BB), 256, 0, stream>>>(xsrc, xbs, xThi, xTlo);
    k_e2<<<dim3(BB * NP / 4), 256, 0, stream>>>(
        a_cross, p2w + (size_t)l * DQ * DQ, p2b + (size_t)l * DQ, E2);
    k_qk_m<<<dim3(BB * 24 / 4), 256, 0, stream>>>(
        xThi, xTlo, pThi, pTlo,
        Wqhi + (size_t)l * DQ * CH, Wqlo + (size_t)l * DQ * CH,
        Wkhi + (size_t)l * DQ * CH, Wklo + (size_t)l * DQ * CH,
        E2, XQ, XQhi, XQlo, KLThi, KLTlo, KP2hi, KP2lo);
    k_q1c1<<<dim3(BB), 256, 0, stream>>>(
        XQ, p1w + (size_t)l * DQ * DQ, p1b + (size_t)l * DQ, Q1, C1);
    k_energy_m<<<dim3(BB * 16 / 4), 256, 0, stream>>>(
        XQhi, XQlo, KLThi, KLTlo, KP2hi, KP2lo, beta_w, l, EN);
    k_bias<<<dim3(BB * NP), 128, 0, stream>>>(EN, Q1, C1, a_self, beta_w, l);
    k_pt<<<dim3(4, BB), 256, 0, stream>>>(EN, PTbf, SCL);
    k_u_m<<<dim3(512), 256, 0, stream>>>(
        xThi, pThi, Wvbf + (size_t)l * CH * CH, Wvpbf + (size_t)l * CH * CH,
        beta_x, l, Ubf);
    k_t_m<<<dim3(512), 256, 0, stream>>>(Ubf, PTbf, SCL, xThi, TbfT);
    k_h_m<<<dim3(512), 256, 0, stream>>>(
        Wlbf + (size_t)l * CH * CH, TbfT, bl + (size_t)l * CH,
        bng + (size_t)l * CH, bnb + (size_t)l * CH, xsrc, xbs, out, l);
  }
}

// Round 6
// 404.248 us; speedup vs baseline: 2.2030x; 1.1211x over previous
//
#include <hip/hip_runtime.h>
#include <cstdint>
#include <cstddef>

// Round 6: schedule restructure. (1) All pca-dependent GEMMs (KP2=Wq@pca+E2,
// UP=(1-bx)*Wvp@pca, E2) hoisted out of the layer loop into 3 big pre-launches.
// (2) qk+u fused into k_qu (768 blocks), energy+q1c1 fused into k_eq.
// (3) x-transpose fused into k_h_m epilogue (wave already holds out fragments).
// (4) 5 one-time cvts merged into 1. Dispatches 46 -> 28.

#define BB 64      // batch
#define CH 256     // channels
#define NP 128     // points
#define DQ 64      // q/k dim
#define NLAYERS 4

#define ANG_FACTOR 3.8197186342054885f   // 180/(pi*15) = 12/pi
#define DIV_STEP   0.28782313662425575f  // ln(10000)/32

typedef unsigned short u16;
typedef __attribute__((ext_vector_type(8))) short sh8;   // 8 bf16 = 4 VGPR
typedef __attribute__((ext_vector_type(4))) float f32x4; // MFMA C/D
#define MFMA(a, b, c) __builtin_amdgcn_mfma_f32_16x16x32_bf16(a, b, c, 0, 0, 0)

static __device__ __forceinline__ u16 f2bf(float x) {
  unsigned u = __float_as_uint(x);
  return (u16)((u + 0x7FFFu + ((u >> 16) & 1u)) >> 16);
}
static __device__ __forceinline__ float bf2f(u16 h) {
  return __uint_as_float(((unsigned)h) << 16);
}

// ---------------------------------------------------------------------------
// One-time weight conversions, all merged. blocks [0,256)=Wv, [256,512)=Wvp,
// [512,768)=Wl (plain bf16); [768,832)=Wq, [832,896)=Wk (hi/lo split).
__global__ __launch_bounds__(256) void k_cvt_all(
    const float* __restrict__ Wv, const float* __restrict__ Wvp,
    const float* __restrict__ Wl, const float* __restrict__ Wq,
    const float* __restrict__ Wk, u16* __restrict__ Wvbf,
    u16* __restrict__ Wvpbf, u16* __restrict__ Wlbf,
    u16* __restrict__ Wqhi, u16* __restrict__ Wqlo,
    u16* __restrict__ Wkhi, u16* __restrict__ Wklo)
{
  int blk = blockIdx.x, tid = threadIdx.x;
  if (blk < 768) {
    const float* s = (blk < 256) ? Wv : (blk < 512) ? Wvp : Wl;
    u16* d = (blk < 256) ? Wvbf : (blk < 512) ? Wvpbf : Wlbf;
    int i = ((blk & 255) * 256 + tid) * 4;
    float4 v = *(const float4*)(s + i);
    u16 o[4] = {f2bf(v.x), f2bf(v.y), f2bf(v.z), f2bf(v.w)};
    *(uint2*)(d + i) = *(const uint2*)o;
  } else {
    int bb = blk - 768;
    const float* s = (bb < 64) ? Wq : Wk;
    u16* dh = (bb < 64) ? Wqhi : Wkhi;
    u16* dl = (bb < 64) ? Wqlo : Wklo;
    int i = ((bb & 63) * 256 + tid) * 4;
    float4 v = *(const float4*)(s + i);
    float vv[4] = {v.x, v.y, v.z, v.w};
    u16 h[4], l[4];
#pragma unroll
    for (int r = 0; r < 4; r++) {
      h[r] = f2bf(vv[r]);
      l[r] = f2bf(vv[r] - bf2f(h[r]));
    }
    *(uint2*)(dh + i) = *(const uint2*)h;
    *(uint2*)(dl + i) = *(const uint2*)l;
  }
}

// ---------------------------------------------------------------------------
// Init transpose+split: y>>2 selects src (0=pca, 1=lrf); both stride CH*NP.
__global__ __launch_bounds__(256) void k_xt2(
    const float* __restrict__ pca, const float* __restrict__ lrf,
    u16* __restrict__ pThi, u16* __restrict__ pTlo,
    u16* __restrict__ xThi, u16* __restrict__ xTlo)
{
  int nt = blockIdx.x, y = blockIdx.y, b = blockIdx.z;
  int ct = y & 3, is_lrf = y >> 2;
  const float* x = is_lrf ? lrf : pca;
  u16* hiT = is_lrf ? xThi : pThi;
  u16* loT = is_lrf ? xTlo : pTlo;
  __shared__ float tl[64][65];
  int tid = threadIdx.x;
  {
    int col = tid & 63, rq = tid >> 6;
    const float* src = x + (size_t)b * CH * NP + (size_t)(ct * 64) * NP + nt * 64;
#pragma unroll
    for (int i = 0; i < 16; i++) {
      int c = rq + i * 4;
      tl[col][c] = src[(size_t)c * NP + col];
    }
  }
  __syncthreads();
  {
    int cloc = tid & 63, nq = tid >> 6;
#pragma unroll
    for (int i = 0; i < 16; i++) {
      int n = nq + i * 4;
      float v = tl[n][cloc];
      u16 h = f2bf(v);
      u16 l = f2bf(v - bf2f(h));
      size_t off = ((size_t)b * NP + nt * 64 + n) * CH + ct * 64 + cloc;
      hiT[off] = h;
      loT[off] = l;
    }
  }
}

// ---------------------------------------------------------------------------
// E2A[l][b][m][o] = sum_d p2w[l][o][d]*emb2[b][m][d] + p2b[l][o], all layers.
__global__ __launch_bounds__(256) void k_e2_all(
    const float* __restrict__ ac, const float* __restrict__ p2w,
    const float* __restrict__ p2b, float* __restrict__ E2A)
{
  int l = blockIdx.y;
  const float* pwg = p2w + (size_t)l * DQ * DQ;
  const float* pbg = p2b + (size_t)l * DQ;
  float* E2 = E2A + (size_t)l * BB * NP * DQ;
  __shared__ float pw[DQ][65];
  __shared__ float emb[4][DQ];
  __shared__ float pb[DQ];
  int tid = threadIdx.x;
  int bm0 = blockIdx.x * 4;
#pragma unroll
  for (int i = 0; i < 16; i++) {
    int idx = tid + i * 256;
    pw[idx >> 6][idx & 63] = pwg[idx];
  }
  if (tid < DQ) pb[tid] = pbg[tid];
  if (tid < 128) {
    int ml = tid >> 5, j = tid & 31;
    float a = ac[bm0 + ml];
    float s, c;
    __sincosf(a * ANG_FACTOR * __expf(-(float)j * DIV_STEP), &s, &c);
    emb[ml][2 * j] = s;
    emb[ml][2 * j + 1] = c;
  }
  __syncthreads();
  int mloc = tid >> 6, o = tid & 63;
  float acc = pb[o];
#pragma unroll
  for (int d = 0; d < DQ; d++) acc = fmaf(pw[o][d], emb[mloc][d], acc);
  E2[(size_t)(bm0 + mloc) * DQ + o] = acc;
}

// ---------------------------------------------------------------------------
// Precompute for all layers: blocks [0,512): KP2A[l] = split(Wq[l]@pca + E2A[l])
// (split-bf16 triple-MFMA); blocks [512,2560): UPA[l] = bf((1-bx[l])*Wvp[l]@pca).
__global__ __launch_bounds__(256) void k_pre(
    const u16* __restrict__ pThi, const u16* __restrict__ pTlo,
    const u16* __restrict__ Wqhi, const u16* __restrict__ Wqlo,
    const u16* __restrict__ Wvpbf, const float* __restrict__ E2A,
    const float* __restrict__ beta_x,
    u16* __restrict__ KP2hiA, u16* __restrict__ KP2loA, u16* __restrict__ UPA)
{
  int lane = threadIdx.x & 63;
  int lm = lane & 15, lk = lane >> 4;
  if (blockIdx.x < 512) {
    int wid = blockIdx.x * 4 + (threadIdx.x >> 6);   // 0..2047
    int l = wid >> 9, r = wid & 511;
    int b = r >> 3, t = r & 7, nt = t >> 1, dt = t & 1;
    const u16* Ah = Wqhi + (size_t)l * DQ * CH;
    const u16* Al = Wqlo + (size_t)l * DQ * CH;
    const u16* Bh = pThi + (size_t)b * NP * CH;
    const u16* Bl = pTlo + (size_t)b * NP * CH;
    const u16* A0h = Ah + ((size_t)(dt * 32) + lm) * CH + lk * 8;
    const u16* A1h = A0h + 16 * CH;
    const u16* A0l = Al + ((size_t)(dt * 32) + lm) * CH + lk * 8;
    const u16* A1l = A0l + 16 * CH;
    const u16* B0h = Bh + ((size_t)(nt * 32) + lm) * CH + lk * 8;
    const u16* B1h = B0h + 16 * CH;
    const u16* B0l = Bl + ((size_t)(nt * 32) + lm) * CH + lk * 8;
    const u16* B1l = B0l + 16 * CH;
    f32x4 acc[2][2] = {};
#pragma unroll
    for (int ks = 0; ks < 8; ks++) {
      int o = ks * 32;
      sh8 a0h = *(const sh8*)(A0h + o), a1h = *(const sh8*)(A1h + o);
      sh8 a0l = *(const sh8*)(A0l + o), a1l = *(const sh8*)(A1l + o);
      sh8 b0h = *(const sh8*)(B0h + o), b1h = *(const sh8*)(B1h + o);
      sh8 b0l = *(const sh8*)(B0l + o), b1l = *(const sh8*)(B1l + o);
      acc[0][0] = MFMA(a0h, b0h, acc[0][0]);
      acc[0][0] = MFMA(a0h, b0l, acc[0][0]);
      acc[0][0] = MFMA(a0l, b0h, acc[0][0]);
      acc[0][1] = MFMA(a0h, b1h, acc[0][1]);
      acc[0][1] = MFMA(a0h, b1l, acc[0][1]);
      acc[0][1] = MFMA(a0l, b1h, acc[0][1]);
      acc[1][0] = MFMA(a1h, b0h, acc[1][0]);
      acc[1][0] = MFMA(a1h, b0l, acc[1][0]);
      acc[1][0] = MFMA(a1l, b0h, acc[1][0]);
      acc[1][1] = MFMA(a1h, b1h, acc[1][1]);
      acc[1][1] = MFMA(a1h, b1l, acc[1][1]);
      acc[1][1] = MFMA(a1l, b1h, acc[1][1]);
    }
#pragma unroll
    for (int i = 0; i < 2; i++)
#pragma unroll
      for (int j = 0; j < 2; j++) {
        int n = nt * 32 + j * 16 + lm;
        int d0 = dt * 32 + i * 16 + lk * 4;
        size_t off = (((size_t)l * BB + b) * NP + n) * DQ + d0;
        f32x4 v = acc[i][j];
        float4 e = *(const float4*)&E2A[off];
        v[0] += e.x; v[1] += e.y; v[2] += e.z; v[3] += e.w;
        u16 h[4], lo[4];
#pragma unroll
        for (int r2 = 0; r2 < 4; r2++) {
          h[r2] = f2bf(v[r2]);
          lo[r2] = f2bf(v[r2] - bf2f(h[r2]));
        }
        *(uint2*)&KP2hiA[off] = *(const uint2*)h;
        *(uint2*)&KP2loA[off] = *(const uint2*)lo;
      }
  } else {
    int wid = (blockIdx.x - 512) * 4 + (threadIdx.x >> 6);  // 0..8191
    int l = wid >> 11, r = wid & 2047;
    int b = r >> 5, q = r & 31, nt = q >> 3, ct = q & 7;
    float obx = 1.0f - beta_x[l];
    const u16* A0 = pThi + ((size_t)b * NP + nt * 32 + lm) * CH + lk * 8;
    const u16* A1 = A0 + 16 * CH;
    const u16* B0 = Wvpbf + (size_t)l * CH * CH + ((size_t)(ct * 32) + lm) * CH + lk * 8;
    const u16* B1 = B0 + 16 * CH;
    f32x4 a00 = {}, a01 = {}, a10 = {}, a11 = {};
#pragma unroll
    for (int ks = 0; ks < 8; ks++) {
      int o = ks * 32;
      sh8 a0 = *(const sh8*)(A0 + o), a1 = *(const sh8*)(A1 + o);
      sh8 b0 = *(const sh8*)(B0 + o), b1 = *(const sh8*)(B1 + o);
      a00 = MFMA(a0, b0, a00);
      a01 = MFMA(a0, b1, a01);
      a10 = MFMA(a1, b0, a10);
      a11 = MFMA(a1, b1, a11);
    }
    f32x4 acc[2][2] = {{a00, a01}, {a10, a11}};
#pragma unroll
    for (int i = 0; i < 2; i++)
#pragma unroll
      for (int j = 0; j < 2; j++) {
        int c = ct * 32 + j * 16 + lm;
        int n0 = nt * 32 + i * 16 + lk * 4;
        u16 ov[4];
#pragma unroll
        for (int r2 = 0; r2 < 4; r2++) ov[r2] = f2bf(obx * acc[i][j][r2]);
        *(uint2*)&UPA[(((size_t)l * BB + b) * CH + c) * NP + n0] = *(const uint2*)ov;
      }
  }
}

// ---------------------------------------------------------------------------
// Per-layer fused: blocks [0,256): split-bf16 QK projections (mat0: XQ fp32 +
// hi/lo, mat1: KLT hi/lo); blocks [256,768): U = bf(bx*Wv@x) + UPA[l].
__global__ __launch_bounds__(256) void k_qu(
    const u16* __restrict__ xThi, const u16* __restrict__ xTlo,
    const u16* __restrict__ Wqhi, const u16* __restrict__ Wqlo,
    const u16* __restrict__ Wkhi, const u16* __restrict__ Wklo,
    const u16* __restrict__ Wv, const u16* __restrict__ UP,
    const float* __restrict__ beta_x, int layer,
    float* __restrict__ XQ, u16* __restrict__ XQhi, u16* __restrict__ XQlo,
    u16* __restrict__ KLThi, u16* __restrict__ KLTlo, u16* __restrict__ U)
{
  int lane = threadIdx.x & 63;
  int lm = lane & 15, lk = lane >> 4;
  if (blockIdx.x < 256) {
    int wid = blockIdx.x * 4 + (threadIdx.x >> 6);   // 0..1023
    int b = wid >> 4, q = wid & 15;
    int mat = q >> 3, t = q & 7, nt = t >> 1, dt = t & 1;
    const u16* Ah = mat ? Wkhi : Wqhi;
    const u16* Al = mat ? Wklo : Wqlo;
    const u16* Bh = xThi + (size_t)b * NP * CH;
    const u16* Bl = xTlo + (size_t)b * NP * CH;
    const u16* A0h = Ah + ((size_t)(dt * 32) + lm) * CH + lk * 8;
    const u16* A1h = A0h + 16 * CH;
    const u16* A0l = Al + ((size_t)(dt * 32) + lm) * CH + lk * 8;
    const u16* A1l = A0l + 16 * CH;
    const u16* B0h = Bh + ((size_t)(nt * 32) + lm) * CH + lk * 8;
    const u16* B1h = B0h + 16 * CH;
    const u16* B0l = Bl + ((size_t)(nt * 32) + lm) * CH + lk * 8;
    const u16* B1l = B0l + 16 * CH;
    f32x4 acc[2][2] = {};
#pragma unroll
    for (int ks = 0; ks < 8; ks++) {
      int o = ks * 32;
      sh8 a0h = *(const sh8*)(A0h + o), a1h = *(const sh8*)(A1h + o);
      sh8 a0l = *(const sh8*)(A0l + o), a1l = *(const sh8*)(A1l + o);
      sh8 b0h = *(const sh8*)(B0h + o), b1h = *(const sh8*)(B1h + o);
      sh8 b0l = *(const sh8*)(B0l + o), b1l = *(const sh8*)(B1l + o);
      acc[0][0] = MFMA(a0h, b0h, acc[0][0]);
      acc[0][0] = MFMA(a0h, b0l, acc[0][0]);
      acc[0][0] = MFMA(a0l, b0h, acc[0][0]);
      acc[0][1] = MFMA(a0h, b1h, acc[0][1]);
      acc[0][1] = MFMA(a0h, b1l, acc[0][1]);
      acc[0][1] = MFMA(a0l, b1h, acc[0][1]);
      acc[1][0] = MFMA(a1h, b0h, acc[1][0]);
      acc[1][0] = MFMA(a1h, b0l, acc[1][0]);
      acc[1][0] = MFMA(a1l, b0h, acc[1][0]);
      acc[1][1] = MFMA(a1h, b1h, acc[1][1]);
      acc[1][1] = MFMA(a1h, b1l, acc[1][1]);
      acc[1][1] = MFMA(a1l, b1h, acc[1][1]);
    }
#pragma unroll
    for (int i = 0; i < 2; i++)
#pragma unroll
      for (int j = 0; j < 2; j++) {
        int n = nt * 32 + j * 16 + lm;
        int d0 = dt * 32 + i * 16 + lk * 4;
        size_t off = ((size_t)b * NP + n) * DQ + d0;
        f32x4 v = acc[i][j];
        u16 h[4], lo[4];
#pragma unroll
        for (int r2 = 0; r2 < 4; r2++) {
          h[r2] = f2bf(v[r2]);
          lo[r2] = f2bf(v[r2] - bf2f(h[r2]));
        }
        if (mat == 0) {
          float4 vo = {v[0], v[1], v[2], v[3]};
          *(float4*)&XQ[off] = vo;
          *(uint2*)&XQhi[off] = *(const uint2*)h;
          *(uint2*)&XQlo[off] = *(const uint2*)lo;
        } else {
          *(uint2*)&KLThi[off] = *(const uint2*)h;
          *(uint2*)&KLTlo[off] = *(const uint2*)lo;
        }
      }
  } else {
    int wid = (blockIdx.x - 256) * 4 + (threadIdx.x >> 6);  // 0..2047
    int b = wid >> 5, q = wid & 31, nt = q >> 3, ct = q & 7;
    float bx = beta_x[layer];
    const u16* A0 = xThi + ((size_t)b * NP + nt * 32 + lm) * CH + lk * 8;
    const u16* A1 = A0 + 16 * CH;
    const u16* B0 = Wv + ((size_t)(ct * 32) + lm) * CH + lk * 8;
    const u16* B1 = B0 + 16 * CH;
    f32x4 a00 = {}, a01 = {}, a10 = {}, a11 = {};
#pragma unroll
    for (int ks = 0; ks < 8; ks++) {
      int o = ks * 32;
      sh8 a0 = *(const sh8*)(A0 + o), a1 = *(const sh8*)(A1 + o);
      sh8 b0 = *(const sh8*)(B0 + o), b1 = *(const sh8*)(B1 + o);
      a00 = MFMA(a0, b0, a00);
      a01 = MFMA(a0, b1, a01);
      a10 = MFMA(a1, b0, a10);
      a11 = MFMA(a1, b1, a11);
    }
    f32x4 acc[2][2] = {{a00, a01}, {a10, a11}};
#pragma unroll
    for (int i = 0; i < 2; i++)
#pragma unroll
      for (int j = 0; j < 2; j++) {
        int c = ct * 32 + j * 16 + lm;
        int n0 = nt * 32 + i * 16 + lk * 4;
        size_t off = ((size_t)b * CH + c) * NP + n0;
        uint2 up = *(const uint2*)&UP[off];
        const u16* uph = (const u16*)&up;
        u16 ov[4];
#pragma unroll
        for (int r2 = 0; r2 < 4; r2++)
          ov[r2] = f2bf(bx * acc[i][j][r2] + bf2f(uph[r2]));
        *(uint2*)&U[off] = *(const uint2*)ov;
      }
  }
}

// ---------------------------------------------------------------------------
// Per-layer fused: blocks [0,256): split-bf16 energy EN = bw*xq.KLT +
// (1-bw)*xq.KP2A[l]; blocks [256,320): q1c1 (Q1 = XQ@p1w, C1 = XQ@p1b).
__global__ __launch_bounds__(256) void k_eq(
    const float* __restrict__ XQ,
    const u16* __restrict__ XQhi, const u16* __restrict__ XQlo,
    const u16* __restrict__ KLThi, const u16* __restrict__ KLTlo,
    const u16* __restrict__ KP2hi, const u16* __restrict__ KP2lo,
    const float* __restrict__ beta_w, int layer, float* __restrict__ EN,
    const float* __restrict__ p1w, const float* __restrict__ p1b,
    float* __restrict__ Q1, float* __restrict__ C1)
{
  if (blockIdx.x < 256) {
    int wid = blockIdx.x * 4 + (threadIdx.x >> 6);
    int lane = threadIdx.x & 63;
    int b = wid >> 4, q = wid & 15;
    int mt = q >> 2, ntl = q & 3;
    int lm = lane & 15, lk = lane >> 4;
    size_t arow = ((size_t)b * NP + mt * 32 + lm) * DQ + lk * 8;
    size_t brow = ((size_t)b * NP + ntl * 32 + lm) * DQ + lk * 8;
    const u16* L0h = KLThi + arow; const u16* L1h = L0h + 16 * DQ;
    const u16* L0l = KLTlo + arow; const u16* L1l = L0l + 16 * DQ;
    const u16* P0h = KP2hi + arow; const u16* P1h = P0h + 16 * DQ;
    const u16* P0l = KP2lo + arow; const u16* P1l = P0l + 16 * DQ;
    const u16* X0h = XQhi + brow;  const u16* X1h = X0h + 16 * DQ;
    const u16* X0l = XQlo + brow;  const u16* X1l = X0l + 16 * DQ;
    f32x4 aL[2][2] = {};
    f32x4 aP[2][2] = {};
#pragma unroll
    for (int ks = 0; ks < 2; ks++) {
      int o = ks * 32;
      sh8 x0h = *(const sh8*)(X0h + o), x1h = *(const sh8*)(X1h + o);
      sh8 x0l = *(const sh8*)(X0l + o), x1l = *(const sh8*)(X1l + o);
      {
        sh8 k0h = *(const sh8*)(L0h + o), k1h = *(const sh8*)(L1h + o);
        sh8 k0l = *(const sh8*)(L0l + o), k1l = *(const sh8*)(L1l + o);
        aL[0][0] = MFMA(k0h, x0h, aL[0][0]);
        aL[0][0] = MFMA(k0h, x0l, aL[0][0]);
        aL[0][0] = MFMA(k0l, x0h, aL[0][0]);
        aL[0][1] = MFMA(k0h, x1h, aL[0][1]);
        aL[0][1] = MFMA(k0h, x1l, aL[0][1]);
        aL[0][1] = MFMA(k0l, x1h, aL[0][1]);
        aL[1][0] = MFMA(k1h, x0h, aL[1][0]);
        aL[1][0] = MFMA(k1h, x0l, aL[1][0]);
        aL[1][0] = MFMA(k1l, x0h, aL[1][0]);
        aL[1][1] = MFMA(k1h, x1h, aL[1][1]);
        aL[1][1] = MFMA(k1h, x1l, aL[1][1]);
        aL[1][1] = MFMA(k1l, x1h, aL[1][1]);
      }
      {
        sh8 k0h = *(const sh8*)(P0h + o), k1h = *(const sh8*)(P1h + o);
        sh8 k0l = *(const sh8*)(P0l + o), k1l = *(const sh8*)(P1l + o);
        aP[0][0] = MFMA(k0h, x0h, aP[0][0]);
        aP[0][0] = MFMA(k0h, x0l, aP[0][0]);
        aP[0][0] = MFMA(k0l, x0h, aP[0][0]);
        aP[0][1] = MFMA(k0h, x1h, aP[0][1]);
        aP[0][1] = MFMA(k0h, x1l, aP[0][1]);
        aP[0][1] = MFMA(k0l, x1h, aP[0][1]);
        aP[1][0] = MFMA(k1h, x0h, aP[1][0]);
        aP[1][0] = MFMA(k1h, x0l, aP[1][0]);
        aP[1][0] = MFMA(k1l, x0h, aP[1][0]);
        aP[1][1] = MFMA(k1h, x1h, aP[1][1]);
        aP[1][1] = MFMA(k1h, x1l, aP[1][1]);
        aP[1][1] = MFMA(k1l, x1h, aP[1][1]);
      }
    }
    float bw = beta_w[layer], obw = 1.0f - bw;
#pragma unroll
    for (int i = 0; i < 2; i++)
#pragma unroll
      for (int j = 0; j < 2; j++) {
        int n = ntl * 32 + j * 16 + lm;
        int m0 = mt * 32 + i * 16 + lk * 4;
        float4 v;
        v.x = bw * aL[i][j][0] + obw * aP[i][j][0];
        v.y = bw * aL[i][j][1] + obw * aP[i][j][1];
        v.z = bw * aL[i][j][2] + obw * aP[i][j][2];
        v.w = bw * aL[i][j][3] + obw * aP[i][j][3];
        *(float4*)&EN[((size_t)b * NP + n) * NP + m0] = v;
      }
  } else {
    int b = blockIdx.x - 256, tid = threadIdx.x;
    __shared__ float xqs[NP][65];
    __shared__ float pw[DQ][65];
    __shared__ float pb[DQ];
#pragma unroll
    for (int i = 0; i < 32; i++) {
      int idx = tid + i * 256;
      xqs[idx >> 6][idx & 63] = XQ[(size_t)b * NP * DQ + idx];
    }
#pragma unroll
    for (int i = 0; i < 16; i++) {
      int idx = tid + i * 256;
      pw[idx >> 6][idx & 63] = p1w[idx];
    }
    if (tid < DQ) pb[tid] = p1b[tid];
    __syncthreads();
    int n = tid >> 1, d0 = (tid & 1) * 32;
    float acc[32] = {};
    float cacc = 0.0f;
    for (int o = 0; o < DQ; o++) {
      float xv = xqs[n][o];
      cacc = fmaf(pb[o], xv, cacc);
#pragma unroll
      for (int dd = 0; dd < 32; dd++) acc[dd] = fmaf(pw[o][d0 + dd], xv, acc[dd]);
    }
#pragma unroll
    for (int dd = 0; dd < 32; dd += 4) {
      float4 v = {acc[dd], acc[dd + 1], acc[dd + 2], acc[dd + 3]};
      *(float4*)&Q1[((size_t)b * NP + n) * DQ + d0 + dd] = v;
    }
    if ((tid & 1) == 0) C1[b * NP + n] = cacc;
  }
}

// ---------------------------------------------------------------------------
// P = softmax_m(EN + bw*(q1.emb1 + c1)); in place into EN.
__global__ __launch_bounds__(128) void k_bias(
    float* __restrict__ EN, const float* __restrict__ Q1,
    const float* __restrict__ C1, const float* __restrict__ AS,
    const float* __restrict__ beta_w, int layer)
{
  int blk = blockIdx.x;
  int b = blk >> 7, n = blk & 127;
  int m = threadIdx.x;
  __shared__ float q1s[DQ];
  __shared__ float divs[32];
  __shared__ float xred[2];
  __shared__ float sred[2];
  if (m < DQ) q1s[m] = Q1[((size_t)b * NP + n) * DQ + m];
  if (m >= 96) divs[m - 96] = __expf(-(float)(m - 96) * DIV_STEP);
  __syncthreads();
  float bw = beta_w[layer];
  size_t row = ((size_t)b * NP + n) * NP;
  float E = EN[row + m];
  float bias = C1[b * NP + n];
  float idxv = AS[row + m] * ANG_FACTOR;
#pragma unroll
  for (int j = 0; j < 32; j++) {
    float s, c;
    __sincosf(idxv * divs[j], &s, &c);
    bias = fmaf(q1s[2 * j], s, bias);
    bias = fmaf(q1s[2 * j + 1], c, bias);
  }
  E += bw * bias;
  float v = E;
#pragma unroll
  for (int off = 32; off; off >>= 1) v = fmaxf(v, __shfl_xor(v, off));
  if ((m & 63) == 0) xred[m >> 6] = v;
  __syncthreads();
  float mx = fmaxf(xred[0], xred[1]);
  float p = __expf(E - mx);
  v = p;
#pragma unroll
  for (int off = 32; off; off >>= 1) v += __shfl_xor(v, off);
  if ((m & 63) == 0) sred[m >> 6] = v;
  __syncthreads();
  float s = sred[0] + sred[1];
  EN[row + m] = p / s;
}

// ---------------------------------------------------------------------------
// P fp32 [b][n][m] -> PT bf16 [b][m][n]; SCL[b][m] = 1/(1e-12 + sum_n P[n][m])
__global__ __launch_bounds__(256) void k_pt(const float* __restrict__ EN,
                                            u16* __restrict__ PT,
                                            float* __restrict__ SCL)
{
  int mt = blockIdx.x, b = blockIdx.y;
  __shared__ float tl[128][33];
  int tid = threadIdx.x;
  {
    int ml = tid & 31, nr = tid >> 5;
    const float* src = EN + (size_t)b * NP * NP + mt * 32;
#pragma unroll
    for (int i = 0; i < 16; i++) {
      int n = nr + i * 8;
      tl[n][ml] = src[(size_t)n * NP + ml];
    }
  }
  __syncthreads();
  int m = tid >> 3, nc = (tid & 7) * 16;
  float s = 0.0f;
  u16 tmp[16];
#pragma unroll
  for (int k = 0; k < 16; k++) {
    float v = tl[nc + k][m];
    s += v;
    tmp[k] = f2bf(v);
  }
  u16* dst = PT + ((size_t)b * NP + mt * 32 + m) * NP + nc;
  *(uint4*)&dst[0] = *(const uint4*)&tmp[0];
  *(uint4*)&dst[8] = *(const uint4*)&tmp[8];
  s += __shfl_xor(s, 1);
  s += __shfl_xor(s, 2);
  s += __shfl_xor(s, 4);
  if ((tid & 7) == 0) SCL[b * NP + mt * 32 + m] = 1.0f / (1e-12f + s);
}

// ---------------------------------------------------------------------------
// MFMA: T^T[b][m][c] = bf(x^T[m][c]) - (sum_n U[c][n] PT[m][n]) * SCL[m]
__global__ __launch_bounds__(256) void k_t_m(
    const u16* __restrict__ U, const u16* __restrict__ PT,
    const float* __restrict__ SCL, const u16* __restrict__ xT,
    u16* __restrict__ TT)
{
  int wid = blockIdx.x * 4 + (threadIdx.x >> 6);
  int lane = threadIdx.x & 63;
  int b = wid >> 5, q = wid & 31;
  int ct = q >> 2, mt = q & 3;
  int lm = lane & 15, lk = lane >> 4;
  const u16* A0 = U + ((size_t)b * CH + ct * 32 + lm) * NP + lk * 8;
  const u16* A1 = A0 + 16 * NP;
  const u16* B0 = PT + ((size_t)b * NP + mt * 32 + lm) * NP + lk * 8;
  const u16* B1 = B0 + 16 * NP;
  f32x4 a00 = {}, a01 = {}, a10 = {}, a11 = {};
#pragma unroll
  for (int ks = 0; ks < 4; ks++) {
    int o = ks * 32;
    sh8 a0 = *(const sh8*)(A0 + o), a1 = *(const sh8*)(A1 + o);
    sh8 b0 = *(const sh8*)(B0 + o), b1 = *(const sh8*)(B1 + o);
    a00 = MFMA(a0, b0, a00);
    a01 = MFMA(a0, b1, a01);
    a10 = MFMA(a1, b0, a10);
    a11 = MFMA(a1, b1, a11);
  }
  f32x4 acc[2][2] = {{a00, a01}, {a10, a11}};
#pragma unroll
  for (int i = 0; i < 2; i++)
#pragma unroll
    for (int j = 0; j < 2; j++) {
      int m = mt * 32 + j * 16 + lm;
      int c0 = ct * 32 + i * 16 + lk * 4;
      float scl = SCL[b * NP + m];
      uint2 xv = *(const uint2*)(xT + ((size_t)b * NP + m) * CH + c0);
      const u16* xh = (const u16*)&xv;
      u16 ov[4];
#pragma unroll
      for (int r = 0; r < 4; r++)
        ov[r] = f2bf(bf2f(xh[r]) - acc[i][j][r] * scl);
      *(uint2*)&TT[((size_t)b * NP + m) * CH + c0] = *(const uint2*)ov;
    }
}

// ---------------------------------------------------------------------------
// MFMA: out = x + gelu(BN(Wl@T + bl)); also writes next layer's xT hi/lo.
__global__ __launch_bounds__(256) void k_h_m(
    const u16* __restrict__ Wl, const u16* __restrict__ TT,
    const float* __restrict__ bl, const float* __restrict__ bng,
    const float* __restrict__ bnb, const float* __restrict__ xsrc, int xbs,
    float* __restrict__ out, int layer,
    u16* __restrict__ xThi_o, u16* __restrict__ xTlo_o)
{
  int wid = blockIdx.x * 4 + (threadIdx.x >> 6);
  int lane = threadIdx.x & 63;
  int b = wid >> 5, q = wid & 31;
  int ct = q >> 2, nt = q & 3;
  int lm = lane & 15, lk = lane >> 4;
  const u16* A0 = Wl + ((size_t)(ct * 32) + lm) * CH + lk * 8;
  const u16* A1 = A0 + 16 * CH;
  const u16* B0 = TT + ((size_t)b * NP + nt * 32 + lm) * CH + lk * 8;
  const u16* B1 = B0 + 16 * CH;
  f32x4 a00 = {}, a01 = {}, a10 = {}, a11 = {};
#pragma unroll
  for (int ks = 0; ks < 8; ks++) {
    int o = ks * 32;
    sh8 a0 = *(const sh8*)(A0 + o), a1 = *(const sh8*)(A1 + o);
    sh8 b0 = *(const sh8*)(B0 + o), b1 = *(const sh8*)(B1 + o);
    a00 = MFMA(a0, b0, a00);
    a01 = MFMA(a0, b1, a01);
    a10 = MFMA(a1, b0, a10);
    a11 = MFMA(a1, b1, a11);
  }
  f32x4 acc[2][2] = {{a00, a01}, {a10, a11}};
  const float rbn = 0.999995000037499687f;  // 1/sqrt(1+1e-5)
#pragma unroll
  for (int i = 0; i < 2; i++)
#pragma unroll
    for (int j = 0; j < 2; j++) {
      int n = nt * 32 + j * 16 + lm;
      int cb = ct * 32 + i * 16 + lk * 4;
      u16 hh[4], ll[4];
#pragma unroll
      for (int r = 0; r < 4; r++) {
        int c = cb + r;
        float h = acc[i][j][r] + bl[c];
        h = h * rbn * bng[c] + bnb[c];
        float g = 0.5f * h * (1.0f + erff(h * 0.70710678118654752440f));
        float ov = xsrc[(size_t)b * xbs + (size_t)c * NP + n] + g;
        out[((size_t)b * 4 * CH + (size_t)layer * CH + c) * NP + n] = ov;
        hh[r] = f2bf(ov);
        ll[r] = f2bf(ov - bf2f(hh[r]));
      }
      size_t xoff = ((size_t)b * NP + n) * CH + cb;
      *(uint2*)&xThi_o[xoff] = *(const uint2*)hh;
      *(uint2*)&xTlo_o[xoff] = *(const uint2*)ll;
    }
}

// ---------------------------------------------------------------------------
extern "C" void kernel_launch(void* const* d_in, const int* in_sizes, int n_in,
                              void* d_out, int out_size, void* d_ws, size_t ws_size,
                              hipStream_t stream)
{
  (void)in_sizes; (void)n_in; (void)out_size; (void)ws_size;
  const float* lrf     = (const float*)d_in[0];
  const float* pca     = (const float*)d_in[1];
  const float* a_self  = (const float*)d_in[2];
  const float* a_cross = (const float*)d_in[3];
  const float* Wq  = (const float*)d_in[4];
  const float* Wk  = (const float*)d_in[5];
  const float* Wv  = (const float*)d_in[6];
  const float* Wvp = (const float*)d_in[7];
  const float* Wl  = (const float*)d_in[8];
  const float* bl  = (const float*)d_in[9];
  const float* bng = (const float*)d_in[10];
  const float* bnb = (const float*)d_in[11];
  const float* p1w = (const float*)d_in[12];
  const float* p1b = (const float*)d_in[13];
  const float* p2w = (const float*)d_in[14];
  const float* p2b = (const float*)d_in[15];
  const float* beta_x = (const float*)d_in[16];
  const float* beta_w = (const float*)d_in[17];
  float* out = (float*)d_out;
  float* ws  = (float*)d_ws;

  // ---- workspace carve ----
  const size_t QKN = (size_t)BB * NP * DQ;        // 524288
  const size_t ENN = (size_t)BB * NP * NP;        // 1048576
  const size_t XCN = (size_t)BB * NP * CH;        // 2097152 (u16 count)

  float* XQ  = ws;
  float* Q1  = XQ + QKN;
  float* C1  = Q1 + QKN;
  float* EN  = C1 + (size_t)BB * NP;
  float* SCL = EN + ENN;
  float* E2A = SCL + (size_t)BB * NP;
  u16* up = (u16*)(E2A + (size_t)NLAYERS * QKN);
  u16* xThi = up;   up += XCN;
  u16* xTlo = up;   up += XCN;
  u16* pThi = up;   up += XCN;
  u16* pTlo = up;   up += XCN;
  u16* XQhi = up;   up += QKN;
  u16* XQlo = up;   up += QKN;
  u16* KLThi = up;  up += QKN;
  u16* KLTlo = up;  up += QKN;
  u16* KP2hiA = up; up += (size_t)NLAYERS * QKN;
  u16* KP2loA = up; up += (size_t)NLAYERS * QKN;
  u16* UPA = up;    up += (size_t)NLAYERS * BB * CH * NP;
  u16* Ubf = up;    up += (size_t)BB * CH * NP;
  u16* PTbf = up;   up += ENN;
  u16* TbfT = up;   up += XCN;
  u16* Wvbf = up;   up += (size_t)NLAYERS * CH * CH;
  u16* Wvpbf = up;  up += (size_t)NLAYERS * CH * CH;
  u16* Wlbf = up;   up += (size_t)NLAYERS * CH * CH;
  u16* Wqhi = up;   up += (size_t)NLAYERS * DQ * CH;
  u16* Wqlo = up;   up += (size_t)NLAYERS * DQ * CH;
  u16* Wkhi = up;   up += (size_t)NLAYERS * DQ * CH;
  u16* Wklo = up;   up += (size_t)NLAYERS * DQ * CH;

  // ---- pre-loop (4 launches) ----
  k_cvt_all<<<dim3(896), 256, 0, stream>>>(
      Wv, Wvp, Wl, Wq, Wk, Wvbf, Wvpbf, Wlbf, Wqhi, Wqlo, Wkhi, Wklo);
  k_xt2<<<dim3(2, 8, BB), 256, 0, stream>>>(pca, lrf, pThi, pTlo, xThi, xTlo);
  k_e2_all<<<dim3(BB * NP / 4, NLAYERS), 256, 0, stream>>>(a_cross, p2w, p2b, E2A);
  k_pre<<<dim3(2560), 256, 0, stream>>>(
      pThi, pTlo, Wqhi, Wqlo, Wvpbf, E2A, beta_x, KP2hiA, KP2loA, UPA);

  // ---- layer loop (6 launches each) ----
  for (int l = 0; l < NLAYERS; l++) {
    const float* xsrc = (l == 0) ? lrf : (out + (size_t)(l - 1) * CH * NP);
    int xbs = (l == 0) ? CH * NP : 4 * CH * NP;
    k_qu<<<dim3(768), 256, 0, stream>>>(
        xThi, xTlo,
        Wqhi + (size_t)l * DQ * CH, Wqlo + (size_t)l * DQ * CH,
        Wkhi + (size_t)l * DQ * CH, Wklo + (size_t)l * DQ * CH,
        Wvbf + (size_t)l * CH * CH, UPA + (size_t)l * BB * CH * NP,
        beta_x, l, XQ, XQhi, XQlo, KLThi, KLTlo, Ubf);
    k_eq<<<dim3(320), 256, 0, stream>>>(
        XQ, XQhi, XQlo, KLThi, KLTlo,
        KP2hiA + (size_t)l * QKN, KP2loA + (size_t)l * QKN,
        beta_w, l, EN, p1w + (size_t)l * DQ * DQ, p1b + (size_t)l * DQ, Q1, C1);
    k_bias<<<dim3(BB * NP), 128, 0, stream>>>(EN, Q1, C1, a_self, beta_w, l);
    k_pt<<<dim3(4, BB), 256, 0, stream>>>(EN, PTbf, SCL);
    k_t_m<<<dim3(512), 256, 0, stream>>>(Ubf, PTbf, SCL, xThi, TbfT);
    k_h_m<<<dim3(512), 256, 0, stream>>>(
        Wlbf + (size_t)l * CH * CH, TbfT, bl + (size_t)l * CH,
        bng + (size_t)l * CH, bnb + (size_t)l * CH, xsrc, xbs, out, l,
        xThi, xTlo);
  }
}

// Round 7
// 402.170 us; speedup vs baseline: 2.2144x; 1.0052x over previous
//
#include <hip/hip_runtime.h>
#include <cstdint>
#include <cstddef>

// Round 7: memory-level-parallelism fix for the latency-bound no-LDS MFMA
// kernels. Operand loads grouped into register batches (16 loads in flight
// per stall instead of 4-8), cutting serialized L2 round-trips per wave from
// 8 to 2-4. Math unchanged from round 6.

#define BB 64      // batch
#define CH 256     // channels
#define NP 128     // points
#define DQ 64      // q/k dim
#define NLAYERS 4

#define ANG_FACTOR 3.8197186342054885f   // 180/(pi*15) = 12/pi
#define DIV_STEP   0.28782313662425575f  // ln(10000)/32

typedef unsigned short u16;
typedef __attribute__((ext_vector_type(8))) short sh8;   // 8 bf16 = 4 VGPR
typedef __attribute__((ext_vector_type(4))) float f32x4; // MFMA C/D
#define MFMA(a, b, c) __builtin_amdgcn_mfma_f32_16x16x32_bf16(a, b, c, 0, 0, 0)

static __device__ __forceinline__ u16 f2bf(float x) {
  unsigned u = __float_as_uint(x);
  return (u16)((u + 0x7FFFu + ((u >> 16) & 1u)) >> 16);
}
static __device__ __forceinline__ float bf2f(u16 h) {
  return __uint_as_float(((unsigned)h) << 16);
}

// ---------------------------------------------------------------------------
// One-time weight conversions, all merged.
__global__ __launch_bounds__(256) void k_cvt_all(
    const float* __restrict__ Wv, const float* __restrict__ Wvp,
    const float* __restrict__ Wl, const float* __restrict__ Wq,
    const float* __restrict__ Wk, u16* __restrict__ Wvbf,
    u16* __restrict__ Wvpbf, u16* __restrict__ Wlbf,
    u16* __restrict__ Wqhi, u16* __restrict__ Wqlo,
    u16* __restrict__ Wkhi, u16* __restrict__ Wklo)
{
  int blk = blockIdx.x, tid = threadIdx.x;
  if (blk < 768) {
    const float* s = (blk < 256) ? Wv : (blk < 512) ? Wvp : Wl;
    u16* d = (blk < 256) ? Wvbf : (blk < 512) ? Wvpbf : Wlbf;
    int i = ((blk & 255) * 256 + tid) * 4;
    float4 v = *(const float4*)(s + i);
    u16 o[4] = {f2bf(v.x), f2bf(v.y), f2bf(v.z), f2bf(v.w)};
    *(uint2*)(d + i) = *(const uint2*)o;
  } else {
    int bb = blk - 768;
    const float* s = (bb < 64) ? Wq : Wk;
    u16* dh = (bb < 64) ? Wqhi : Wkhi;
    u16* dl = (bb < 64) ? Wqlo : Wklo;
    int i = ((bb & 63) * 256 + tid) * 4;
    float4 v = *(const float4*)(s + i);
    float vv[4] = {v.x, v.y, v.z, v.w};
    u16 h[4], l[4];
#pragma unroll
    for (int r = 0; r < 4; r++) {
      h[r] = f2bf(vv[r]);
      l[r] = f2bf(vv[r] - bf2f(h[r]));
    }
    *(uint2*)(dh + i) = *(const uint2*)h;
    *(uint2*)(dl + i) = *(const uint2*)l;
  }
}

// ---------------------------------------------------------------------------
// Init transpose+split: y>>2 selects src (0=pca, 1=lrf).
__global__ __launch_bounds__(256) void k_xt2(
    const float* __restrict__ pca, const float* __restrict__ lrf,
    u16* __restrict__ pThi, u16* __restrict__ pTlo,
    u16* __restrict__ xThi, u16* __restrict__ xTlo)
{
  int nt = blockIdx.x, y = blockIdx.y, b = blockIdx.z;
  int ct = y & 3, is_lrf = y >> 2;
  const float* x = is_lrf ? lrf : pca;
  u16* hiT = is_lrf ? xThi : pThi;
  u16* loT = is_lrf ? xTlo : pTlo;
  __shared__ float tl[64][65];
  int tid = threadIdx.x;
  {
    int col = tid & 63, rq = tid >> 6;
    const float* src = x + (size_t)b * CH * NP + (size_t)(ct * 64) * NP + nt * 64;
#pragma unroll
    for (int i = 0; i < 16; i++) {
      int c = rq + i * 4;
      tl[col][c] = src[(size_t)c * NP + col];
    }
  }
  __syncthreads();
  {
    int cloc = tid & 63, nq = tid >> 6;
#pragma unroll
    for (int i = 0; i < 16; i++) {
      int n = nq + i * 4;
      float v = tl[n][cloc];
      u16 h = f2bf(v);
      u16 l = f2bf(v - bf2f(h));
      size_t off = ((size_t)b * NP + nt * 64 + n) * CH + ct * 64 + cloc;
      hiT[off] = h;
      loT[off] = l;
    }
  }
}

// ---------------------------------------------------------------------------
// E2A[l][b][m][o] = sum_d p2w[l][o][d]*emb2[b][m][d] + p2b[l][o], all layers.
__global__ __launch_bounds__(256) void k_e2_all(
    const float* __restrict__ ac, const float* __restrict__ p2w,
    const float* __restrict__ p2b, float* __restrict__ E2A)
{
  int l = blockIdx.y;
  const float* pwg = p2w + (size_t)l * DQ * DQ;
  const float* pbg = p2b + (size_t)l * DQ;
  float* E2 = E2A + (size_t)l * BB * NP * DQ;
  __shared__ float pw[DQ][65];
  __shared__ float emb[4][DQ];
  __shared__ float pb[DQ];
  int tid = threadIdx.x;
  int bm0 = blockIdx.x * 4;
#pragma unroll
  for (int i = 0; i < 16; i++) {
    int idx = tid + i * 256;
    pw[idx >> 6][idx & 63] = pwg[idx];
  }
  if (tid < DQ) pb[tid] = pbg[tid];
  if (tid < 128) {
    int ml = tid >> 5, j = tid & 31;
    float a = ac[bm0 + ml];
    float s, c;
    __sincosf(a * ANG_FACTOR * __expf(-(float)j * DIV_STEP), &s, &c);
    emb[ml][2 * j] = s;
    emb[ml][2 * j + 1] = c;
  }
  __syncthreads();
  int mloc = tid >> 6, o = tid & 63;
  float acc = pb[o];
#pragma unroll
  for (int d = 0; d < DQ; d++) acc = fmaf(pw[o][d], emb[mloc][d], acc);
  E2[(size_t)(bm0 + mloc) * DQ + o] = acc;
}

// ---------------------------------------------------------------------------
// Triple-MFMA (split-bf16) body, batched loads: 4 batches of 2 K-steps.
// 16 loads in flight per batch; 24 MFMA per batch.
#define TRIPLE_BODY(acc)                                                     \
  _Pragma("unroll")                                                          \
  for (int kb = 0; kb < 4; kb++) {                                           \
    sh8 rA0h[2], rA1h[2], rA0l[2], rA1l[2];                                  \
    sh8 rB0h[2], rB1h[2], rB0l[2], rB1l[2];                                  \
    _Pragma("unroll")                                                        \
    for (int u = 0; u < 2; u++) {                                            \
      int o = (kb * 2 + u) * 32;                                             \
      rA0h[u] = *(const sh8*)(A0h + o); rA1h[u] = *(const sh8*)(A1h + o);    \
      rA0l[u] = *(const sh8*)(A0l + o); rA1l[u] = *(const sh8*)(A1l + o);    \
      rB0h[u] = *(const sh8*)(B0h + o); rB1h[u] = *(const sh8*)(B1h + o);    \
      rB0l[u] = *(const sh8*)(B0l + o); rB1l[u] = *(const sh8*)(B1l + o);    \
    }                                                                        \
    _Pragma("unroll")                                                        \
    for (int u = 0; u < 2; u++) {                                            \
      acc[0][0] = MFMA(rA0h[u], rB0h[u], acc[0][0]);                         \
      acc[0][0] = MFMA(rA0h[u], rB0l[u], acc[0][0]);                         \
      acc[0][0] = MFMA(rA0l[u], rB0h[u], acc[0][0]);                         \
      acc[0][1] = MFMA(rA0h[u], rB1h[u], acc[0][1]);                         \
      acc[0][1] = MFMA(rA0h[u], rB1l[u], acc[0][1]);                         \
      acc[0][1] = MFMA(rA0l[u], rB1h[u], acc[0][1]);                         \
      acc[1][0] = MFMA(rA1h[u], rB0h[u], acc[1][0]);                         \
      acc[1][0] = MFMA(rA1h[u], rB0l[u], acc[1][0]);                         \
      acc[1][0] = MFMA(rA1l[u], rB0h[u], acc[1][0]);                         \
      acc[1][1] = MFMA(rA1h[u], rB1h[u], acc[1][1]);                         \
      acc[1][1] = MFMA(rA1h[u], rB1l[u], acc[1][1]);                         \
      acc[1][1] = MFMA(rA1l[u], rB1h[u], acc[1][1]);                         \
    }                                                                        \
  }

// Plain-MFMA body, batched loads: 2 batches of 4 K-steps. 16 loads/batch.
#define PLAIN_BODY8(a00, a01, a10, a11)                                      \
  _Pragma("unroll")                                                          \
  for (int kb = 0; kb < 2; kb++) {                                           \
    sh8 rA0[4], rA1[4], rB0[4], rB1[4];                                      \
    _Pragma("unroll")                                                        \
    for (int u = 0; u < 4; u++) {                                            \
      int o = (kb * 4 + u) * 32;                                             \
      rA0[u] = *(const sh8*)(A0 + o); rA1[u] = *(const sh8*)(A1 + o);        \
      rB0[u] = *(const sh8*)(B0 + o); rB1[u] = *(const sh8*)(B1 + o);        \
    }                                                                        \
    _Pragma("unroll")                                                        \
    for (int u = 0; u < 4; u++) {                                            \
      a00 = MFMA(rA0[u], rB0[u], a00);                                       \
      a01 = MFMA(rA0[u], rB1[u], a01);                                       \
      a10 = MFMA(rA1[u], rB0[u], a10);                                       \
      a11 = MFMA(rA1[u], rB1[u], a11);                                       \
    }                                                                        \
  }

// ---------------------------------------------------------------------------
// Precompute: blocks [0,512): KP2A[l] = split(Wq[l]@pca + E2A[l]);
// blocks [512,2560): UPA[l] = bf((1-bx[l])*Wvp[l]@pca).
__global__ __launch_bounds__(256) void k_pre(
    const u16* __restrict__ pThi, const u16* __restrict__ pTlo,
    const u16* __restrict__ Wqhi, const u16* __restrict__ Wqlo,
    const u16* __restrict__ Wvpbf, const float* __restrict__ E2A,
    const float* __restrict__ beta_x,
    u16* __restrict__ KP2hiA, u16* __restrict__ KP2loA, u16* __restrict__ UPA)
{
  int lane = threadIdx.x & 63;
  int lm = lane & 15, lk = lane >> 4;
  if (blockIdx.x < 512) {
    int wid = blockIdx.x * 4 + (threadIdx.x >> 6);   // 0..2047
    int l = wid >> 9, r = wid & 511;
    int b = r >> 3, t = r & 7, nt = t >> 1, dt = t & 1;
    const u16* A0h = Wqhi + (size_t)l * DQ * CH + ((size_t)(dt * 32) + lm) * CH + lk * 8;
    const u16* A1h = A0h + 16 * CH;
    const u16* A0l = Wqlo + (size_t)l * DQ * CH + ((size_t)(dt * 32) + lm) * CH + lk * 8;
    const u16* A1l = A0l + 16 * CH;
    const u16* B0h = pThi + ((size_t)b * NP + nt * 32 + lm) * CH + lk * 8;
    const u16* B1h = B0h + 16 * CH;
    const u16* B0l = pTlo + ((size_t)b * NP + nt * 32 + lm) * CH + lk * 8;
    const u16* B1l = B0l + 16 * CH;
    f32x4 acc[2][2] = {};
    TRIPLE_BODY(acc)
#pragma unroll
    for (int i = 0; i < 2; i++)
#pragma unroll
      for (int j = 0; j < 2; j++) {
        int n = nt * 32 + j * 16 + lm;
        int d0 = dt * 32 + i * 16 + lk * 4;
        size_t off = (((size_t)l * BB + b) * NP + n) * DQ + d0;
        f32x4 v = acc[i][j];
        float4 e = *(const float4*)&E2A[off];
        v[0] += e.x; v[1] += e.y; v[2] += e.z; v[3] += e.w;
        u16 h[4], lo[4];
#pragma unroll
        for (int r2 = 0; r2 < 4; r2++) {
          h[r2] = f2bf(v[r2]);
          lo[r2] = f2bf(v[r2] - bf2f(h[r2]));
        }
        *(uint2*)&KP2hiA[off] = *(const uint2*)h;
        *(uint2*)&KP2loA[off] = *(const uint2*)lo;
      }
  } else {
    int wid = (blockIdx.x - 512) * 4 + (threadIdx.x >> 6);  // 0..8191
    int l = wid >> 11, r = wid & 2047;
    int b = r >> 5, q = r & 31, nt = q >> 3, ct = q & 7;
    float obx = 1.0f - beta_x[l];
    const u16* A0 = pThi + ((size_t)b * NP + nt * 32 + lm) * CH + lk * 8;
    const u16* A1 = A0 + 16 * CH;
    const u16* B0 = Wvpbf + (size_t)l * CH * CH + ((size_t)(ct * 32) + lm) * CH + lk * 8;
    const u16* B1 = B0 + 16 * CH;
    f32x4 a00 = {}, a01 = {}, a10 = {}, a11 = {};
    PLAIN_BODY8(a00, a01, a10, a11)
    f32x4 acc[2][2] = {{a00, a01}, {a10, a11}};
#pragma unroll
    for (int i = 0; i < 2; i++)
#pragma unroll
      for (int j = 0; j < 2; j++) {
        int c = ct * 32 + j * 16 + lm;
        int n0 = nt * 32 + i * 16 + lk * 4;
        u16 ov[4];
#pragma unroll
        for (int r2 = 0; r2 < 4; r2++) ov[r2] = f2bf(obx * acc[i][j][r2]);
        *(uint2*)&UPA[(((size_t)l * BB + b) * CH + c) * NP + n0] = *(const uint2*)ov;
      }
  }
}

// ---------------------------------------------------------------------------
// Per-layer fused: blocks [0,256): split-bf16 QK projections; blocks
// [256,768): U = bf(bx*Wv@x) + UPA[l].
__global__ __launch_bounds__(256) void k_qu(
    const u16* __restrict__ xThi, const u16* __restrict__ xTlo,
    const u16* __restrict__ Wqhi, const u16* __restrict__ Wqlo,
    const u16* __restrict__ Wkhi, const u16* __restrict__ Wklo,
    const u16* __restrict__ Wv, const u16* __restrict__ UP,
    const float* __restrict__ beta_x, int layer,
    float* __restrict__ XQ, u16* __restrict__ XQhi, u16* __restrict__ XQlo,
    u16* __restrict__ KLThi, u16* __restrict__ KLTlo, u16* __restrict__ U)
{
  int lane = threadIdx.x & 63;
  int lm = lane & 15, lk = lane >> 4;
  if (blockIdx.x < 256) {
    int wid = blockIdx.x * 4 + (threadIdx.x >> 6);   // 0..1023
    int b = wid >> 4, q = wid & 15;
    int mat = q >> 3, t = q & 7, nt = t >> 1, dt = t & 1;
    const u16* Ah = mat ? Wkhi : Wqhi;
    const u16* Al = mat ? Wklo : Wqlo;
    const u16* A0h = Ah + ((size_t)(dt * 32) + lm) * CH + lk * 8;
    const u16* A1h = A0h + 16 * CH;
    const u16* A0l = Al + ((size_t)(dt * 32) + lm) * CH + lk * 8;
    const u16* A1l = A0l + 16 * CH;
    const u16* B0h = xThi + ((size_t)b * NP + nt * 32 + lm) * CH + lk * 8;
    const u16* B1h = B0h + 16 * CH;
    const u16* B0l = xTlo + ((size_t)b * NP + nt * 32 + lm) * CH + lk * 8;
    const u16* B1l = B0l + 16 * CH;
    f32x4 acc[2][2] = {};
    TRIPLE_BODY(acc)
#pragma unroll
    for (int i = 0; i < 2; i++)
#pragma unroll
      for (int j = 0; j < 2; j++) {
        int n = nt * 32 + j * 16 + lm;
        int d0 = dt * 32 + i * 16 + lk * 4;
        size_t off = ((size_t)b * NP + n) * DQ + d0;
        f32x4 v = acc[i][j];
        u16 h[4], lo[4];
#pragma unroll
        for (int r2 = 0; r2 < 4; r2++) {
          h[r2] = f2bf(v[r2]);
          lo[r2] = f2bf(v[r2] - bf2f(h[r2]));
        }
        if (mat == 0) {
          float4 vo = {v[0], v[1], v[2], v[3]};
          *(float4*)&XQ[off] = vo;
          *(uint2*)&XQhi[off] = *(const uint2*)h;
          *(uint2*)&XQlo[off] = *(const uint2*)lo;
        } else {
          *(uint2*)&KLThi[off] = *(const uint2*)h;
          *(uint2*)&KLTlo[off] = *(const uint2*)lo;
        }
      }
  } else {
    int wid = (blockIdx.x - 256) * 4 + (threadIdx.x >> 6);  // 0..2047
    int b = wid >> 5, q = wid & 31, nt = q >> 3, ct = q & 7;
    float bx = beta_x[layer];
    const u16* A0 = xThi + ((size_t)b * NP + nt * 32 + lm) * CH + lk * 8;
    const u16* A1 = A0 + 16 * CH;
    const u16* B0 = Wv + ((size_t)(ct * 32) + lm) * CH + lk * 8;
    const u16* B1 = B0 + 16 * CH;
    f32x4 a00 = {}, a01 = {}, a10 = {}, a11 = {};
    PLAIN_BODY8(a00, a01, a10, a11)
    f32x4 acc[2][2] = {{a00, a01}, {a10, a11}};
#pragma unroll
    for (int i = 0; i < 2; i++)
#pragma unroll
      for (int j = 0; j < 2; j++) {
        int c = ct * 32 + j * 16 + lm;
        int n0 = nt * 32 + i * 16 + lk * 4;
        size_t off = ((size_t)b * CH + c) * NP + n0;
        uint2 up = *(const uint2*)&UP[off];
        const u16* uph = (const u16*)&up;
        u16 ov[4];
#pragma unroll
        for (int r2 = 0; r2 < 4; r2++)
          ov[r2] = f2bf(bx * acc[i][j][r2] + bf2f(uph[r2]));
        *(uint2*)&U[off] = *(const uint2*)ov;
      }
  }
}

// ---------------------------------------------------------------------------
// Per-layer fused: blocks [0,256): split-bf16 energy; [256,320): q1c1.
__global__ __launch_bounds__(256) void k_eq(
    const float* __restrict__ XQ,
    const u16* __restrict__ XQhi, const u16* __restrict__ XQlo,
    const u16* __restrict__ KLThi, const u16* __restrict__ KLTlo,
    const u16* __restrict__ KP2hi, const u16* __restrict__ KP2lo,
    const float* __restrict__ beta_w, int layer, float* __restrict__ EN,
    const float* __restrict__ p1w, const float* __restrict__ p1b,
    float* __restrict__ Q1, float* __restrict__ C1)
{
  if (blockIdx.x < 256) {
    int wid = blockIdx.x * 4 + (threadIdx.x >> 6);
    int lane = threadIdx.x & 63;
    int b = wid >> 4, q = wid & 15;
    int mt = q >> 2, ntl = q & 3;
    int lm = lane & 15, lk = lane >> 4;
    size_t arow = ((size_t)b * NP + mt * 32 + lm) * DQ + lk * 8;
    size_t brow = ((size_t)b * NP + ntl * 32 + lm) * DQ + lk * 8;
    const u16* L0h = KLThi + arow;
    const u16* L0l = KLTlo + arow;
    const u16* P0h = KP2hi + arow;
    const u16* P0l = KP2lo + arow;
    const u16* X0h = XQhi + brow;
    const u16* X0l = XQlo + brow;
    // batch-load ALL operands (24 sh8) up front: one latency round-trip.
    sh8 xh[2][2], xl[2][2], lh[2][2], ll[2][2], ph[2][2], pl[2][2];
#pragma unroll
    for (int row = 0; row < 2; row++) {
#pragma unroll
      for (int ks = 0; ks < 2; ks++) {
        int o = row * 16 * DQ + ks * 32;
        xh[row][ks] = *(const sh8*)(X0h + o);
        xl[row][ks] = *(const sh8*)(X0l + o);
        lh[row][ks] = *(const sh8*)(L0h + o);
        ll[row][ks] = *(const sh8*)(L0l + o);
        ph[row][ks] = *(const sh8*)(P0h + o);
        pl[row][ks] = *(const sh8*)(P0l + o);
      }
    }
    f32x4 aL[2][2] = {};
    f32x4 aP[2][2] = {};
#pragma unroll
    for (int ks = 0; ks < 2; ks++) {
#pragma unroll
      for (int i = 0; i < 2; i++) {
#pragma unroll
        for (int j = 0; j < 2; j++) {
          aL[i][j] = MFMA(lh[i][ks], xh[j][ks], aL[i][j]);
          aL[i][j] = MFMA(lh[i][ks], xl[j][ks], aL[i][j]);
          aL[i][j] = MFMA(ll[i][ks], xh[j][ks], aL[i][j]);
          aP[i][j] = MFMA(ph[i][ks], xh[j][ks], aP[i][j]);
          aP[i][j] = MFMA(ph[i][ks], xl[j][ks], aP[i][j]);
          aP[i][j] = MFMA(pl[i][ks], xh[j][ks], aP[i][j]);
        }
      }
    }
    float bw = beta_w[layer], obw = 1.0f - bw;
#pragma unroll
    for (int i = 0; i < 2; i++)
#pragma unroll
      for (int j = 0; j < 2; j++) {
        int n = ntl * 32 + j * 16 + lm;
        int m0 = mt * 32 + i * 16 + lk * 4;
        float4 v;
        v.x = bw * aL[i][j][0] + obw * aP[i][j][0];
        v.y = bw * aL[i][j][1] + obw * aP[i][j][1];
        v.z = bw * aL[i][j][2] + obw * aP[i][j][2];
        v.w = bw * aL[i][j][3] + obw * aP[i][j][3];
        *(float4*)&EN[((size_t)b * NP + n) * NP + m0] = v;
      }
  } else {
    int b = blockIdx.x - 256, tid = threadIdx.x;
    __shared__ float xqs[NP][65];
    __shared__ float pw[DQ][65];
    __shared__ float pb[DQ];
#pragma unroll
    for (int i = 0; i < 32; i++) {
      int idx = tid + i * 256;
      xqs[idx >> 6][idx & 63] = XQ[(size_t)b * NP * DQ + idx];
    }
#pragma unroll
    for (int i = 0; i < 16; i++) {
      int idx = tid + i * 256;
      pw[idx >> 6][idx & 63] = p1w[idx];
    }
    if (tid < DQ) pb[tid] = p1b[tid];
    __syncthreads();
    int n = tid >> 1, d0 = (tid & 1) * 32;
    float acc[32] = {};
    float cacc = 0.0f;
    for (int o = 0; o < DQ; o++) {
      float xv = xqs[n][o];
      cacc = fmaf(pb[o], xv, cacc);
#pragma unroll
      for (int dd = 0; dd < 32; dd++) acc[dd] = fmaf(pw[o][d0 + dd], xv, acc[dd]);
    }
#pragma unroll
    for (int dd = 0; dd < 32; dd += 4) {
      float4 v = {acc[dd], acc[dd + 1], acc[dd + 2], acc[dd + 3]};
      *(float4*)&Q1[((size_t)b * NP + n) * DQ + d0 + dd] = v;
    }
    if ((tid & 1) == 0) C1[b * NP + n] = cacc;
  }
}

// ---------------------------------------------------------------------------
// P = softmax_m(EN + bw*(q1.emb1 + c1)); in place into EN.
__global__ __launch_bounds__(128) void k_bias(
    float* __restrict__ EN, const float* __restrict__ Q1,
    const float* __restrict__ C1, const float* __restrict__ AS,
    const float* __restrict__ beta_w, int layer)
{
  int blk = blockIdx.x;
  int b = blk >> 7, n = blk & 127;
  int m = threadIdx.x;
  __shared__ float q1s[DQ];
  __shared__ float divs[32];
  __shared__ float xred[2];
  __shared__ float sred[2];
  if (m < DQ) q1s[m] = Q1[((size_t)b * NP + n) * DQ + m];
  if (m >= 96) divs[m - 96] = __expf(-(float)(m - 96) * DIV_STEP);
  __syncthreads();
  float bw = beta_w[layer];
  size_t row = ((size_t)b * NP + n) * NP;
  float E = EN[row + m];
  float bias = C1[b * NP + n];
  float idxv = AS[row + m] * ANG_FACTOR;
#pragma unroll
  for (int j = 0; j < 32; j++) {
    float s, c;
    __sincosf(idxv * divs[j], &s, &c);
    bias = fmaf(q1s[2 * j], s, bias);
    bias = fmaf(q1s[2 * j + 1], c, bias);
  }
  E += bw * bias;
  float v = E;
#pragma unroll
  for (int off = 32; off; off >>= 1) v = fmaxf(v, __shfl_xor(v, off));
  if ((m & 63) == 0) xred[m >> 6] = v;
  __syncthreads();
  float mx = fmaxf(xred[0], xred[1]);
  float p = __expf(E - mx);
  v = p;
#pragma unroll
  for (int off = 32; off; off >>= 1) v += __shfl_xor(v, off);
  if ((m & 63) == 0) sred[m >> 6] = v;
  __syncthreads();
  float s = sred[0] + sred[1];
  EN[row + m] = p / s;
}

// ---------------------------------------------------------------------------
// P fp32 [b][n][m] -> PT bf16 [b][m][n]; SCL[b][m] = 1/(1e-12 + sum_n P[n][m])
__global__ __launch_bounds__(256) void k_pt(const float* __restrict__ EN,
                                            u16* __restrict__ PT,
                                            float* __restrict__ SCL)
{
  int mt = blockIdx.x, b = blockIdx.y;
  __shared__ float tl[128][33];
  int tid = threadIdx.x;
  {
    int ml = tid & 31, nr = tid >> 5;
    const float* src = EN + (size_t)b * NP * NP + mt * 32;
#pragma unroll
    for (int i = 0; i < 16; i++) {
      int n = nr + i * 8;
      tl[n][ml] = src[(size_t)n * NP + ml];
    }
  }
  __syncthreads();
  int m = tid >> 3, nc = (tid & 7) * 16;
  float s = 0.0f;
  u16 tmp[16];
#pragma unroll
  for (int k = 0; k < 16; k++) {
    float v = tl[nc + k][m];
    s += v;
    tmp[k] = f2bf(v);
  }
  u16* dst = PT + ((size_t)b * NP + mt * 32 + m) * NP + nc;
  *(uint4*)&dst[0] = *(const uint4*)&tmp[0];
  *(uint4*)&dst[8] = *(const uint4*)&tmp[8];
  s += __shfl_xor(s, 1);
  s += __shfl_xor(s, 2);
  s += __shfl_xor(s, 4);
  if ((tid & 7) == 0) SCL[b * NP + mt * 32 + m] = 1.0f / (1e-12f + s);
}

// ---------------------------------------------------------------------------
// MFMA: T^T[b][m][c] = bf(x^T[m][c]) - (sum_n U[c][n] PT[m][n]) * SCL[m]
__global__ __launch_bounds__(256) void k_t_m(
    const u16* __restrict__ U, const u16* __restrict__ PT,
    const float* __restrict__ SCL, const u16* __restrict__ xT,
    u16* __restrict__ TT)
{
  int wid = blockIdx.x * 4 + (threadIdx.x >> 6);
  int lane = threadIdx.x & 63;
  int b = wid >> 5, q = wid & 31;
  int ct = q >> 2, mt = q & 3;
  int lm = lane & 15, lk = lane >> 4;
  const u16* A0 = U + ((size_t)b * CH + ct * 32 + lm) * NP + lk * 8;
  const u16* A1 = A0 + 16 * NP;
  const u16* B0 = PT + ((size_t)b * NP + mt * 32 + lm) * NP + lk * 8;
  const u16* B1 = B0 + 16 * NP;
  // batch-load all 16 operands, then MFMA.
  sh8 rA0[4], rA1[4], rB0[4], rB1[4];
#pragma unroll
  for (int ks = 0; ks < 4; ks++) {
    int o = ks * 32;
    rA0[ks] = *(const sh8*)(A0 + o);
    rA1[ks] = *(const sh8*)(A1 + o);
    rB0[ks] = *(const sh8*)(B0 + o);
    rB1[ks] = *(const sh8*)(B1 + o);
  }
  f32x4 a00 = {}, a01 = {}, a10 = {}, a11 = {};
#pragma unroll
  for (int ks = 0; ks < 4; ks++) {
    a00 = MFMA(rA0[ks], rB0[ks], a00);
    a01 = MFMA(rA0[ks], rB1[ks], a01);
    a10 = MFMA(rA1[ks], rB0[ks], a10);
    a11 = MFMA(rA1[ks], rB1[ks], a11);
  }
  f32x4 acc[2][2] = {{a00, a01}, {a10, a11}};
#pragma unroll
  for (int i = 0; i < 2; i++)
#pragma unroll
    for (int j = 0; j < 2; j++) {
      int m = mt * 32 + j * 16 + lm;
      int c0 = ct * 32 + i * 16 + lk * 4;
      float scl = SCL[b * NP + m];
      uint2 xv = *(const uint2*)(xT + ((size_t)b * NP + m) * CH + c0);
      const u16* xh = (const u16*)&xv;
      u16 ov[4];
#pragma unroll
      for (int r = 0; r < 4; r++)
        ov[r] = f2bf(bf2f(xh[r]) - acc[i][j][r] * scl);
      *(uint2*)&TT[((size_t)b * NP + m) * CH + c0] = *(const uint2*)ov;
    }
}

// ---------------------------------------------------------------------------
// MFMA: out = x + gelu(BN(Wl@T + bl)); also writes next layer's xT hi/lo.
__global__ __launch_bounds__(256) void k_h_m(
    const u16* __restrict__ Wl, const u16* __restrict__ TT,
    const float* __restrict__ bl, const float* __restrict__ bng,
    const float* __restrict__ bnb, const float* __restrict__ xsrc, int xbs,
    float* __restrict__ out, int layer,
    u16* __restrict__ xThi_o, u16* __restrict__ xTlo_o)
{
  int wid = blockIdx.x * 4 + (threadIdx.x >> 6);
  int lane = threadIdx.x & 63;
  int b = wid >> 5, q = wid & 31;
  int ct = q >> 2, nt = q & 3;
  int lm = lane & 15, lk = lane >> 4;
  const u16* A0 = Wl + ((size_t)(ct * 32) + lm) * CH + lk * 8;
  const u16* A1 = A0 + 16 * CH;
  const u16* B0 = TT + ((size_t)b * NP + nt * 32 + lm) * CH + lk * 8;
  const u16* B1 = B0 + 16 * CH;
  f32x4 a00 = {}, a01 = {}, a10 = {}, a11 = {};
  PLAIN_BODY8(a00, a01, a10, a11)
  f32x4 acc[2][2] = {{a00, a01}, {a10, a11}};
  const float rbn = 0.999995000037499687f;  // 1/sqrt(1+1e-5)
#pragma unroll
  for (int i = 0; i < 2; i++)
#pragma unroll
    for (int j = 0; j < 2; j++) {
      int n = nt * 32 + j * 16 + lm;
      int cb = ct * 32 + i * 16 + lk * 4;
      u16 hh[4], ll[4];
#pragma unroll
      for (int r = 0; r < 4; r++) {
        int c = cb + r;
        float h = acc[i][j][r] + bl[c];
        h = h * rbn * bng[c] + bnb[c];
        float g = 0.5f * h * (1.0f + erff(h * 0.70710678118654752440f));
        float ov = xsrc[(size_t)b * xbs + (size_t)c * NP + n] + g;
        out[((size_t)b * 4 * CH + (size_t)layer * CH + c) * NP + n] = ov;
        hh[r] = f2bf(ov);
        ll[r] = f2bf(ov - bf2f(hh[r]));
      }
      size_t xoff = ((size_t)b * NP + n) * CH + cb;
      *(uint2*)&xThi_o[xoff] = *(const uint2*)hh;
      *(uint2*)&xTlo_o[xoff] = *(const uint2*)ll;
    }
}

// ---------------------------------------------------------------------------
extern "C" void kernel_launch(void* const* d_in, const int* in_sizes, int n_in,
                              void* d_out, int out_size, void* d_ws, size_t ws_size,
                              hipStream_t stream)
{
  (void)in_sizes; (void)n_in; (void)out_size; (void)ws_size;
  const float* lrf     = (const float*)d_in[0];
  const float* pca     = (const float*)d_in[1];
  const float* a_self  = (const float*)d_in[2];
  const float* a_cross = (const float*)d_in[3];
  const float* Wq  = (const float*)d_in[4];
  const float* Wk  = (const float*)d_in[5];
  const float* Wv  = (const float*)d_in[6];
  const float* Wvp = (const float*)d_in[7];
  const float* Wl  = (const float*)d_in[8];
  const float* bl  = (const float*)d_in[9];
  const float* bng = (const float*)d_in[10];
  const float* bnb = (const float*)d_in[11];
  const float* p1w = (const float*)d_in[12];
  const float* p1b = (const float*)d_in[13];
  const float* p2w = (const float*)d_in[14];
  const float* p2b = (const float*)d_in[15];
  const float* beta_x = (const float*)d_in[16];
  const float* beta_w = (const float*)d_in[17];
  float* out = (float*)d_out;
  float* ws  = (float*)d_ws;

  // ---- workspace carve ----
  const size_t QKN = (size_t)BB * NP * DQ;        // 524288
  const size_t ENN = (size_t)BB * NP * NP;        // 1048576
  const size_t XCN = (size_t)BB * NP * CH;        // 2097152 (u16 count)

  float* XQ  = ws;
  float* Q1  = XQ + QKN;
  float* C1  = Q1 + QKN;
  float* EN  = C1 + (size_t)BB * NP;
  float* SCL = EN + ENN;
  float* E2A = SCL + (size_t)BB * NP;
  u16* up = (u16*)(E2A + (size_t)NLAYERS * QKN);
  u16* xThi = up;   up += XCN;
  u16* xTlo = up;   up += XCN;
  u16* pThi = up;   up += XCN;
  u16* pTlo = up;   up += XCN;
  u16* XQhi = up;   up += QKN;
  u16* XQlo = up;   up += QKN;
  u16* KLThi = up;  up += QKN;
  u16* KLTlo = up;  up += QKN;
  u16* KP2hiA = up; up += (size_t)NLAYERS * QKN;
  u16* KP2loA = up; up += (size_t)NLAYERS * QKN;
  u16* UPA = up;    up += (size_t)NLAYERS * BB * CH * NP;
  u16* Ubf = up;    up += (size_t)BB * CH * NP;
  u16* PTbf = up;   up += ENN;
  u16* TbfT = up;   up += XCN;
  u16* Wvbf = up;   up += (size_t)NLAYERS * CH * CH;
  u16* Wvpbf = up;  up += (size_t)NLAYERS * CH * CH;
  u16* Wlbf = up;   up += (size_t)NLAYERS * CH * CH;
  u16* Wqhi = up;   up += (size_t)NLAYERS * DQ * CH;
  u16* Wqlo = up;   up += (size_t)NLAYERS * DQ * CH;
  u16* Wkhi = up;   up += (size_t)NLAYERS * DQ * CH;
  u16* Wklo = up;   up += (size_t)NLAYERS * DQ * CH;

  // ---- pre-loop (4 launches) ----
  k_cvt_all<<<dim3(896), 256, 0, stream>>>(
      Wv, Wvp, Wl, Wq, Wk, Wvbf, Wvpbf, Wlbf, Wqhi, Wqlo, Wkhi, Wklo);
  k_xt2<<<dim3(2, 8, BB), 256, 0, stream>>>(pca, lrf, pThi, pTlo, xThi, xTlo);
  k_e2_all<<<dim3(BB * NP / 4, NLAYERS), 256, 0, stream>>>(a_cross, p2w, p2b, E2A);
  k_pre<<<dim3(2560), 256, 0, stream>>>(
      pThi, pTlo, Wqhi, Wqlo, Wvpbf, E2A, beta_x, KP2hiA, KP2loA, UPA);

  // ---- layer loop (6 launches each) ----
  for (int l = 0; l < NLAYERS; l++) {
    const float* xsrc = (l == 0) ? lrf : (out + (size_t)(l - 1) * CH * NP);
    int xbs = (l == 0) ? CH * NP : 4 * CH * NP;
    k_qu<<<dim3(768), 256, 0, stream>>>(
        xThi, xTlo,
        Wqhi + (size_t)l * DQ * CH, Wqlo + (size_t)l * DQ * CH,
        Wkhi + (size_t)l * DQ * CH, Wklo + (size_t)l * DQ * CH,
        Wvbf + (size_t)l * CH * CH, UPA + (size_t)l * BB * CH * NP,
        beta_x, l, XQ, XQhi, XQlo, KLThi, KLTlo, Ubf);
    k_eq<<<dim3(320), 256, 0, stream>>>(
        XQ, XQhi, XQlo, KLThi, KLTlo,
        KP2hiA + (size_t)l * QKN, KP2loA + (size_t)l * QKN,
        beta_w, l, EN, p1w + (size_t)l * DQ * DQ, p1b + (size_t)l * DQ, Q1, C1);
    k_bias<<<dim3(BB * NP), 128, 0, stream>>>(EN, Q1, C1, a_self, beta_w, l);
    k_pt<<<dim3(4, BB), 256, 0, stream>>>(EN, PTbf, SCL);
    k_t_m<<<dim3(512), 256, 0, stream>>>(Ubf, PTbf, SCL, xThi, TbfT);
    k_h_m<<<dim3(512), 256, 0, stream>>>(
        Wlbf + (size_t)l * CH * CH, TbfT, bl + (size_t)l * CH,
        bng + (size_t)l * CH, bnb + (size_t)l * CH, xsrc, xbs, out, l,
        xThi, xTlo);
  }
}

// Round 8
// 358.568 us; speedup vs baseline: 2.4836x; 1.1216x over previous
//
#include <hip/hip_runtime.h>
#include <cstdint>
#include <cstddef>

// Round 8: LDS weight staging for all W-GEMMs. R7 lesson: compiler re-serializes
// register load batches (VGPR=48); instead, stage the shared 32-row weight tile
// in padded LDS (+8 u16/row -> 2-way max conflicts, free) once per block, 4
// waves share it. Halves (plain) / halves (triple: 8->4) the serialized global
// streams and frees VGPRs for the x-side loads. Math unchanged; absmax должен
// stay 0.125.

#define BB 64      // batch
#define CH 256     // channels
#define NP 128     // points
#define DQ 64      // q/k dim
#define NLAYERS 4

#define ANG_FACTOR 3.8197186342054885f   // 180/(pi*15) = 12/pi
#define DIV_STEP   0.28782313662425575f  // ln(10000)/32

#define LROW 264   // padded LDS row stride in u16 (528B = 33*16B, 16B aligned)

typedef unsigned short u16;
typedef __attribute__((ext_vector_type(8))) short sh8;   // 8 bf16 = 4 VGPR
typedef __attribute__((ext_vector_type(4))) float f32x4; // MFMA C/D
#define MFMA(a, b, c) __builtin_amdgcn_mfma_f32_16x16x32_bf16(a, b, c, 0, 0, 0)

static __device__ __forceinline__ u16 f2bf(float x) {
  unsigned u = __float_as_uint(x);
  return (u16)((u + 0x7FFFu + ((u >> 16) & 1u)) >> 16);
}
static __device__ __forceinline__ float bf2f(u16 h) {
  return __uint_as_float(((unsigned)h) << 16);
}

// ---------------------------------------------------------------------------
// One-time weight conversions, all merged.
__global__ __launch_bounds__(256) void k_cvt_all(
    const float* __restrict__ Wv, const float* __restrict__ Wvp,
    const float* __restrict__ Wl, const float* __restrict__ Wq,
    const float* __restrict__ Wk, u16* __restrict__ Wvbf,
    u16* __restrict__ Wvpbf, u16* __restrict__ Wlbf,
    u16* __restrict__ Wqhi, u16* __restrict__ Wqlo,
    u16* __restrict__ Wkhi, u16* __restrict__ Wklo)
{
  int blk = blockIdx.x, tid = threadIdx.x;
  if (blk < 768) {
    const float* s = (blk < 256) ? Wv : (blk < 512) ? Wvp : Wl;
    u16* d = (blk < 256) ? Wvbf : (blk < 512) ? Wvpbf : Wlbf;
    int i = ((blk & 255) * 256 + tid) * 4;
    float4 v = *(const float4*)(s + i);
    u16 o[4] = {f2bf(v.x), f2bf(v.y), f2bf(v.z), f2bf(v.w)};
    *(uint2*)(d + i) = *(const uint2*)o;
  } else {
    int bb = blk - 768;
    const float* s = (bb < 64) ? Wq : Wk;
    u16* dh = (bb < 64) ? Wqhi : Wkhi;
    u16* dl = (bb < 64) ? Wqlo : Wklo;
    int i = ((bb & 63) * 256 + tid) * 4;
    float4 v = *(const float4*)(s + i);
    float vv[4] = {v.x, v.y, v.z, v.w};
    u16 h[4], l[4];
#pragma unroll
    for (int r = 0; r < 4; r++) {
      h[r] = f2bf(vv[r]);
      l[r] = f2bf(vv[r] - bf2f(h[r]));
    }
    *(uint2*)(dh + i) = *(const uint2*)h;
    *(uint2*)(dl + i) = *(const uint2*)l;
  }
}

// ---------------------------------------------------------------------------
// Init transpose+split: y>>2 selects src (0=pca, 1=lrf).
__global__ __launch_bounds__(256) void k_xt2(
    const float* __restrict__ pca, const float* __restrict__ lrf,
    u16* __restrict__ pThi, u16* __restrict__ pTlo,
    u16* __restrict__ xThi, u16* __restrict__ xTlo)
{
  int nt = blockIdx.x, y = blockIdx.y, b = blockIdx.z;
  int ct = y & 3, is_lrf = y >> 2;
  const float* x = is_lrf ? lrf : pca;
  u16* hiT = is_lrf ? xThi : pThi;
  u16* loT = is_lrf ? xTlo : pTlo;
  __shared__ float tl[64][65];
  int tid = threadIdx.x;
  {
    int col = tid & 63, rq = tid >> 6;
    const float* src = x + (size_t)b * CH * NP + (size_t)(ct * 64) * NP + nt * 64;
#pragma unroll
    for (int i = 0; i < 16; i++) {
      int c = rq + i * 4;
      tl[col][c] = src[(size_t)c * NP + col];
    }
  }
  __syncthreads();
  {
    int cloc = tid & 63, nq = tid >> 6;
#pragma unroll
    for (int i = 0; i < 16; i++) {
      int n = nq + i * 4;
      float v = tl[n][cloc];
      u16 h = f2bf(v);
      u16 l = f2bf(v - bf2f(h));
      size_t off = ((size_t)b * NP + nt * 64 + n) * CH + ct * 64 + cloc;
      hiT[off] = h;
      loT[off] = l;
    }
  }
}

// ---------------------------------------------------------------------------
// E2A[l][b][m][o] = sum_d p2w[l][o][d]*emb2[b][m][d] + p2b[l][o], all layers.
__global__ __launch_bounds__(256) void k_e2_all(
    const float* __restrict__ ac, const float* __restrict__ p2w,
    const float* __restrict__ p2b, float* __restrict__ E2A)
{
  int l = blockIdx.y;
  const float* pwg = p2w + (size_t)l * DQ * DQ;
  const float* pbg = p2b + (size_t)l * DQ;
  float* E2 = E2A + (size_t)l * BB * NP * DQ;
  __shared__ float pw[DQ][65];
  __shared__ float emb[4][DQ];
  __shared__ float pb[DQ];
  int tid = threadIdx.x;
  int bm0 = blockIdx.x * 4;
#pragma unroll
  for (int i = 0; i < 16; i++) {
    int idx = tid + i * 256;
    pw[idx >> 6][idx & 63] = pwg[idx];
  }
  if (tid < DQ) pb[tid] = pbg[tid];
  if (tid < 128) {
    int ml = tid >> 5, j = tid & 31;
    float a = ac[bm0 + ml];
    float s, c;
    __sincosf(a * ANG_FACTOR * __expf(-(float)j * DIV_STEP), &s, &c);
    emb[ml][2 * j] = s;
    emb[ml][2 * j + 1] = c;
  }
  __syncthreads();
  int mloc = tid >> 6, o = tid & 63;
  float acc = pb[o];
#pragma unroll
  for (int d = 0; d < DQ; d++) acc = fmaf(pw[o][d], emb[mloc][d], acc);
  E2[(size_t)(bm0 + mloc) * DQ + o] = acc;
}

// ---------------------------------------------------------------------------
// Stage 32 rows x 256 u16 of W into padded LDS [32][LROW]. Coalesced 16B.
#define STAGE_W(dst, src)                                                    \
  _Pragma("unroll")                                                          \
  for (int it = 0; it < 4; it++) {                                           \
    int idx = threadIdx.x + it * 256, row = idx >> 5, ch = idx & 31;         \
    *(uint4*)&dst[row * LROW + ch * 8] =                                     \
        *(const uint4*)(src + row * 256 + ch * 8);                           \
  }

// ---------------------------------------------------------------------------
// KP2A[l] = split(Wq[l]@pca + E2A[l]).  512 blocks = 4l*2dt*64b; 4 waves = nt.
// W hi/lo staged in LDS; pca hi/lo streamed from global (4 streams).
__global__ __launch_bounds__(256) void k_pre_kp2(
    const u16* __restrict__ pThi, const u16* __restrict__ pTlo,
    const u16* __restrict__ Wqhi, const u16* __restrict__ Wqlo,
    const float* __restrict__ E2A,
    u16* __restrict__ KP2hiA, u16* __restrict__ KP2loA)
{
  int bi = blockIdx.x;
  int l = bi >> 7, rest = bi & 127;
  int dt = rest >> 6, b = rest & 63;
  int tid = threadIdx.x, lane = tid & 63, nt = tid >> 6;
  int lm = lane & 15, lk = lane >> 4;
  __shared__ __align__(16) u16 WH[32 * LROW];
  __shared__ __align__(16) u16 WL[32 * LROW];
  {
    const u16* sH = Wqhi + (size_t)l * DQ * CH + (size_t)dt * 32 * CH;
    const u16* sL = Wqlo + (size_t)l * DQ * CH + (size_t)dt * 32 * CH;
    STAGE_W(WH, sH)
    STAGE_W(WL, sL)
  }
  __syncthreads();
  const u16* B0h = pThi + ((size_t)b * NP + nt * 32 + lm) * CH + lk * 8;
  const u16* B1h = B0h + 16 * CH;
  const u16* B0l = pTlo + ((size_t)b * NP + nt * 32 + lm) * CH + lk * 8;
  const u16* B1l = B0l + 16 * CH;
  f32x4 acc[2][2] = {};
#pragma unroll
  for (int kb = 0; kb < 4; kb++) {
    sh8 rb0h[2], rb1h[2], rb0l[2], rb1l[2];
#pragma unroll
    for (int u = 0; u < 2; u++) {
      int o = (kb * 2 + u) * 32;
      rb0h[u] = *(const sh8*)(B0h + o); rb1h[u] = *(const sh8*)(B1h + o);
      rb0l[u] = *(const sh8*)(B0l + o); rb1l[u] = *(const sh8*)(B1l + o);
    }
#pragma unroll
    for (int u = 0; u < 2; u++) {
      int o2 = (kb * 2 + u) * 32 + lk * 8;
      sh8 a0h = *(const sh8*)&WH[lm * LROW + o2];
      sh8 a1h = *(const sh8*)&WH[(16 + lm) * LROW + o2];
      sh8 a0l = *(const sh8*)&WL[lm * LROW + o2];
      sh8 a1l = *(const sh8*)&WL[(16 + lm) * LROW + o2];
      acc[0][0] = MFMA(a0h, rb0h[u], acc[0][0]);
      acc[0][0] = MFMA(a0h, rb0l[u], acc[0][0]);
      acc[0][0] = MFMA(a0l, rb0h[u], acc[0][0]);
      acc[0][1] = MFMA(a0h, rb1h[u], acc[0][1]);
      acc[0][1] = MFMA(a0h, rb1l[u], acc[0][1]);
      acc[0][1] = MFMA(a0l, rb1h[u], acc[0][1]);
      acc[1][0] = MFMA(a1h, rb0h[u], acc[1][0]);
      acc[1][0] = MFMA(a1h, rb0l[u], acc[1][0]);
      acc[1][0] = MFMA(a1l, rb0h[u], acc[1][0]);
      acc[1][1] = MFMA(a1h, rb1h[u], acc[1][1]);
      acc[1][1] = MFMA(a1h, rb1l[u], acc[1][1]);
      acc[1][1] = MFMA(a1l, rb1h[u], acc[1][1]);
    }
  }
#pragma unroll
  for (int i = 0; i < 2; i++)
#pragma unroll
    for (int j = 0; j < 2; j++) {
      int n = nt * 32 + j * 16 + lm;
      int d0 = dt * 32 + i * 16 + lk * 4;
      size_t off = (((size_t)l * BB + b) * NP + n) * DQ + d0;
      f32x4 v = acc[i][j];
      float4 e = *(const float4*)&E2A[off];
      v[0] += e.x; v[1] += e.y; v[2] += e.z; v[3] += e.w;
      u16 h[4], lo[4];
#pragma unroll
      for (int r2 = 0; r2 < 4; r2++) {
        h[r2] = f2bf(v[r2]);
        lo[r2] = f2bf(v[r2] - bf2f(h[r2]));
      }
      *(uint2*)&KP2hiA[off] = *(const uint2*)h;
      *(uint2*)&KP2loA[off] = *(const uint2*)lo;
    }
}

// ---------------------------------------------------------------------------
// UPA[l] = bf((1-bx[l])*Wvp[l]@pca).  2048 blocks = 4l*8ct*64b; 4 waves = nt.
// W staged in LDS (second operand); pca streamed (first operand).
__global__ __launch_bounds__(256) void k_pre_up(
    const u16* __restrict__ pThi, const u16* __restrict__ Wvpbf,
    const float* __restrict__ beta_x, u16* __restrict__ UPA)
{
  int bi = blockIdx.x;
  int l = bi >> 9, rest = bi & 511;
  int ct = rest >> 6, b = rest & 63;
  int tid = threadIdx.x, lane = tid & 63, nt = tid >> 6;
  int lm = lane & 15, lk = lane >> 4;
  __shared__ __align__(16) u16 WH[32 * LROW];
  {
    const u16* sH = Wvpbf + (size_t)l * CH * CH + (size_t)ct * 32 * CH;
    STAGE_W(WH, sH)
  }
  __syncthreads();
  float obx = 1.0f - beta_x[l];
  const u16* X0 = pThi + ((size_t)b * NP + nt * 32 + lm) * CH + lk * 8;
  const u16* X1 = X0 + 16 * CH;
  f32x4 a00 = {}, a01 = {}, a10 = {}, a11 = {};
#pragma unroll
  for (int kb = 0; kb < 2; kb++) {
    sh8 rx0[4], rx1[4];
#pragma unroll
    for (int u = 0; u < 4; u++) {
      int o = (kb * 4 + u) * 32;
      rx0[u] = *(const sh8*)(X0 + o); rx1[u] = *(const sh8*)(X1 + o);
    }
#pragma unroll
    for (int u = 0; u < 4; u++) {
      int o2 = (kb * 4 + u) * 32 + lk * 8;
      sh8 w0 = *(const sh8*)&WH[lm * LROW + o2];
      sh8 w1 = *(const sh8*)&WH[(16 + lm) * LROW + o2];
      a00 = MFMA(rx0[u], w0, a00);
      a01 = MFMA(rx0[u], w1, a01);
      a10 = MFMA(rx1[u], w0, a10);
      a11 = MFMA(rx1[u], w1, a11);
    }
  }
  f32x4 acc[2][2] = {{a00, a01}, {a10, a11}};
#pragma unroll
  for (int i = 0; i < 2; i++)
#pragma unroll
    for (int j = 0; j < 2; j++) {
      int c = ct * 32 + j * 16 + lm;
      int n0 = nt * 32 + i * 16 + lk * 4;
      u16 ov[4];
#pragma unroll
      for (int r2 = 0; r2 < 4; r2++) ov[r2] = f2bf(obx * acc[i][j][r2]);
      *(uint2*)&UPA[(((size_t)l * BB + b) * CH + c) * NP + n0] = *(const uint2*)ov;
    }
}

// ---------------------------------------------------------------------------
// Per-layer split-bf16 QK projections: 256 blocks = 2mat*2dt*64b; waves = nt.
// mat0: XQ fp32+hi/lo = Wq@x; mat1: KLT hi/lo = Wk@x.
__global__ __launch_bounds__(256) void k_qk2(
    const u16* __restrict__ xThi, const u16* __restrict__ xTlo,
    const u16* __restrict__ Wqhi, const u16* __restrict__ Wqlo,
    const u16* __restrict__ Wkhi, const u16* __restrict__ Wklo,
    float* __restrict__ XQ, u16* __restrict__ XQhi, u16* __restrict__ XQlo,
    u16* __restrict__ KLThi, u16* __restrict__ KLTlo)
{
  int bi = blockIdx.x;
  int mat = bi >> 7, rest = bi & 127;
  int dt = rest >> 6, b = rest & 63;
  int tid = threadIdx.x, lane = tid & 63, nt = tid >> 6;
  int lm = lane & 15, lk = lane >> 4;
  __shared__ __align__(16) u16 WH[32 * LROW];
  __shared__ __align__(16) u16 WL[32 * LROW];
  {
    const u16* sH = (mat ? Wkhi : Wqhi) + (size_t)dt * 32 * CH;
    const u16* sL = (mat ? Wklo : Wqlo) + (size_t)dt * 32 * CH;
    STAGE_W(WH, sH)
    STAGE_W(WL, sL)
  }
  __syncthreads();
  const u16* B0h = xThi + ((size_t)b * NP + nt * 32 + lm) * CH + lk * 8;
  const u16* B1h = B0h + 16 * CH;
  const u16* B0l = xTlo + ((size_t)b * NP + nt * 32 + lm) * CH + lk * 8;
  const u16* B1l = B0l + 16 * CH;
  f32x4 acc[2][2] = {};
#pragma unroll
  for (int kb = 0; kb < 4; kb++) {
    sh8 rb0h[2], rb1h[2], rb0l[2], rb1l[2];
#pragma unroll
    for (int u = 0; u < 2; u++) {
      int o = (kb * 2 + u) * 32;
      rb0h[u] = *(const sh8*)(B0h + o); rb1h[u] = *(const sh8*)(B1h + o);
      rb0l[u] = *(const sh8*)(B0l + o); rb1l[u] = *(const sh8*)(B1l + o);
    }
#pragma unroll
    for (int u = 0; u < 2; u++) {
      int o2 = (kb * 2 + u) * 32 + lk * 8;
      sh8 a0h = *(const sh8*)&WH[lm * LROW + o2];
      sh8 a1h = *(const sh8*)&WH[(16 + lm) * LROW + o2];
      sh8 a0l = *(const sh8*)&WL[lm * LROW + o2];
      sh8 a1l = *(const sh8*)&WL[(16 + lm) * LROW + o2];
      acc[0][0] = MFMA(a0h, rb0h[u], acc[0][0]);
      acc[0][0] = MFMA(a0h, rb0l[u], acc[0][0]);
      acc[0][0] = MFMA(a0l, rb0h[u], acc[0][0]);
      acc[0][1] = MFMA(a0h, rb1h[u], acc[0][1]);
      acc[0][1] = MFMA(a0h, rb1l[u], acc[0][1]);
      acc[0][1] = MFMA(a0l, rb1h[u], acc[0][1]);
      acc[1][0] = MFMA(a1h, rb0h[u], acc[1][0]);
      acc[1][0] = MFMA(a1h, rb0l[u], acc[1][0]);
      acc[1][0] = MFMA(a1l, rb0h[u], acc[1][0]);
      acc[1][1] = MFMA(a1h, rb1h[u], acc[1][1]);
      acc[1][1] = MFMA(a1h, rb1l[u], acc[1][1]);
      acc[1][1] = MFMA(a1l, rb1h[u], acc[1][1]);
    }
  }
#pragma unroll
  for (int i = 0; i < 2; i++)
#pragma unroll
    for (int j = 0; j < 2; j++) {
      int n = nt * 32 + j * 16 + lm;
      int d0 = dt * 32 + i * 16 + lk * 4;
      size_t off = ((size_t)b * NP + n) * DQ + d0;
      f32x4 v = acc[i][j];
      u16 h[4], lo[4];
#pragma unroll
      for (int r2 = 0; r2 < 4; r2++) {
        h[r2] = f2bf(v[r2]);
        lo[r2] = f2bf(v[r2] - bf2f(h[r2]));
      }
      if (mat == 0) {
        float4 vo = {v[0], v[1], v[2], v[3]};
        *(float4*)&XQ[off] = vo;
        *(uint2*)&XQhi[off] = *(const uint2*)h;
        *(uint2*)&XQlo[off] = *(const uint2*)lo;
      } else {
        *(uint2*)&KLThi[off] = *(const uint2*)h;
        *(uint2*)&KLTlo[off] = *(const uint2*)lo;
      }
    }
}

// ---------------------------------------------------------------------------
// Per-layer U = bf(bx*Wv@x) + UPA[l].  512 blocks = 8ct*64b; waves = nt.
__global__ __launch_bounds__(256) void k_u2(
    const u16* __restrict__ xThi, const u16* __restrict__ Wv,
    const u16* __restrict__ UP, const float* __restrict__ beta_x, int layer,
    u16* __restrict__ U)
{
  int bi = blockIdx.x;
  int ct = bi >> 6, b = bi & 63;
  int tid = threadIdx.x, lane = tid & 63, nt = tid >> 6;
  int lm = lane & 15, lk = lane >> 4;
  __shared__ __align__(16) u16 WH[32 * LROW];
  {
    const u16* sH = Wv + (size_t)ct * 32 * CH;
    STAGE_W(WH, sH)
  }
  __syncthreads();
  float bx = beta_x[layer];
  const u16* X0 = xThi + ((size_t)b * NP + nt * 32 + lm) * CH + lk * 8;
  const u16* X1 = X0 + 16 * CH;
  f32x4 a00 = {}, a01 = {}, a10 = {}, a11 = {};
#pragma unroll
  for (int kb = 0; kb < 2; kb++) {
    sh8 rx0[4], rx1[4];
#pragma unroll
    for (int u = 0; u < 4; u++) {
      int o = (kb * 4 + u) * 32;
      rx0[u] = *(const sh8*)(X0 + o); rx1[u] = *(const sh8*)(X1 + o);
    }
#pragma unroll
    for (int u = 0; u < 4; u++) {
      int o2 = (kb * 4 + u) * 32 + lk * 8;
      sh8 w0 = *(const sh8*)&WH[lm * LROW + o2];
      sh8 w1 = *(const sh8*)&WH[(16 + lm) * LROW + o2];
      a00 = MFMA(rx0[u], w0, a00);
      a01 = MFMA(rx0[u], w1, a01);
      a10 = MFMA(rx1[u], w0, a10);
      a11 = MFMA(rx1[u], w1, a11);
    }
  }
  f32x4 acc[2][2] = {{a00, a01}, {a10, a11}};
#pragma unroll
  for (int i = 0; i < 2; i++)
#pragma unroll
    for (int j = 0; j < 2; j++) {
      int c = ct * 32 + j * 16 + lm;
      int n0 = nt * 32 + i * 16 + lk * 4;
      size_t off = ((size_t)b * CH + c) * NP + n0;
      uint2 up = *(const uint2*)&UP[off];
      const u16* uph = (const u16*)&up;
      u16 ov[4];
#pragma unroll
      for (int r2 = 0; r2 < 4; r2++)
        ov[r2] = f2bf(bx * acc[i][j][r2] + bf2f(uph[r2]));
      *(uint2*)&U[off] = *(const uint2*)ov;
    }
}

// ---------------------------------------------------------------------------
// Per-layer fused: blocks [0,256): split-bf16 energy; [256,320): q1c1.
__global__ __launch_bounds__(256) void k_eq(
    const float* __restrict__ XQ,
    const u16* __restrict__ XQhi, const u16* __restrict__ XQlo,
    const u16* __restrict__ KLThi, const u16* __restrict__ KLTlo,
    const u16* __restrict__ KP2hi, const u16* __restrict__ KP2lo,
    const float* __restrict__ beta_w, int layer, float* __restrict__ EN,
    const float* __restrict__ p1w, const float* __restrict__ p1b,
    float* __restrict__ Q1, float* __restrict__ C1)
{
  if (blockIdx.x < 256) {
    int wid = blockIdx.x * 4 + (threadIdx.x >> 6);
    int lane = threadIdx.x & 63;
    int b = wid >> 4, q = wid & 15;
    int mt = q >> 2, ntl = q & 3;
    int lm = lane & 15, lk = lane >> 4;
    size_t arow = ((size_t)b * NP + mt * 32 + lm) * DQ + lk * 8;
    size_t brow = ((size_t)b * NP + ntl * 32 + lm) * DQ + lk * 8;
    const u16* L0h = KLThi + arow;
    const u16* L0l = KLTlo + arow;
    const u16* P0h = KP2hi + arow;
    const u16* P0l = KP2lo + arow;
    const u16* X0h = XQhi + brow;
    const u16* X0l = XQlo + brow;
    sh8 xh[2][2], xl[2][2], lh[2][2], ll[2][2], ph[2][2], pl[2][2];
#pragma unroll
    for (int row = 0; row < 2; row++) {
#pragma unroll
      for (int ks = 0; ks < 2; ks++) {
        int o = row * 16 * DQ + ks * 32;
        xh[row][ks] = *(const sh8*)(X0h + o);
        xl[row][ks] = *(const sh8*)(X0l + o);
        lh[row][ks] = *(const sh8*)(L0h + o);
        ll[row][ks] = *(const sh8*)(L0l + o);
        ph[row][ks] = *(const sh8*)(P0h + o);
        pl[row][ks] = *(const sh8*)(P0l + o);
      }
    }
    f32x4 aL[2][2] = {};
    f32x4 aP[2][2] = {};
#pragma unroll
    for (int ks = 0; ks < 2; ks++) {
#pragma unroll
      for (int i = 0; i < 2; i++) {
#pragma unroll
        for (int j = 0; j < 2; j++) {
          aL[i][j] = MFMA(lh[i][ks], xh[j][ks], aL[i][j]);
          aL[i][j] = MFMA(lh[i][ks], xl[j][ks], aL[i][j]);
          aL[i][j] = MFMA(ll[i][ks], xh[j][ks], aL[i][j]);
          aP[i][j] = MFMA(ph[i][ks], xh[j][ks], aP[i][j]);
          aP[i][j] = MFMA(ph[i][ks], xl[j][ks], aP[i][j]);
          aP[i][j] = MFMA(pl[i][ks], xh[j][ks], aP[i][j]);
        }
      }
    }
    float bw = beta_w[layer], obw = 1.0f - bw;
#pragma unroll
    for (int i = 0; i < 2; i++)
#pragma unroll
      for (int j = 0; j < 2; j++) {
        int n = ntl * 32 + j * 16 + lm;
        int m0 = mt * 32 + i * 16 + lk * 4;
        float4 v;
        v.x = bw * aL[i][j][0] + obw * aP[i][j][0];
        v.y = bw * aL[i][j][1] + obw * aP[i][j][1];
        v.z = bw * aL[i][j][2] + obw * aP[i][j][2];
        v.w = bw * aL[i][j][3] + obw * aP[i][j][3];
        *(float4*)&EN[((size_t)b * NP + n) * NP + m0] = v;
      }
  } else {
    int b = blockIdx.x - 256, tid = threadIdx.x;
    __shared__ float xqs[NP][65];
    __shared__ float pw[DQ][65];
    __shared__ float pb[DQ];
#pragma unroll
    for (int i = 0; i < 32; i++) {
      int idx = tid + i * 256;
      xqs[idx >> 6][idx & 63] = XQ[(size_t)b * NP * DQ + idx];
    }
#pragma unroll
    for (int i = 0; i < 16; i++) {
      int idx = tid + i * 256;
      pw[idx >> 6][idx & 63] = p1w[idx];
    }
    if (tid < DQ) pb[tid] = p1b[tid];
    __syncthreads();
    int n = tid >> 1, d0 = (tid & 1) * 32;
    float acc[32] = {};
    float cacc = 0.0f;
    for (int o = 0; o < DQ; o++) {
      float xv = xqs[n][o];
      cacc = fmaf(pb[o], xv, cacc);
#pragma unroll
      for (int dd = 0; dd < 32; dd++) acc[dd] = fmaf(pw[o][d0 + dd], xv, acc[dd]);
    }
#pragma unroll
    for (int dd = 0; dd < 32; dd += 4) {
      float4 v = {acc[dd], acc[dd + 1], acc[dd + 2], acc[dd + 3]};
      *(float4*)&Q1[((size_t)b * NP + n) * DQ + d0 + dd] = v;
    }
    if ((tid & 1) == 0) C1[b * NP + n] = cacc;
  }
}

// ---------------------------------------------------------------------------
// P = softmax_m(EN + bw*(q1.emb1 + c1)); in place into EN.
__global__ __launch_bounds__(128) void k_bias(
    float* __restrict__ EN, const float* __restrict__ Q1,
    const float* __restrict__ C1, const float* __restrict__ AS,
    const float* __restrict__ beta_w, int layer)
{
  int blk = blockIdx.x;
  int b = blk >> 7, n = blk & 127;
  int m = threadIdx.x;
  __shared__ float q1s[DQ];
  __shared__ float divs[32];
  __shared__ float xred[2];
  __shared__ float sred[2];
  if (m < DQ) q1s[m] = Q1[((size_t)b * NP + n) * DQ + m];
  if (m >= 96) divs[m - 96] = __expf(-(float)(m - 96) * DIV_STEP);
  __syncthreads();
  float bw = beta_w[layer];
  size_t row = ((size_t)b * NP + n) * NP;
  float E = EN[row + m];
  float bias = C1[b * NP + n];
  float idxv = AS[row + m] * ANG_FACTOR;
#pragma unroll
  for (int j = 0; j < 32; j++) {
    float s, c;
    __sincosf(idxv * divs[j], &s, &c);
    bias = fmaf(q1s[2 * j], s, bias);
    bias = fmaf(q1s[2 * j + 1], c, bias);
  }
  E += bw * bias;
  float v = E;
#pragma unroll
  for (int off = 32; off; off >>= 1) v = fmaxf(v, __shfl_xor(v, off));
  if ((m & 63) == 0) xred[m >> 6] = v;
  __syncthreads();
  float mx = fmaxf(xred[0], xred[1]);
  float p = __expf(E - mx);
  v = p;
#pragma unroll
  for (int off = 32; off; off >>= 1) v += __shfl_xor(v, off);
  if ((m & 63) == 0) sred[m >> 6] = v;
  __syncthreads();
  float s = sred[0] + sred[1];
  EN[row + m] = p / s;
}

// ---------------------------------------------------------------------------
// P fp32 [b][n][m] -> PT bf16 [b][m][n]; SCL[b][m] = 1/(1e-12 + sum_n P[n][m])
__global__ __launch_bounds__(256) void k_pt(const float* __restrict__ EN,
                                            u16* __restrict__ PT,
                                            float* __restrict__ SCL)
{
  int mt = blockIdx.x, b = blockIdx.y;
  __shared__ float tl[128][33];
  int tid = threadIdx.x;
  {
    int ml = tid & 31, nr = tid >> 5;
    const float* src = EN + (size_t)b * NP * NP + mt * 32;
#pragma unroll
    for (int i = 0; i < 16; i++) {
      int n = nr + i * 8;
      tl[n][ml] = src[(size_t)n * NP + ml];
    }
  }
  __syncthreads();
  int m = tid >> 3, nc = (tid & 7) * 16;
  float s = 0.0f;
  u16 tmp[16];
#pragma unroll
  for (int k = 0; k < 16; k++) {
    float v = tl[nc + k][m];
    s += v;
    tmp[k] = f2bf(v);
  }
  u16* dst = PT + ((size_t)b * NP + mt * 32 + m) * NP + nc;
  *(uint4*)&dst[0] = *(const uint4*)&tmp[0];
  *(uint4*)&dst[8] = *(const uint4*)&tmp[8];
  s += __shfl_xor(s, 1);
  s += __shfl_xor(s, 2);
  s += __shfl_xor(s, 4);
  if ((tid & 7) == 0) SCL[b * NP + mt * 32 + m] = 1.0f / (1e-12f + s);
}

// ---------------------------------------------------------------------------
// MFMA: T^T[b][m][c] = bf(x^T[m][c]) - (sum_n U[c][n] PT[m][n]) * SCL[m]
__global__ __launch_bounds__(256) void k_t_m(
    const u16* __restrict__ U, const u16* __restrict__ PT,
    const float* __restrict__ SCL, const u16* __restrict__ xT,
    u16* __restrict__ TT)
{
  int wid = blockIdx.x * 4 + (threadIdx.x >> 6);
  int lane = threadIdx.x & 63;
  int b = wid >> 5, q = wid & 31;
  int ct = q >> 2, mt = q & 3;
  int lm = lane & 15, lk = lane >> 4;
  const u16* A0 = U + ((size_t)b * CH + ct * 32 + lm) * NP + lk * 8;
  const u16* A1 = A0 + 16 * NP;
  const u16* B0 = PT + ((size_t)b * NP + mt * 32 + lm) * NP + lk * 8;
  const u16* B1 = B0 + 16 * NP;
  sh8 rA0[4], rA1[4], rB0[4], rB1[4];
#pragma unroll
  for (int ks = 0; ks < 4; ks++) {
    int o = ks * 32;
    rA0[ks] = *(const sh8*)(A0 + o);
    rA1[ks] = *(const sh8*)(A1 + o);
    rB0[ks] = *(const sh8*)(B0 + o);
    rB1[ks] = *(const sh8*)(B1 + o);
  }
  f32x4 a00 = {}, a01 = {}, a10 = {}, a11 = {};
#pragma unroll
  for (int ks = 0; ks < 4; ks++) {
    a00 = MFMA(rA0[ks], rB0[ks], a00);
    a01 = MFMA(rA0[ks], rB1[ks], a01);
    a10 = MFMA(rA1[ks], rB0[ks], a10);
    a11 = MFMA(rA1[ks], rB1[ks], a11);
  }
  f32x4 acc[2][2] = {{a00, a01}, {a10, a11}};
#pragma unroll
  for (int i = 0; i < 2; i++)
#pragma unroll
    for (int j = 0; j < 2; j++) {
      int m = mt * 32 + j * 16 + lm;
      int c0 = ct * 32 + i * 16 + lk * 4;
      float scl = SCL[b * NP + m];
      uint2 xv = *(const uint2*)(xT + ((size_t)b * NP + m) * CH + c0);
      const u16* xh = (const u16*)&xv;
      u16 ov[4];
#pragma unroll
      for (int r = 0; r < 4; r++)
        ov[r] = f2bf(bf2f(xh[r]) - acc[i][j][r] * scl);
      *(uint2*)&TT[((size_t)b * NP + m) * CH + c0] = *(const uint2*)ov;
    }
}

// ---------------------------------------------------------------------------
// out = x + gelu(BN(Wl@T + bl)); also writes next layer's xT hi/lo.
// 512 blocks = 8ct*64b; waves = nt. Wl staged in LDS (first operand).
__global__ __launch_bounds__(256) void k_h2(
    const u16* __restrict__ Wl, const u16* __restrict__ TT,
    const float* __restrict__ bl, const float* __restrict__ bng,
    const float* __restrict__ bnb, const float* __restrict__ xsrc, int xbs,
    float* __restrict__ out, int layer,
    u16* __restrict__ xThi_o, u16* __restrict__ xTlo_o)
{
  int bi = blockIdx.x;
  int ct = bi >> 6, b = bi & 63;
  int tid = threadIdx.x, lane = tid & 63, nt = tid >> 6;
  int lm = lane & 15, lk = lane >> 4;
  __shared__ __align__(16) u16 WH[32 * LROW];
  {
    const u16* sH = Wl + (size_t)ct * 32 * CH;
    STAGE_W(WH, sH)
  }
  __syncthreads();
  const u16* B0 = TT + ((size_t)b * NP + nt * 32 + lm) * CH + lk * 8;
  const u16* B1 = B0 + 16 * CH;
  f32x4 a00 = {}, a01 = {}, a10 = {}, a11 = {};
#pragma unroll
  for (int kb = 0; kb < 2; kb++) {
    sh8 rt0[4], rt1[4];
#pragma unroll
    for (int u = 0; u < 4; u++) {
      int o = (kb * 4 + u) * 32;
      rt0[u] = *(const sh8*)(B0 + o); rt1[u] = *(const sh8*)(B1 + o);
    }
#pragma unroll
    for (int u = 0; u < 4; u++) {
      int o2 = (kb * 4 + u) * 32 + lk * 8;
      sh8 w0 = *(const sh8*)&WH[lm * LROW + o2];
      sh8 w1 = *(const sh8*)&WH[(16 + lm) * LROW + o2];
      a00 = MFMA(w0, rt0[u], a00);
      a01 = MFMA(w0, rt1[u], a01);
      a10 = MFMA(w1, rt0[u], a10);
      a11 = MFMA(w1, rt1[u], a11);
    }
  }
  f32x4 acc[2][2] = {{a00, a01}, {a10, a11}};
  const float rbn = 0.999995000037499687f;  // 1/sqrt(1+1e-5)
#pragma unroll
  for (int i = 0; i < 2; i++)
#pragma unroll
    for (int j = 0; j < 2; j++) {
      int n = nt * 32 + j * 16 + lm;
      int cb = ct * 32 + i * 16 + lk * 4;
      u16 hh[4], llv[4];
#pragma unroll
      for (int r = 0; r < 4; r++) {
        int c = cb + r;
        float h = acc[i][j][r] + bl[c];
        h = h * rbn * bng[c] + bnb[c];
        float g = 0.5f * h * (1.0f + erff(h * 0.70710678118654752440f));
        float ov = xsrc[(size_t)b * xbs + (size_t)c * NP + n] + g;
        out[((size_t)b * 4 * CH + (size_t)layer * CH + c) * NP + n] = ov;
        hh[r] = f2bf(ov);
        llv[r] = f2bf(ov - bf2f(hh[r]));
      }
      size_t xoff = ((size_t)b * NP + n) * CH + cb;
      *(uint2*)&xThi_o[xoff] = *(const uint2*)hh;
      *(uint2*)&xTlo_o[xoff] = *(const uint2*)llv;
    }
}

// ---------------------------------------------------------------------------
extern "C" void kernel_launch(void* const* d_in, const int* in_sizes, int n_in,
                              void* d_out, int out_size, void* d_ws, size_t ws_size,
                              hipStream_t stream)
{
  (void)in_sizes; (void)n_in; (void)out_size; (void)ws_size;
  const float* lrf     = (const float*)d_in[0];
  const float* pca     = (const float*)d_in[1];
  const float* a_self  = (const float*)d_in[2];
  const float* a_cross = (const float*)d_in[3];
  const float* Wq  = (const float*)d_in[4];
  const float* Wk  = (const float*)d_in[5];
  const float* Wv  = (const float*)d_in[6];
  const float* Wvp = (const float*)d_in[7];
  const float* Wl  = (const float*)d_in[8];
  const float* bl  = (const float*)d_in[9];
  const float* bng = (const float*)d_in[10];
  const float* bnb = (const float*)d_in[11];
  const float* p1w = (const float*)d_in[12];
  const float* p1b = (const float*)d_in[13];
  const float* p2w = (const float*)d_in[14];
  const float* p2b = (const float*)d_in[15];
  const float* beta_x = (const float*)d_in[16];
  const float* beta_w = (const float*)d_in[17];
  float* out = (float*)d_out;
  float* ws  = (float*)d_ws;

  // ---- workspace carve ----
  const size_t QKN = (size_t)BB * NP * DQ;        // 524288
  const size_t ENN = (size_t)BB * NP * NP;        // 1048576
  const size_t XCN = (size_t)BB * NP * CH;        // 2097152 (u16 count)

  float* XQ  = ws;
  float* Q1  = XQ + QKN;
  float* C1  = Q1 + QKN;
  float* EN  = C1 + (size_t)BB * NP;
  float* SCL = EN + ENN;
  float* E2A = SCL + (size_t)BB * NP;
  u16* up = (u16*)(E2A + (size_t)NLAYERS * QKN);
  u16* xThi = up;   up += XCN;
  u16* xTlo = up;   up += XCN;
  u16* pThi = up;   up += XCN;
  u16* pTlo = up;   up += XCN;
  u16* XQhi = up;   up += QKN;
  u16* XQlo = up;   up += QKN;
  u16* KLThi = up;  up += QKN;
  u16* KLTlo = up;  up += QKN;
  u16* KP2hiA = up; up += (size_t)NLAYERS * QKN;
  u16* KP2loA = up; up += (size_t)NLAYERS * QKN;
  u16* UPA = up;    up += (size_t)NLAYERS * BB * CH * NP;
  u16* Ubf = up;    up += (size_t)BB * CH * NP;
  u16* PTbf = up;   up += ENN;
  u16* TbfT = up;   up += XCN;
  u16* Wvbf = up;   up += (size_t)NLAYERS * CH * CH;
  u16* Wvpbf = up;  up += (size_t)NLAYERS * CH * CH;
  u16* Wlbf = up;   up += (size_t)NLAYERS * CH * CH;
  u16* Wqhi = up;   up += (size_t)NLAYERS * DQ * CH;
  u16* Wqlo = up;   up += (size_t)NLAYERS * DQ * CH;
  u16* Wkhi = up;   up += (size_t)NLAYERS * DQ * CH;
  u16* Wklo = up;   up += (size_t)NLAYERS * DQ * CH;

  // ---- pre-loop (5 launches) ----
  k_cvt_all<<<dim3(896), 256, 0, stream>>>(
      Wv, Wvp, Wl, Wq, Wk, Wvbf, Wvpbf, Wlbf, Wqhi, Wqlo, Wkhi, Wklo);
  k_xt2<<<dim3(2, 8, BB), 256, 0, stream>>>(pca, lrf, pThi, pTlo, xThi, xTlo);
  k_e2_all<<<dim3(BB * NP / 4, NLAYERS), 256, 0, stream>>>(a_cross, p2w, p2b, E2A);
  k_pre_kp2<<<dim3(512), 256, 0, stream>>>(
      pThi, pTlo, Wqhi, Wqlo, E2A, KP2hiA, KP2loA);
  k_pre_up<<<dim3(2048), 256, 0, stream>>>(pThi, Wvpbf, beta_x, UPA);

  // ---- layer loop (7 launches each) ----
  for (int l = 0; l < NLAYERS; l++) {
    const float* xsrc = (l == 0) ? lrf : (out + (size_t)(l - 1) * CH * NP);
    int xbs = (l == 0) ? CH * NP : 4 * CH * NP;
    k_qk2<<<dim3(256), 256, 0, stream>>>(
        xThi, xTlo,
        Wqhi + (size_t)l * DQ * CH, Wqlo + (size_t)l * DQ * CH,
        Wkhi + (size_t)l * DQ * CH, Wklo + (size_t)l * DQ * CH,
        XQ, XQhi, XQlo, KLThi, KLTlo);
    k_u2<<<dim3(512), 256, 0, stream>>>(
        xThi, Wvbf + (size_t)l * CH * CH, UPA + (size_t)l * BB * CH * NP,
        beta_x, l, Ubf);
    k_eq<<<dim3(320), 256, 0, stream>>>(
        XQ, XQhi, XQlo, KLThi, KLTlo,
        KP2hiA + (size_t)l * QKN, KP2loA + (size_t)l * QKN,
        beta_w, l, EN, p1w + (size_t)l * DQ * DQ, p1b + (size_t)l * DQ, Q1, C1);
    k_bias<<<dim3(BB * NP), 128, 0, stream>>>(EN, Q1, C1, a_self, beta_w, l);
    k_pt<<<dim3(4, BB), 256, 0, stream>>>(EN, PTbf, SCL);
    k_t_m<<<dim3(512), 256, 0, stream>>>(Ubf, PTbf, SCL, xThi, TbfT);
    k_h2<<<dim3(512), 256, 0, stream>>>(
        Wlbf + (size_t)l * CH * CH, TbfT, bl + (size_t)l * CH,
        bng + (size_t)l * CH, bnb + (size_t)l * CH, xsrc, xbs, out, l,
        xThi, xTlo);
  }
}

// Round 9
// 274.495 us; speedup vs baseline: 3.2443x; 1.3063x over previous
//
#include <hip/hip_runtime.h>
#include <cstdint>
#include <cstddef>

// Round 9: fusion round. k_eq+k_bias+k_pt -> k_att (one kernel: energy MFMA ->
// LDS, in-block q1/c1, bias+softmax, P^T bf16 + colsum partials). EN/Q1/C1
// buffers eliminated. k_qk2+k_u2 merged (union LDS); k_pre_* re-merged.
// Dispatches 33 -> 20. Math and reduction order unchanged -> absmax 0.125.

#define BB 64      // batch
#define CH 256     // channels
#define NP 128     // points
#define DQ 64      // q/k dim
#define NLAYERS 4

#define ANG_FACTOR 3.8197186342054885f   // 180/(pi*15) = 12/pi
#define DIV_STEP   0.28782313662425575f  // ln(10000)/32

#define LROW 264   // padded LDS row stride in u16 (528B, 16B aligned)

typedef unsigned short u16;
typedef __attribute__((ext_vector_type(8))) short sh8;   // 8 bf16 = 4 VGPR
typedef __attribute__((ext_vector_type(4))) float f32x4; // MFMA C/D
#define MFMA(a, b, c) __builtin_amdgcn_mfma_f32_16x16x32_bf16(a, b, c, 0, 0, 0)

static __device__ __forceinline__ u16 f2bf(float x) {
  unsigned u = __float_as_uint(x);
  return (u16)((u + 0x7FFFu + ((u >> 16) & 1u)) >> 16);
}
static __device__ __forceinline__ float bf2f(u16 h) {
  return __uint_as_float(((unsigned)h) << 16);
}

// ---------------------------------------------------------------------------
// One-time weight conversions, all merged.
__global__ __launch_bounds__(256) void k_cvt_all(
    const float* __restrict__ Wv, const float* __restrict__ Wvp,
    const float* __restrict__ Wl, const float* __restrict__ Wq,
    const float* __restrict__ Wk, u16* __restrict__ Wvbf,
    u16* __restrict__ Wvpbf, u16* __restrict__ Wlbf,
    u16* __restrict__ Wqhi, u16* __restrict__ Wqlo,
    u16* __restrict__ Wkhi, u16* __restrict__ Wklo)
{
  int blk = blockIdx.x, tid = threadIdx.x;
  if (blk < 768) {
    const float* s = (blk < 256) ? Wv : (blk < 512) ? Wvp : Wl;
    u16* d = (blk < 256) ? Wvbf : (blk < 512) ? Wvpbf : Wlbf;
    int i = ((blk & 255) * 256 + tid) * 4;
    float4 v = *(const float4*)(s + i);
    u16 o[4] = {f2bf(v.x), f2bf(v.y), f2bf(v.z), f2bf(v.w)};
    *(uint2*)(d + i) = *(const uint2*)o;
  } else {
    int bb = blk - 768;
    const float* s = (bb < 64) ? Wq : Wk;
    u16* dh = (bb < 64) ? Wqhi : Wkhi;
    u16* dl = (bb < 64) ? Wqlo : Wklo;
    int i = ((bb & 63) * 256 + tid) * 4;
    float4 v = *(const float4*)(s + i);
    float vv[4] = {v.x, v.y, v.z, v.w};
    u16 h[4], l[4];
#pragma unroll
    for (int r = 0; r < 4; r++) {
      h[r] = f2bf(vv[r]);
      l[r] = f2bf(vv[r] - bf2f(h[r]));
    }
    *(uint2*)(dh + i) = *(const uint2*)h;
    *(uint2*)(dl + i) = *(const uint2*)l;
  }
}

// ---------------------------------------------------------------------------
// Init transpose+split: y>>2 selects src (0=pca, 1=lrf).
__global__ __launch_bounds__(256) void k_xt2(
    const float* __restrict__ pca, const float* __restrict__ lrf,
    u16* __restrict__ pThi, u16* __restrict__ pTlo,
    u16* __restrict__ xThi, u16* __restrict__ xTlo)
{
  int nt = blockIdx.x, y = blockIdx.y, b = blockIdx.z;
  int ct = y & 3, is_lrf = y >> 2;
  const float* x = is_lrf ? lrf : pca;
  u16* hiT = is_lrf ? xThi : pThi;
  u16* loT = is_lrf ? xTlo : pTlo;
  __shared__ float tl[64][65];
  int tid = threadIdx.x;
  {
    int col = tid & 63, rq = tid >> 6;
    const float* src = x + (size_t)b * CH * NP + (size_t)(ct * 64) * NP + nt * 64;
#pragma unroll
    for (int i = 0; i < 16; i++) {
      int c = rq + i * 4;
      tl[col][c] = src[(size_t)c * NP + col];
    }
  }
  __syncthreads();
  {
    int cloc = tid & 63, nq = tid >> 6;
#pragma unroll
    for (int i = 0; i < 16; i++) {
      int n = nq + i * 4;
      float v = tl[n][cloc];
      u16 h = f2bf(v);
      u16 l = f2bf(v - bf2f(h));
      size_t off = ((size_t)b * NP + nt * 64 + n) * CH + ct * 64 + cloc;
      hiT[off] = h;
      loT[off] = l;
    }
  }
}

// ---------------------------------------------------------------------------
// E2A[l][b][m][o] = sum_d p2w[l][o][d]*emb2[b][m][d] + p2b[l][o], all layers.
__global__ __launch_bounds__(256) void k_e2_all(
    const float* __restrict__ ac, const float* __restrict__ p2w,
    const float* __restrict__ p2b, float* __restrict__ E2A)
{
  int l = blockIdx.y;
  const float* pwg = p2w + (size_t)l * DQ * DQ;
  const float* pbg = p2b + (size_t)l * DQ;
  float* E2 = E2A + (size_t)l * BB * NP * DQ;
  __shared__ float pw[DQ][65];
  __shared__ float emb[4][DQ];
  __shared__ float pb[DQ];
  int tid = threadIdx.x;
  int bm0 = blockIdx.x * 4;
#pragma unroll
  for (int i = 0; i < 16; i++) {
    int idx = tid + i * 256;
    pw[idx >> 6][idx & 63] = pwg[idx];
  }
  if (tid < DQ) pb[tid] = pbg[tid];
  if (tid < 128) {
    int ml = tid >> 5, j = tid & 31;
    float a = ac[bm0 + ml];
    float s, c;
    __sincosf(a * ANG_FACTOR * __expf(-(float)j * DIV_STEP), &s, &c);
    emb[ml][2 * j] = s;
    emb[ml][2 * j + 1] = c;
  }
  __syncthreads();
  int mloc = tid >> 6, o = tid & 63;
  float acc = pb[o];
#pragma unroll
  for (int d = 0; d < DQ; d++) acc = fmaf(pw[o][d], emb[mloc][d], acc);
  E2[(size_t)(bm0 + mloc) * DQ + o] = acc;
}

// ---------------------------------------------------------------------------
// Stage 32 rows x 256 u16 of W into padded LDS [32][LROW]. Coalesced 16B.
#define STAGE_W(dst, src)                                                    \
  _Pragma("unroll")                                                          \
  for (int it = 0; it < 4; it++) {                                           \
    int idx = threadIdx.x + it * 256, row = idx >> 5, ch = idx & 31;         \
    *(uint4*)&dst[row * LROW + ch * 8] =                                     \
        *(const uint4*)(src + row * 256 + ch * 8);                           \
  }

// ---------------------------------------------------------------------------
// Merged precompute: blocks [0,512): KP2A[l] = split(Wq[l]@pca + E2A[l]);
// [512,2560): UPA[l] = bf((1-bx[l])*Wvp[l]@pca).  Union LDS.
__global__ __launch_bounds__(256) void k_pre2(
    const u16* __restrict__ pThi, const u16* __restrict__ pTlo,
    const u16* __restrict__ Wqhi, const u16* __restrict__ Wqlo,
    const u16* __restrict__ Wvpbf, const float* __restrict__ E2A,
    const float* __restrict__ beta_x,
    u16* __restrict__ KP2hiA, u16* __restrict__ KP2loA, u16* __restrict__ UPA)
{
  __shared__ __align__(16) u16 WS[2 * 32 * LROW];
  int tid = threadIdx.x, lane = tid & 63;
  int lm = lane & 15, lk = lane >> 4;
  if (blockIdx.x < 512) {
    int bi = blockIdx.x;
    int l = bi >> 7, rest = bi & 127;
    int dt = rest >> 6, b = rest & 63;
    int nt = tid >> 6;
    u16* WH = WS;
    u16* WL = WS + 32 * LROW;
    {
      const u16* sH = Wqhi + (size_t)l * DQ * CH + (size_t)dt * 32 * CH;
      const u16* sL = Wqlo + (size_t)l * DQ * CH + (size_t)dt * 32 * CH;
      STAGE_W(WH, sH)
      STAGE_W(WL, sL)
    }
    __syncthreads();
    const u16* B0h = pThi + ((size_t)b * NP + nt * 32 + lm) * CH + lk * 8;
    const u16* B1h = B0h + 16 * CH;
    const u16* B0l = pTlo + ((size_t)b * NP + nt * 32 + lm) * CH + lk * 8;
    const u16* B1l = B0l + 16 * CH;
    f32x4 acc[2][2] = {};
#pragma unroll
    for (int kb = 0; kb < 4; kb++) {
      sh8 rb0h[2], rb1h[2], rb0l[2], rb1l[2];
#pragma unroll
      for (int u = 0; u < 2; u++) {
        int o = (kb * 2 + u) * 32;
        rb0h[u] = *(const sh8*)(B0h + o); rb1h[u] = *(const sh8*)(B1h + o);
        rb0l[u] = *(const sh8*)(B0l + o); rb1l[u] = *(const sh8*)(B1l + o);
      }
#pragma unroll
      for (int u = 0; u < 2; u++) {
        int o2 = (kb * 2 + u) * 32 + lk * 8;
        sh8 a0h = *(const sh8*)&WH[lm * LROW + o2];
        sh8 a1h = *(const sh8*)&WH[(16 + lm) * LROW + o2];
        sh8 a0l = *(const sh8*)&WL[lm * LROW + o2];
        sh8 a1l = *(const sh8*)&WL[(16 + lm) * LROW + o2];
        acc[0][0] = MFMA(a0h, rb0h[u], acc[0][0]);
        acc[0][0] = MFMA(a0h, rb0l[u], acc[0][0]);
        acc[0][0] = MFMA(a0l, rb0h[u], acc[0][0]);
        acc[0][1] = MFMA(a0h, rb1h[u], acc[0][1]);
        acc[0][1] = MFMA(a0h, rb1l[u], acc[0][1]);
        acc[0][1] = MFMA(a0l, rb1h[u], acc[0][1]);
        acc[1][0] = MFMA(a1h, rb0h[u], acc[1][0]);
        acc[1][0] = MFMA(a1h, rb0l[u], acc[1][0]);
        acc[1][0] = MFMA(a1l, rb0h[u], acc[1][0]);
        acc[1][1] = MFMA(a1h, rb1h[u], acc[1][1]);
        acc[1][1] = MFMA(a1h, rb1l[u], acc[1][1]);
        acc[1][1] = MFMA(a1l, rb1h[u], acc[1][1]);
      }
    }
#pragma unroll
    for (int i = 0; i < 2; i++)
#pragma unroll
      for (int j = 0; j < 2; j++) {
        int n = nt * 32 + j * 16 + lm;
        int d0 = dt * 32 + i * 16 + lk * 4;
        size_t off = (((size_t)l * BB + b) * NP + n) * DQ + d0;
        f32x4 v = acc[i][j];
        float4 e = *(const float4*)&E2A[off];
        v[0] += e.x; v[1] += e.y; v[2] += e.z; v[3] += e.w;
        u16 h[4], lo[4];
#pragma unroll
        for (int r2 = 0; r2 < 4; r2++) {
          h[r2] = f2bf(v[r2]);
          lo[r2] = f2bf(v[r2] - bf2f(h[r2]));
        }
        *(uint2*)&KP2hiA[off] = *(const uint2*)h;
        *(uint2*)&KP2loA[off] = *(const uint2*)lo;
      }
  } else {
    int bi = blockIdx.x - 512;
    int l = bi >> 9, rest = bi & 511;
    int ct = rest >> 6, b = rest & 63;
    int nt = tid >> 6;
    u16* WH = WS;
    {
      const u16* sH = Wvpbf + (size_t)l * CH * CH + (size_t)ct * 32 * CH;
      STAGE_W(WH, sH)
    }
    __syncthreads();
    float obx = 1.0f - beta_x[l];
    const u16* X0 = pThi + ((size_t)b * NP + nt * 32 + lm) * CH + lk * 8;
    const u16* X1 = X0 + 16 * CH;
    f32x4 a00 = {}, a01 = {}, a10 = {}, a11 = {};
#pragma unroll
    for (int kb = 0; kb < 2; kb++) {
      sh8 rx0[4], rx1[4];
#pragma unroll
      for (int u = 0; u < 4; u++) {
        int o = (kb * 4 + u) * 32;
        rx0[u] = *(const sh8*)(X0 + o); rx1[u] = *(const sh8*)(X1 + o);
      }
#pragma unroll
      for (int u = 0; u < 4; u++) {
        int o2 = (kb * 4 + u) * 32 + lk * 8;
        sh8 w0 = *(const sh8*)&WH[lm * LROW + o2];
        sh8 w1 = *(const sh8*)&WH[(16 + lm) * LROW + o2];
        a00 = MFMA(rx0[u], w0, a00);
        a01 = MFMA(rx0[u], w1, a01);
        a10 = MFMA(rx1[u], w0, a10);
        a11 = MFMA(rx1[u], w1, a11);
      }
    }
    f32x4 acc[2][2] = {{a00, a01}, {a10, a11}};
#pragma unroll
    for (int i = 0; i < 2; i++)
#pragma unroll
      for (int j = 0; j < 2; j++) {
        int c = ct * 32 + j * 16 + lm;
        int n0 = nt * 32 + i * 16 + lk * 4;
        u16 ov[4];
#pragma unroll
        for (int r2 = 0; r2 < 4; r2++) ov[r2] = f2bf(obx * acc[i][j][r2]);
        *(uint2*)&UPA[(((size_t)l * BB + b) * CH + c) * NP + n0] = *(const uint2*)ov;
      }
  }
}

// ---------------------------------------------------------------------------
// Merged per-layer: blocks [0,256): split-bf16 QK projections (XQ fp32+hi/lo,
// KLT hi/lo); [256,768): U = bf(bx*Wv@x) + UPA[l].  Union LDS.
__global__ __launch_bounds__(256) void k_qu2(
    const u16* __restrict__ xThi, const u16* __restrict__ xTlo,
    const u16* __restrict__ Wqhi, const u16* __restrict__ Wqlo,
    const u16* __restrict__ Wkhi, const u16* __restrict__ Wklo,
    const u16* __restrict__ Wv, const u16* __restrict__ UP,
    const float* __restrict__ beta_x, int layer,
    float* __restrict__ XQ, u16* __restrict__ XQhi, u16* __restrict__ XQlo,
    u16* __restrict__ KLThi, u16* __restrict__ KLTlo, u16* __restrict__ U)
{
  __shared__ __align__(16) u16 WS[2 * 32 * LROW];
  int tid = threadIdx.x, lane = tid & 63;
  int lm = lane & 15, lk = lane >> 4;
  if (blockIdx.x < 256) {
    int bi = blockIdx.x;
    int mat = bi >> 7, rest = bi & 127;
    int dt = rest >> 6, b = rest & 63;
    int nt = tid >> 6;
    u16* WH = WS;
    u16* WL = WS + 32 * LROW;
    {
      const u16* sH = (mat ? Wkhi : Wqhi) + (size_t)dt * 32 * CH;
      const u16* sL = (mat ? Wklo : Wqlo) + (size_t)dt * 32 * CH;
      STAGE_W(WH, sH)
      STAGE_W(WL, sL)
    }
    __syncthreads();
    const u16* B0h = xThi + ((size_t)b * NP + nt * 32 + lm) * CH + lk * 8;
    const u16* B1h = B0h + 16 * CH;
    const u16* B0l = xTlo + ((size_t)b * NP + nt * 32 + lm) * CH + lk * 8;
    const u16* B1l = B0l + 16 * CH;
    f32x4 acc[2][2] = {};
#pragma unroll
    for (int kb = 0; kb < 4; kb++) {
      sh8 rb0h[2], rb1h[2], rb0l[2], rb1l[2];
#pragma unroll
      for (int u = 0; u < 2; u++) {
        int o = (kb * 2 + u) * 32;
        rb0h[u] = *(const sh8*)(B0h + o); rb1h[u] = *(const sh8*)(B1h + o);
        rb0l[u] = *(const sh8*)(B0l + o); rb1l[u] = *(const sh8*)(B1l + o);
      }
#pragma unroll
      for (int u = 0; u < 2; u++) {
        int o2 = (kb * 2 + u) * 32 + lk * 8;
        sh8 a0h = *(const sh8*)&WH[lm * LROW + o2];
        sh8 a1h = *(const sh8*)&WH[(16 + lm) * LROW + o2];
        sh8 a0l = *(const sh8*)&WL[lm * LROW + o2];
        sh8 a1l = *(const sh8*)&WL[(16 + lm) * LROW + o2];
        acc[0][0] = MFMA(a0h, rb0h[u], acc[0][0]);
        acc[0][0] = MFMA(a0h, rb0l[u], acc[0][0]);
        acc[0][0] = MFMA(a0l, rb0h[u], acc[0][0]);
        acc[0][1] = MFMA(a0h, rb1h[u], acc[0][1]);
        acc[0][1] = MFMA(a0h, rb1l[u], acc[0][1]);
        acc[0][1] = MFMA(a0l, rb1h[u], acc[0][1]);
        acc[1][0] = MFMA(a1h, rb0h[u], acc[1][0]);
        acc[1][0] = MFMA(a1h, rb0l[u], acc[1][0]);
        acc[1][0] = MFMA(a1l, rb0h[u], acc[1][0]);
        acc[1][1] = MFMA(a1h, rb1h[u], acc[1][1]);
        acc[1][1] = MFMA(a1h, rb1l[u], acc[1][1]);
        acc[1][1] = MFMA(a1l, rb1h[u], acc[1][1]);
      }
    }
#pragma unroll
    for (int i = 0; i < 2; i++)
#pragma unroll
      for (int j = 0; j < 2; j++) {
        int n = nt * 32 + j * 16 + lm;
        int d0 = dt * 32 + i * 16 + lk * 4;
        size_t off = ((size_t)b * NP + n) * DQ + d0;
        f32x4 v = acc[i][j];
        u16 h[4], lo[4];
#pragma unroll
        for (int r2 = 0; r2 < 4; r2++) {
          h[r2] = f2bf(v[r2]);
          lo[r2] = f2bf(v[r2] - bf2f(h[r2]));
        }
        if (mat == 0) {
          float4 vo = {v[0], v[1], v[2], v[3]};
          *(float4*)&XQ[off] = vo;
          *(uint2*)&XQhi[off] = *(const uint2*)h;
          *(uint2*)&XQlo[off] = *(const uint2*)lo;
        } else {
          *(uint2*)&KLThi[off] = *(const uint2*)h;
          *(uint2*)&KLTlo[off] = *(const uint2*)lo;
        }
      }
  } else {
    int bi = blockIdx.x - 256;
    int ct = bi >> 6, b = bi & 63;
    int nt = tid >> 6;
    u16* WH = WS;
    {
      const u16* sH = Wv + (size_t)ct * 32 * CH;
      STAGE_W(WH, sH)
    }
    __syncthreads();
    float bx = beta_x[layer];
    const u16* X0 = xThi + ((size_t)b * NP + nt * 32 + lm) * CH + lk * 8;
    const u16* X1 = X0 + 16 * CH;
    f32x4 a00 = {}, a01 = {}, a10 = {}, a11 = {};
#pragma unroll
    for (int kb = 0; kb < 2; kb++) {
      sh8 rx0[4], rx1[4];
#pragma unroll
      for (int u = 0; u < 4; u++) {
        int o = (kb * 4 + u) * 32;
        rx0[u] = *(const sh8*)(X0 + o); rx1[u] = *(const sh8*)(X1 + o);
      }
#pragma unroll
      for (int u = 0; u < 4; u++) {
        int o2 = (kb * 4 + u) * 32 + lk * 8;
        sh8 w0 = *(const sh8*)&WH[lm * LROW + o2];
        sh8 w1 = *(const sh8*)&WH[(16 + lm) * LROW + o2];
        a00 = MFMA(rx0[u], w0, a00);
        a01 = MFMA(rx0[u], w1, a01);
        a10 = MFMA(rx1[u], w0, a10);
        a11 = MFMA(rx1[u], w1, a11);
      }
    }
    f32x4 acc[2][2] = {{a00, a01}, {a10, a11}};
#pragma unroll
    for (int i = 0; i < 2; i++)
#pragma unroll
      for (int j = 0; j < 2; j++) {
        int c = ct * 32 + j * 16 + lm;
        int n0 = nt * 32 + i * 16 + lk * 4;
        size_t off = ((size_t)b * CH + c) * NP + n0;
        uint2 up = *(const uint2*)&UP[off];
        const u16* uph = (const u16*)&up;
        u16 ov[4];
#pragma unroll
        for (int r2 = 0; r2 < 4; r2++)
          ov[r2] = f2bf(bx * acc[i][j][r2] + bf2f(uph[r2]));
        *(uint2*)&U[off] = *(const uint2*)ov;
      }
  }
}

// ---------------------------------------------------------------------------
// Fused attention middle. Block = (g: 32-row n-group, b). Phases:
//  0) stage XQ rows (fp32), p1w, p1b, divs into LDS
//  1) q1/c1 in-block (VALU); energy MFMA (32n x 128m) -> Esh (fp32)
//  2) bias (sincos) + row softmax over 128 m -> P into Esh
//  3) P^T bf16 -> PT[b][m][g*32..]; colsum partial -> SCLp[b][g][m]
__global__ __launch_bounds__(256) void k_att(
    const float* __restrict__ XQ,
    const u16* __restrict__ XQhi, const u16* __restrict__ XQlo,
    const u16* __restrict__ KLThi, const u16* __restrict__ KLTlo,
    const u16* __restrict__ KP2hi, const u16* __restrict__ KP2lo,
    const float* __restrict__ p1w, const float* __restrict__ p1b,
    const float* __restrict__ AS, const float* __restrict__ beta_w, int layer,
    u16* __restrict__ PT, float* __restrict__ SCLp)
{
  int g = blockIdx.x, b = blockIdx.y;
  int tid = threadIdx.x;
  int wave = tid >> 6, lane = tid & 63;
  int lm = lane & 15, lk = lane >> 4;
  __shared__ float xqs[32][65];
  __shared__ __align__(16) float pwsh[64][68];
  __shared__ float pbsh[64];
  __shared__ float divs[32];
  __shared__ float q1sh[32][66];
  __shared__ float c1sh[32];
  __shared__ __align__(16) float Esh[32][132];

  // phase 0: stage
  {
    const float* src = XQ + ((size_t)b * NP + g * 32) * DQ;
#pragma unroll
    for (int i = 0; i < 8; i++) {
      int idx = tid + i * 256;
      xqs[idx >> 6][idx & 63] = src[idx];
    }
#pragma unroll
    for (int i = 0; i < 16; i++) {
      int idx = tid + i * 256;
      pwsh[idx >> 6][idx & 63] = p1w[idx];
    }
    if (tid < 64) pbsh[tid] = p1b[tid];
    if (tid >= 224) divs[tid - 224] = __expf(-(float)(tid - 224) * DIV_STEP);
  }
  __syncthreads();
  float bw = beta_w[layer], obw = 1.0f - bw;
  // phase 1a: q1/c1 (thread: n = tid>>3, d0 = (tid&7)*8)
  {
    int n = tid >> 3, d0 = (tid & 7) * 8;
    float acc[8] = {};
    float cacc = 0.0f;
    for (int o = 0; o < DQ; o++) {
      float xv = xqs[n][o];
      cacc = fmaf(pbsh[o], xv, cacc);
#pragma unroll
      for (int dd = 0; dd < 8; dd++) acc[dd] = fmaf(pwsh[o][d0 + dd], xv, acc[dd]);
    }
#pragma unroll
    for (int dd = 0; dd < 8; dd++) q1sh[n][d0 + dd] = acc[dd];
    if ((tid & 7) == 0) c1sh[n] = cacc;
  }
  // phase 1b: energy MFMA (wave = m-tile)
  {
    int mt = wave;
    size_t arow = ((size_t)b * NP + mt * 32 + lm) * DQ + lk * 8;
    size_t brow = ((size_t)b * NP + g * 32 + lm) * DQ + lk * 8;
    const u16* L0h = KLThi + arow;
    const u16* L0l = KLTlo + arow;
    const u16* P0h = KP2hi + arow;
    const u16* P0l = KP2lo + arow;
    const u16* X0h = XQhi + brow;
    const u16* X0l = XQlo + brow;
    sh8 xh[2][2], xl[2][2], lh[2][2], ll[2][2], ph[2][2], pl[2][2];
#pragma unroll
    for (int row = 0; row < 2; row++) {
#pragma unroll
      for (int ks = 0; ks < 2; ks++) {
        int o = row * 16 * DQ + ks * 32;
        xh[row][ks] = *(const sh8*)(X0h + o);
        xl[row][ks] = *(const sh8*)(X0l + o);
        lh[row][ks] = *(const sh8*)(L0h + o);
        ll[row][ks] = *(const sh8*)(L0l + o);
        ph[row][ks] = *(const sh8*)(P0h + o);
        pl[row][ks] = *(const sh8*)(P0l + o);
      }
    }
    f32x4 aL[2][2] = {};
    f32x4 aP[2][2] = {};
#pragma unroll
    for (int ks = 0; ks < 2; ks++) {
#pragma unroll
      for (int i = 0; i < 2; i++) {
#pragma unroll
        for (int j = 0; j < 2; j++) {
          aL[i][j] = MFMA(lh[i][ks], xh[j][ks], aL[i][j]);
          aL[i][j] = MFMA(lh[i][ks], xl[j][ks], aL[i][j]);
          aL[i][j] = MFMA(ll[i][ks], xh[j][ks], aL[i][j]);
          aP[i][j] = MFMA(ph[i][ks], xh[j][ks], aP[i][j]);
          aP[i][j] = MFMA(ph[i][ks], xl[j][ks], aP[i][j]);
          aP[i][j] = MFMA(pl[i][ks], xh[j][ks], aP[i][j]);
        }
      }
    }
#pragma unroll
    for (int i = 0; i < 2; i++)
#pragma unroll
      for (int j = 0; j < 2; j++) {
        int nloc = j * 16 + lm;
        int mloc = mt * 32 + i * 16 + lk * 4;
        float4 v;
        v.x = bw * aL[i][j][0] + obw * aP[i][j][0];
        v.y = bw * aL[i][j][1] + obw * aP[i][j][1];
        v.z = bw * aL[i][j][2] + obw * aP[i][j][2];
        v.w = bw * aL[i][j][3] + obw * aP[i][j][3];
        *(float4*)&Esh[nloc][mloc] = v;
      }
  }
  __syncthreads();
  // phase 2: bias + softmax (thread: n = tid>>3, mc = (tid&7)*16)
  {
    int n = tid >> 3, mc = (tid & 7) * 16;
    size_t asrow = ((size_t)b * NP + g * 32 + n) * NP + mc;
    float idxv[16], bias[16];
    float c1v = c1sh[n];
#pragma unroll
    for (int k4 = 0; k4 < 4; k4++) {
      float4 a4 = *(const float4*)&AS[asrow + k4 * 4];
      idxv[k4 * 4 + 0] = a4.x * ANG_FACTOR;
      idxv[k4 * 4 + 1] = a4.y * ANG_FACTOR;
      idxv[k4 * 4 + 2] = a4.z * ANG_FACTOR;
      idxv[k4 * 4 + 3] = a4.w * ANG_FACTOR;
    }
#pragma unroll
    for (int k = 0; k < 16; k++) bias[k] = c1v;
    for (int j = 0; j < 32; j++) {
      float dv = divs[j];
      float qs = q1sh[n][2 * j], qc = q1sh[n][2 * j + 1];
#pragma unroll
      for (int k = 0; k < 16; k++) {
        float s, c;
        __sincosf(idxv[k] * dv, &s, &c);
        bias[k] = fmaf(qs, s, bias[k]);
        bias[k] = fmaf(qc, c, bias[k]);
      }
    }
    float ev[16], mx = -1e30f;
#pragma unroll
    for (int k = 0; k < 16; k++) {
      ev[k] = Esh[n][mc + k] + bw * bias[k];
      mx = fmaxf(mx, ev[k]);
    }
    mx = fmaxf(mx, __shfl_xor(mx, 1));
    mx = fmaxf(mx, __shfl_xor(mx, 2));
    mx = fmaxf(mx, __shfl_xor(mx, 4));
    float s = 0.0f;
#pragma unroll
    for (int k = 0; k < 16; k++) {
      ev[k] = __expf(ev[k] - mx);
      s += ev[k];
    }
    s += __shfl_xor(s, 1);
    s += __shfl_xor(s, 2);
    s += __shfl_xor(s, 4);
    float inv = 1.0f / s;
#pragma unroll
    for (int k = 0; k < 16; k++) Esh[n][mc + k] = ev[k] * inv;
  }
  __syncthreads();
  // phase 3: P^T bf16 + colsum partial (thread: m = tid>>1, nc = (tid&1)*16)
  {
    int m = tid >> 1, nc = (tid & 1) * 16;
    float s = 0.0f;
    u16 tmp[16];
#pragma unroll
    for (int k = 0; k < 16; k++) {
      float v = Esh[nc + k][m];
      s += v;
      tmp[k] = f2bf(v);
    }
    u16* dst = PT + ((size_t)b * NP + m) * NP + g * 32 + nc;
    *(uint4*)&dst[0] = *(const uint4*)&tmp[0];
    *(uint4*)&dst[8] = *(const uint4*)&tmp[8];
    s += __shfl_xor(s, 1);
    if ((tid & 1) == 0) SCLp[((size_t)b * 4 + g) * NP + m] = s;
  }
}

// ---------------------------------------------------------------------------
// MFMA: T^T[b][m][c] = bf(x^T[m][c]) - (sum_n U[c][n] PT[m][n]) / (1e-12+colsum)
__global__ __launch_bounds__(256) void k_t_m(
    const u16* __restrict__ U, const u16* __restrict__ PT,
    const float* __restrict__ SCLp, const u16* __restrict__ xT,
    u16* __restrict__ TT)
{
  int wid = blockIdx.x * 4 + (threadIdx.x >> 6);
  int lane = threadIdx.x & 63;
  int b = wid >> 5, q = wid & 31;
  int ct = q >> 2, mt = q & 3;
  int lm = lane & 15, lk = lane >> 4;
  const u16* A0 = U + ((size_t)b * CH + ct * 32 + lm) * NP + lk * 8;
  const u16* A1 = A0 + 16 * NP;
  const u16* B0 = PT + ((size_t)b * NP + mt * 32 + lm) * NP + lk * 8;
  const u16* B1 = B0 + 16 * NP;
  sh8 rA0[4], rA1[4], rB0[4], rB1[4];
#pragma unroll
  for (int ks = 0; ks < 4; ks++) {
    int o = ks * 32;
    rA0[ks] = *(const sh8*)(A0 + o);
    rA1[ks] = *(const sh8*)(A1 + o);
    rB0[ks] = *(const sh8*)(B0 + o);
    rB1[ks] = *(const sh8*)(B1 + o);
  }
  f32x4 a00 = {}, a01 = {}, a10 = {}, a11 = {};
#pragma unroll
  for (int ks = 0; ks < 4; ks++) {
    a00 = MFMA(rA0[ks], rB0[ks], a00);
    a01 = MFMA(rA0[ks], rB1[ks], a01);
    a10 = MFMA(rA1[ks], rB0[ks], a10);
    a11 = MFMA(rA1[ks], rB1[ks], a11);
  }
  f32x4 acc[2][2] = {{a00, a01}, {a10, a11}};
#pragma unroll
  for (int i = 0; i < 2; i++)
#pragma unroll
    for (int j = 0; j < 2; j++) {
      int m = mt * 32 + j * 16 + lm;
      int c0 = ct * 32 + i * 16 + lk * 4;
      const float* sp = SCLp + (size_t)b * 4 * NP + m;
      float scl = 1.0f / (1e-12f + sp[0] + sp[NP] + sp[2 * NP] + sp[3 * NP]);
      uint2 xv = *(const uint2*)(xT + ((size_t)b * NP + m) * CH + c0);
      const u16* xh = (const u16*)&xv;
      u16 ov[4];
#pragma unroll
      for (int r = 0; r < 4; r++)
        ov[r] = f2bf(bf2f(xh[r]) - acc[i][j][r] * scl);
      *(uint2*)&TT[((size_t)b * NP + m) * CH + c0] = *(const uint2*)ov;
    }
}

// ---------------------------------------------------------------------------
// out = x + gelu(BN(Wl@T + bl)); also writes next layer's xT hi/lo.
__global__ __launch_bounds__(256) void k_h2(
    const u16* __restrict__ Wl, const u16* __restrict__ TT,
    const float* __restrict__ bl, const float* __restrict__ bng,
    const float* __restrict__ bnb, const float* __restrict__ xsrc, int xbs,
    float* __restrict__ out, int layer,
    u16* __restrict__ xThi_o, u16* __restrict__ xTlo_o)
{
  int bi = blockIdx.x;
  int ct = bi >> 6, b = bi & 63;
  int tid = threadIdx.x, lane = tid & 63, nt = tid >> 6;
  int lm = lane & 15, lk = lane >> 4;
  __shared__ __align__(16) u16 WH[32 * LROW];
  {
    const u16* sH = Wl + (size_t)ct * 32 * CH;
    STAGE_W(WH, sH)
  }
  __syncthreads();
  const u16* B0 = TT + ((size_t)b * NP + nt * 32 + lm) * CH + lk * 8;
  const u16* B1 = B0 + 16 * CH;
  f32x4 a00 = {}, a01 = {}, a10 = {}, a11 = {};
#pragma unroll
  for (int kb = 0; kb < 2; kb++) {
    sh8 rt0[4], rt1[4];
#pragma unroll
    for (int u = 0; u < 4; u++) {
      int o = (kb * 4 + u) * 32;
      rt0[u] = *(const sh8*)(B0 + o); rt1[u] = *(const sh8*)(B1 + o);
    }
#pragma unroll
    for (int u = 0; u < 4; u++) {
      int o2 = (kb * 4 + u) * 32 + lk * 8;
      sh8 w0 = *(const sh8*)&WH[lm * LROW + o2];
      sh8 w1 = *(const sh8*)&WH[(16 + lm) * LROW + o2];
      a00 = MFMA(w0, rt0[u], a00);
      a01 = MFMA(w0, rt1[u], a01);
      a10 = MFMA(w1, rt0[u], a10);
      a11 = MFMA(w1, rt1[u], a11);
    }
  }
  f32x4 acc[2][2] = {{a00, a01}, {a10, a11}};
  const float rbn = 0.999995000037499687f;  // 1/sqrt(1+1e-5)
#pragma unroll
  for (int i = 0; i < 2; i++)
#pragma unroll
    for (int j = 0; j < 2; j++) {
      int n = nt * 32 + j * 16 + lm;
      int cb = ct * 32 + i * 16 + lk * 4;
      u16 hh[4], llv[4];
#pragma unroll
      for (int r = 0; r < 4; r++) {
        int c = cb + r;
        float h = acc[i][j][r] + bl[c];
        h = h * rbn * bng[c] + bnb[c];
        float gg = 0.5f * h * (1.0f + erff(h * 0.70710678118654752440f));
        float ov = xsrc[(size_t)b * xbs + (size_t)c * NP + n] + gg;
        out[((size_t)b * 4 * CH + (size_t)layer * CH + c) * NP + n] = ov;
        hh[r] = f2bf(ov);
        llv[r] = f2bf(ov - bf2f(hh[r]));
      }
      size_t xoff = ((size_t)b * NP + n) * CH + cb;
      *(uint2*)&xThi_o[xoff] = *(const uint2*)hh;
      *(uint2*)&xTlo_o[xoff] = *(const uint2*)llv;
    }
}

// ---------------------------------------------------------------------------
extern "C" void kernel_launch(void* const* d_in, const int* in_sizes, int n_in,
                              void* d_out, int out_size, void* d_ws, size_t ws_size,
                              hipStream_t stream)
{
  (void)in_sizes; (void)n_in; (void)out_size; (void)ws_size;
  const float* lrf     = (const float*)d_in[0];
  const float* pca     = (const float*)d_in[1];
  const float* a_self  = (const float*)d_in[2];
  const float* a_cross = (const float*)d_in[3];
  const float* Wq  = (const float*)d_in[4];
  const float* Wk  = (const float*)d_in[5];
  const float* Wv  = (const float*)d_in[6];
  const float* Wvp = (const float*)d_in[7];
  const float* Wl  = (const float*)d_in[8];
  const float* bl  = (const float*)d_in[9];
  const float* bng = (const float*)d_in[10];
  const float* bnb = (const float*)d_in[11];
  const float* p1w = (const float*)d_in[12];
  const float* p1b = (const float*)d_in[13];
  const float* p2w = (const float*)d_in[14];
  const float* p2b = (const float*)d_in[15];
  const float* beta_x = (const float*)d_in[16];
  const float* beta_w = (const float*)d_in[17];
  float* out = (float*)d_out;
  float* ws  = (float*)d_ws;

  // ---- workspace carve ----
  const size_t QKN = (size_t)BB * NP * DQ;        // 524288
  const size_t ENN = (size_t)BB * NP * NP;        // 1048576
  const size_t XCN = (size_t)BB * NP * CH;        // 2097152 (u16 count)

  float* XQ   = ws;
  float* E2A  = XQ + QKN;
  float* SCLp = E2A + (size_t)NLAYERS * QKN;
  u16* up = (u16*)(SCLp + (size_t)BB * 4 * NP);
  u16* xThi = up;   up += XCN;
  u16* xTlo = up;   up += XCN;
  u16* pThi = up;   up += XCN;
  u16* pTlo = up;   up += XCN;
  u16* XQhi = up;   up += QKN;
  u16* XQlo = up;   up += QKN;
  u16* KLThi = up;  up += QKN;
  u16* KLTlo = up;  up += QKN;
  u16* KP2hiA = up; up += (size_t)NLAYERS * QKN;
  u16* KP2loA = up; up += (size_t)NLAYERS * QKN;
  u16* UPA = up;    up += (size_t)NLAYERS * BB * CH * NP;
  u16* Ubf = up;    up += (size_t)BB * CH * NP;
  u16* PTbf = up;   up += ENN;
  u16* TbfT = up;   up += XCN;
  u16* Wvbf = up;   up += (size_t)NLAYERS * CH * CH;
  u16* Wvpbf = up;  up += (size_t)NLAYERS * CH * CH;
  u16* Wlbf = up;   up += (size_t)NLAYERS * CH * CH;
  u16* Wqhi = up;   up += (size_t)NLAYERS * DQ * CH;
  u16* Wqlo = up;   up += (size_t)NLAYERS * DQ * CH;
  u16* Wkhi = up;   up += (size_t)NLAYERS * DQ * CH;
  u16* Wklo = up;   up += (size_t)NLAYERS * DQ * CH;

  // ---- pre-loop (4 launches) ----
  k_cvt_all<<<dim3(896), 256, 0, stream>>>(
      Wv, Wvp, Wl, Wq, Wk, Wvbf, Wvpbf, Wlbf, Wqhi, Wqlo, Wkhi, Wklo);
  k_xt2<<<dim3(2, 8, BB), 256, 0, stream>>>(pca, lrf, pThi, pTlo, xThi, xTlo);
  k_e2_all<<<dim3(BB * NP / 4, NLAYERS), 256, 0, stream>>>(a_cross, p2w, p2b, E2A);
  k_pre2<<<dim3(2560), 256, 0, stream>>>(
      pThi, pTlo, Wqhi, Wqlo, Wvpbf, E2A, beta_x, KP2hiA, KP2loA, UPA);

  // ---- layer loop (4 launches each) ----
  for (int l = 0; l < NLAYERS; l++) {
    const float* xsrc = (l == 0) ? lrf : (out + (size_t)(l - 1) * CH * NP);
    int xbs = (l == 0) ? CH * NP : 4 * CH * NP;
    k_qu2<<<dim3(768), 256, 0, stream>>>(
        xThi, xTlo,
        Wqhi + (size_t)l * DQ * CH, Wqlo + (size_t)l * DQ * CH,
        Wkhi + (size_t)l * DQ * CH, Wklo + (size_t)l * DQ * CH,
        Wvbf + (size_t)l * CH * CH, UPA + (size_t)l * BB * CH * NP,
        beta_x, l, XQ, XQhi, XQlo, KLThi, KLTlo, Ubf);
    k_att<<<dim3(4, BB), 256, 0, stream>>>(
        XQ, XQhi, XQlo, KLThi, KLTlo,
        KP2hiA + (size_t)l * QKN, KP2loA + (size_t)l * QKN,
        p1w + (size_t)l * DQ * DQ, p1b + (size_t)l * DQ,
        a_self, beta_w, l, PTbf, SCLp);
    k_t_m<<<dim3(512), 256, 0, stream>>>(Ubf, PTbf, SCLp, xThi, TbfT);
    k_h2<<<dim3(512), 256, 0, stream>>>(
        Wlbf + (size_t)l * CH * CH, TbfT, bl + (size_t)l * CH,
        bng + (size_t)l * CH, bnb + (size_t)l * CH, xsrc, xbs, out, l,
        xThi, xTlo);
  }
}

// Round 10
// 270.424 us; speedup vs baseline: 3.2932x; 1.0151x over previous
//
#include <hip/hip_runtime.h>
#include <cstdint>
#include <cstddef>

// Round 10: chain 4->3 per layer via linearity: Wl@(x - U@P*scl) =
// Wl@x - (Wl@U)@P*scl. A=Wl@x joins k_qu3 (1280 blk); WlU=Wl@U runs merged
// with attention (k_attwlu, 768 blk); k_h3 = A - WlU@P*scl epilogue GEMM.
// U/UP transposed to [n][c] so WlU's K is contiguous. 16 launches total.

#define BB 64      // batch
#define CH 256     // channels
#define NP 128     // points
#define DQ 64      // q/k dim
#define NLAYERS 4

#define ANG_FACTOR 3.8197186342054885f   // 180/(pi*15) = 12/pi
#define DIV_STEP   0.28782313662425575f  // ln(10000)/32

#define LROW 264   // padded LDS row stride (u16) for 256-wide W tiles
#define LROW2 136  // padded LDS row stride (u16) for 128-wide WlU tiles

typedef unsigned short u16;
typedef __attribute__((ext_vector_type(8))) short sh8;   // 8 bf16 = 4 VGPR
typedef __attribute__((ext_vector_type(4))) float f32x4; // MFMA C/D
#define MFMA(a, b, c) __builtin_amdgcn_mfma_f32_16x16x32_bf16(a, b, c, 0, 0, 0)

static __device__ __forceinline__ u16 f2bf(float x) {
  unsigned u = __float_as_uint(x);
  return (u16)((u + 0x7FFFu + ((u >> 16) & 1u)) >> 16);
}
static __device__ __forceinline__ float bf2f(u16 h) {
  return __uint_as_float(((unsigned)h) << 16);
}

// ---------------------------------------------------------------------------
__global__ __launch_bounds__(256) void k_cvt_all(
    const float* __restrict__ Wv, const float* __restrict__ Wvp,
    const float* __restrict__ Wl, const float* __restrict__ Wq,
    const float* __restrict__ Wk, u16* __restrict__ Wvbf,
    u16* __restrict__ Wvpbf, u16* __restrict__ Wlbf,
    u16* __restrict__ Wqhi, u16* __restrict__ Wqlo,
    u16* __restrict__ Wkhi, u16* __restrict__ Wklo)
{
  int blk = blockIdx.x, tid = threadIdx.x;
  if (blk < 768) {
    const float* s = (blk < 256) ? Wv : (blk < 512) ? Wvp : Wl;
    u16* d = (blk < 256) ? Wvbf : (blk < 512) ? Wvpbf : Wlbf;
    int i = ((blk & 255) * 256 + tid) * 4;
    float4 v = *(const float4*)(s + i);
    u16 o[4] = {f2bf(v.x), f2bf(v.y), f2bf(v.z), f2bf(v.w)};
    *(uint2*)(d + i) = *(const uint2*)o;
  } else {
    int bb = blk - 768;
    const float* s = (bb < 64) ? Wq : Wk;
    u16* dh = (bb < 64) ? Wqhi : Wkhi;
    u16* dl = (bb < 64) ? Wqlo : Wklo;
    int i = ((bb & 63) * 256 + tid) * 4;
    float4 v = *(const float4*)(s + i);
    float vv[4] = {v.x, v.y, v.z, v.w};
    u16 h[4], l[4];
#pragma unroll
    for (int r = 0; r < 4; r++) {
      h[r] = f2bf(vv[r]);
      l[r] = f2bf(vv[r] - bf2f(h[r]));
    }
    *(uint2*)(dh + i) = *(const uint2*)h;
    *(uint2*)(dl + i) = *(const uint2*)l;
  }
}

// ---------------------------------------------------------------------------
__global__ __launch_bounds__(256) void k_xt2(
    const float* __restrict__ pca, const float* __restrict__ lrf,
    u16* __restrict__ pThi, u16* __restrict__ pTlo,
    u16* __restrict__ xThi, u16* __restrict__ xTlo)
{
  int nt = blockIdx.x, y = blockIdx.y, b = blockIdx.z;
  int ct = y & 3, is_lrf = y >> 2;
  const float* x = is_lrf ? lrf : pca;
  u16* hiT = is_lrf ? xThi : pThi;
  u16* loT = is_lrf ? xTlo : pTlo;
  __shared__ float tl[64][65];
  int tid = threadIdx.x;
  {
    int col = tid & 63, rq = tid >> 6;
    const float* src = x + (size_t)b * CH * NP + (size_t)(ct * 64) * NP + nt * 64;
#pragma unroll
    for (int i = 0; i < 16; i++) {
      int c = rq + i * 4;
      tl[col][c] = src[(size_t)c * NP + col];
    }
  }
  __syncthreads();
  {
    int cloc = tid & 63, nq = tid >> 6;
#pragma unroll
    for (int i = 0; i < 16; i++) {
      int n = nq + i * 4;
      float v = tl[n][cloc];
      u16 h = f2bf(v);
      u16 l = f2bf(v - bf2f(h));
      size_t off = ((size_t)b * NP + nt * 64 + n) * CH + ct * 64 + cloc;
      hiT[off] = h;
      loT[off] = l;
    }
  }
}

// ---------------------------------------------------------------------------
__global__ __launch_bounds__(256) void k_e2_all(
    const float* __restrict__ ac, const float* __restrict__ p2w,
    const float* __restrict__ p2b, float* __restrict__ E2A)
{
  int l = blockIdx.y;
  const float* pwg = p2w + (size_t)l * DQ * DQ;
  const float* pbg = p2b + (size_t)l * DQ;
  float* E2 = E2A + (size_t)l * BB * NP * DQ;
  __shared__ float pw[DQ][65];
  __shared__ float emb[4][DQ];
  __shared__ float pb[DQ];
  int tid = threadIdx.x;
  int bm0 = blockIdx.x * 4;
#pragma unroll
  for (int i = 0; i < 16; i++) {
    int idx = tid + i * 256;
    pw[idx >> 6][idx & 63] = pwg[idx];
  }
  if (tid < DQ) pb[tid] = pbg[tid];
  if (tid < 128) {
    int ml = tid >> 5, j = tid & 31;
    float a = ac[bm0 + ml];
    float s, c;
    __sincosf(a * ANG_FACTOR * __expf(-(float)j * DIV_STEP), &s, &c);
    emb[ml][2 * j] = s;
    emb[ml][2 * j + 1] = c;
  }
  __syncthreads();
  int mloc = tid >> 6, o = tid & 63;
  float acc = pb[o];
#pragma unroll
  for (int d = 0; d < DQ; d++) acc = fmaf(pw[o][d], emb[mloc][d], acc);
  E2[(size_t)(bm0 + mloc) * DQ + o] = acc;
}

// ---------------------------------------------------------------------------
#define STAGE_W(dst, src)                                                    \
  _Pragma("unroll")                                                          \
  for (int it = 0; it < 4; it++) {                                           \
    int idx = threadIdx.x + it * 256, row = idx >> 5, ch = idx & 31;         \
    *(uint4*)&dst[row * LROW + ch * 8] =                                     \
        *(const uint4*)(src + row * 256 + ch * 8);                           \
  }

// ---------------------------------------------------------------------------
// blocks [0,512): KP2A[l] = split(Wq[l]@pca + E2A[l]);
// [512,2560): UPt[l][b][n][c] = bf((1-bx[l])*Wvp[l]@pca) (transposed store).
__global__ __launch_bounds__(256) void k_pre2(
    const u16* __restrict__ pThi, const u16* __restrict__ pTlo,
    const u16* __restrict__ Wqhi, const u16* __restrict__ Wqlo,
    const u16* __restrict__ Wvpbf, const float* __restrict__ E2A,
    const float* __restrict__ beta_x,
    u16* __restrict__ KP2hiA, u16* __restrict__ KP2loA, u16* __restrict__ UPt)
{
  __shared__ __align__(16) u16 WS[2 * 32 * LROW];
  int tid = threadIdx.x, lane = tid & 63;
  int lm = lane & 15, lk = lane >> 4;
  if (blockIdx.x < 512) {
    int bi = blockIdx.x;
    int l = bi >> 7, rest = bi & 127;
    int dt = rest >> 6, b = rest & 63;
    int nt = tid >> 6;
    u16* WH = WS;
    u16* WL = WS + 32 * LROW;
    {
      const u16* sH = Wqhi + (size_t)l * DQ * CH + (size_t)dt * 32 * CH;
      const u16* sL = Wqlo + (size_t)l * DQ * CH + (size_t)dt * 32 * CH;
      STAGE_W(WH, sH)
      STAGE_W(WL, sL)
    }
    __syncthreads();
    const u16* B0h = pThi + ((size_t)b * NP + nt * 32 + lm) * CH + lk * 8;
    const u16* B1h = B0h + 16 * CH;
    const u16* B0l = pTlo + ((size_t)b * NP + nt * 32 + lm) * CH + lk * 8;
    const u16* B1l = B0l + 16 * CH;
    f32x4 acc[2][2] = {};
#pragma unroll
    for (int kb = 0; kb < 4; kb++) {
      sh8 rb0h[2], rb1h[2], rb0l[2], rb1l[2];
#pragma unroll
      for (int u = 0; u < 2; u++) {
        int o = (kb * 2 + u) * 32;
        rb0h[u] = *(const sh8*)(B0h + o); rb1h[u] = *(const sh8*)(B1h + o);
        rb0l[u] = *(const sh8*)(B0l + o); rb1l[u] = *(const sh8*)(B1l + o);
      }
#pragma unroll
      for (int u = 0; u < 2; u++) {
        int o2 = (kb * 2 + u) * 32 + lk * 8;
        sh8 a0h = *(const sh8*)&WH[lm * LROW + o2];
        sh8 a1h = *(const sh8*)&WH[(16 + lm) * LROW + o2];
        sh8 a0l = *(const sh8*)&WL[lm * LROW + o2];
        sh8 a1l = *(const sh8*)&WL[(16 + lm) * LROW + o2];
        acc[0][0] = MFMA(a0h, rb0h[u], acc[0][0]);
        acc[0][0] = MFMA(a0h, rb0l[u], acc[0][0]);
        acc[0][0] = MFMA(a0l, rb0h[u], acc[0][0]);
        acc[0][1] = MFMA(a0h, rb1h[u], acc[0][1]);
        acc[0][1] = MFMA(a0h, rb1l[u], acc[0][1]);
        acc[0][1] = MFMA(a0l, rb1h[u], acc[0][1]);
        acc[1][0] = MFMA(a1h, rb0h[u], acc[1][0]);
        acc[1][0] = MFMA(a1h, rb0l[u], acc[1][0]);
        acc[1][0] = MFMA(a1l, rb0h[u], acc[1][0]);
        acc[1][1] = MFMA(a1h, rb1h[u], acc[1][1]);
        acc[1][1] = MFMA(a1h, rb1l[u], acc[1][1]);
        acc[1][1] = MFMA(a1l, rb1h[u], acc[1][1]);
      }
    }
#pragma unroll
    for (int i = 0; i < 2; i++)
#pragma unroll
      for (int j = 0; j < 2; j++) {
        int n = nt * 32 + j * 16 + lm;
        int d0 = dt * 32 + i * 16 + lk * 4;
        size_t off = (((size_t)l * BB + b) * NP + n) * DQ + d0;
        f32x4 v = acc[i][j];
        float4 e = *(const float4*)&E2A[off];
        v[0] += e.x; v[1] += e.y; v[2] += e.z; v[3] += e.w;
        u16 h[4], lo[4];
#pragma unroll
        for (int r2 = 0; r2 < 4; r2++) {
          h[r2] = f2bf(v[r2]);
          lo[r2] = f2bf(v[r2] - bf2f(h[r2]));
        }
        *(uint2*)&KP2hiA[off] = *(const uint2*)h;
        *(uint2*)&KP2loA[off] = *(const uint2*)lo;
      }
  } else {
    int bi = blockIdx.x - 512;
    int l = bi >> 9, rest = bi & 511;
    int ct = rest >> 6, b = rest & 63;
    int nt = tid >> 6;
    u16* WH = WS;
    {
      const u16* sH = Wvpbf + (size_t)l * CH * CH + (size_t)ct * 32 * CH;
      STAGE_W(WH, sH)
    }
    __syncthreads();
    float obx = 1.0f - beta_x[l];
    const u16* X0 = pThi + ((size_t)b * NP + nt * 32 + lm) * CH + lk * 8;
    const u16* X1 = X0 + 16 * CH;
    f32x4 a00 = {}, a01 = {}, a10 = {}, a11 = {};
    // i = W-row half (c), j = x-row half (n): D[row=c][col=n]
#pragma unroll
    for (int kb = 0; kb < 2; kb++) {
      sh8 rx0[4], rx1[4];
#pragma unroll
      for (int u = 0; u < 4; u++) {
        int o = (kb * 4 + u) * 32;
        rx0[u] = *(const sh8*)(X0 + o); rx1[u] = *(const sh8*)(X1 + o);
      }
#pragma unroll
      for (int u = 0; u < 4; u++) {
        int o2 = (kb * 4 + u) * 32 + lk * 8;
        sh8 w0 = *(const sh8*)&WH[lm * LROW + o2];
        sh8 w1 = *(const sh8*)&WH[(16 + lm) * LROW + o2];
        a00 = MFMA(w0, rx0[u], a00);
        a01 = MFMA(w0, rx1[u], a01);
        a10 = MFMA(w1, rx0[u], a10);
        a11 = MFMA(w1, rx1[u], a11);
      }
    }
    f32x4 acc[2][2] = {{a00, a01}, {a10, a11}};
#pragma unroll
    for (int i = 0; i < 2; i++)
#pragma unroll
      for (int j = 0; j < 2; j++) {
        int c0 = ct * 32 + i * 16 + lk * 4;
        int n = nt * 32 + j * 16 + lm;
        u16 ov[4];
#pragma unroll
        for (int r2 = 0; r2 < 4; r2++) ov[r2] = f2bf(obx * acc[i][j][r2]);
        *(uint2*)&UPt[(((size_t)l * BB + b) * NP + n) * CH + c0] = *(const uint2*)ov;
      }
  }
}

// ---------------------------------------------------------------------------
// Per-layer: [0,256): QK split-bf16 (XQ fp32+hi/lo, KLT hi/lo);
// [256,768): Ut[b][n][c] = bf(bx*Wv@x) + UPt[l];
// [768,1280): Afp[b][c][n] = Wl@x (fp32).
__global__ __launch_bounds__(256) void k_qu3(
    const u16* __restrict__ xThi, const u16* __restrict__ xTlo,
    const u16* __restrict__ Wqhi, const u16* __restrict__ Wqlo,
    const u16* __restrict__ Wkhi, const u16* __restrict__ Wklo,
    const u16* __restrict__ Wv, const u16* __restrict__ Wlbf,
    const u16* __restrict__ UPt, const float* __restrict__ beta_x, int layer,
    float* __restrict__ XQ, u16* __restrict__ XQhi, u16* __restrict__ XQlo,
    u16* __restrict__ KLThi, u16* __restrict__ KLTlo,
    u16* __restrict__ Ut, float* __restrict__ Afp)
{
  __shared__ __align__(16) u16 WS[2 * 32 * LROW];
  int tid = threadIdx.x, lane = tid & 63;
  int lm = lane & 15, lk = lane >> 4;
  if (blockIdx.x < 256) {
    int bi = blockIdx.x;
    int mat = bi >> 7, rest = bi & 127;
    int dt = rest >> 6, b = rest & 63;
    int nt = tid >> 6;
    u16* WH = WS;
    u16* WL = WS + 32 * LROW;
    {
      const u16* sH = (mat ? Wkhi : Wqhi) + (size_t)dt * 32 * CH;
      const u16* sL = (mat ? Wklo : Wqlo) + (size_t)dt * 32 * CH;
      STAGE_W(WH, sH)
      STAGE_W(WL, sL)
    }
    __syncthreads();
    const u16* B0h = xThi + ((size_t)b * NP + nt * 32 + lm) * CH + lk * 8;
    const u16* B1h = B0h + 16 * CH;
    const u16* B0l = xTlo + ((size_t)b * NP + nt * 32 + lm) * CH + lk * 8;
    const u16* B1l = B0l + 16 * CH;
    f32x4 acc[2][2] = {};
#pragma unroll
    for (int kb = 0; kb < 4; kb++) {
      sh8 rb0h[2], rb1h[2], rb0l[2], rb1l[2];
#pragma unroll
      for (int u = 0; u < 2; u++) {
        int o = (kb * 2 + u) * 32;
        rb0h[u] = *(const sh8*)(B0h + o); rb1h[u] = *(const sh8*)(B1h + o);
        rb0l[u] = *(const sh8*)(B0l + o); rb1l[u] = *(const sh8*)(B1l + o);
      }
#pragma unroll
      for (int u = 0; u < 2; u++) {
        int o2 = (kb * 2 + u) * 32 + lk * 8;
        sh8 a0h = *(const sh8*)&WH[lm * LROW + o2];
        sh8 a1h = *(const sh8*)&WH[(16 + lm) * LROW + o2];
        sh8 a0l = *(const sh8*)&WL[lm * LROW + o2];
        sh8 a1l = *(const sh8*)&WL[(16 + lm) * LROW + o2];
        acc[0][0] = MFMA(a0h, rb0h[u], acc[0][0]);
        acc[0][0] = MFMA(a0h, rb0l[u], acc[0][0]);
        acc[0][0] = MFMA(a0l, rb0h[u], acc[0][0]);
        acc[0][1] = MFMA(a0h, rb1h[u], acc[0][1]);
        acc[0][1] = MFMA(a0h, rb1l[u], acc[0][1]);
        acc[0][1] = MFMA(a0l, rb1h[u], acc[0][1]);
        acc[1][0] = MFMA(a1h, rb0h[u], acc[1][0]);
        acc[1][0] = MFMA(a1h, rb0l[u], acc[1][0]);
        acc[1][0] = MFMA(a1l, rb0h[u], acc[1][0]);
        acc[1][1] = MFMA(a1h, rb1h[u], acc[1][1]);
        acc[1][1] = MFMA(a1h, rb1l[u], acc[1][1]);
        acc[1][1] = MFMA(a1l, rb1h[u], acc[1][1]);
      }
    }
#pragma unroll
    for (int i = 0; i < 2; i++)
#pragma unroll
      for (int j = 0; j < 2; j++) {
        int n = nt * 32 + j * 16 + lm;
        int d0 = dt * 32 + i * 16 + lk * 4;
        size_t off = ((size_t)b * NP + n) * DQ + d0;
        f32x4 v = acc[i][j];
        u16 h[4], lo[4];
#pragma unroll
        for (int r2 = 0; r2 < 4; r2++) {
          h[r2] = f2bf(v[r2]);
          lo[r2] = f2bf(v[r2] - bf2f(h[r2]));
        }
        if (mat == 0) {
          float4 vo = {v[0], v[1], v[2], v[3]};
          *(float4*)&XQ[off] = vo;
          *(uint2*)&XQhi[off] = *(const uint2*)h;
          *(uint2*)&XQlo[off] = *(const uint2*)lo;
        } else {
          *(uint2*)&KLThi[off] = *(const uint2*)h;
          *(uint2*)&KLTlo[off] = *(const uint2*)lo;
        }
      }
  } else if (blockIdx.x < 768) {
    int bi = blockIdx.x - 256;
    int ct = bi >> 6, b = bi & 63;
    int nt = tid >> 6;
    u16* WH = WS;
    {
      const u16* sH = Wv + (size_t)ct * 32 * CH;
      STAGE_W(WH, sH)
    }
    __syncthreads();
    float bx = beta_x[layer];
    const u16* X0 = xThi + ((size_t)b * NP + nt * 32 + lm) * CH + lk * 8;
    const u16* X1 = X0 + 16 * CH;
    f32x4 a00 = {}, a01 = {}, a10 = {}, a11 = {};
    // D[row=c][col=n]
#pragma unroll
    for (int kb = 0; kb < 2; kb++) {
      sh8 rx0[4], rx1[4];
#pragma unroll
      for (int u = 0; u < 4; u++) {
        int o = (kb * 4 + u) * 32;
        rx0[u] = *(const sh8*)(X0 + o); rx1[u] = *(const sh8*)(X1 + o);
      }
#pragma unroll
      for (int u = 0; u < 4; u++) {
        int o2 = (kb * 4 + u) * 32 + lk * 8;
        sh8 w0 = *(const sh8*)&WH[lm * LROW + o2];
        sh8 w1 = *(const sh8*)&WH[(16 + lm) * LROW + o2];
        a00 = MFMA(w0, rx0[u], a00);
        a01 = MFMA(w0, rx1[u], a01);
        a10 = MFMA(w1, rx0[u], a10);
        a11 = MFMA(w1, rx1[u], a11);
      }
    }
    f32x4 acc[2][2] = {{a00, a01}, {a10, a11}};
#pragma unroll
    for (int i = 0; i < 2; i++)
#pragma unroll
      for (int j = 0; j < 2; j++) {
        int c0 = ct * 32 + i * 16 + lk * 4;
        int n = nt * 32 + j * 16 + lm;
        size_t off = ((size_t)b * NP + n) * CH + c0;
        uint2 up = *(const uint2*)&UPt[off];
        const u16* uph = (const u16*)&up;
        u16 ov[4];
#pragma unroll
        for (int r2 = 0; r2 < 4; r2++)
          ov[r2] = f2bf(bx * acc[i][j][r2] + bf2f(uph[r2]));
        *(uint2*)&Ut[off] = *(const uint2*)ov;
      }
  } else {
    int bi = blockIdx.x - 768;
    int ct = bi >> 6, b = bi & 63;
    int nt = tid >> 6;
    u16* WH = WS;
    {
      const u16* sH = Wlbf + (size_t)ct * 32 * CH;
      STAGE_W(WH, sH)
    }
    __syncthreads();
    const u16* X0 = xThi + ((size_t)b * NP + nt * 32 + lm) * CH + lk * 8;
    const u16* X1 = X0 + 16 * CH;
    f32x4 a00 = {}, a01 = {}, a10 = {}, a11 = {};
    // D[row=n][col=c]
#pragma unroll
    for (int kb = 0; kb < 2; kb++) {
      sh8 rx0[4], rx1[4];
#pragma unroll
      for (int u = 0; u < 4; u++) {
        int o = (kb * 4 + u) * 32;
        rx0[u] = *(const sh8*)(X0 + o); rx1[u] = *(const sh8*)(X1 + o);
      }
#pragma unroll
      for (int u = 0; u < 4; u++) {
        int o2 = (kb * 4 + u) * 32 + lk * 8;
        sh8 w0 = *(const sh8*)&WH[lm * LROW + o2];
        sh8 w1 = *(const sh8*)&WH[(16 + lm) * LROW + o2];
        a00 = MFMA(rx0[u], w0, a00);
        a01 = MFMA(rx0[u], w1, a01);
        a10 = MFMA(rx1[u], w0, a10);
        a11 = MFMA(rx1[u], w1, a11);
      }
    }
    f32x4 acc[2][2] = {{a00, a01}, {a10, a11}};
#pragma unroll
    for (int i = 0; i < 2; i++)
#pragma unroll
      for (int j = 0; j < 2; j++) {
        int n0 = nt * 32 + i * 16 + lk * 4;
        int c = ct * 32 + j * 16 + lm;
        float4 v = {acc[i][j][0], acc[i][j][1], acc[i][j][2], acc[i][j][3]};
        *(float4*)&Afp[((size_t)b * CH + c) * NP + n0] = v;
      }
  }
}

// ---------------------------------------------------------------------------
// Merged: blocks [0,256): fused attention middle (energy MFMA + q1/c1 + bias
// sincos + softmax + P^T bf16 + colsum partials); [256,768): WlU = Wl@Ut.
__global__ __launch_bounds__(256) void k_attwlu(
    const float* __restrict__ XQ,
    const u16* __restrict__ XQhi, const u16* __restrict__ XQlo,
    const u16* __restrict__ KLThi, const u16* __restrict__ KLTlo,
    const u16* __restrict__ KP2hi, const u16* __restrict__ KP2lo,
    const float* __restrict__ p1w, const float* __restrict__ p1b,
    const float* __restrict__ AS, const float* __restrict__ beta_w, int layer,
    u16* __restrict__ PT, float* __restrict__ SCLp,
    const u16* __restrict__ Ut, const u16* __restrict__ Wlbf,
    u16* __restrict__ WlU)
{
  __shared__ __align__(16) char smem[51584];
  int tid = threadIdx.x;
  int lane = tid & 63;
  int lm = lane & 15, lk = lane >> 4;
  if (blockIdx.x < 256) {
    int g = blockIdx.x & 3, b = blockIdx.x >> 2;
    int wave = tid >> 6;
    float* xqs  = (float*)smem;              // [32][65]
    float* pwsh = xqs + 32 * 65;             // [64][68]
    float* pbsh = pwsh + 64 * 68;            // [64]
    float* divs = pbsh + 64;                 // [32]
    float* q1sh = divs + 32;                 // [32][66]
    float* c1sh = q1sh + 32 * 66;            // [32]
    float* Esh  = c1sh + 32;                 // [32][132]
    // phase 0: stage
    {
      const float* src = XQ + ((size_t)b * NP + g * 32) * DQ;
#pragma unroll
      for (int i = 0; i < 8; i++) {
        int idx = tid + i * 256;
        xqs[(idx >> 6) * 65 + (idx & 63)] = src[idx];
      }
#pragma unroll
      for (int i = 0; i < 16; i++) {
        int idx = tid + i * 256;
        pwsh[(idx >> 6) * 68 + (idx & 63)] = p1w[idx];
      }
      if (tid < 64) pbsh[tid] = p1b[tid];
      if (tid >= 224) divs[tid - 224] = __expf(-(float)(tid - 224) * DIV_STEP);
    }
    __syncthreads();
    float bw = beta_w[layer], obw = 1.0f - bw;
    // phase 1a: q1/c1
    {
      int n = tid >> 3, d0 = (tid & 7) * 8;
      float acc[8] = {};
      float cacc = 0.0f;
      for (int o = 0; o < DQ; o++) {
        float xv = xqs[n * 65 + o];
        cacc = fmaf(pbsh[o], xv, cacc);
#pragma unroll
        for (int dd = 0; dd < 8; dd++)
          acc[dd] = fmaf(pwsh[o * 68 + d0 + dd], xv, acc[dd]);
      }
#pragma unroll
      for (int dd = 0; dd < 8; dd++) q1sh[n * 66 + d0 + dd] = acc[dd];
      if ((tid & 7) == 0) c1sh[n] = cacc;
    }
    // phase 1b: energy MFMA
    {
      int mt = wave;
      size_t arow = ((size_t)b * NP + mt * 32 + lm) * DQ + lk * 8;
      size_t brow = ((size_t)b * NP + g * 32 + lm) * DQ + lk * 8;
      const u16* L0h = KLThi + arow;
      const u16* L0l = KLTlo + arow;
      const u16* P0h = KP2hi + arow;
      const u16* P0l = KP2lo + arow;
      const u16* X0h = XQhi + brow;
      const u16* X0l = XQlo + brow;
      sh8 xh[2][2], xl[2][2], lh[2][2], llr[2][2], ph[2][2], pl[2][2];
#pragma unroll
      for (int row = 0; row < 2; row++) {
#pragma unroll
        for (int ks = 0; ks < 2; ks++) {
          int o = row * 16 * DQ + ks * 32;
          xh[row][ks] = *(const sh8*)(X0h + o);
          xl[row][ks] = *(const sh8*)(X0l + o);
          lh[row][ks] = *(const sh8*)(L0h + o);
          llr[row][ks] = *(const sh8*)(L0l + o);
          ph[row][ks] = *(const sh8*)(P0h + o);
          pl[row][ks] = *(const sh8*)(P0l + o);
        }
      }
      f32x4 aL[2][2] = {};
      f32x4 aP[2][2] = {};
#pragma unroll
      for (int ks = 0; ks < 2; ks++) {
#pragma unroll
        for (int i = 0; i < 2; i++) {
#pragma unroll
          for (int j = 0; j < 2; j++) {
            aL[i][j] = MFMA(lh[i][ks], xh[j][ks], aL[i][j]);
            aL[i][j] = MFMA(lh[i][ks], xl[j][ks], aL[i][j]);
            aL[i][j] = MFMA(llr[i][ks], xh[j][ks], aL[i][j]);
            aP[i][j] = MFMA(ph[i][ks], xh[j][ks], aP[i][j]);
            aP[i][j] = MFMA(ph[i][ks], xl[j][ks], aP[i][j]);
            aP[i][j] = MFMA(pl[i][ks], xh[j][ks], aP[i][j]);
          }
        }
      }
#pragma unroll
      for (int i = 0; i < 2; i++)
#pragma unroll
        for (int j = 0; j < 2; j++) {
          int nloc = j * 16 + lm;
          int mloc = mt * 32 + i * 16 + lk * 4;
          float4 v;
          v.x = bw * aL[i][j][0] + obw * aP[i][j][0];
          v.y = bw * aL[i][j][1] + obw * aP[i][j][1];
          v.z = bw * aL[i][j][2] + obw * aP[i][j][2];
          v.w = bw * aL[i][j][3] + obw * aP[i][j][3];
          *(float4*)&Esh[nloc * 132 + mloc] = v;
        }
    }
    __syncthreads();
    // phase 2: bias + softmax
    {
      int n = tid >> 3, mc = (tid & 7) * 16;
      size_t asrow = ((size_t)b * NP + g * 32 + n) * NP + mc;
      float idxv[16], bias[16];
      float c1v = c1sh[n];
#pragma unroll
      for (int k4 = 0; k4 < 4; k4++) {
        float4 a4 = *(const float4*)&AS[asrow + k4 * 4];
        idxv[k4 * 4 + 0] = a4.x * ANG_FACTOR;
        idxv[k4 * 4 + 1] = a4.y * ANG_FACTOR;
        idxv[k4 * 4 + 2] = a4.z * ANG_FACTOR;
        idxv[k4 * 4 + 3] = a4.w * ANG_FACTOR;
      }
#pragma unroll
      for (int k = 0; k < 16; k++) bias[k] = c1v;
      for (int j = 0; j < 32; j++) {
        float dv = divs[j];
        float qs = q1sh[n * 66 + 2 * j], qc = q1sh[n * 66 + 2 * j + 1];
#pragma unroll
        for (int k = 0; k < 16; k++) {
          float s, c;
          __sincosf(idxv[k] * dv, &s, &c);
          bias[k] = fmaf(qs, s, bias[k]);
          bias[k] = fmaf(qc, c, bias[k]);
        }
      }
      float ev[16], mx = -1e30f;
#pragma unroll
      for (int k = 0; k < 16; k++) {
        ev[k] = Esh[n * 132 + mc + k] + bw * bias[k];
        mx = fmaxf(mx, ev[k]);
      }
      mx = fmaxf(mx, __shfl_xor(mx, 1));
      mx = fmaxf(mx, __shfl_xor(mx, 2));
      mx = fmaxf(mx, __shfl_xor(mx, 4));
      float s = 0.0f;
#pragma unroll
      for (int k = 0; k < 16; k++) {
        ev[k] = __expf(ev[k] - mx);
        s += ev[k];
      }
      s += __shfl_xor(s, 1);
      s += __shfl_xor(s, 2);
      s += __shfl_xor(s, 4);
      float inv = 1.0f / s;
#pragma unroll
      for (int k = 0; k < 16; k++) Esh[n * 132 + mc + k] = ev[k] * inv;
    }
    __syncthreads();
    // phase 3: P^T bf16 + colsum partial
    {
      int m = tid >> 1, nc = (tid & 1) * 16;
      float s = 0.0f;
      u16 tmp[16];
#pragma unroll
      for (int k = 0; k < 16; k++) {
        float v = Esh[(nc + k) * 132 + m];
        s += v;
        tmp[k] = f2bf(v);
      }
      u16* dst = PT + ((size_t)b * NP + m) * NP + g * 32 + nc;
      *(uint4*)&dst[0] = *(const uint4*)&tmp[0];
      *(uint4*)&dst[8] = *(const uint4*)&tmp[8];
      s += __shfl_xor(s, 1);
      if ((tid & 1) == 0) SCLp[((size_t)b * 4 + g) * NP + m] = s;
    }
  } else {
    // wlu: WlU[b][c'][n] = Wl@Ut (K=256 over c). D[row=n][col=c'].
    int bi = blockIdx.x - 256;
    int ct = bi >> 6, b = bi & 63;
    int nt = tid >> 6;
    u16* WH = (u16*)smem;
    {
      const u16* sH = Wlbf + (size_t)ct * 32 * CH;
      STAGE_W(WH, sH)
    }
    __syncthreads();
    const u16* A0 = Ut + ((size_t)b * NP + nt * 32 + lm) * CH + lk * 8;
    const u16* A1 = A0 + 16 * CH;
    f32x4 a00 = {}, a01 = {}, a10 = {}, a11 = {};
#pragma unroll
    for (int kb = 0; kb < 2; kb++) {
      sh8 rA0[4], rA1[4];
#pragma unroll
      for (int u = 0; u < 4; u++) {
        int o = (kb * 4 + u) * 32;
        rA0[u] = *(const sh8*)(A0 + o); rA1[u] = *(const sh8*)(A1 + o);
      }
#pragma unroll
      for (int u = 0; u < 4; u++) {
        int o2 = (kb * 4 + u) * 32 + lk * 8;
        sh8 w0 = *(const sh8*)&WH[lm * LROW + o2];
        sh8 w1 = *(const sh8*)&WH[(16 + lm) * LROW + o2];
        a00 = MFMA(rA0[u], w0, a00);
        a01 = MFMA(rA0[u], w1, a01);
        a10 = MFMA(rA1[u], w0, a10);
        a11 = MFMA(rA1[u], w1, a11);
      }
    }
    f32x4 acc[2][2] = {{a00, a01}, {a10, a11}};
#pragma unroll
    for (int i = 0; i < 2; i++)
#pragma unroll
      for (int j = 0; j < 2; j++) {
        int n0 = nt * 32 + i * 16 + lk * 4;
        int c = ct * 32 + j * 16 + lm;
        u16 ov[4];
#pragma unroll
        for (int r2 = 0; r2 < 4; r2++) ov[r2] = f2bf(acc[i][j][r2]);
        *(uint2*)&WlU[((size_t)b * CH + c) * NP + n0] = *(const uint2*)ov;
      }
  }
}

// ---------------------------------------------------------------------------
// out = x + gelu(BN(Afp - (WlU@P)*scl + bl)); writes next layer's xT hi/lo.
__global__ __launch_bounds__(256) void k_h3(
    const u16* __restrict__ WlU, const u16* __restrict__ PT,
    const float* __restrict__ SCLp, const float* __restrict__ Afp,
    const float* __restrict__ bl, const float* __restrict__ bng,
    const float* __restrict__ bnb, const float* __restrict__ xsrc, int xbs,
    float* __restrict__ out, int layer,
    u16* __restrict__ xThi_o, u16* __restrict__ xTlo_o)
{
  int bi = blockIdx.x;
  int ct = bi >> 6, b = bi & 63;
  int tid = threadIdx.x, lane = tid & 63, nt = tid >> 6;
  int lm = lane & 15, lk = lane >> 4;
  __shared__ __align__(16) u16 WS2[32 * LROW2];
  {
    const u16* src = WlU + ((size_t)b * CH + ct * 32) * NP;
#pragma unroll
    for (int it = 0; it < 2; it++) {
      int idx = tid + it * 256, row = idx >> 4, chq = idx & 15;
      *(uint4*)&WS2[row * LROW2 + chq * 8] = *(const uint4*)(src + row * NP + chq * 8);
    }
  }
  __syncthreads();
  const u16* B0 = PT + ((size_t)b * NP + nt * 32 + lm) * NP + lk * 8;
  const u16* B1 = B0 + 16 * NP;
  sh8 rB0[4], rB1[4];
#pragma unroll
  for (int ks = 0; ks < 4; ks++) {
    int o = ks * 32;
    rB0[ks] = *(const sh8*)(B0 + o);
    rB1[ks] = *(const sh8*)(B1 + o);
  }
  f32x4 a00 = {}, a01 = {}, a10 = {}, a11 = {};
  // D[row=c'][col=m]
#pragma unroll
  for (int ks = 0; ks < 4; ks++) {
    int o2 = ks * 32 + lk * 8;
    sh8 w0 = *(const sh8*)&WS2[lm * LROW2 + o2];
    sh8 w1 = *(const sh8*)&WS2[(16 + lm) * LROW2 + o2];
    a00 = MFMA(w0, rB0[ks], a00);
    a01 = MFMA(w0, rB1[ks], a01);
    a10 = MFMA(w1, rB0[ks], a10);
    a11 = MFMA(w1, rB1[ks], a11);
  }
  f32x4 acc[2][2] = {{a00, a01}, {a10, a11}};
  const float rbn = 0.999995000037499687f;  // 1/sqrt(1+1e-5)
#pragma unroll
  for (int i = 0; i < 2; i++)
#pragma unroll
    for (int j = 0; j < 2; j++) {
      int m = nt * 32 + j * 16 + lm;
      int cq = ct * 32 + i * 16 + lk * 4;
      const float* sp = SCLp + (size_t)b * 4 * NP + m;
      float scl = 1.0f / (1e-12f + sp[0] + sp[NP] + sp[2 * NP] + sp[3 * NP]);
      u16 hh[4], llv[4];
#pragma unroll
      for (int r = 0; r < 4; r++) {
        int c = cq + r;
        float a = Afp[((size_t)b * CH + c) * NP + m];
        float h = a - acc[i][j][r] * scl + bl[c];
        h = h * rbn * bng[c] + bnb[c];
        float gg = 0.5f * h * (1.0f + erff(h * 0.70710678118654752440f));
        float ov = xsrc[(size_t)b * xbs + (size_t)c * NP + m] + gg;
        out[((size_t)b * 4 * CH + (size_t)layer * CH + c) * NP + m] = ov;
        hh[r] = f2bf(ov);
        llv[r] = f2bf(ov - bf2f(hh[r]));
      }
      size_t xoff = ((size_t)b * NP + m) * CH + cq;
      *(uint2*)&xThi_o[xoff] = *(const uint2*)hh;
      *(uint2*)&xTlo_o[xoff] = *(const uint2*)llv;
    }
}

// ---------------------------------------------------------------------------
extern "C" void kernel_launch(void* const* d_in, const int* in_sizes, int n_in,
                              void* d_out, int out_size, void* d_ws, size_t ws_size,
                              hipStream_t stream)
{
  (void)in_sizes; (void)n_in; (void)out_size; (void)ws_size;
  const float* lrf     = (const float*)d_in[0];
  const float* pca     = (const float*)d_in[1];
  const float* a_self  = (const float*)d_in[2];
  const float* a_cross = (const float*)d_in[3];
  const float* Wq  = (const float*)d_in[4];
  const float* Wk  = (const float*)d_in[5];
  const float* Wv  = (const float*)d_in[6];
  const float* Wvp = (const float*)d_in[7];
  const float* Wl  = (const float*)d_in[8];
  const float* bl  = (const float*)d_in[9];
  const float* bng = (const float*)d_in[10];
  const float* bnb = (const float*)d_in[11];
  const float* p1w = (const float*)d_in[12];
  const float* p1b = (const float*)d_in[13];
  const float* p2w = (const float*)d_in[14];
  const float* p2b = (const float*)d_in[15];
  const float* beta_x = (const float*)d_in[16];
  const float* beta_w = (const float*)d_in[17];
  float* out = (float*)d_out;
  float* ws  = (float*)d_ws;

  // ---- workspace carve ----
  const size_t QKN = (size_t)BB * NP * DQ;        // 524288
  const size_t ENN = (size_t)BB * NP * NP;        // 1048576
  const size_t XCN = (size_t)BB * NP * CH;        // 2097152

  float* XQ   = ws;
  float* E2A  = XQ + QKN;
  float* SCLp = E2A + (size_t)NLAYERS * QKN;
  float* Afp  = SCLp + (size_t)BB * 4 * NP;
  u16* up = (u16*)(Afp + (size_t)BB * CH * NP);
  u16* xThi = up;   up += XCN;
  u16* xTlo = up;   up += XCN;
  u16* pThi = up;   up += XCN;
  u16* pTlo = up;   up += XCN;
  u16* XQhi = up;   up += QKN;
  u16* XQlo = up;   up += QKN;
  u16* KLThi = up;  up += QKN;
  u16* KLTlo = up;  up += QKN;
  u16* KP2hiA = up; up += (size_t)NLAYERS * QKN;
  u16* KP2loA = up; up += (size_t)NLAYERS * QKN;
  u16* UPt = up;    up += (size_t)NLAYERS * XCN;
  u16* Ut = up;     up += XCN;
  u16* WlUb = up;   up += XCN;
  u16* PTbf = up;   up += ENN;
  u16* Wvbf = up;   up += (size_t)NLAYERS * CH * CH;
  u16* Wvpbf = up;  up += (size_t)NLAYERS * CH * CH;
  u16* Wlbf = up;   up += (size_t)NLAYERS * CH * CH;
  u16* Wqhi = up;   up += (size_t)NLAYERS * DQ * CH;
  u16* Wqlo = up;   up += (size_t)NLAYERS * DQ * CH;
  u16* Wkhi = up;   up += (size_t)NLAYERS * DQ * CH;
  u16* Wklo = up;   up += (size_t)NLAYERS * DQ * CH;

  // ---- pre-loop (4 launches) ----
  k_cvt_all<<<dim3(896), 256, 0, stream>>>(
      Wv, Wvp, Wl, Wq, Wk, Wvbf, Wvpbf, Wlbf, Wqhi, Wqlo, Wkhi, Wklo);
  k_xt2<<<dim3(2, 8, BB), 256, 0, stream>>>(pca, lrf, pThi, pTlo, xThi, xTlo);
  k_e2_all<<<dim3(BB * NP / 4, NLAYERS), 256, 0, stream>>>(a_cross, p2w, p2b, E2A);
  k_pre2<<<dim3(2560), 256, 0, stream>>>(
      pThi, pTlo, Wqhi, Wqlo, Wvpbf, E2A, beta_x, KP2hiA, KP2loA, UPt);

  // ---- layer loop (3 launches each) ----
  for (int l = 0; l < NLAYERS; l++) {
    const float* xsrc = (l == 0) ? lrf : (out + (size_t)(l - 1) * CH * NP);
    int xbs = (l == 0) ? CH * NP : 4 * CH * NP;
    k_qu3<<<dim3(1280), 256, 0, stream>>>(
        xThi, xTlo,
        Wqhi + (size_t)l * DQ * CH, Wqlo + (size_t)l * DQ * CH,
        Wkhi + (size_t)l * DQ * CH, Wklo + (size_t)l * DQ * CH,
        Wvbf + (size_t)l * CH * CH, Wlbf + (size_t)l * CH * CH,
        UPt + (size_t)l * XCN, beta_x, l,
        XQ, XQhi, XQlo, KLThi, KLTlo, Ut, Afp);
    k_attwlu<<<dim3(768), 256, 0, stream>>>(
        XQ, XQhi, XQlo, KLThi, KLTlo,
        KP2hiA + (size_t)l * QKN, KP2loA + (size_t)l * QKN,
        p1w + (size_t)l * DQ * DQ, p1b + (size_t)l * DQ,
        a_self, beta_w, l, PTbf, SCLp,
        Ut, Wlbf + (size_t)l * CH * CH, WlUb);
    k_h3<<<dim3(512), 256, 0, stream>>>(
        WlUb, PTbf, SCLp, Afp, bl + (size_t)l * CH, bng + (size_t)l * CH,
        bnb + (size_t)l * CH, xsrc, xbs, out, l, xThi, xTlo);
  }
}

// Round 11
// 258.306 us; speedup vs baseline: 3.4477x; 1.0469x over previous
//
#include <hip/hip_runtime.h>
#include <cstdint>
#include <cstddef>

// Round 11: (1) k_attwlu att-part: q1 via MFMA on XQhi@p1wT (waves 0-1) + c1
// via 8-lane shuffle dot; kills the serial q1c1 VALU/LDS chain and the
// xqs/pwsh stages (att LDS 51.6->25.9KB). (2) XQ fp32 plane dropped (only
// consumer was q1c1). (3) cvt/xt2/e2/p1wT merged into one k_init launch.
// Launches 16 -> 14.

#define BB 64      // batch
#define CH 256     // channels
#define NP 128     // points
#define DQ 64      // q/k dim
#define NLAYERS 4

#define ANG_FACTOR 3.8197186342054885f   // 180/(pi*15) = 12/pi
#define DIV_STEP   0.28782313662425575f  // ln(10000)/32

#define LROW 264   // padded LDS row stride (u16) for 256-wide W tiles
#define LROW2 136  // padded LDS row stride (u16) for 128-wide WlU tiles

typedef unsigned short u16;
typedef __attribute__((ext_vector_type(8))) short sh8;   // 8 bf16 = 4 VGPR
typedef __attribute__((ext_vector_type(4))) float f32x4; // MFMA C/D
#define MFMA(a, b, c) __builtin_amdgcn_mfma_f32_16x16x32_bf16(a, b, c, 0, 0, 0)

static __device__ __forceinline__ u16 f2bf(float x) {
  unsigned u = __float_as_uint(x);
  return (u16)((u + 0x7FFFu + ((u >> 16) & 1u)) >> 16);
}
static __device__ __forceinline__ float bf2f(u16 h) {
  return __uint_as_float(((unsigned)h) << 16);
}

// ---------------------------------------------------------------------------
// Merged init: [0,768) value-weight cvt; [768,896) Wq/Wk hi/lo cvt;
// [896,900) p1wT; [900,1924) x/pca transpose+split; [1924,10116) E2A.
__global__ __launch_bounds__(256) void k_init(
    const float* __restrict__ Wv, const float* __restrict__ Wvp,
    const float* __restrict__ Wl, const float* __restrict__ Wq,
    const float* __restrict__ Wk, const float* __restrict__ p1w,
    const float* __restrict__ pca, const float* __restrict__ lrf,
    const float* __restrict__ ac, const float* __restrict__ p2w,
    const float* __restrict__ p2b,
    u16* __restrict__ Wvbf, u16* __restrict__ Wvpbf, u16* __restrict__ Wlbf,
    u16* __restrict__ Wqhi, u16* __restrict__ Wqlo,
    u16* __restrict__ Wkhi, u16* __restrict__ Wklo, u16* __restrict__ p1wT,
    u16* __restrict__ pThi, u16* __restrict__ pTlo,
    u16* __restrict__ xThi, u16* __restrict__ xTlo,
    float* __restrict__ E2A)
{
  __shared__ __align__(16) char smem[17920];
  int blk = blockIdx.x, tid = threadIdx.x;
  if (blk < 768) {
    const float* s = (blk < 256) ? Wv : (blk < 512) ? Wvp : Wl;
    u16* d = (blk < 256) ? Wvbf : (blk < 512) ? Wvpbf : Wlbf;
    int i = ((blk & 255) * 256 + tid) * 4;
    float4 v = *(const float4*)(s + i);
    u16 o[4] = {f2bf(v.x), f2bf(v.y), f2bf(v.z), f2bf(v.w)};
    *(uint2*)(d + i) = *(const uint2*)o;
  } else if (blk < 896) {
    int bb = blk - 768;
    const float* s = (bb < 64) ? Wq : Wk;
    u16* dh = (bb < 64) ? Wqhi : Wkhi;
    u16* dl = (bb < 64) ? Wqlo : Wklo;
    int i = ((bb & 63) * 256 + tid) * 4;
    float4 v = *(const float4*)(s + i);
    float vv[4] = {v.x, v.y, v.z, v.w};
    u16 h[4], l[4];
#pragma unroll
    for (int r = 0; r < 4; r++) {
      h[r] = f2bf(vv[r]);
      l[r] = f2bf(vv[r] - bf2f(h[r]));
    }
    *(uint2*)(dh + i) = *(const uint2*)h;
    *(uint2*)(dl + i) = *(const uint2*)l;
  } else if (blk < 900) {
    // p1wT[l][d][o] = bf(p1w[l][o][d])
    int l = blk - 896;
    const float* src = p1w + (size_t)l * DQ * DQ;
    u16* dst = p1wT + (size_t)l * DQ * DQ;
#pragma unroll
    for (int i = 0; i < 16; i++) {
      int idx = tid + i * 256;
      int dd = idx >> 6, oo = idx & 63;
      dst[idx] = f2bf(src[oo * DQ + dd]);
    }
  } else if (blk < 1924) {
    int bi = blk - 900;
    int nt = bi & 1, y = (bi >> 1) & 7, b = bi >> 4;
    int ct = y & 3, is_lrf = y >> 2;
    const float* x = is_lrf ? lrf : pca;
    u16* hiT = is_lrf ? xThi : pThi;
    u16* loT = is_lrf ? xTlo : pTlo;
    float* tl = (float*)smem;   // [64][65]
    {
      int col = tid & 63, rq = tid >> 6;
      const float* src = x + (size_t)b * CH * NP + (size_t)(ct * 64) * NP + nt * 64;
#pragma unroll
      for (int i = 0; i < 16; i++) {
        int c = rq + i * 4;
        tl[col * 65 + c] = src[(size_t)c * NP + col];
      }
    }
    __syncthreads();
    {
      int cloc = tid & 63, nq = tid >> 6;
#pragma unroll
      for (int i = 0; i < 16; i++) {
        int n = nq + i * 4;
        float v = tl[n * 65 + cloc];
        u16 h = f2bf(v);
        u16 l = f2bf(v - bf2f(h));
        size_t off = ((size_t)b * NP + nt * 64 + n) * CH + ct * 64 + cloc;
        hiT[off] = h;
        loT[off] = l;
      }
    }
  } else {
    int bi = blk - 1924;
    int l = bi >> 11, xx = bi & 2047;
    const float* pwg = p2w + (size_t)l * DQ * DQ;
    const float* pbg = p2b + (size_t)l * DQ;
    float* E2 = E2A + (size_t)l * BB * NP * DQ;
    float* pw = (float*)smem;        // [64][65]
    float* emb = pw + 64 * 65;       // [4][64]
    float* pb = emb + 4 * 64;        // [64]
    int bm0 = xx * 4;
#pragma unroll
    for (int i = 0; i < 16; i++) {
      int idx = tid + i * 256;
      pw[(idx >> 6) * 65 + (idx & 63)] = pwg[idx];
    }
    if (tid < DQ) pb[tid] = pbg[tid];
    if (tid < 128) {
      int ml = tid >> 5, j = tid & 31;
      float a = ac[bm0 + ml];
      float s, c;
      __sincosf(a * ANG_FACTOR * __expf(-(float)j * DIV_STEP), &s, &c);
      emb[ml * DQ + 2 * j] = s;
      emb[ml * DQ + 2 * j + 1] = c;
    }
    __syncthreads();
    int mloc = tid >> 6, o = tid & 63;
    float acc = pb[o];
#pragma unroll
    for (int d = 0; d < DQ; d++) acc = fmaf(pw[o * 65 + d], emb[mloc * DQ + d], acc);
    E2[(size_t)(bm0 + mloc) * DQ + o] = acc;
  }
}

// ---------------------------------------------------------------------------
#define STAGE_W(dst, src)                                                    \
  _Pragma("unroll")                                                          \
  for (int it = 0; it < 4; it++) {                                           \
    int idx = threadIdx.x + it * 256, row = idx >> 5, ch = idx & 31;         \
    *(uint4*)&dst[row * LROW + ch * 8] =                                     \
        *(const uint4*)(src + row * 256 + ch * 8);                           \
  }

// ---------------------------------------------------------------------------
// blocks [0,512): KP2A[l] = split(Wq[l]@pca + E2A[l]);
// [512,2560): UPt[l][b][n][c] = bf((1-bx[l])*Wvp[l]@pca).
__global__ __launch_bounds__(256) void k_pre2(
    const u16* __restrict__ pThi, const u16* __restrict__ pTlo,
    const u16* __restrict__ Wqhi, const u16* __restrict__ Wqlo,
    const u16* __restrict__ Wvpbf, const float* __restrict__ E2A,
    const float* __restrict__ beta_x,
    u16* __restrict__ KP2hiA, u16* __restrict__ KP2loA, u16* __restrict__ UPt)
{
  __shared__ __align__(16) u16 WS[2 * 32 * LROW];
  int tid = threadIdx.x, lane = tid & 63;
  int lm = lane & 15, lk = lane >> 4;
  if (blockIdx.x < 512) {
    int bi = blockIdx.x;
    int l = bi >> 7, rest = bi & 127;
    int dt = rest >> 6, b = rest & 63;
    int nt = tid >> 6;
    u16* WH = WS;
    u16* WL = WS + 32 * LROW;
    {
      const u16* sH = Wqhi + (size_t)l * DQ * CH + (size_t)dt * 32 * CH;
      const u16* sL = Wqlo + (size_t)l * DQ * CH + (size_t)dt * 32 * CH;
      STAGE_W(WH, sH)
      STAGE_W(WL, sL)
    }
    __syncthreads();
    const u16* B0h = pThi + ((size_t)b * NP + nt * 32 + lm) * CH + lk * 8;
    const u16* B1h = B0h + 16 * CH;
    const u16* B0l = pTlo + ((size_t)b * NP + nt * 32 + lm) * CH + lk * 8;
    const u16* B1l = B0l + 16 * CH;
    f32x4 acc[2][2] = {};
#pragma unroll
    for (int kb = 0; kb < 4; kb++) {
      sh8 rb0h[2], rb1h[2], rb0l[2], rb1l[2];
#pragma unroll
      for (int u = 0; u < 2; u++) {
        int o = (kb * 2 + u) * 32;
        rb0h[u] = *(const sh8*)(B0h + o); rb1h[u] = *(const sh8*)(B1h + o);
        rb0l[u] = *(const sh8*)(B0l + o); rb1l[u] = *(const sh8*)(B1l + o);
      }
#pragma unroll
      for (int u = 0; u < 2; u++) {
        int o2 = (kb * 2 + u) * 32 + lk * 8;
        sh8 a0h = *(const sh8*)&WH[lm * LROW + o2];
        sh8 a1h = *(const sh8*)&WH[(16 + lm) * LROW + o2];
        sh8 a0l = *(const sh8*)&WL[lm * LROW + o2];
        sh8 a1l = *(const sh8*)&WL[(16 + lm) * LROW + o2];
        acc[0][0] = MFMA(a0h, rb0h[u], acc[0][0]);
        acc[0][0] = MFMA(a0h, rb0l[u], acc[0][0]);
        acc[0][0] = MFMA(a0l, rb0h[u], acc[0][0]);
        acc[0][1] = MFMA(a0h, rb1h[u], acc[0][1]);
        acc[0][1] = MFMA(a0h, rb1l[u], acc[0][1]);
        acc[0][1] = MFMA(a0l, rb1h[u], acc[0][1]);
        acc[1][0] = MFMA(a1h, rb0h[u], acc[1][0]);
        acc[1][0] = MFMA(a1h, rb0l[u], acc[1][0]);
        acc[1][0] = MFMA(a1l, rb0h[u], acc[1][0]);
        acc[1][1] = MFMA(a1h, rb1h[u], acc[1][1]);
        acc[1][1] = MFMA(a1h, rb1l[u], acc[1][1]);
        acc[1][1] = MFMA(a1l, rb1h[u], acc[1][1]);
      }
    }
#pragma unroll
    for (int i = 0; i < 2; i++)
#pragma unroll
      for (int j = 0; j < 2; j++) {
        int n = nt * 32 + j * 16 + lm;
        int d0 = dt * 32 + i * 16 + lk * 4;
        size_t off = (((size_t)l * BB + b) * NP + n) * DQ + d0;
        f32x4 v = acc[i][j];
        float4 e = *(const float4*)&E2A[off];
        v[0] += e.x; v[1] += e.y; v[2] += e.z; v[3] += e.w;
        u16 h[4], lo[4];
#pragma unroll
        for (int r2 = 0; r2 < 4; r2++) {
          h[r2] = f2bf(v[r2]);
          lo[r2] = f2bf(v[r2] - bf2f(h[r2]));
        }
        *(uint2*)&KP2hiA[off] = *(const uint2*)h;
        *(uint2*)&KP2loA[off] = *(const uint2*)lo;
      }
  } else {
    int bi = blockIdx.x - 512;
    int l = bi >> 9, rest = bi & 511;
    int ct = rest >> 6, b = rest & 63;
    int nt = tid >> 6;
    u16* WH = WS;
    {
      const u16* sH = Wvpbf + (size_t)l * CH * CH + (size_t)ct * 32 * CH;
      STAGE_W(WH, sH)
    }
    __syncthreads();
    float obx = 1.0f - beta_x[l];
    const u16* X0 = pThi + ((size_t)b * NP + nt * 32 + lm) * CH + lk * 8;
    const u16* X1 = X0 + 16 * CH;
    f32x4 a00 = {}, a01 = {}, a10 = {}, a11 = {};
#pragma unroll
    for (int kb = 0; kb < 2; kb++) {
      sh8 rx0[4], rx1[4];
#pragma unroll
      for (int u = 0; u < 4; u++) {
        int o = (kb * 4 + u) * 32;
        rx0[u] = *(const sh8*)(X0 + o); rx1[u] = *(const sh8*)(X1 + o);
      }
#pragma unroll
      for (int u = 0; u < 4; u++) {
        int o2 = (kb * 4 + u) * 32 + lk * 8;
        sh8 w0 = *(const sh8*)&WH[lm * LROW + o2];
        sh8 w1 = *(const sh8*)&WH[(16 + lm) * LROW + o2];
        a00 = MFMA(w0, rx0[u], a00);
        a01 = MFMA(w0, rx1[u], a01);
        a10 = MFMA(w1, rx0[u], a10);
        a11 = MFMA(w1, rx1[u], a11);
      }
    }
    f32x4 acc[2][2] = {{a00, a01}, {a10, a11}};
#pragma unroll
    for (int i = 0; i < 2; i++)
#pragma unroll
      for (int j = 0; j < 2; j++) {
        int c0 = ct * 32 + i * 16 + lk * 4;
        int n = nt * 32 + j * 16 + lm;
        u16 ov[4];
#pragma unroll
        for (int r2 = 0; r2 < 4; r2++) ov[r2] = f2bf(obx * acc[i][j][r2]);
        *(uint2*)&UPt[(((size_t)l * BB + b) * NP + n) * CH + c0] = *(const uint2*)ov;
      }
  }
}

// ---------------------------------------------------------------------------
// Per-layer: [0,256): QK split-bf16 (XQ hi/lo, KLT hi/lo);
// [256,768): Ut[b][n][c]; [768,1280): Afp[b][c][n] = Wl@x (fp32).
__global__ __launch_bounds__(256) void k_qu3(
    const u16* __restrict__ xThi, const u16* __restrict__ xTlo,
    const u16* __restrict__ Wqhi, const u16* __restrict__ Wqlo,
    const u16* __restrict__ Wkhi, const u16* __restrict__ Wklo,
    const u16* __restrict__ Wv, const u16* __restrict__ Wlbf,
    const u16* __restrict__ UPt, const float* __restrict__ beta_x, int layer,
    u16* __restrict__ XQhi, u16* __restrict__ XQlo,
    u16* __restrict__ KLThi, u16* __restrict__ KLTlo,
    u16* __restrict__ Ut, float* __restrict__ Afp)
{
  __shared__ __align__(16) u16 WS[2 * 32 * LROW];
  int tid = threadIdx.x, lane = tid & 63;
  int lm = lane & 15, lk = lane >> 4;
  if (blockIdx.x < 256) {
    int bi = blockIdx.x;
    int mat = bi >> 7, rest = bi & 127;
    int dt = rest >> 6, b = rest & 63;
    int nt = tid >> 6;
    u16* WH = WS;
    u16* WL = WS + 32 * LROW;
    {
      const u16* sH = (mat ? Wkhi : Wqhi) + (size_t)dt * 32 * CH;
      const u16* sL = (mat ? Wklo : Wqlo) + (size_t)dt * 32 * CH;
      STAGE_W(WH, sH)
      STAGE_W(WL, sL)
    }
    __syncthreads();
    const u16* B0h = xThi + ((size_t)b * NP + nt * 32 + lm) * CH + lk * 8;
    const u16* B1h = B0h + 16 * CH;
    const u16* B0l = xTlo + ((size_t)b * NP + nt * 32 + lm) * CH + lk * 8;
    const u16* B1l = B0l + 16 * CH;
    f32x4 acc[2][2] = {};
#pragma unroll
    for (int kb = 0; kb < 4; kb++) {
      sh8 rb0h[2], rb1h[2], rb0l[2], rb1l[2];
#pragma unroll
      for (int u = 0; u < 2; u++) {
        int o = (kb * 2 + u) * 32;
        rb0h[u] = *(const sh8*)(B0h + o); rb1h[u] = *(const sh8*)(B1h + o);
        rb0l[u] = *(const sh8*)(B0l + o); rb1l[u] = *(const sh8*)(B1l + o);
      }
#pragma unroll
      for (int u = 0; u < 2; u++) {
        int o2 = (kb * 2 + u) * 32 + lk * 8;
        sh8 a0h = *(const sh8*)&WH[lm * LROW + o2];
        sh8 a1h = *(const sh8*)&WH[(16 + lm) * LROW + o2];
        sh8 a0l = *(const sh8*)&WL[lm * LROW + o2];
        sh8 a1l = *(const sh8*)&WL[(16 + lm) * LROW + o2];
        acc[0][0] = MFMA(a0h, rb0h[u], acc[0][0]);
        acc[0][0] = MFMA(a0h, rb0l[u], acc[0][0]);
        acc[0][0] = MFMA(a0l, rb0h[u], acc[0][0]);
        acc[0][1] = MFMA(a0h, rb1h[u], acc[0][1]);
        acc[0][1] = MFMA(a0h, rb1l[u], acc[0][1]);
        acc[0][1] = MFMA(a0l, rb1h[u], acc[0][1]);
        acc[1][0] = MFMA(a1h, rb0h[u], acc[1][0]);
        acc[1][0] = MFMA(a1h, rb0l[u], acc[1][0]);
        acc[1][0] = MFMA(a1l, rb0h[u], acc[1][0]);
        acc[1][1] = MFMA(a1h, rb1h[u], acc[1][1]);
        acc[1][1] = MFMA(a1h, rb1l[u], acc[1][1]);
        acc[1][1] = MFMA(a1l, rb1h[u], acc[1][1]);
      }
    }
#pragma unroll
    for (int i = 0; i < 2; i++)
#pragma unroll
      for (int j = 0; j < 2; j++) {
        int n = nt * 32 + j * 16 + lm;
        int d0 = dt * 32 + i * 16 + lk * 4;
        size_t off = ((size_t)b * NP + n) * DQ + d0;
        f32x4 v = acc[i][j];
        u16 h[4], lo[4];
#pragma unroll
        for (int r2 = 0; r2 < 4; r2++) {
          h[r2] = f2bf(v[r2]);
          lo[r2] = f2bf(v[r2] - bf2f(h[r2]));
        }
        if (mat == 0) {
          *(uint2*)&XQhi[off] = *(const uint2*)h;
          *(uint2*)&XQlo[off] = *(const uint2*)lo;
        } else {
          *(uint2*)&KLThi[off] = *(const uint2*)h;
          *(uint2*)&KLTlo[off] = *(const uint2*)lo;
        }
      }
  } else if (blockIdx.x < 768) {
    int bi = blockIdx.x - 256;
    int ct = bi >> 6, b = bi & 63;
    int nt = tid >> 6;
    u16* WH = WS;
    {
      const u16* sH = Wv + (size_t)ct * 32 * CH;
      STAGE_W(WH, sH)
    }
    __syncthreads();
    float bx = beta_x[layer];
    const u16* X0 = xThi + ((size_t)b * NP + nt * 32 + lm) * CH + lk * 8;
    const u16* X1 = X0 + 16 * CH;
    f32x4 a00 = {}, a01 = {}, a10 = {}, a11 = {};
#pragma unroll
    for (int kb = 0; kb < 2; kb++) {
      sh8 rx0[4], rx1[4];
#pragma unroll
      for (int u = 0; u < 4; u++) {
        int o = (kb * 4 + u) * 32;
        rx0[u] = *(const sh8*)(X0 + o); rx1[u] = *(const sh8*)(X1 + o);
      }
#pragma unroll
      for (int u = 0; u < 4; u++) {
        int o2 = (kb * 4 + u) * 32 + lk * 8;
        sh8 w0 = *(const sh8*)&WH[lm * LROW + o2];
        sh8 w1 = *(const sh8*)&WH[(16 + lm) * LROW + o2];
        a00 = MFMA(w0, rx0[u], a00);
        a01 = MFMA(w0, rx1[u], a01);
        a10 = MFMA(w1, rx0[u], a10);
        a11 = MFMA(w1, rx1[u], a11);
      }
    }
    f32x4 acc[2][2] = {{a00, a01}, {a10, a11}};
#pragma unroll
    for (int i = 0; i < 2; i++)
#pragma unroll
      for (int j = 0; j < 2; j++) {
        int c0 = ct * 32 + i * 16 + lk * 4;
        int n = nt * 32 + j * 16 + lm;
        size_t off = ((size_t)b * NP + n) * CH + c0;
        uint2 up = *(const uint2*)&UPt[off];
        const u16* uph = (const u16*)&up;
        u16 ov[4];
#pragma unroll
        for (int r2 = 0; r2 < 4; r2++)
          ov[r2] = f2bf(bx * acc[i][j][r2] + bf2f(uph[r2]));
        *(uint2*)&Ut[off] = *(const uint2*)ov;
      }
  } else {
    int bi = blockIdx.x - 768;
    int ct = bi >> 6, b = bi & 63;
    int nt = tid >> 6;
    u16* WH = WS;
    {
      const u16* sH = Wlbf + (size_t)ct * 32 * CH;
      STAGE_W(WH, sH)
    }
    __syncthreads();
    const u16* X0 = xThi + ((size_t)b * NP + nt * 32 + lm) * CH + lk * 8;
    const u16* X1 = X0 + 16 * CH;
    f32x4 a00 = {}, a01 = {}, a10 = {}, a11 = {};
#pragma unroll
    for (int kb = 0; kb < 2; kb++) {
      sh8 rx0[4], rx1[4];
#pragma unroll
      for (int u = 0; u < 4; u++) {
        int o = (kb * 4 + u) * 32;
        rx0[u] = *(const sh8*)(X0 + o); rx1[u] = *(const sh8*)(X1 + o);
      }
#pragma unroll
      for (int u = 0; u < 4; u++) {
        int o2 = (kb * 4 + u) * 32 + lk * 8;
        sh8 w0 = *(const sh8*)&WH[lm * LROW + o2];
        sh8 w1 = *(const sh8*)&WH[(16 + lm) * LROW + o2];
        a00 = MFMA(rx0[u], w0, a00);
        a01 = MFMA(rx0[u], w1, a01);
        a10 = MFMA(rx1[u], w0, a10);
        a11 = MFMA(rx1[u], w1, a11);
      }
    }
    f32x4 acc[2][2] = {{a00, a01}, {a10, a11}};
#pragma unroll
    for (int i = 0; i < 2; i++)
#pragma unroll
      for (int j = 0; j < 2; j++) {
        int n0 = nt * 32 + i * 16 + lk * 4;
        int c = ct * 32 + j * 16 + lm;
        float4 v = {acc[i][j][0], acc[i][j][1], acc[i][j][2], acc[i][j][3]};
        *(float4*)&Afp[((size_t)b * CH + c) * NP + n0] = v;
      }
  }
}

// ---------------------------------------------------------------------------
// Merged: [0,256): fused attention (energy MFMA + q1-MFMA + c1 + sincos bias
// + softmax + P^T bf16 + colsum partials); [256,768): WlU = Wl@Ut.
__global__ __launch_bounds__(256) void k_attwlu(
    const u16* __restrict__ XQhi, const u16* __restrict__ XQlo,
    const u16* __restrict__ KLThi, const u16* __restrict__ KLTlo,
    const u16* __restrict__ KP2hi, const u16* __restrict__ KP2lo,
    const u16* __restrict__ p1wT, const float* __restrict__ p1b,
    const float* __restrict__ AS, const float* __restrict__ beta_w, int layer,
    u16* __restrict__ PT, float* __restrict__ SCLp,
    const u16* __restrict__ Ut, const u16* __restrict__ Wlbf,
    u16* __restrict__ WlU)
{
  __shared__ __align__(16) char smem[25856];
  int tid = threadIdx.x;
  int lane = tid & 63;
  int lm = lane & 15, lk = lane >> 4;
  if (blockIdx.x < 256) {
    int g = blockIdx.x & 3, b = blockIdx.x >> 2;
    int wave = tid >> 6;
    float* q1sh = (float*)smem;          // [32][66]
    float* c1sh = q1sh + 32 * 66;        // [32]
    float* divs = c1sh + 32;             // [32]
    float* Esh  = divs + 32;             // [32][132]
    if (tid < 32) divs[tid] = __expf(-(float)tid * DIV_STEP);
    float bw = beta_w[layer], obw = 1.0f - bw;
    // energy MFMA (all 4 waves; wave = m-tile)
    {
      int mt = wave;
      size_t arow = ((size_t)b * NP + mt * 32 + lm) * DQ + lk * 8;
      size_t brow = ((size_t)b * NP + g * 32 + lm) * DQ + lk * 8;
      const u16* L0h = KLThi + arow;
      const u16* L0l = KLTlo + arow;
      const u16* P0h = KP2hi + arow;
      const u16* P0l = KP2lo + arow;
      const u16* X0h = XQhi + brow;
      const u16* X0l = XQlo + brow;
      sh8 xh[2][2], xl[2][2], lh[2][2], llr[2][2], ph[2][2], pl[2][2];
#pragma unroll
      for (int row = 0; row < 2; row++) {
#pragma unroll
        for (int ks = 0; ks < 2; ks++) {
          int o = row * 16 * DQ + ks * 32;
          xh[row][ks] = *(const sh8*)(X0h + o);
          xl[row][ks] = *(const sh8*)(X0l + o);
          lh[row][ks] = *(const sh8*)(L0h + o);
          llr[row][ks] = *(const sh8*)(L0l + o);
          ph[row][ks] = *(const sh8*)(P0h + o);
          pl[row][ks] = *(const sh8*)(P0l + o);
        }
      }
      f32x4 aL[2][2] = {};
      f32x4 aP[2][2] = {};
#pragma unroll
      for (int ks = 0; ks < 2; ks++) {
#pragma unroll
        for (int i = 0; i < 2; i++) {
#pragma unroll
          for (int j = 0; j < 2; j++) {
            aL[i][j] = MFMA(lh[i][ks], xh[j][ks], aL[i][j]);
            aL[i][j] = MFMA(lh[i][ks], xl[j][ks], aL[i][j]);
            aL[i][j] = MFMA(llr[i][ks], xh[j][ks], aL[i][j]);
            aP[i][j] = MFMA(ph[i][ks], xh[j][ks], aP[i][j]);
            aP[i][j] = MFMA(ph[i][ks], xl[j][ks], aP[i][j]);
            aP[i][j] = MFMA(pl[i][ks], xh[j][ks], aP[i][j]);
          }
        }
      }
#pragma unroll
      for (int i = 0; i < 2; i++)
#pragma unroll
        for (int j = 0; j < 2; j++) {
          int nloc = j * 16 + lm;
          int mloc = mt * 32 + i * 16 + lk * 4;
          float4 v;
          v.x = bw * aL[i][j][0] + obw * aP[i][j][0];
          v.y = bw * aL[i][j][1] + obw * aP[i][j][1];
          v.z = bw * aL[i][j][2] + obw * aP[i][j][2];
          v.w = bw * aL[i][j][3] + obw * aP[i][j][3];
          *(float4*)&Esh[nloc * 132 + mloc] = v;
        }
    }
    // q1 via MFMA (waves 0,1): q1[n][d] = sum_o XQhi[n][o] p1wT[d][o]
    if (wave < 2) {
      const u16* A0 = XQhi + ((size_t)b * NP + g * 32 + lm) * DQ + lk * 8;
      const u16* A1 = A0 + 16 * DQ;
      const u16* B0 = p1wT + ((size_t)(wave * 32) + lm) * DQ + lk * 8;
      const u16* B1 = B0 + 16 * DQ;
      f32x4 q[2][2] = {};
#pragma unroll
      for (int ks = 0; ks < 2; ks++) {
        int o = ks * 32;
        sh8 a0 = *(const sh8*)(A0 + o), a1 = *(const sh8*)(A1 + o);
        sh8 b0 = *(const sh8*)(B0 + o), b1 = *(const sh8*)(B1 + o);
        q[0][0] = MFMA(a0, b0, q[0][0]);
        q[0][1] = MFMA(a0, b1, q[0][1]);
        q[1][0] = MFMA(a1, b0, q[1][0]);
        q[1][1] = MFMA(a1, b1, q[1][1]);
      }
#pragma unroll
      for (int i = 0; i < 2; i++)
#pragma unroll
        for (int j = 0; j < 2; j++)
#pragma unroll
          for (int r = 0; r < 4; r++)
            q1sh[(i * 16 + lk * 4 + r) * 66 + wave * 32 + j * 16 + lm] = q[i][j][r];
    }
    // c1 (all threads): c1[n] = sum_o XQhi[n][o]*p1b[o]
    {
      int n = tid >> 3, o0 = (tid & 7) * 8;
      const u16* xs = XQhi + ((size_t)b * NP + g * 32 + n) * DQ + o0;
      uint2 w0 = *(const uint2*)xs;
      uint2 w1 = *(const uint2*)(xs + 4);
      const u16* hh = (const u16*)&w0;
      const u16* h2 = (const u16*)&w1;
      float s = 0.0f;
#pragma unroll
      for (int k = 0; k < 4; k++) s = fmaf(bf2f(hh[k]), p1b[o0 + k], s);
#pragma unroll
      for (int k = 0; k < 4; k++) s = fmaf(bf2f(h2[k]), p1b[o0 + 4 + k], s);
      s += __shfl_xor(s, 1);
      s += __shfl_xor(s, 2);
      s += __shfl_xor(s, 4);
      if ((tid & 7) == 0) c1sh[n] = s;
    }
    __syncthreads();
    // bias + softmax
    {
      int n = tid >> 3, mc = (tid & 7) * 16;
      size_t asrow = ((size_t)b * NP + g * 32 + n) * NP + mc;
      float idxv[16], bias[16];
      float c1v = c1sh[n];
#pragma unroll
      for (int k4 = 0; k4 < 4; k4++) {
        float4 a4 = *(const float4*)&AS[asrow + k4 * 4];
        idxv[k4 * 4 + 0] = a4.x * ANG_FACTOR;
        idxv[k4 * 4 + 1] = a4.y * ANG_FACTOR;
        idxv[k4 * 4 + 2] = a4.z * ANG_FACTOR;
        idxv[k4 * 4 + 3] = a4.w * ANG_FACTOR;
      }
#pragma unroll
      for (int k = 0; k < 16; k++) bias[k] = c1v;
      for (int j = 0; j < 32; j++) {
        float dv = divs[j];
        float qs = q1sh[n * 66 + 2 * j], qc = q1sh[n * 66 + 2 * j + 1];
#pragma unroll
        for (int k = 0; k < 16; k++) {
          float s, c;
          __sincosf(idxv[k] * dv, &s, &c);
          bias[k] = fmaf(qs, s, bias[k]);
          bias[k] = fmaf(qc, c, bias[k]);
        }
      }
      float ev[16], mx = -1e30f;
#pragma unroll
      for (int k = 0; k < 16; k++) {
        ev[k] = Esh[n * 132 + mc + k] + bw * bias[k];
        mx = fmaxf(mx, ev[k]);
      }
      mx = fmaxf(mx, __shfl_xor(mx, 1));
      mx = fmaxf(mx, __shfl_xor(mx, 2));
      mx = fmaxf(mx, __shfl_xor(mx, 4));
      float s = 0.0f;
#pragma unroll
      for (int k = 0; k < 16; k++) {
        ev[k] = __expf(ev[k] - mx);
        s += ev[k];
      }
      s += __shfl_xor(s, 1);
      s += __shfl_xor(s, 2);
      s += __shfl_xor(s, 4);
      float inv = 1.0f / s;
#pragma unroll
      for (int k = 0; k < 16; k++) Esh[n * 132 + mc + k] = ev[k] * inv;
    }
    __syncthreads();
    // P^T bf16 + colsum partial
    {
      int m = tid >> 1, nc = (tid & 1) * 16;
      float s = 0.0f;
      u16 tmp[16];
#pragma unroll
      for (int k = 0; k < 16; k++) {
        float v = Esh[(nc + k) * 132 + m];
        s += v;
        tmp[k] = f2bf(v);
      }
      u16* dst = PT + ((size_t)b * NP + m) * NP + g * 32 + nc;
      *(uint4*)&dst[0] = *(const uint4*)&tmp[0];
      *(uint4*)&dst[8] = *(const uint4*)&tmp[8];
      s += __shfl_xor(s, 1);
      if ((tid & 1) == 0) SCLp[((size_t)b * 4 + g) * NP + m] = s;
    }
  } else {
    // WlU[b][c'][n] = Wl@Ut (K=256 over c). D[row=n][col=c'].
    int bi = blockIdx.x - 256;
    int ct = bi >> 6, b = bi & 63;
    int nt = tid >> 6;
    u16* WH = (u16*)smem;
    {
      const u16* sH = Wlbf + (size_t)ct * 32 * CH;
      STAGE_W(WH, sH)
    }
    __syncthreads();
    const u16* A0 = Ut + ((size_t)b * NP + nt * 32 + lm) * CH + lk * 8;
    const u16* A1 = A0 + 16 * CH;
    f32x4 a00 = {}, a01 = {}, a10 = {}, a11 = {};
#pragma unroll
    for (int kb = 0; kb < 2; kb++) {
      sh8 rA0[4], rA1[4];
#pragma unroll
      for (int u = 0; u < 4; u++) {
        int o = (kb * 4 + u) * 32;
        rA0[u] = *(const sh8*)(A0 + o); rA1[u] = *(const sh8*)(A1 + o);
      }
#pragma unroll
      for (int u = 0; u < 4; u++) {
        int o2 = (kb * 4 + u) * 32 + lk * 8;
        sh8 w0 = *(const sh8*)&WH[lm * LROW + o2];
        sh8 w1 = *(const sh8*)&WH[(16 + lm) * LROW + o2];
        a00 = MFMA(rA0[u], w0, a00);
        a01 = MFMA(rA0[u], w1, a01);
        a10 = MFMA(rA1[u], w0, a10);
        a11 = MFMA(rA1[u], w1, a11);
      }
    }
    f32x4 acc[2][2] = {{a00, a01}, {a10, a11}};
#pragma unroll
    for (int i = 0; i < 2; i++)
#pragma unroll
      for (int j = 0; j < 2; j++) {
        int n0 = nt * 32 + i * 16 + lk * 4;
        int c = ct * 32 + j * 16 + lm;
        u16 ov[4];
#pragma unroll
        for (int r2 = 0; r2 < 4; r2++) ov[r2] = f2bf(acc[i][j][r2]);
        *(uint2*)&WlU[((size_t)b * CH + c) * NP + n0] = *(const uint2*)ov;
      }
  }
}

// ---------------------------------------------------------------------------
// out = x + gelu(BN(Afp - (WlU@P)*scl + bl)); writes next layer's xT hi/lo.
__global__ __launch_bounds__(256) void k_h3(
    const u16* __restrict__ WlU, const u16* __restrict__ PT,
    const float* __restrict__ SCLp, const float* __restrict__ Afp,
    const float* __restrict__ bl, const float* __restrict__ bng,
    const float* __restrict__ bnb, const float* __restrict__ xsrc, int xbs,
    float* __restrict__ out, int layer,
    u16* __restrict__ xThi_o, u16* __restrict__ xTlo_o)
{
  int bi = blockIdx.x;
  int ct = bi >> 6, b = bi & 63;
  int tid = threadIdx.x, lane = tid & 63, nt = tid >> 6;
  int lm = lane & 15, lk = lane >> 4;
  __shared__ __align__(16) u16 WS2[32 * LROW2];
  {
    const u16* src = WlU + ((size_t)b * CH + ct * 32) * NP;
#pragma unroll
    for (int it = 0; it < 2; it++) {
      int idx = tid + it * 256, row = idx >> 4, chq = idx & 15;
      *(uint4*)&WS2[row * LROW2 + chq * 8] = *(const uint4*)(src + row * NP + chq * 8);
    }
  }
  __syncthreads();
  const u16* B0 = PT + ((size_t)b * NP + nt * 32 + lm) * NP + lk * 8;
  const u16* B1 = B0 + 16 * NP;
  sh8 rB0[4], rB1[4];
#pragma unroll
  for (int ks = 0; ks < 4; ks++) {
    int o = ks * 32;
    rB0[ks] = *(const sh8*)(B0 + o);
    rB1[ks] = *(const sh8*)(B1 + o);
  }
  f32x4 a00 = {}, a01 = {}, a10 = {}, a11 = {};
#pragma unroll
  for (int ks = 0; ks < 4; ks++) {
    int o2 = ks * 32 + lk * 8;
    sh8 w0 = *(const sh8*)&WS2[lm * LROW2 + o2];
    sh8 w1 = *(const sh8*)&WS2[(16 + lm) * LROW2 + o2];
    a00 = MFMA(w0, rB0[ks], a00);
    a01 = MFMA(w0, rB1[ks], a01);
    a10 = MFMA(w1, rB0[ks], a10);
    a11 = MFMA(w1, rB1[ks], a11);
  }
  f32x4 acc[2][2] = {{a00, a01}, {a10, a11}};
  const float rbn = 0.999995000037499687f;  // 1/sqrt(1+1e-5)
#pragma unroll
  for (int i = 0; i < 2; i++)
#pragma unroll
    for (int j = 0; j < 2; j++) {
      int m = nt * 32 + j * 16 + lm;
      int cq = ct * 32 + i * 16 + lk * 4;
      const float* sp = SCLp + (size_t)b * 4 * NP + m;
      float scl = 1.0f / (1e-12f + sp[0] + sp[NP] + sp[2 * NP] + sp[3 * NP]);
      u16 hh[4], llv[4];
#pragma unroll
      for (int r = 0; r < 4; r++) {
        int c = cq + r;
        float a = Afp[((size_t)b * CH + c) * NP + m];
        float h = a - acc[i][j][r] * scl + bl[c];
        h = h * rbn * bng[c] + bnb[c];
        float gg = 0.5f * h * (1.0f + erff(h * 0.70710678118654752440f));
        float ov = xsrc[(size_t)b * xbs + (size_t)c * NP + m] + gg;
        out[((size_t)b * 4 * CH + (size_t)layer * CH + c) * NP + m] = ov;
        hh[r] = f2bf(ov);
        llv[r] = f2bf(ov - bf2f(hh[r]));
      }
      size_t xoff = ((size_t)b * NP + m) * CH + cq;
      *(uint2*)&xThi_o[xoff] = *(const uint2*)hh;
      *(uint2*)&xTlo_o[xoff] = *(const uint2*)llv;
    }
}

// ---------------------------------------------------------------------------
extern "C" void kernel_launch(void* const* d_in, const int* in_sizes, int n_in,
                              void* d_out, int out_size, void* d_ws, size_t ws_size,
                              hipStream_t stream)
{
  (void)in_sizes; (void)n_in; (void)out_size; (void)ws_size;
  const float* lrf     = (const float*)d_in[0];
  const float* pca     = (const float*)d_in[1];
  const float* a_self  = (const float*)d_in[2];
  const float* a_cross = (const float*)d_in[3];
  const float* Wq  = (const float*)d_in[4];
  const float* Wk  = (const float*)d_in[5];
  const float* Wv  = (const float*)d_in[6];
  const float* Wvp = (const float*)d_in[7];
  const float* Wl  = (const float*)d_in[8];
  const float* bl  = (const float*)d_in[9];
  const float* bng = (const float*)d_in[10];
  const float* bnb = (const float*)d_in[11];
  const float* p1w = (const float*)d_in[12];
  const float* p1b = (const float*)d_in[13];
  const float* p2w = (const float*)d_in[14];
  const float* p2b = (const float*)d_in[15];
  const float* beta_x = (const float*)d_in[16];
  const float* beta_w = (const float*)d_in[17];
  float* out = (float*)d_out;
  float* ws  = (float*)d_ws;

  // ---- workspace carve ----
  const size_t QKN = (size_t)BB * NP * DQ;        // 524288
  const size_t ENN = (size_t)BB * NP * NP;        // 1048576
  const size_t XCN = (size_t)BB * NP * CH;        // 2097152

  float* E2A  = ws;
  float* SCLp = E2A + (size_t)NLAYERS * QKN;
  float* Afp  = SCLp + (size_t)BB * 4 * NP;
  u16* up = (u16*)(Afp + (size_t)BB * CH * NP);
  u16* xThi = up;   up += XCN;
  u16* xTlo = up;   up += XCN;
  u16* pThi = up;   up += XCN;
  u16* pTlo = up;   up += XCN;
  u16* XQhi = up;   up += QKN;
  u16* XQlo = up;   up += QKN;
  u16* KLThi = up;  up += QKN;
  u16* KLTlo = up;  up += QKN;
  u16* KP2hiA = up; up += (size_t)NLAYERS * QKN;
  u16* KP2loA = up; up += (size_t)NLAYERS * QKN;
  u16* UPt = up;    up += (size_t)NLAYERS * XCN;
  u16* Ut = up;     up += XCN;
  u16* WlUb = up;   up += XCN;
  u16* PTbf = up;   up += ENN;
  u16* Wvbf = up;   up += (size_t)NLAYERS * CH * CH;
  u16* Wvpbf = up;  up += (size_t)NLAYERS * CH * CH;
  u16* Wlbf = up;   up += (size_t)NLAYERS * CH * CH;
  u16* Wqhi = up;   up += (size_t)NLAYERS * DQ * CH;
  u16* Wqlo = up;   up += (size_t)NLAYERS * DQ * CH;
  u16* Wkhi = up;   up += (size_t)NLAYERS * DQ * CH;
  u16* Wklo = up;   up += (size_t)NLAYERS * DQ * CH;
  u16* p1wT = up;   up += (size_t)NLAYERS * DQ * DQ;

  // ---- pre-loop (2 launches) ----
  k_init<<<dim3(10116), 256, 0, stream>>>(
      Wv, Wvp, Wl, Wq, Wk, p1w, pca, lrf, a_cross, p2w, p2b,
      Wvbf, Wvpbf, Wlbf, Wqhi, Wqlo, Wkhi, Wklo, p1wT,
      pThi, pTlo, xThi, xTlo, E2A);
  k_pre2<<<dim3(2560), 256, 0, stream>>>(
      pThi, pTlo, Wqhi, Wqlo, Wvpbf, E2A, beta_x, KP2hiA, KP2loA, UPt);

  // ---- layer loop (3 launches each) ----
  for (int l = 0; l < NLAYERS; l++) {
    const float* xsrc = (l == 0) ? lrf : (out + (size_t)(l - 1) * CH * NP);
    int xbs = (l == 0) ? CH * NP : 4 * CH * NP;
    k_qu3<<<dim3(1280), 256, 0, stream>>>(
        xThi, xTlo,
        Wqhi + (size_t)l * DQ * CH, Wqlo + (size_t)l * DQ * CH,
        Wkhi + (size_t)l * DQ * CH, Wklo + (size_t)l * DQ * CH,
        Wvbf + (size_t)l * CH * CH, Wlbf + (size_t)l * CH * CH,
        UPt + (size_t)l * XCN, beta_x, l,
        XQhi, XQlo, KLThi, KLTlo, Ut, Afp);
    k_attwlu<<<dim3(768), 256, 0, stream>>>(
        XQhi, XQlo, KLThi, KLTlo,
        KP2hiA + (size_t)l * QKN, KP2loA + (size_t)l * QKN,
        p1wT + (size_t)l * DQ * DQ, p1b + (size_t)l * DQ,
        a_self, beta_w, l, PTbf, SCLp,
        Ut, Wlbf + (size_t)l * CH * CH, WlUb);
    k_h3<<<dim3(512), 256, 0, stream>>>(
        WlUb, PTbf, SCLp, Afp, bl + (size_t)l * CH, bng + (size_t)l * CH,
        bnb + (size_t)l * CH, xsrc, xbs, out, l, xThi, xTlo);
  }
}

// Round 12
// 238.991 us; speedup vs baseline: 3.7263x; 1.0808x over previous
//
#include <hip/hip_runtime.h>
#include <cstdint>
#include <cstddef>

// Round 12: algebraic dedup. (1) Ut eliminated: WlU = M@x + M2@pca with
// M = bx*Wl@Wv, M2 = (1-bx)*Wl@Wvp precomputed (k_mm). k_att is now att-only
// (256 blocks). (2) E2A eliminated: emb2 (layer-indep) bf16 once, E2 fused
// into k_pre2's KP2 MFMA as K=64 terms + p2b in epilogue. 15 launches.

#define BB 64      // batch
#define CH 256     // channels
#define NP 128     // points
#define DQ 64      // q/k dim
#define NLAYERS 4

#define ANG_FACTOR 3.8197186342054885f   // 180/(pi*15) = 12/pi
#define DIV_STEP   0.28782313662425575f  // ln(10000)/32

#define LROW 264   // padded LDS row stride (u16) for 256-wide tiles
#define LROW2 136  // padded LDS row stride (u16) for 128-wide WlU tiles

typedef unsigned short u16;
typedef __attribute__((ext_vector_type(8))) short sh8;   // 8 bf16 = 4 VGPR
typedef __attribute__((ext_vector_type(4))) float f32x4; // MFMA C/D
#define MFMA(a, b, c) __builtin_amdgcn_mfma_f32_16x16x32_bf16(a, b, c, 0, 0, 0)

static __device__ __forceinline__ u16 f2bf(float x) {
  unsigned u = __float_as_uint(x);
  return (u16)((u + 0x7FFFu + ((u >> 16) & 1u)) >> 16);
}
static __device__ __forceinline__ float bf2f(u16 h) {
  return __uint_as_float(((unsigned)h) << 16);
}

// ---------------------------------------------------------------------------
// Merged init:
// [0,256): Wl cvt; [256,384): Wq/Wk hi/lo; [384,388): p1wT; [388,392): p2wbf;
// [392,1416): x/pca transpose+split; [1416,1544): WvT/WvpT transpose-cvt;
// [1544,2568): emb2 bf16 (layer-independent sinusoidal embedding).
__global__ __launch_bounds__(256) void k_init(
    const float* __restrict__ Wv, const float* __restrict__ Wvp,
    const float* __restrict__ Wl, const float* __restrict__ Wq,
    const float* __restrict__ Wk, const float* __restrict__ p1w,
    const float* __restrict__ p2w, const float* __restrict__ pca,
    const float* __restrict__ lrf, const float* __restrict__ ac,
    u16* __restrict__ Wlbf, u16* __restrict__ Wqhi, u16* __restrict__ Wqlo,
    u16* __restrict__ Wkhi, u16* __restrict__ Wklo, u16* __restrict__ p1wT,
    u16* __restrict__ p2wbf, u16* __restrict__ pThi, u16* __restrict__ pTlo,
    u16* __restrict__ xThi, u16* __restrict__ xTlo,
    u16* __restrict__ WvT, u16* __restrict__ WvpT, u16* __restrict__ emb2bf)
{
  __shared__ __align__(16) float tl[64 * 65];
  int blk = blockIdx.x, tid = threadIdx.x;
  if (blk < 256) {
    int i = (blk * 256 + tid) * 4;
    float4 v = *(const float4*)(Wl + i);
    u16 o[4] = {f2bf(v.x), f2bf(v.y), f2bf(v.z), f2bf(v.w)};
    *(uint2*)(Wlbf + i) = *(const uint2*)o;
  } else if (blk < 384) {
    int bb = blk - 256;
    const float* s = (bb < 64) ? Wq : Wk;
    u16* dh = (bb < 64) ? Wqhi : Wkhi;
    u16* dl = (bb < 64) ? Wqlo : Wklo;
    int i = ((bb & 63) * 256 + tid) * 4;
    float4 v = *(const float4*)(s + i);
    float vv[4] = {v.x, v.y, v.z, v.w};
    u16 h[4], l[4];
#pragma unroll
    for (int r = 0; r < 4; r++) {
      h[r] = f2bf(vv[r]);
      l[r] = f2bf(vv[r] - bf2f(h[r]));
    }
    *(uint2*)(dh + i) = *(const uint2*)h;
    *(uint2*)(dl + i) = *(const uint2*)l;
  } else if (blk < 388) {
    // p1wT[l][d][o] = bf(p1w[l][o][d])
    int l = blk - 384;
    const float* src = p1w + (size_t)l * DQ * DQ;
    u16* dst = p1wT + (size_t)l * DQ * DQ;
#pragma unroll
    for (int i = 0; i < 16; i++) {
      int idx = tid + i * 256;
      int dd = idx >> 6, oo = idx & 63;
      dst[idx] = f2bf(src[oo * DQ + dd]);
    }
  } else if (blk < 392) {
    int l = blk - 388;
    const float* src = p2w + (size_t)l * DQ * DQ;
    u16* dst = p2wbf + (size_t)l * DQ * DQ;
#pragma unroll
    for (int i = 0; i < 16; i++) {
      int idx = tid + i * 256;
      dst[idx] = f2bf(src[idx]);
    }
  } else if (blk < 1416) {
    int bi = blk - 392;
    int nt = bi & 1, y = (bi >> 1) & 7, b = bi >> 4;
    int ct = y & 3, is_lrf = y >> 2;
    const float* x = is_lrf ? lrf : pca;
    u16* hiT = is_lrf ? xThi : pThi;
    u16* loT = is_lrf ? xTlo : pTlo;
    {
      int col = tid & 63, rq = tid >> 6;
      const float* src = x + (size_t)b * CH * NP + (size_t)(ct * 64) * NP + nt * 64;
#pragma unroll
      for (int i = 0; i < 16; i++) {
        int c = rq + i * 4;
        tl[col * 65 + c] = src[(size_t)c * NP + col];
      }
    }
    __syncthreads();
    {
      int cloc = tid & 63, nq = tid >> 6;
#pragma unroll
      for (int i = 0; i < 16; i++) {
        int n = nq + i * 4;
        float v = tl[n * 65 + cloc];
        u16 h = f2bf(v);
        u16 l = f2bf(v - bf2f(h));
        size_t off = ((size_t)b * NP + nt * 64 + n) * CH + ct * 64 + cloc;
        hiT[off] = h;
        loT[off] = l;
      }
    }
  } else if (blk < 1544) {
    // WvT[c_in][c_out] = bf(Wv[c_out][c_in]) (and Wvp)
    int bi = blk - 1416;
    int mat = bi >> 4, t = bi & 15;
    int l = mat & 3;
    const float* src = ((mat < 4) ? Wv : Wvp) + (size_t)l * CH * CH;
    u16* dst = ((mat < 4) ? WvT : WvpT) + (size_t)l * CH * CH;
    int tr = t >> 2, tc = t & 3;
    {
      int col = tid & 63, rq = tid >> 6;   // col = c_in loc
#pragma unroll
      for (int i = 0; i < 16; i++) {
        int co = rq + i * 4;               // c_out loc
        tl[col * 65 + co] = src[(size_t)(tr * 64 + co) * CH + tc * 64 + col];
      }
    }
    __syncthreads();
    {
      int cloc = tid & 63, nq = tid >> 6;  // cloc = c_out loc
#pragma unroll
      for (int i = 0; i < 16; i++) {
        int n = nq + i * 4;                // c_in loc
        dst[(size_t)(tc * 64 + n) * CH + tr * 64 + cloc] = f2bf(tl[n * 65 + cloc]);
      }
    }
  } else {
    // emb2bf[row=(b*NP+m)][2j]=sin, [2j+1]=cos; row0 = bi*8
    int bi = blk - 1544;
    int row0 = bi * 8;
    int r = tid >> 5, j = tid & 31;
    int row = row0 + r;
    float a = ac[row];
    float s, c;
    __sincosf(a * ANG_FACTOR * __expf(-(float)j * DIV_STEP), &s, &c);
    emb2bf[(size_t)row * DQ + 2 * j] = f2bf(s);
    emb2bf[(size_t)row * DQ + 2 * j + 1] = f2bf(c);
  }
}

// ---------------------------------------------------------------------------
// M[l] = bx*Wl@Wv, M2[l] = (1-bx)*Wl@Wvp, bf16 rows [c'][c] (k=c contiguous).
// 512 wave-tiles of 32x32 (A=WvT/WvpT rows c, B=Wl rows c', K=256).
__global__ __launch_bounds__(256) void k_mm(
    const u16* __restrict__ WvT, const u16* __restrict__ WvpT,
    const u16* __restrict__ Wlbf, const float* __restrict__ beta_x,
    u16* __restrict__ Mb, u16* __restrict__ M2b)
{
  int tid = threadIdx.x, lane = tid & 63;
  int lm = lane & 15, lk = lane >> 4;
  int tt = blockIdx.x * 4 + (tid >> 6);
  int which = tt >> 8, rest = tt & 255;
  int l = rest >> 6, t = rest & 63;
  int tcp = t >> 3, tcc = t & 7;
  const u16* WT = (which ? WvpT : WvT) + (size_t)l * CH * CH;
  const u16* A0 = WT + ((size_t)(tcc * 32) + lm) * CH + lk * 8;
  const u16* A1 = A0 + 16 * CH;
  const u16* B0 = Wlbf + (size_t)l * CH * CH + ((size_t)(tcp * 32) + lm) * CH + lk * 8;
  const u16* B1 = B0 + 16 * CH;
  f32x4 a00 = {}, a01 = {}, a10 = {}, a11 = {};
#pragma unroll
  for (int ks = 0; ks < 8; ks++) {
    int o = ks * 32;
    sh8 a0 = *(const sh8*)(A0 + o), a1 = *(const sh8*)(A1 + o);
    sh8 b0 = *(const sh8*)(B0 + o), b1 = *(const sh8*)(B1 + o);
    a00 = MFMA(a0, b0, a00);
    a01 = MFMA(a0, b1, a01);
    a10 = MFMA(a1, b0, a10);
    a11 = MFMA(a1, b1, a11);
  }
  float bx = beta_x[l];
  float sc = which ? (1.0f - bx) : bx;
  u16* out = (which ? M2b : Mb) + (size_t)l * CH * CH;
  f32x4 acc[2][2] = {{a00, a01}, {a10, a11}};
#pragma unroll
  for (int i = 0; i < 2; i++)
#pragma unroll
    for (int j = 0; j < 2; j++) {
      int c0 = tcc * 32 + i * 16 + lk * 4;
      int cp = tcp * 32 + j * 16 + lm;
      u16 ov[4];
#pragma unroll
      for (int r = 0; r < 4; r++) ov[r] = f2bf(sc * acc[i][j][r]);
      *(uint2*)&out[(size_t)cp * CH + c0] = *(const uint2*)ov;
    }
}

// ---------------------------------------------------------------------------
#define STAGE_W(dst, src)                                                    \
  _Pragma("unroll")                                                          \
  for (int it = 0; it < 4; it++) {                                           \
    int idx = threadIdx.x + it * 256, row = idx >> 5, ch = idx & 31;         \
    *(uint4*)&dst[row * LROW + ch * 8] =                                     \
        *(const uint4*)(src + row * 256 + ch * 8);                           \
  }

// ---------------------------------------------------------------------------
// [0,512): KP2A[l] = split(Wq[l]@pca + emb2@p2w[l]^T + p2b[l]);
// [512,2560): WlUPA[l][b][c'][n] = bf(M2[l]@pca).
__global__ __launch_bounds__(256) void k_pre2(
    const u16* __restrict__ pThi, const u16* __restrict__ pTlo,
    const u16* __restrict__ Wqhi, const u16* __restrict__ Wqlo,
    const u16* __restrict__ M2b, const u16* __restrict__ p2wbf,
    const u16* __restrict__ emb2bf, const float* __restrict__ p2b,
    u16* __restrict__ KP2hiA, u16* __restrict__ KP2loA, u16* __restrict__ WlUPA)
{
  __shared__ __align__(16) u16 WS[2 * 32 * LROW];
  int tid = threadIdx.x, lane = tid & 63;
  int lm = lane & 15, lk = lane >> 4;
  if (blockIdx.x < 512) {
    int bi = blockIdx.x;
    int l = bi >> 7, rest = bi & 127;
    int dt = rest >> 6, b = rest & 63;
    int nt = tid >> 6;
    u16* WH = WS;
    u16* WL = WS + 32 * LROW;
    {
      const u16* sH = Wqhi + (size_t)l * DQ * CH + (size_t)dt * 32 * CH;
      const u16* sL = Wqlo + (size_t)l * DQ * CH + (size_t)dt * 32 * CH;
      STAGE_W(WH, sH)
      STAGE_W(WL, sL)
    }
    __syncthreads();
    const u16* B0h = pThi + ((size_t)b * NP + nt * 32 + lm) * CH + lk * 8;
    const u16* B1h = B0h + 16 * CH;
    const u16* B0l = pTlo + ((size_t)b * NP + nt * 32 + lm) * CH + lk * 8;
    const u16* B1l = B0l + 16 * CH;
    f32x4 acc[2][2] = {};
#pragma unroll
    for (int kb = 0; kb < 4; kb++) {
      sh8 rb0h[2], rb1h[2], rb0l[2], rb1l[2];
#pragma unroll
      for (int u = 0; u < 2; u++) {
        int o = (kb * 2 + u) * 32;
        rb0h[u] = *(const sh8*)(B0h + o); rb1h[u] = *(const sh8*)(B1h + o);
        rb0l[u] = *(const sh8*)(B0l + o); rb1l[u] = *(const sh8*)(B1l + o);
      }
#pragma unroll
      for (int u = 0; u < 2; u++) {
        int o2 = (kb * 2 + u) * 32 + lk * 8;
        sh8 a0h = *(const sh8*)&WH[lm * LROW + o2];
        sh8 a1h = *(const sh8*)&WH[(16 + lm) * LROW + o2];
        sh8 a0l = *(const sh8*)&WL[lm * LROW + o2];
        sh8 a1l = *(const sh8*)&WL[(16 + lm) * LROW + o2];
        acc[0][0] = MFMA(a0h, rb0h[u], acc[0][0]);
        acc[0][0] = MFMA(a0h, rb0l[u], acc[0][0]);
        acc[0][0] = MFMA(a0l, rb0h[u], acc[0][0]);
        acc[0][1] = MFMA(a0h, rb1h[u], acc[0][1]);
        acc[0][1] = MFMA(a0h, rb1l[u], acc[0][1]);
        acc[0][1] = MFMA(a0l, rb1h[u], acc[0][1]);
        acc[1][0] = MFMA(a1h, rb0h[u], acc[1][0]);
        acc[1][0] = MFMA(a1h, rb0l[u], acc[1][0]);
        acc[1][0] = MFMA(a1l, rb0h[u], acc[1][0]);
        acc[1][1] = MFMA(a1h, rb1h[u], acc[1][1]);
        acc[1][1] = MFMA(a1h, rb1l[u], acc[1][1]);
        acc[1][1] = MFMA(a1l, rb1h[u], acc[1][1]);
      }
    }
    // E2 terms: A=p2w rows (o = dt*32..), B=emb2 rows (m), K=64
    {
      const u16* A20 = p2wbf + (size_t)l * DQ * DQ + ((size_t)(dt * 32) + lm) * DQ + lk * 8;
      const u16* A21 = A20 + 16 * DQ;
      const u16* B20 = emb2bf + ((size_t)b * NP + nt * 32 + lm) * DQ + lk * 8;
      const u16* B21 = B20 + 16 * DQ;
#pragma unroll
      for (int ks = 0; ks < 2; ks++) {
        int o = ks * 32;
        sh8 a0 = *(const sh8*)(A20 + o), a1 = *(const sh8*)(A21 + o);
        sh8 b0 = *(const sh8*)(B20 + o), b1 = *(const sh8*)(B21 + o);
        acc[0][0] = MFMA(a0, b0, acc[0][0]);
        acc[0][1] = MFMA(a0, b1, acc[0][1]);
        acc[1][0] = MFMA(a1, b0, acc[1][0]);
        acc[1][1] = MFMA(a1, b1, acc[1][1]);
      }
    }
#pragma unroll
    for (int i = 0; i < 2; i++)
#pragma unroll
      for (int j = 0; j < 2; j++) {
        int n = nt * 32 + j * 16 + lm;
        int d0 = dt * 32 + i * 16 + lk * 4;
        size_t off = (((size_t)l * BB + b) * NP + n) * DQ + d0;
        f32x4 v = acc[i][j];
        u16 h[4], lo[4];
#pragma unroll
        for (int r2 = 0; r2 < 4; r2++) {
          float vv = v[r2] + p2b[l * DQ + d0 + r2];
          h[r2] = f2bf(vv);
          lo[r2] = f2bf(vv - bf2f(h[r2]));
        }
        *(uint2*)&KP2hiA[off] = *(const uint2*)h;
        *(uint2*)&KP2loA[off] = *(const uint2*)lo;
      }
  } else {
    int bi = blockIdx.x - 512;
    int l = bi >> 9, rest = bi & 511;
    int ct = rest >> 6, b = rest & 63;
    int nt = tid >> 6;
    u16* WH = WS;
    {
      const u16* sH = M2b + (size_t)l * CH * CH + (size_t)ct * 32 * CH;
      STAGE_W(WH, sH)
    }
    __syncthreads();
    const u16* X0 = pThi + ((size_t)b * NP + nt * 32 + lm) * CH + lk * 8;
    const u16* X1 = X0 + 16 * CH;
    f32x4 a00 = {}, a01 = {}, a10 = {}, a11 = {};
#pragma unroll
    for (int kb = 0; kb < 2; kb++) {
      sh8 rx0[4], rx1[4];
#pragma unroll
      for (int u = 0; u < 4; u++) {
        int o = (kb * 4 + u) * 32;
        rx0[u] = *(const sh8*)(X0 + o); rx1[u] = *(const sh8*)(X1 + o);
      }
#pragma unroll
      for (int u = 0; u < 4; u++) {
        int o2 = (kb * 4 + u) * 32 + lk * 8;
        sh8 w0 = *(const sh8*)&WH[lm * LROW + o2];
        sh8 w1 = *(const sh8*)&WH[(16 + lm) * LROW + o2];
        a00 = MFMA(rx0[u], w0, a00);
        a01 = MFMA(rx0[u], w1, a01);
        a10 = MFMA(rx1[u], w0, a10);
        a11 = MFMA(rx1[u], w1, a11);
      }
    }
    f32x4 acc[2][2] = {{a00, a01}, {a10, a11}};
#pragma unroll
    for (int i = 0; i < 2; i++)
#pragma unroll
      for (int j = 0; j < 2; j++) {
        int n0 = nt * 32 + i * 16 + lk * 4;
        int c = ct * 32 + j * 16 + lm;
        u16 ov[4];
#pragma unroll
        for (int r2 = 0; r2 < 4; r2++) ov[r2] = f2bf(acc[i][j][r2]);
        *(uint2*)&WlUPA[(((size_t)l * BB + b) * CH + c) * NP + n0] = *(const uint2*)ov;
      }
  }
}

// ---------------------------------------------------------------------------
// Per-layer: [0,256): QK split-bf16; [256,768): WlU[b][c'][n] = M@x + WlUP;
// [768,1280): Afp[b][c][n] = Wl@x (fp32).
__global__ __launch_bounds__(256) void k_qu4(
    const u16* __restrict__ xThi, const u16* __restrict__ xTlo,
    const u16* __restrict__ Wqhi, const u16* __restrict__ Wqlo,
    const u16* __restrict__ Wkhi, const u16* __restrict__ Wklo,
    const u16* __restrict__ Mb, const u16* __restrict__ Wlbf,
    const u16* __restrict__ WlUP, u16* __restrict__ XQhi, u16* __restrict__ XQlo,
    u16* __restrict__ KLThi, u16* __restrict__ KLTlo,
    u16* __restrict__ WlU, float* __restrict__ Afp)
{
  __shared__ __align__(16) u16 WS[2 * 32 * LROW];
  int tid = threadIdx.x, lane = tid & 63;
  int lm = lane & 15, lk = lane >> 4;
  if (blockIdx.x < 256) {
    int bi = blockIdx.x;
    int mat = bi >> 7, rest = bi & 127;
    int dt = rest >> 6, b = rest & 63;
    int nt = tid >> 6;
    u16* WH = WS;
    u16* WL = WS + 32 * LROW;
    {
      const u16* sH = (mat ? Wkhi : Wqhi) + (size_t)dt * 32 * CH;
      const u16* sL = (mat ? Wklo : Wqlo) + (size_t)dt * 32 * CH;
      STAGE_W(WH, sH)
      STAGE_W(WL, sL)
    }
    __syncthreads();
    const u16* B0h = xThi + ((size_t)b * NP + nt * 32 + lm) * CH + lk * 8;
    const u16* B1h = B0h + 16 * CH;
    const u16* B0l = xTlo + ((size_t)b * NP + nt * 32 + lm) * CH + lk * 8;
    const u16* B1l = B0l + 16 * CH;
    f32x4 acc[2][2] = {};
#pragma unroll
    for (int kb = 0; kb < 4; kb++) {
      sh8 rb0h[2], rb1h[2], rb0l[2], rb1l[2];
#pragma unroll
      for (int u = 0; u < 2; u++) {
        int o = (kb * 2 + u) * 32;
        rb0h[u] = *(const sh8*)(B0h + o); rb1h[u] = *(const sh8*)(B1h + o);
        rb0l[u] = *(const sh8*)(B0l + o); rb1l[u] = *(const sh8*)(B1l + o);
      }
#pragma unroll
      for (int u = 0; u < 2; u++) {
        int o2 = (kb * 2 + u) * 32 + lk * 8;
        sh8 a0h = *(const sh8*)&WH[lm * LROW + o2];
        sh8 a1h = *(const sh8*)&WH[(16 + lm) * LROW + o2];
        sh8 a0l = *(const sh8*)&WL[lm * LROW + o2];
        sh8 a1l = *(const sh8*)&WL[(16 + lm) * LROW + o2];
        acc[0][0] = MFMA(a0h, rb0h[u], acc[0][0]);
        acc[0][0] = MFMA(a0h, rb0l[u], acc[0][0]);
        acc[0][0] = MFMA(a0l, rb0h[u], acc[0][0]);
        acc[0][1] = MFMA(a0h, rb1h[u], acc[0][1]);
        acc[0][1] = MFMA(a0h, rb1l[u], acc[0][1]);
        acc[0][1] = MFMA(a0l, rb1h[u], acc[0][1]);
        acc[1][0] = MFMA(a1h, rb0h[u], acc[1][0]);
        acc[1][0] = MFMA(a1h, rb0l[u], acc[1][0]);
        acc[1][0] = MFMA(a1l, rb0h[u], acc[1][0]);
        acc[1][1] = MFMA(a1h, rb1h[u], acc[1][1]);
        acc[1][1] = MFMA(a1h, rb1l[u], acc[1][1]);
        acc[1][1] = MFMA(a1l, rb1h[u], acc[1][1]);
      }
    }
#pragma unroll
    for (int i = 0; i < 2; i++)
#pragma unroll
      for (int j = 0; j < 2; j++) {
        int n = nt * 32 + j * 16 + lm;
        int d0 = dt * 32 + i * 16 + lk * 4;
        size_t off = ((size_t)b * NP + n) * DQ + d0;
        f32x4 v = acc[i][j];
        u16 h[4], lo[4];
#pragma unroll
        for (int r2 = 0; r2 < 4; r2++) {
          h[r2] = f2bf(v[r2]);
          lo[r2] = f2bf(v[r2] - bf2f(h[r2]));
        }
        if (mat == 0) {
          *(uint2*)&XQhi[off] = *(const uint2*)h;
          *(uint2*)&XQlo[off] = *(const uint2*)lo;
        } else {
          *(uint2*)&KLThi[off] = *(const uint2*)h;
          *(uint2*)&KLTlo[off] = *(const uint2*)lo;
        }
      }
  } else if (blockIdx.x < 768) {
    int bi = blockIdx.x - 256;
    int ct = bi >> 6, b = bi & 63;
    int nt = tid >> 6;
    u16* WH = WS;
    {
      const u16* sH = Mb + (size_t)ct * 32 * CH;
      STAGE_W(WH, sH)
    }
    __syncthreads();
    const u16* X0 = xThi + ((size_t)b * NP + nt * 32 + lm) * CH + lk * 8;
    const u16* X1 = X0 + 16 * CH;
    f32x4 a00 = {}, a01 = {}, a10 = {}, a11 = {};
#pragma unroll
    for (int kb = 0; kb < 2; kb++) {
      sh8 rx0[4], rx1[4];
#pragma unroll
      for (int u = 0; u < 4; u++) {
        int o = (kb * 4 + u) * 32;
        rx0[u] = *(const sh8*)(X0 + o); rx1[u] = *(const sh8*)(X1 + o);
      }
#pragma unroll
      for (int u = 0; u < 4; u++) {
        int o2 = (kb * 4 + u) * 32 + lk * 8;
        sh8 w0 = *(const sh8*)&WH[lm * LROW + o2];
        sh8 w1 = *(const sh8*)&WH[(16 + lm) * LROW + o2];
        a00 = MFMA(rx0[u], w0, a00);
        a01 = MFMA(rx0[u], w1, a01);
        a10 = MFMA(rx1[u], w0, a10);
        a11 = MFMA(rx1[u], w1, a11);
      }
    }
    f32x4 acc[2][2] = {{a00, a01}, {a10, a11}};
#pragma unroll
    for (int i = 0; i < 2; i++)
#pragma unroll
      for (int j = 0; j < 2; j++) {
        int n0 = nt * 32 + i * 16 + lk * 4;
        int c = ct * 32 + j * 16 + lm;
        size_t off = ((size_t)b * CH + c) * NP + n0;
        uint2 up = *(const uint2*)&WlUP[off];
        const u16* uph = (const u16*)&up;
        u16 ov[4];
#pragma unroll
        for (int r2 = 0; r2 < 4; r2++)
          ov[r2] = f2bf(acc[i][j][r2] + bf2f(uph[r2]));
        *(uint2*)&WlU[off] = *(const uint2*)ov;
      }
  } else {
    int bi = blockIdx.x - 768;
    int ct = bi >> 6, b = bi & 63;
    int nt = tid >> 6;
    u16* WH = WS;
    {
      const u16* sH = Wlbf + (size_t)ct * 32 * CH;
      STAGE_W(WH, sH)
    }
    __syncthreads();
    const u16* X0 = xThi + ((size_t)b * NP + nt * 32 + lm) * CH + lk * 8;
    const u16* X1 = X0 + 16 * CH;
    f32x4 a00 = {}, a01 = {}, a10 = {}, a11 = {};
#pragma unroll
    for (int kb = 0; kb < 2; kb++) {
      sh8 rx0[4], rx1[4];
#pragma unroll
      for (int u = 0; u < 4; u++) {
        int o = (kb * 4 + u) * 32;
        rx0[u] = *(const sh8*)(X0 + o); rx1[u] = *(const sh8*)(X1 + o);
      }
#pragma unroll
      for (int u = 0; u < 4; u++) {
        int o2 = (kb * 4 + u) * 32 + lk * 8;
        sh8 w0 = *(const sh8*)&WH[lm * LROW + o2];
        sh8 w1 = *(const sh8*)&WH[(16 + lm) * LROW + o2];
        a00 = MFMA(rx0[u], w0, a00);
        a01 = MFMA(rx0[u], w1, a01);
        a10 = MFMA(rx1[u], w0, a10);
        a11 = MFMA(rx1[u], w1, a11);
      }
    }
    f32x4 acc[2][2] = {{a00, a01}, {a10, a11}};
#pragma unroll
    for (int i = 0; i < 2; i++)
#pragma unroll
      for (int j = 0; j < 2; j++) {
        int n0 = nt * 32 + i * 16 + lk * 4;
        int c = ct * 32 + j * 16 + lm;
        float4 v = {acc[i][j][0], acc[i][j][1], acc[i][j][2], acc[i][j][3]};
        *(float4*)&Afp[((size_t)b * CH + c) * NP + n0] = v;
      }
  }
}

// ---------------------------------------------------------------------------
// Fused attention (256 blocks): energy MFMA + q1-MFMA + c1 + sincos bias +
// softmax + P^T bf16 + colsum partials.
__global__ __launch_bounds__(256) void k_att(
    const u16* __restrict__ XQhi, const u16* __restrict__ XQlo,
    const u16* __restrict__ KLThi, const u16* __restrict__ KLTlo,
    const u16* __restrict__ KP2hi, const u16* __restrict__ KP2lo,
    const u16* __restrict__ p1wT, const float* __restrict__ p1b,
    const float* __restrict__ AS, const float* __restrict__ beta_w, int layer,
    u16* __restrict__ PT, float* __restrict__ SCLp)
{
  __shared__ __align__(16) char smem[25856];
  int tid = threadIdx.x;
  int lane = tid & 63;
  int lm = lane & 15, lk = lane >> 4;
  int g = blockIdx.x & 3, b = blockIdx.x >> 2;
  int wave = tid >> 6;
  float* q1sh = (float*)smem;          // [32][66]
  float* c1sh = q1sh + 32 * 66;        // [32]
  float* divs = c1sh + 32;             // [32]
  float* Esh  = divs + 32;             // [32][132]
  if (tid < 32) divs[tid] = __expf(-(float)tid * DIV_STEP);
  float bw = beta_w[layer], obw = 1.0f - bw;
  // energy MFMA (all 4 waves; wave = m-tile)
  {
    int mt = wave;
    size_t arow = ((size_t)b * NP + mt * 32 + lm) * DQ + lk * 8;
    size_t brow = ((size_t)b * NP + g * 32 + lm) * DQ + lk * 8;
    const u16* L0h = KLThi + arow;
    const u16* L0l = KLTlo + arow;
    const u16* P0h = KP2hi + arow;
    const u16* P0l = KP2lo + arow;
    const u16* X0h = XQhi + brow;
    const u16* X0l = XQlo + brow;
    sh8 xh[2][2], xl[2][2], lh[2][2], llr[2][2], ph[2][2], pl[2][2];
#pragma unroll
    for (int row = 0; row < 2; row++) {
#pragma unroll
      for (int ks = 0; ks < 2; ks++) {
        int o = row * 16 * DQ + ks * 32;
        xh[row][ks] = *(const sh8*)(X0h + o);
        xl[row][ks] = *(const sh8*)(X0l + o);
        lh[row][ks] = *(const sh8*)(L0h + o);
        llr[row][ks] = *(const sh8*)(L0l + o);
        ph[row][ks] = *(const sh8*)(P0h + o);
        pl[row][ks] = *(const sh8*)(P0l + o);
      }
    }
    f32x4 aL[2][2] = {};
    f32x4 aP[2][2] = {};
#pragma unroll
    for (int ks = 0; ks < 2; ks++) {
#pragma unroll
      for (int i = 0; i < 2; i++) {
#pragma unroll
        for (int j = 0; j < 2; j++) {
          aL[i][j] = MFMA(lh[i][ks], xh[j][ks], aL[i][j]);
          aL[i][j] = MFMA(lh[i][ks], xl[j][ks], aL[i][j]);
          aL[i][j] = MFMA(llr[i][ks], xh[j][ks], aL[i][j]);
          aP[i][j] = MFMA(ph[i][ks], xh[j][ks], aP[i][j]);
          aP[i][j] = MFMA(ph[i][ks], xl[j][ks], aP[i][j]);
          aP[i][j] = MFMA(pl[i][ks], xh[j][ks], aP[i][j]);
        }
      }
    }
#pragma unroll
    for (int i = 0; i < 2; i++)
#pragma unroll
      for (int j = 0; j < 2; j++) {
        int nloc = j * 16 + lm;
        int mloc = mt * 32 + i * 16 + lk * 4;
        float4 v;
        v.x = bw * aL[i][j][0] + obw * aP[i][j][0];
        v.y = bw * aL[i][j][1] + obw * aP[i][j][1];
        v.z = bw * aL[i][j][2] + obw * aP[i][j][2];
        v.w = bw * aL[i][j][3] + obw * aP[i][j][3];
        *(float4*)&Esh[nloc * 132 + mloc] = v;
      }
  }
  // q1 via MFMA (waves 0,1)
  if (wave < 2) {
    const u16* A0 = XQhi + ((size_t)b * NP + g * 32 + lm) * DQ + lk * 8;
    const u16* A1 = A0 + 16 * DQ;
    const u16* B0 = p1wT + ((size_t)(wave * 32) + lm) * DQ + lk * 8;
    const u16* B1 = B0 + 16 * DQ;
    f32x4 q[2][2] = {};
#pragma unroll
    for (int ks = 0; ks < 2; ks++) {
      int o = ks * 32;
      sh8 a0 = *(const sh8*)(A0 + o), a1 = *(const sh8*)(A1 + o);
      sh8 b0 = *(const sh8*)(B0 + o), b1 = *(const sh8*)(B1 + o);
      q[0][0] = MFMA(a0, b0, q[0][0]);
      q[0][1] = MFMA(a0, b1, q[0][1]);
      q[1][0] = MFMA(a1, b0, q[1][0]);
      q[1][1] = MFMA(a1, b1, q[1][1]);
    }
#pragma unroll
    for (int i = 0; i < 2; i++)
#pragma unroll
      for (int j = 0; j < 2; j++)
#pragma unroll
        for (int r = 0; r < 4; r++)
          q1sh[(i * 16 + lk * 4 + r) * 66 + wave * 32 + j * 16 + lm] = q[i][j][r];
  }
  // c1
  {
    int n = tid >> 3, o0 = (tid & 7) * 8;
    const u16* xs = XQhi + ((size_t)b * NP + g * 32 + n) * DQ + o0;
    uint2 w0 = *(const uint2*)xs;
    uint2 w1 = *(const uint2*)(xs + 4);
    const u16* hh = (const u16*)&w0;
    const u16* h2 = (const u16*)&w1;
    float s = 0.0f;
#pragma unroll
    for (int k = 0; k < 4; k++) s = fmaf(bf2f(hh[k]), p1b[o0 + k], s);
#pragma unroll
    for (int k = 0; k < 4; k++) s = fmaf(bf2f(h2[k]), p1b[o0 + 4 + k], s);
    s += __shfl_xor(s, 1);
    s += __shfl_xor(s, 2);
    s += __shfl_xor(s, 4);
    if ((tid & 7) == 0) c1sh[n] = s;
  }
  __syncthreads();
  // bias + softmax
  {
    int n = tid >> 3, mc = (tid & 7) * 16;
    size_t asrow = ((size_t)b * NP + g * 32 + n) * NP + mc;
    float idxv[16], bias[16];
    float c1v = c1sh[n];
#pragma unroll
    for (int k4 = 0; k4 < 4; k4++) {
      float4 a4 = *(const float4*)&AS[asrow + k4 * 4];
      idxv[k4 * 4 + 0] = a4.x * ANG_FACTOR;
      idxv[k4 * 4 + 1] = a4.y * ANG_FACTOR;
      idxv[k4 * 4 + 2] = a4.z * ANG_FACTOR;
      idxv[k4 * 4 + 3] = a4.w * ANG_FACTOR;
    }
#pragma unroll
    for (int k = 0; k < 16; k++) bias[k] = c1v;
    for (int j = 0; j < 32; j++) {
      float dv = divs[j];
      float qs = q1sh[n * 66 + 2 * j], qc = q1sh[n * 66 + 2 * j + 1];
#pragma unroll
      for (int k = 0; k < 16; k++) {
        float s, c;
        __sincosf(idxv[k] * dv, &s, &c);
        bias[k] = fmaf(qs, s, bias[k]);
        bias[k] = fmaf(qc, c, bias[k]);
      }
    }
    float ev[16], mx = -1e30f;
#pragma unroll
    for (int k = 0; k < 16; k++) {
      ev[k] = Esh[n * 132 + mc + k] + bw * bias[k];
      mx = fmaxf(mx, ev[k]);
    }
    mx = fmaxf(mx, __shfl_xor(mx, 1));
    mx = fmaxf(mx, __shfl_xor(mx, 2));
    mx = fmaxf(mx, __shfl_xor(mx, 4));
    float s = 0.0f;
#pragma unroll
    for (int k = 0; k < 16; k++) {
      ev[k] = __expf(ev[k] - mx);
      s += ev[k];
    }
    s += __shfl_xor(s, 1);
    s += __shfl_xor(s, 2);
    s += __shfl_xor(s, 4);
    float inv = 1.0f / s;
#pragma unroll
    for (int k = 0; k < 16; k++) Esh[n * 132 + mc + k] = ev[k] * inv;
  }
  __syncthreads();
  // P^T bf16 + colsum partial
  {
    int m = tid >> 1, nc = (tid & 1) * 16;
    float s = 0.0f;
    u16 tmp[16];
#pragma unroll
    for (int k = 0; k < 16; k++) {
      float v = Esh[(nc + k) * 132 + m];
      s += v;
      tmp[k] = f2bf(v);
    }
    u16* dst = PT + ((size_t)b * NP + m) * NP + g * 32 + nc;
    *(uint4*)&dst[0] = *(const uint4*)&tmp[0];
    *(uint4*)&dst[8] = *(const uint4*)&tmp[8];
    s += __shfl_xor(s, 1);
    if ((tid & 1) == 0) SCLp[((size_t)b * 4 + g) * NP + m] = s;
  }
}

// ---------------------------------------------------------------------------
// out = x + gelu(BN(Afp - (WlU@P)*scl + bl)); writes next layer's xT hi/lo.
__global__ __launch_bounds__(256) void k_h3(
    const u16* __restrict__ WlU, const u16* __restrict__ PT,
    const float* __restrict__ SCLp, const float* __restrict__ Afp,
    const float* __restrict__ bl, const float* __restrict__ bng,
    const float* __restrict__ bnb, const float* __restrict__ xsrc, int xbs,
    float* __restrict__ out, int layer,
    u16* __restrict__ xThi_o, u16* __restrict__ xTlo_o)
{
  int bi = blockIdx.x;
  int ct = bi >> 6, b = bi & 63;
  int tid = threadIdx.x, lane = tid & 63, nt = tid >> 6;
  int lm = lane & 15, lk = lane >> 4;
  __shared__ __align__(16) u16 WS2[32 * LROW2];
  {
    const u16* src = WlU + ((size_t)b * CH + ct * 32) * NP;
#pragma unroll
    for (int it = 0; it < 2; it++) {
      int idx = tid + it * 256, row = idx >> 4, chq = idx & 15;
      *(uint4*)&WS2[row * LROW2 + chq * 8] = *(const uint4*)(src + row * NP + chq * 8);
    }
  }
  __syncthreads();
  const u16* B0 = PT + ((size_t)b * NP + nt * 32 + lm) * NP + lk * 8;
  const u16* B1 = B0 + 16 * NP;
  sh8 rB0[4], rB1[4];
#pragma unroll
  for (int ks = 0; ks < 4; ks++) {
    int o = ks * 32;
    rB0[ks] = *(const sh8*)(B0 + o);
    rB1[ks] = *(const sh8*)(B1 + o);
  }
  f32x4 a00 = {}, a01 = {}, a10 = {}, a11 = {};
#pragma unroll
  for (int ks = 0; ks < 4; ks++) {
    int o2 = ks * 32 + lk * 8;
    sh8 w0 = *(const sh8*)&WS2[lm * LROW2 + o2];
    sh8 w1 = *(const sh8*)&WS2[(16 + lm) * LROW2 + o2];
    a00 = MFMA(w0, rB0[ks], a00);
    a01 = MFMA(w0, rB1[ks], a01);
    a10 = MFMA(w1, rB0[ks], a10);
    a11 = MFMA(w1, rB1[ks], a11);
  }
  f32x4 acc[2][2] = {{a00, a01}, {a10, a11}};
  const float rbn = 0.999995000037499687f;  // 1/sqrt(1+1e-5)
#pragma unroll
  for (int i = 0; i < 2; i++)
#pragma unroll
    for (int j = 0; j < 2; j++) {
      int m = nt * 32 + j * 16 + lm;
      int cq = ct * 32 + i * 16 + lk * 4;
      const float* sp = SCLp + (size_t)b * 4 * NP + m;
      float scl = 1.0f / (1e-12f + sp[0] + sp[NP] + sp[2 * NP] + sp[3 * NP]);
      u16 hh[4], llv[4];
#pragma unroll
      for (int r = 0; r < 4; r++) {
        int c = cq + r;
        float a = Afp[((size_t)b * CH + c) * NP + m];
        float h = a - acc[i][j][r] * scl + bl[c];
        h = h * rbn * bng[c] + bnb[c];
        float gg = 0.5f * h * (1.0f + erff(h * 0.70710678118654752440f));
        float ov = xsrc[(size_t)b * xbs + (size_t)c * NP + m] + gg;
        out[((size_t)b * 4 * CH + (size_t)layer * CH + c) * NP + m] = ov;
        hh[r] = f2bf(ov);
        llv[r] = f2bf(ov - bf2f(hh[r]));
      }
      size_t xoff = ((size_t)b * NP + m) * CH + cq;
      *(uint2*)&xThi_o[xoff] = *(const uint2*)hh;
      *(uint2*)&xTlo_o[xoff] = *(const uint2*)llv;
    }
}

// ---------------------------------------------------------------------------
extern "C" void kernel_launch(void* const* d_in, const int* in_sizes, int n_in,
                              void* d_out, int out_size, void* d_ws, size_t ws_size,
                              hipStream_t stream)
{
  (void)in_sizes; (void)n_in; (void)out_size; (void)ws_size;
  const float* lrf     = (const float*)d_in[0];
  const float* pca     = (const float*)d_in[1];
  const float* a_self  = (const float*)d_in[2];
  const float* a_cross = (const float*)d_in[3];
  const float* Wq  = (const float*)d_in[4];
  const float* Wk  = (const float*)d_in[5];
  const float* Wv  = (const float*)d_in[6];
  const float* Wvp = (const float*)d_in[7];
  const float* Wl  = (const float*)d_in[8];
  const float* bl  = (const float*)d_in[9];
  const float* bng = (const float*)d_in[10];
  const float* bnb = (const float*)d_in[11];
  const float* p1w = (const float*)d_in[12];
  const float* p1b = (const float*)d_in[13];
  const float* p2w = (const float*)d_in[14];
  const float* p2b = (const float*)d_in[15];
  const float* beta_x = (const float*)d_in[16];
  const float* beta_w = (const float*)d_in[17];
  float* out = (float*)d_out;
  float* ws  = (float*)d_ws;

  // ---- workspace carve ----
  const size_t QKN = (size_t)BB * NP * DQ;        // 524288
  const size_t ENN = (size_t)BB * NP * NP;        // 1048576
  const size_t XCN = (size_t)BB * NP * CH;        // 2097152

  float* SCLp = ws;
  float* Afp  = SCLp + (size_t)BB * 4 * NP;
  u16* up = (u16*)(Afp + (size_t)BB * CH * NP);
  u16* xThi = up;   up += XCN;
  u16* xTlo = up;   up += XCN;
  u16* pThi = up;   up += XCN;
  u16* pTlo = up;   up += XCN;
  u16* XQhi = up;   up += QKN;
  u16* XQlo = up;   up += QKN;
  u16* KLThi = up;  up += QKN;
  u16* KLTlo = up;  up += QKN;
  u16* KP2hiA = up; up += (size_t)NLAYERS * QKN;
  u16* KP2loA = up; up += (size_t)NLAYERS * QKN;
  u16* WlUPA = up;  up += (size_t)NLAYERS * XCN;
  u16* WlUb = up;   up += XCN;
  u16* PTbf = up;   up += ENN;
  u16* Wlbf = up;   up += (size_t)NLAYERS * CH * CH;
  u16* WvT = up;    up += (size_t)NLAYERS * CH * CH;
  u16* WvpT = up;   up += (size_t)NLAYERS * CH * CH;
  u16* Mb = up;     up += (size_t)NLAYERS * CH * CH;
  u16* M2b = up;    up += (size_t)NLAYERS * CH * CH;
  u16* Wqhi = up;   up += (size_t)NLAYERS * DQ * CH;
  u16* Wqlo = up;   up += (size_t)NLAYERS * DQ * CH;
  u16* Wkhi = up;   up += (size_t)NLAYERS * DQ * CH;
  u16* Wklo = up;   up += (size_t)NLAYERS * DQ * CH;
  u16* p1wT = up;   up += (size_t)NLAYERS * DQ * DQ;
  u16* p2wbf = up;  up += (size_t)NLAYERS * DQ * DQ;
  u16* emb2bf = up; up += QKN;

  // ---- pre-loop (3 launches) ----
  k_init<<<dim3(2568), 256, 0, stream>>>(
      Wv, Wvp, Wl, Wq, Wk, p1w, p2w, pca, lrf, a_cross,
      Wlbf, Wqhi, Wqlo, Wkhi, Wklo, p1wT, p2wbf,
      pThi, pTlo, xThi, xTlo, WvT, WvpT, emb2bf);
  k_mm<<<dim3(128), 256, 0, stream>>>(WvT, WvpT, Wlbf, beta_x, Mb, M2b);
  k_pre2<<<dim3(2560), 256, 0, stream>>>(
      pThi, pTlo, Wqhi, Wqlo, M2b, p2wbf, emb2bf, p2b,
      KP2hiA, KP2loA, WlUPA);

  // ---- layer loop (3 launches each) ----
  for (int l = 0; l < NLAYERS; l++) {
    const float* xsrc = (l == 0) ? lrf : (out + (size_t)(l - 1) * CH * NP);
    int xbs = (l == 0) ? CH * NP : 4 * CH * NP;
    k_qu4<<<dim3(1280), 256, 0, stream>>>(
        xThi, xTlo,
        Wqhi + (size_t)l * DQ * CH, Wqlo + (size_t)l * DQ * CH,
        Wkhi + (size_t)l * DQ * CH, Wklo + (size_t)l * DQ * CH,
        Mb + (size_t)l * CH * CH, Wlbf + (size_t)l * CH * CH,
        WlUPA + (size_t)l * XCN,
        XQhi, XQlo, KLThi, KLTlo, WlUb, Afp);
    k_att<<<dim3(256), 256, 0, stream>>>(
        XQhi, XQlo, KLThi, KLTlo,
        KP2hiA + (size_t)l * QKN, KP2loA + (size_t)l * QKN,
        p1wT + (size_t)l * DQ * DQ, p1b + (size_t)l * DQ,
        a_self, beta_w, l, PTbf, SCLp);
    k_h3<<<dim3(512), 256, 0, stream>>>(
        WlUb, PTbf, SCLp, Afp, bl + (size_t)l * CH, bng + (size_t)l * CH,
        bnb + (size_t)l * CH, xsrc, xbs, out, l, xThi, xTlo);
  }
}

// Round 14
// 207.477 us; speedup vs baseline: 4.2923x; 1.1519x over previous
//
#include <hip/hip_runtime.h>
#include <cstdint>
#include <cstddef>

// Round 14: round-13 resubmit (infra failure) + RACE FIX: k_h4 both reads
// xThi (phase-1 GEMM operand, all columns) and wrote it (epilogue, own
// column tile) -> cross-block hazard. Now double-buffered: layer l reads
// xT[l&1], writes xT[(l+1)&1]. Everything else identical to round 13.

#define BB 64      // batch
#define CH 256     // channels
#define NP 128     // points
#define DQ 64      // q/k dim
#define NLAYERS 4

#define ANG_FACTOR 3.8197186342054885f   // 180/(pi*15) = 12/pi
#define DIV_STEP   0.28782313662425575f  // ln(10000)/32

#define LROW 264   // padded LDS row stride (u16) for 256-wide tiles

typedef unsigned short u16;
typedef __attribute__((ext_vector_type(8))) short sh8;   // 8 bf16 = 4 VGPR
typedef __attribute__((ext_vector_type(4))) float f32x4; // MFMA C/D
#define MFMA(a, b, c) __builtin_amdgcn_mfma_f32_16x16x32_bf16(a, b, c, 0, 0, 0)

static __device__ __forceinline__ u16 f2bf(float x) {
  unsigned u = __float_as_uint(x);
  return (u16)((u + 0x7FFFu + ((u >> 16) & 1u)) >> 16);
}
static __device__ __forceinline__ float bf2f(u16 h) {
  return __uint_as_float(((unsigned)h) << 16);
}

// ---------------------------------------------------------------------------
// Merged init (2568 blocks): weight cvts, transposes, emb2 bf16.
__global__ __launch_bounds__(256) void k_init(
    const float* __restrict__ Wv, const float* __restrict__ Wvp,
    const float* __restrict__ Wl, const float* __restrict__ Wq,
    const float* __restrict__ Wk, const float* __restrict__ p1w,
    const float* __restrict__ p2w, const float* __restrict__ pca,
    const float* __restrict__ lrf, const float* __restrict__ ac,
    u16* __restrict__ Wlbf, u16* __restrict__ Wqhi, u16* __restrict__ Wqlo,
    u16* __restrict__ Wkhi, u16* __restrict__ Wklo, u16* __restrict__ p1wT,
    u16* __restrict__ p2wbf, u16* __restrict__ pThi, u16* __restrict__ pTlo,
    u16* __restrict__ xThi, u16* __restrict__ xTlo,
    u16* __restrict__ WvT, u16* __restrict__ WvpT, u16* __restrict__ emb2bf)
{
  __shared__ __align__(16) float tl[64 * 65];
  int blk = blockIdx.x, tid = threadIdx.x;
  if (blk < 256) {
    int i = (blk * 256 + tid) * 4;
    float4 v = *(const float4*)(Wl + i);
    u16 o[4] = {f2bf(v.x), f2bf(v.y), f2bf(v.z), f2bf(v.w)};
    *(uint2*)(Wlbf + i) = *(const uint2*)o;
  } else if (blk < 384) {
    int bb = blk - 256;
    const float* s = (bb < 64) ? Wq : Wk;
    u16* dh = (bb < 64) ? Wqhi : Wkhi;
    u16* dl = (bb < 64) ? Wqlo : Wklo;
    int i = ((bb & 63) * 256 + tid) * 4;
    float4 v = *(const float4*)(s + i);
    float vv[4] = {v.x, v.y, v.z, v.w};
    u16 h[4], l[4];
#pragma unroll
    for (int r = 0; r < 4; r++) {
      h[r] = f2bf(vv[r]);
      l[r] = f2bf(vv[r] - bf2f(h[r]));
    }
    *(uint2*)(dh + i) = *(const uint2*)h;
    *(uint2*)(dl + i) = *(const uint2*)l;
  } else if (blk < 388) {
    int l = blk - 384;
    const float* src = p1w + (size_t)l * DQ * DQ;
    u16* dst = p1wT + (size_t)l * DQ * DQ;
#pragma unroll
    for (int i = 0; i < 16; i++) {
      int idx = tid + i * 256;
      int dd = idx >> 6, oo = idx & 63;
      dst[idx] = f2bf(src[oo * DQ + dd]);
    }
  } else if (blk < 392) {
    int l = blk - 388;
    const float* src = p2w + (size_t)l * DQ * DQ;
    u16* dst = p2wbf + (size_t)l * DQ * DQ;
#pragma unroll
    for (int i = 0; i < 16; i++) {
      int idx = tid + i * 256;
      dst[idx] = f2bf(src[idx]);
    }
  } else if (blk < 1416) {
    int bi = blk - 392;
    int nt = bi & 1, y = (bi >> 1) & 7, b = bi >> 4;
    int ct = y & 3, is_lrf = y >> 2;
    const float* x = is_lrf ? lrf : pca;
    u16* hiT = is_lrf ? xThi : pThi;
    u16* loT = is_lrf ? xTlo : pTlo;
    {
      int col = tid & 63, rq = tid >> 6;
      const float* src = x + (size_t)b * CH * NP + (size_t)(ct * 64) * NP + nt * 64;
#pragma unroll
      for (int i = 0; i < 16; i++) {
        int c = rq + i * 4;
        tl[col * 65 + c] = src[(size_t)c * NP + col];
      }
    }
    __syncthreads();
    {
      int cloc = tid & 63, nq = tid >> 6;
#pragma unroll
      for (int i = 0; i < 16; i++) {
        int n = nq + i * 4;
        float v = tl[n * 65 + cloc];
        u16 h = f2bf(v);
        u16 l = f2bf(v - bf2f(h));
        size_t off = ((size_t)b * NP + nt * 64 + n) * CH + ct * 64 + cloc;
        hiT[off] = h;
        loT[off] = l;
      }
    }
  } else if (blk < 1544) {
    // WvT[c_in][c_out] = bf(Wv[c_out][c_in]) (and Wvp)
    int bi = blk - 1416;
    int mat = bi >> 4, t = bi & 15;
    int l = mat & 3;
    const float* src = ((mat < 4) ? Wv : Wvp) + (size_t)l * CH * CH;
    u16* dst = ((mat < 4) ? WvT : WvpT) + (size_t)l * CH * CH;
    int tr = t >> 2, tc = t & 3;
    {
      int col = tid & 63, rq = tid >> 6;
#pragma unroll
      for (int i = 0; i < 16; i++) {
        int co = rq + i * 4;
        tl[col * 65 + co] = src[(size_t)(tr * 64 + co) * CH + tc * 64 + col];
      }
    }
    __syncthreads();
    {
      int cloc = tid & 63, nq = tid >> 6;
#pragma unroll
      for (int i = 0; i < 16; i++) {
        int n = nq + i * 4;
        dst[(size_t)(tc * 64 + n) * CH + tr * 64 + cloc] = f2bf(tl[n * 65 + cloc]);
      }
    }
  } else {
    int bi = blk - 1544;
    int row0 = bi * 8;
    int r = tid >> 5, j = tid & 31;
    int row = row0 + r;
    float a = ac[row];
    float s, c;
    __sincosf(a * ANG_FACTOR * __expf(-(float)j * DIV_STEP), &s, &c);
    emb2bf[(size_t)row * DQ + 2 * j] = f2bf(s);
    emb2bf[(size_t)row * DQ + 2 * j + 1] = f2bf(c);
  }
}

// ---------------------------------------------------------------------------
// M[l] = bx*Wl@Wv, M2[l] = (1-bx)*Wl@Wvp, bf16 [c'][c] (k=c contiguous).
__global__ __launch_bounds__(256) void k_mm(
    const u16* __restrict__ WvT, const u16* __restrict__ WvpT,
    const u16* __restrict__ Wlbf, const float* __restrict__ beta_x,
    u16* __restrict__ Mb, u16* __restrict__ M2b)
{
  int tid = threadIdx.x, lane = tid & 63;
  int lm = lane & 15, lk = lane >> 4;
  int tt = blockIdx.x * 4 + (tid >> 6);
  int which = tt >> 8, rest = tt & 255;
  int l = rest >> 6, t = rest & 63;
  int tcp = t >> 3, tcc = t & 7;
  const u16* WT = (which ? WvpT : WvT) + (size_t)l * CH * CH;
  const u16* A0 = WT + ((size_t)(tcc * 32) + lm) * CH + lk * 8;
  const u16* A1 = A0 + 16 * CH;
  const u16* B0 = Wlbf + (size_t)l * CH * CH + ((size_t)(tcp * 32) + lm) * CH + lk * 8;
  const u16* B1 = B0 + 16 * CH;
  f32x4 a00 = {}, a01 = {}, a10 = {}, a11 = {};
#pragma unroll
  for (int ks = 0; ks < 8; ks++) {
    int o = ks * 32;
    sh8 a0 = *(const sh8*)(A0 + o), a1 = *(const sh8*)(A1 + o);
    sh8 b0 = *(const sh8*)(B0 + o), b1 = *(const sh8*)(B1 + o);
    a00 = MFMA(a0, b0, a00);
    a01 = MFMA(a0, b1, a01);
    a10 = MFMA(a1, b0, a10);
    a11 = MFMA(a1, b1, a11);
  }
  float bx = beta_x[l];
  float sc = which ? (1.0f - bx) : bx;
  u16* out = (which ? M2b : Mb) + (size_t)l * CH * CH;
  f32x4 acc[2][2] = {{a00, a01}, {a10, a11}};
#pragma unroll
  for (int i = 0; i < 2; i++)
#pragma unroll
    for (int j = 0; j < 2; j++) {
      int c0 = tcc * 32 + i * 16 + lk * 4;
      int cp = tcp * 32 + j * 16 + lm;
      u16 ov[4];
#pragma unroll
      for (int r = 0; r < 4; r++) ov[r] = f2bf(sc * acc[i][j][r]);
      *(uint2*)&out[(size_t)cp * CH + c0] = *(const uint2*)ov;
    }
}

// ---------------------------------------------------------------------------
#define STAGE_W(dst, src)                                                    \
  _Pragma("unroll")                                                          \
  for (int it = 0; it < 4; it++) {                                           \
    int idx = threadIdx.x + it * 256, row = idx >> 5, ch = idx & 31;         \
    *(uint4*)&dst[row * LROW + ch * 8] =                                     \
        *(const uint4*)(src + row * 256 + ch * 8);                           \
  }

// ---------------------------------------------------------------------------
// [0,512): KP2A[l] = split(Wq[l]@pca + emb2@p2w[l]^T + p2b[l]);
// [512,2560): WlUPA[l][b][n][c'] = bf(M2[l]@pca).
__global__ __launch_bounds__(256) void k_pre2(
    const u16* __restrict__ pThi, const u16* __restrict__ pTlo,
    const u16* __restrict__ Wqhi, const u16* __restrict__ Wqlo,
    const u16* __restrict__ M2b, const u16* __restrict__ p2wbf,
    const u16* __restrict__ emb2bf, const float* __restrict__ p2b,
    u16* __restrict__ KP2hiA, u16* __restrict__ KP2loA, u16* __restrict__ WlUPA)
{
  __shared__ __align__(16) u16 WS[2 * 32 * LROW];
  int tid = threadIdx.x, lane = tid & 63;
  int lm = lane & 15, lk = lane >> 4;
  if (blockIdx.x < 512) {
    int bi = blockIdx.x;
    int l = bi >> 7, rest = bi & 127;
    int dt = rest >> 6, b = rest & 63;
    int nt = tid >> 6;
    u16* WH = WS;
    u16* WL = WS + 32 * LROW;
    {
      const u16* sH = Wqhi + (size_t)l * DQ * CH + (size_t)dt * 32 * CH;
      const u16* sL = Wqlo + (size_t)l * DQ * CH + (size_t)dt * 32 * CH;
      STAGE_W(WH, sH)
      STAGE_W(WL, sL)
    }
    __syncthreads();
    const u16* B0h = pThi + ((size_t)b * NP + nt * 32 + lm) * CH + lk * 8;
    const u16* B1h = B0h + 16 * CH;
    const u16* B0l = pTlo + ((size_t)b * NP + nt * 32 + lm) * CH + lk * 8;
    const u16* B1l = B0l + 16 * CH;
    f32x4 acc[2][2] = {};
#pragma unroll
    for (int kb = 0; kb < 4; kb++) {
      sh8 rb0h[2], rb1h[2], rb0l[2], rb1l[2];
#pragma unroll
      for (int u = 0; u < 2; u++) {
        int o = (kb * 2 + u) * 32;
        rb0h[u] = *(const sh8*)(B0h + o); rb1h[u] = *(const sh8*)(B1h + o);
        rb0l[u] = *(const sh8*)(B0l + o); rb1l[u] = *(const sh8*)(B1l + o);
      }
#pragma unroll
      for (int u = 0; u < 2; u++) {
        int o2 = (kb * 2 + u) * 32 + lk * 8;
        sh8 a0h = *(const sh8*)&WH[lm * LROW + o2];
        sh8 a1h = *(const sh8*)&WH[(16 + lm) * LROW + o2];
        sh8 a0l = *(const sh8*)&WL[lm * LROW + o2];
        sh8 a1l = *(const sh8*)&WL[(16 + lm) * LROW + o2];
        acc[0][0] = MFMA(a0h, rb0h[u], acc[0][0]);
        acc[0][0] = MFMA(a0h, rb0l[u], acc[0][0]);
        acc[0][0] = MFMA(a0l, rb0h[u], acc[0][0]);
        acc[0][1] = MFMA(a0h, rb1h[u], acc[0][1]);
        acc[0][1] = MFMA(a0h, rb1l[u], acc[0][1]);
        acc[0][1] = MFMA(a0l, rb1h[u], acc[0][1]);
        acc[1][0] = MFMA(a1h, rb0h[u], acc[1][0]);
        acc[1][0] = MFMA(a1h, rb0l[u], acc[1][0]);
        acc[1][0] = MFMA(a1l, rb0h[u], acc[1][0]);
        acc[1][1] = MFMA(a1h, rb1h[u], acc[1][1]);
        acc[1][1] = MFMA(a1h, rb1l[u], acc[1][1]);
        acc[1][1] = MFMA(a1l, rb1h[u], acc[1][1]);
      }
    }
    // E2 terms: A = p2w rows (o = dt*32..), B = emb2 rows (m), K = 64
    {
      const u16* A20 = p2wbf + (size_t)l * DQ * DQ + ((size_t)(dt * 32) + lm) * DQ + lk * 8;
      const u16* A21 = A20 + 16 * DQ;
      const u16* B20 = emb2bf + ((size_t)b * NP + nt * 32 + lm) * DQ + lk * 8;
      const u16* B21 = B20 + 16 * DQ;
#pragma unroll
      for (int ks = 0; ks < 2; ks++) {
        int o = ks * 32;
        sh8 a0 = *(const sh8*)(A20 + o), a1 = *(const sh8*)(A21 + o);
        sh8 b0 = *(const sh8*)(B20 + o), b1 = *(const sh8*)(B21 + o);
        acc[0][0] = MFMA(a0, b0, acc[0][0]);
        acc[0][1] = MFMA(a0, b1, acc[0][1]);
        acc[1][0] = MFMA(a1, b0, acc[1][0]);
        acc[1][1] = MFMA(a1, b1, acc[1][1]);
      }
    }
#pragma unroll
    for (int i = 0; i < 2; i++)
#pragma unroll
      for (int j = 0; j < 2; j++) {
        int n = nt * 32 + j * 16 + lm;
        int d0 = dt * 32 + i * 16 + lk * 4;
        size_t off = (((size_t)l * BB + b) * NP + n) * DQ + d0;
        f32x4 v = acc[i][j];
        u16 h[4], lo[4];
#pragma unroll
        for (int r2 = 0; r2 < 4; r2++) {
          float vv = v[r2] + p2b[l * DQ + d0 + r2];
          h[r2] = f2bf(vv);
          lo[r2] = f2bf(vv - bf2f(h[r2]));
        }
        *(uint2*)&KP2hiA[off] = *(const uint2*)h;
        *(uint2*)&KP2loA[off] = *(const uint2*)lo;
      }
  } else {
    int bi = blockIdx.x - 512;
    int l = bi >> 9, rest = bi & 511;
    int ct = rest >> 6, b = rest & 63;
    int nt = tid >> 6;
    {
      const u16* sH = M2b + (size_t)l * CH * CH + (size_t)ct * 32 * CH;
      STAGE_W(WS, sH)
    }
    __syncthreads();
    const u16* X0 = pThi + ((size_t)b * NP + nt * 32 + lm) * CH + lk * 8;
    const u16* X1 = X0 + 16 * CH;
    f32x4 a00 = {}, a01 = {}, a10 = {}, a11 = {};
    // A = M2 rows c' (LDS), B = pca rows n -> D[row=c'][col=n]
#pragma unroll
    for (int kb = 0; kb < 2; kb++) {
      sh8 rx0[4], rx1[4];
#pragma unroll
      for (int u = 0; u < 4; u++) {
        int o = (kb * 4 + u) * 32;
        rx0[u] = *(const sh8*)(X0 + o); rx1[u] = *(const sh8*)(X1 + o);
      }
#pragma unroll
      for (int u = 0; u < 4; u++) {
        int o2 = (kb * 4 + u) * 32 + lk * 8;
        sh8 w0 = *(const sh8*)&WS[lm * LROW + o2];
        sh8 w1 = *(const sh8*)&WS[(16 + lm) * LROW + o2];
        a00 = MFMA(w0, rx0[u], a00);
        a01 = MFMA(w0, rx1[u], a01);
        a10 = MFMA(w1, rx0[u], a10);
        a11 = MFMA(w1, rx1[u], a11);
      }
    }
    f32x4 acc[2][2] = {{a00, a01}, {a10, a11}};
#pragma unroll
    for (int i = 0; i < 2; i++)
#pragma unroll
      for (int j = 0; j < 2; j++) {
        int c0 = ct * 32 + i * 16 + lk * 4;
        int n = nt * 32 + j * 16 + lm;
        u16 ov[4];
#pragma unroll
        for (int r2 = 0; r2 < 4; r2++) ov[r2] = f2bf(acc[i][j][r2]);
        *(uint2*)&WlUPA[(((size_t)l * BB + b) * NP + n) * CH + c0] = *(const uint2*)ov;
      }
  }
}

// ---------------------------------------------------------------------------
// Per-layer QK projections (256 blocks): XQ hi/lo = Wq@x, KLT hi/lo = Wk@x.
__global__ __launch_bounds__(256) void k_qk(
    const u16* __restrict__ xThi, const u16* __restrict__ xTlo,
    const u16* __restrict__ Wqhi, const u16* __restrict__ Wqlo,
    const u16* __restrict__ Wkhi, const u16* __restrict__ Wklo,
    u16* __restrict__ XQhi, u16* __restrict__ XQlo,
    u16* __restrict__ KLThi, u16* __restrict__ KLTlo)
{
  __shared__ __align__(16) u16 WS[2 * 32 * LROW];
  int tid = threadIdx.x, lane = tid & 63;
  int lm = lane & 15, lk = lane >> 4;
  int bi = blockIdx.x;
  int mat = bi >> 7, rest = bi & 127;
  int dt = rest >> 6, b = rest & 63;
  int nt = tid >> 6;
  u16* WH = WS;
  u16* WL = WS + 32 * LROW;
  {
    const u16* sH = (mat ? Wkhi : Wqhi) + (size_t)dt * 32 * CH;
    const u16* sL = (mat ? Wklo : Wqlo) + (size_t)dt * 32 * CH;
    STAGE_W(WH, sH)
    STAGE_W(WL, sL)
  }
  __syncthreads();
  const u16* B0h = xThi + ((size_t)b * NP + nt * 32 + lm) * CH + lk * 8;
  const u16* B1h = B0h + 16 * CH;
  const u16* B0l = xTlo + ((size_t)b * NP + nt * 32 + lm) * CH + lk * 8;
  const u16* B1l = B0l + 16 * CH;
  f32x4 acc[2][2] = {};
#pragma unroll
  for (int kb = 0; kb < 4; kb++) {
    sh8 rb0h[2], rb1h[2], rb0l[2], rb1l[2];
#pragma unroll
    for (int u = 0; u < 2; u++) {
      int o = (kb * 2 + u) * 32;
      rb0h[u] = *(const sh8*)(B0h + o); rb1h[u] = *(const sh8*)(B1h + o);
      rb0l[u] = *(const sh8*)(B0l + o); rb1l[u] = *(const sh8*)(B1l + o);
    }
#pragma unroll
    for (int u = 0; u < 2; u++) {
      int o2 = (kb * 2 + u) * 32 + lk * 8;
      sh8 a0h = *(const sh8*)&WH[lm * LROW + o2];
      sh8 a1h = *(const sh8*)&WH[(16 + lm) * LROW + o2];
      sh8 a0l = *(const sh8*)&WL[lm * LROW + o2];
      sh8 a1l = *(const sh8*)&WL[(16 + lm) * LROW + o2];
      acc[0][0] = MFMA(a0h, rb0h[u], acc[0][0]);
      acc[0][0] = MFMA(a0h, rb0l[u], acc[0][0]);
      acc[0][0] = MFMA(a0l, rb0h[u], acc[0][0]);
      acc[0][1] = MFMA(a0h, rb1h[u], acc[0][1]);
      acc[0][1] = MFMA(a0h, rb1l[u], acc[0][1]);
      acc[0][1] = MFMA(a0l, rb1h[u], acc[0][1]);
      acc[1][0] = MFMA(a1h, rb0h[u], acc[1][0]);
      acc[1][0] = MFMA(a1h, rb0l[u], acc[1][0]);
      acc[1][0] = MFMA(a1l, rb0h[u], acc[1][0]);
      acc[1][1] = MFMA(a1h, rb1h[u], acc[1][1]);
      acc[1][1] = MFMA(a1h, rb1l[u], acc[1][1]);
      acc[1][1] = MFMA(a1l, rb1h[u], acc[1][1]);
    }
  }
#pragma unroll
  for (int i = 0; i < 2; i++)
#pragma unroll
    for (int j = 0; j < 2; j++) {
      int n = nt * 32 + j * 16 + lm;
      int d0 = dt * 32 + i * 16 + lk * 4;
      size_t off = ((size_t)b * NP + n) * DQ + d0;
      f32x4 v = acc[i][j];
      u16 h[4], lo[4];
#pragma unroll
      for (int r2 = 0; r2 < 4; r2++) {
        h[r2] = f2bf(v[r2]);
        lo[r2] = f2bf(v[r2] - bf2f(h[r2]));
      }
      if (mat == 0) {
        *(uint2*)&XQhi[off] = *(const uint2*)h;
        *(uint2*)&XQlo[off] = *(const uint2*)lo;
      } else {
        *(uint2*)&KLThi[off] = *(const uint2*)h;
        *(uint2*)&KLTlo[off] = *(const uint2*)lo;
      }
    }
}

// ---------------------------------------------------------------------------
// Fused attention (256 blocks): energy MFMA + q1-MFMA + c1 + sincos bias +
// softmax + P^T bf16 + colsum partials.
__global__ __launch_bounds__(256) void k_att(
    const u16* __restrict__ XQhi, const u16* __restrict__ XQlo,
    const u16* __restrict__ KLThi, const u16* __restrict__ KLTlo,
    const u16* __restrict__ KP2hi, const u16* __restrict__ KP2lo,
    const u16* __restrict__ p1wT, const float* __restrict__ p1b,
    const float* __restrict__ AS, const float* __restrict__ beta_w, int layer,
    u16* __restrict__ PT, float* __restrict__ SCLp)
{
  __shared__ __align__(16) char smem[25856];
  int tid = threadIdx.x;
  int lane = tid & 63;
  int lm = lane & 15, lk = lane >> 4;
  int g = blockIdx.x & 3, b = blockIdx.x >> 2;
  int wave = tid >> 6;
  float* q1sh = (float*)smem;          // [32][66]
  float* c1sh = q1sh + 32 * 66;        // [32]
  float* divs = c1sh + 32;             // [32]
  float* Esh  = divs + 32;             // [32][132]
  if (tid < 32) divs[tid] = __expf(-(float)tid * DIV_STEP);
  float bw = beta_w[layer], obw = 1.0f - bw;
  {
    int mt = wave;
    size_t arow = ((size_t)b * NP + mt * 32 + lm) * DQ + lk * 8;
    size_t brow = ((size_t)b * NP + g * 32 + lm) * DQ + lk * 8;
    const u16* L0h = KLThi + arow;
    const u16* L0l = KLTlo + arow;
    const u16* P0h = KP2hi + arow;
    const u16* P0l = KP2lo + arow;
    const u16* X0h = XQhi + brow;
    const u16* X0l = XQlo + brow;
    sh8 xh[2][2], xl[2][2], lh[2][2], llr[2][2], ph[2][2], pl[2][2];
#pragma unroll
    for (int row = 0; row < 2; row++) {
#pragma unroll
      for (int ks = 0; ks < 2; ks++) {
        int o = row * 16 * DQ + ks * 32;
        xh[row][ks] = *(const sh8*)(X0h + o);
        xl[row][ks] = *(const sh8*)(X0l + o);
        lh[row][ks] = *(const sh8*)(L0h + o);
        llr[row][ks] = *(const sh8*)(L0l + o);
        ph[row][ks] = *(const sh8*)(P0h + o);
        pl[row][ks] = *(const sh8*)(P0l + o);
      }
    }
    f32x4 aL[2][2] = {};
    f32x4 aP[2][2] = {};
#pragma unroll
    for (int ks = 0; ks < 2; ks++) {
#pragma unroll
      for (int i = 0; i < 2; i++) {
#pragma unroll
        for (int j = 0; j < 2; j++) {
          aL[i][j] = MFMA(lh[i][ks], xh[j][ks], aL[i][j]);
          aL[i][j] = MFMA(lh[i][ks], xl[j][ks], aL[i][j]);
          aL[i][j] = MFMA(llr[i][ks], xh[j][ks], aL[i][j]);
          aP[i][j] = MFMA(ph[i][ks], xh[j][ks], aP[i][j]);
          aP[i][j] = MFMA(ph[i][ks], xl[j][ks], aP[i][j]);
          aP[i][j] = MFMA(pl[i][ks], xh[j][ks], aP[i][j]);
        }
      }
    }
#pragma unroll
    for (int i = 0; i < 2; i++)
#pragma unroll
      for (int j = 0; j < 2; j++) {
        int nloc = j * 16 + lm;
        int mloc = mt * 32 + i * 16 + lk * 4;
        float4 v;
        v.x = bw * aL[i][j][0] + obw * aP[i][j][0];
        v.y = bw * aL[i][j][1] + obw * aP[i][j][1];
        v.z = bw * aL[i][j][2] + obw * aP[i][j][2];
        v.w = bw * aL[i][j][3] + obw * aP[i][j][3];
        *(float4*)&Esh[nloc * 132 + mloc] = v;
      }
  }
  if (wave < 2) {
    const u16* A0 = XQhi + ((size_t)b * NP + g * 32 + lm) * DQ + lk * 8;
    const u16* A1 = A0 + 16 * DQ;
    const u16* B0 = p1wT + ((size_t)(wave * 32) + lm) * DQ + lk * 8;
    const u16* B1 = B0 + 16 * DQ;
    f32x4 q[2][2] = {};
#pragma unroll
    for (int ks = 0; ks < 2; ks++) {
      int o = ks * 32;
      sh8 a0 = *(const sh8*)(A0 + o), a1 = *(const sh8*)(A1 + o);
      sh8 b0 = *(const sh8*)(B0 + o), b1 = *(const sh8*)(B1 + o);
      q[0][0] = MFMA(a0, b0, q[0][0]);
      q[0][1] = MFMA(a0, b1, q[0][1]);
      q[1][0] = MFMA(a1, b0, q[1][0]);
      q[1][1] = MFMA(a1, b1, q[1][1]);
    }
#pragma unroll
    for (int i = 0; i < 2; i++)
#pragma unroll
      for (int j = 0; j < 2; j++)
#pragma unroll
        for (int r = 0; r < 4; r++)
          q1sh[(i * 16 + lk * 4 + r) * 66 + wave * 32 + j * 16 + lm] = q[i][j][r];
  }
  {
    int n = tid >> 3, o0 = (tid & 7) * 8;
    const u16* xs = XQhi + ((size_t)b * NP + g * 32 + n) * DQ + o0;
    uint2 w0 = *(const uint2*)xs;
    uint2 w1 = *(const uint2*)(xs + 4);
    const u16* hh = (const u16*)&w0;
    const u16* h2 = (const u16*)&w1;
    float s = 0.0f;
#pragma unroll
    for (int k = 0; k < 4; k++) s = fmaf(bf2f(hh[k]), p1b[o0 + k], s);
#pragma unroll
    for (int k = 0; k < 4; k++) s = fmaf(bf2f(h2[k]), p1b[o0 + 4 + k], s);
    s += __shfl_xor(s, 1);
    s += __shfl_xor(s, 2);
    s += __shfl_xor(s, 4);
    if ((tid & 7) == 0) c1sh[n] = s;
  }
  __syncthreads();
  {
    int n = tid >> 3, mc = (tid & 7) * 16;
    size_t asrow = ((size_t)b * NP + g * 32 + n) * NP + mc;
    float idxv[16], bias[16];
    float c1v = c1sh[n];
#pragma unroll
    for (int k4 = 0; k4 < 4; k4++) {
      float4 a4 = *(const float4*)&AS[asrow + k4 * 4];
      idxv[k4 * 4 + 0] = a4.x * ANG_FACTOR;
      idxv[k4 * 4 + 1] = a4.y * ANG_FACTOR;
      idxv[k4 * 4 + 2] = a4.z * ANG_FACTOR;
      idxv[k4 * 4 + 3] = a4.w * ANG_FACTOR;
    }
#pragma unroll
    for (int k = 0; k < 16; k++) bias[k] = c1v;
    for (int j = 0; j < 32; j++) {
      float dv = divs[j];
      float qs = q1sh[n * 66 + 2 * j], qc = q1sh[n * 66 + 2 * j + 1];
#pragma unroll
      for (int k = 0; k < 16; k++) {
        float s, c;
        __sincosf(idxv[k] * dv, &s, &c);
        bias[k] = fmaf(qs, s, bias[k]);
        bias[k] = fmaf(qc, c, bias[k]);
      }
    }
    float ev[16], mx = -1e30f;
#pragma unroll
    for (int k = 0; k < 16; k++) {
      ev[k] = Esh[n * 132 + mc + k] + bw * bias[k];
      mx = fmaxf(mx, ev[k]);
    }
    mx = fmaxf(mx, __shfl_xor(mx, 1));
    mx = fmaxf(mx, __shfl_xor(mx, 2));
    mx = fmaxf(mx, __shfl_xor(mx, 4));
    float s = 0.0f;
#pragma unroll
    for (int k = 0; k < 16; k++) {
      ev[k] = __expf(ev[k] - mx);
      s += ev[k];
    }
    s += __shfl_xor(s, 1);
    s += __shfl_xor(s, 2);
    s += __shfl_xor(s, 4);
    float inv = 1.0f / s;
#pragma unroll
    for (int k = 0; k < 16; k++) Esh[n * 132 + mc + k] = ev[k] * inv;
  }
  __syncthreads();
  {
    int m = tid >> 1, nc = (tid & 1) * 16;
    float s = 0.0f;
    u16 tmp[16];
#pragma unroll
    for (int k = 0; k < 16; k++) {
      float v = Esh[(nc + k) * 132 + m];
      s += v;
      tmp[k] = f2bf(v);
    }
    u16* dst = PT + ((size_t)b * NP + m) * NP + g * 32 + nc;
    *(uint4*)&dst[0] = *(const uint4*)&tmp[0];
    *(uint4*)&dst[8] = *(const uint4*)&tmp[8];
    s += __shfl_xor(s, 1);
    if ((tid & 1) == 0) SCLp[((size_t)b * 4 + g) * NP + m] = s;
  }
}

// ---------------------------------------------------------------------------
// Merged value epilogue (512 blocks = 8ct x 64b). Per block:
// phase1: wlu = M@x (+WlUP), afp = Wl@x (K=256, x loaded once, afp in VGPRs);
// phase2: acc2 = wlu @ P (K=128, wlu via LDS overlay); epilogue:
// out = x + gelu(BN(afp - acc2*scl + bl)); writes NEXT-layer xT plane (o).
__global__ __launch_bounds__(256) void k_h4(
    const u16* __restrict__ xThi, const u16* __restrict__ Mb,
    const u16* __restrict__ Wlbf, const u16* __restrict__ WlUP,
    const u16* __restrict__ PT, const float* __restrict__ SCLp,
    const float* __restrict__ bl, const float* __restrict__ bng,
    const float* __restrict__ bnb, const float* __restrict__ xsrc, int xbs,
    float* __restrict__ out, int layer,
    u16* __restrict__ xThi_o, u16* __restrict__ xTlo_o)
{
  __shared__ __align__(16) u16 WS[2 * 32 * LROW];
  int ct = blockIdx.x >> 6, b = blockIdx.x & 63;
  int tid = threadIdx.x, lane = tid & 63, wave = tid >> 6;
  int lm = lane & 15, lk = lane >> 4;
  u16* MT = WS;
  u16* WT = WS + 32 * LROW;
  {
    const u16* sM = Mb + (size_t)ct * 32 * CH;
    const u16* sW = Wlbf + (size_t)ct * 32 * CH;
    STAGE_W(MT, sM)
    STAGE_W(WT, sW)
  }
  __syncthreads();
  // phase 1: both K=256 GEMMs share the x operand load
  const u16* X0 = xThi + ((size_t)b * NP + wave * 32 + lm) * CH + lk * 8;
  const u16* X1 = X0 + 16 * CH;
  f32x4 awl[2][2] = {};
  f32x4 afp[2][2] = {};
#pragma unroll
  for (int kb = 0; kb < 2; kb++) {
    sh8 rx0[4], rx1[4];
#pragma unroll
    for (int u = 0; u < 4; u++) {
      int o = (kb * 4 + u) * 32;
      rx0[u] = *(const sh8*)(X0 + o);
      rx1[u] = *(const sh8*)(X1 + o);
    }
#pragma unroll
    for (int u = 0; u < 4; u++) {
      int o2 = (kb * 4 + u) * 32 + lk * 8;
      sh8 m0 = *(const sh8*)&MT[lm * LROW + o2];
      sh8 m1 = *(const sh8*)&MT[(16 + lm) * LROW + o2];
      sh8 w0 = *(const sh8*)&WT[lm * LROW + o2];
      sh8 w1 = *(const sh8*)&WT[(16 + lm) * LROW + o2];
      awl[0][0] = MFMA(m0, rx0[u], awl[0][0]);
      awl[0][1] = MFMA(m0, rx1[u], awl[0][1]);
      awl[1][0] = MFMA(m1, rx0[u], awl[1][0]);
      awl[1][1] = MFMA(m1, rx1[u], awl[1][1]);
      afp[0][0] = MFMA(w0, rx0[u], afp[0][0]);
      afp[0][1] = MFMA(w0, rx1[u], afp[0][1]);
      afp[1][0] = MFMA(w1, rx0[u], afp[1][0]);
      afp[1][1] = MFMA(w1, rx1[u], afp[1][1]);
    }
  }
  __syncthreads();   // MT reads done everywhere
  u16* wluS = WS;    // overlay: [32 c'][136 n]
#pragma unroll
  for (int i = 0; i < 2; i++)
#pragma unroll
    for (int j = 0; j < 2; j++) {
      int cl = i * 16 + lk * 4;
      int n = wave * 32 + j * 16 + lm;
      uint2 up = *(const uint2*)&WlUP[((size_t)b * NP + n) * CH + ct * 32 + cl];
      const u16* uph = (const u16*)&up;
#pragma unroll
      for (int r = 0; r < 4; r++)
        wluS[(cl + r) * 136 + n] = f2bf(awl[i][j][r] + bf2f(uph[r]));
    }
  __syncthreads();
  // phase 2: acc2 = wlu @ P (K=128 over n); B = PT rows m (wave's 32-range)
  const u16* B0 = PT + ((size_t)b * NP + wave * 32 + lm) * NP + lk * 8;
  const u16* B1 = B0 + 16 * NP;
  f32x4 acc2[2][2] = {};
#pragma unroll
  for (int ks = 0; ks < 4; ks++) {
    int o = ks * 32;
    sh8 b0 = *(const sh8*)(B0 + o);
    sh8 b1 = *(const sh8*)(B1 + o);
    int o2 = ks * 32 + lk * 8;
    sh8 a0 = *(const sh8*)&wluS[lm * 136 + o2];
    sh8 a1 = *(const sh8*)&wluS[(16 + lm) * 136 + o2];
    acc2[0][0] = MFMA(a0, b0, acc2[0][0]);
    acc2[0][1] = MFMA(a0, b1, acc2[0][1]);
    acc2[1][0] = MFMA(a1, b0, acc2[1][0]);
    acc2[1][1] = MFMA(a1, b1, acc2[1][1]);
  }
  const float rbn = 0.999995000037499687f;  // 1/sqrt(1+1e-5)
#pragma unroll
  for (int i = 0; i < 2; i++)
#pragma unroll
    for (int j = 0; j < 2; j++) {
      int m = wave * 32 + j * 16 + lm;
      int cq = ct * 32 + i * 16 + lk * 4;
      const float* sp = SCLp + (size_t)b * 4 * NP + m;
      float scl = 1.0f / (1e-12f + sp[0] + sp[NP] + sp[2 * NP] + sp[3 * NP]);
      u16 hh[4], llv[4];
#pragma unroll
      for (int r = 0; r < 4; r++) {
        int c = cq + r;
        float h = afp[i][j][r] - acc2[i][j][r] * scl + bl[c];
        h = h * rbn * bng[c] + bnb[c];
        float gg = 0.5f * h * (1.0f + erff(h * 0.70710678118654752440f));
        float ov = xsrc[(size_t)b * xbs + (size_t)c * NP + m] + gg;
        out[((size_t)b * 4 * CH + (size_t)layer * CH + c) * NP + m] = ov;
        hh[r] = f2bf(ov);
        llv[r] = f2bf(ov - bf2f(hh[r]));
      }
      size_t xoff = ((size_t)b * NP + m) * CH + cq;
      *(uint2*)&xThi_o[xoff] = *(const uint2*)hh;
      *(uint2*)&xTlo_o[xoff] = *(const uint2*)llv;
    }
}

// ---------------------------------------------------------------------------
extern "C" void kernel_launch(void* const* d_in, const int* in_sizes, int n_in,
                              void* d_out, int out_size, void* d_ws, size_t ws_size,
                              hipStream_t stream)
{
  (void)in_sizes; (void)n_in; (void)out_size; (void)ws_size;
  const float* lrf     = (const float*)d_in[0];
  const float* pca     = (const float*)d_in[1];
  const float* a_self  = (const float*)d_in[2];
  const float* a_cross = (const float*)d_in[3];
  const float* Wq  = (const float*)d_in[4];
  const float* Wk  = (const float*)d_in[5];
  const float* Wv  = (const float*)d_in[6];
  const float* Wvp = (const float*)d_in[7];
  const float* Wl  = (const float*)d_in[8];
  const float* bl  = (const float*)d_in[9];
  const float* bng = (const float*)d_in[10];
  const float* bnb = (const float*)d_in[11];
  const float* p1w = (const float*)d_in[12];
  const float* p1b = (const float*)d_in[13];
  const float* p2w = (const float*)d_in[14];
  const float* p2b = (const float*)d_in[15];
  const float* beta_x = (const float*)d_in[16];
  const float* beta_w = (const float*)d_in[17];
  float* out = (float*)d_out;
  float* ws  = (float*)d_ws;

  // ---- workspace carve ----
  const size_t QKN = (size_t)BB * NP * DQ;        // 524288
  const size_t ENN = (size_t)BB * NP * NP;        // 1048576
  const size_t XCN = (size_t)BB * NP * CH;        // 2097152

  float* SCLp = ws;
  u16* up = (u16*)(SCLp + (size_t)BB * 4 * NP);
  u16* xThiA = up;  up += XCN;   // double-buffered x^T planes
  u16* xTloA = up;  up += XCN;
  u16* xThiB = up;  up += XCN;
  u16* xTloB = up;  up += XCN;
  u16* pThi = up;   up += XCN;
  u16* pTlo = up;   up += XCN;
  u16* XQhi = up;   up += QKN;
  u16* XQlo = up;   up += QKN;
  u16* KLThi = up;  up += QKN;
  u16* KLTlo = up;  up += QKN;
  u16* KP2hiA = up; up += (size_t)NLAYERS * QKN;
  u16* KP2loA = up; up += (size_t)NLAYERS * QKN;
  u16* WlUPA = up;  up += (size_t)NLAYERS * XCN;
  u16* PTbf = up;   up += ENN;
  u16* Wlbf = up;   up += (size_t)NLAYERS * CH * CH;
  u16* WvT = up;    up += (size_t)NLAYERS * CH * CH;
  u16* WvpT = up;   up += (size_t)NLAYERS * CH * CH;
  u16* Mb = up;     up += (size_t)NLAYERS * CH * CH;
  u16* M2b = up;    up += (size_t)NLAYERS * CH * CH;
  u16* Wqhi = up;   up += (size_t)NLAYERS * DQ * CH;
  u16* Wqlo = up;   up += (size_t)NLAYERS * DQ * CH;
  u16* Wkhi = up;   up += (size_t)NLAYERS * DQ * CH;
  u16* Wklo = up;   up += (size_t)NLAYERS * DQ * CH;
  u16* p1wT = up;   up += (size_t)NLAYERS * DQ * DQ;
  u16* p2wbf = up;  up += (size_t)NLAYERS * DQ * DQ;
  u16* emb2bf = up; up += QKN;

  // ---- pre-loop (3 launches) ----
  k_init<<<dim3(2568), 256, 0, stream>>>(
      Wv, Wvp, Wl, Wq, Wk, p1w, p2w, pca, lrf, a_cross,
      Wlbf, Wqhi, Wqlo, Wkhi, Wklo, p1wT, p2wbf,
      pThi, pTlo, xThiA, xTloA, WvT, WvpT, emb2bf);
  k_mm<<<dim3(128), 256, 0, stream>>>(WvT, WvpT, Wlbf, beta_x, Mb, M2b);
  k_pre2<<<dim3(2560), 256, 0, stream>>>(
      pThi, pTlo, Wqhi, Wqlo, M2b, p2wbf, emb2bf, p2b,
      KP2hiA, KP2loA, WlUPA);

  // ---- layer loop (3 launches each) ----
  for (int l = 0; l < NLAYERS; l++) {
    const float* xsrc = (l == 0) ? lrf : (out + (size_t)(l - 1) * CH * NP);
    int xbs = (l == 0) ? CH * NP : 4 * CH * NP;
    u16* xhi_in  = (l & 1) ? xThiB : xThiA;
    u16* xlo_in  = (l & 1) ? xTloB : xTloA;
    u16* xhi_out = (l & 1) ? xThiA : xThiB;
    u16* xlo_out = (l & 1) ? xTloA : xTloB;
    k_qk<<<dim3(256), 256, 0, stream>>>(
        xhi_in, xlo_in,
        Wqhi + (size_t)l * DQ * CH, Wqlo + (size_t)l * DQ * CH,
        Wkhi + (size_t)l * DQ * CH, Wklo + (size_t)l * DQ * CH,
        XQhi, XQlo, KLThi, KLTlo);
    k_att<<<dim3(256), 256, 0, stream>>>(
        XQhi, XQlo, KLThi, KLTlo,
        KP2hiA + (size_t)l * QKN, KP2loA + (size_t)l * QKN,
        p1wT + (size_t)l * DQ * DQ, p1b + (size_t)l * DQ,
        a_self, beta_w, l, PTbf, SCLp);
    k_h4<<<dim3(512), 256, 0, stream>>>(
        xhi_in, Mb + (size_t)l * CH * CH, Wlbf + (size_t)l * CH * CH,
        WlUPA + (size_t)l * XCN, PTbf, SCLp,
        bl + (size_t)l * CH, bng + (size_t)l * CH, bnb + (size_t)l * CH,
        xsrc, xbs, out, l, xhi_out, xlo_out);
  }
}

// Round 15
// 204.488 us; speedup vs baseline: 4.3550x; 1.0146x over previous
//
#include <hip/hip_runtime.h>
#include <cstdint>
#include <cstddef>

// Round 15: (1) k_att bias loop: __sincosf -> raw v_sin/v_cos with inputs
// pre-scaled to revolutions (args bounded by 0.61 rev -> no range reduction
// needed); 1 fma + 2 trans per pair instead of ~6 ops. (2) k_qk occupancy
// 2x: 512 blocks (mat,dt,b,nh), each wave a 16-row n-tile (acc[2] 16x16
// frags) -> 2 waves/SIMD. Rest identical to round 14.

#define BB 64      // batch
#define CH 256     // channels
#define NP 128     // points
#define DQ 64      // q/k dim
#define NLAYERS 4

#define ANG_FACTOR 3.8197186342054885f   // 180/(pi*15) = 12/pi
#define ANG_REV    0.6079271018540267f   // ANG_FACTOR / (2*pi)
#define DIV_STEP   0.28782313662425575f  // ln(10000)/32

#define LROW 264   // padded LDS row stride (u16) for 256-wide tiles

typedef unsigned short u16;
typedef __attribute__((ext_vector_type(8))) short sh8;   // 8 bf16 = 4 VGPR
typedef __attribute__((ext_vector_type(4))) float f32x4; // MFMA C/D
#define MFMA(a, b, c) __builtin_amdgcn_mfma_f32_16x16x32_bf16(a, b, c, 0, 0, 0)

static __device__ __forceinline__ u16 f2bf(float x) {
  unsigned u = __float_as_uint(x);
  return (u16)((u + 0x7FFFu + ((u >> 16) & 1u)) >> 16);
}
static __device__ __forceinline__ float bf2f(u16 h) {
  return __uint_as_float(((unsigned)h) << 16);
}
// HW trig, input in REVOLUTIONS (valid: our args bounded by +-0.61 rev)
static __device__ __forceinline__ float hw_sin(float rev) {
  float r;
  asm("v_sin_f32 %0, %1" : "=v"(r) : "v"(rev));
  return r;
}
static __device__ __forceinline__ float hw_cos(float rev) {
  float r;
  asm("v_cos_f32 %0, %1" : "=v"(r) : "v"(rev));
  return r;
}

// ---------------------------------------------------------------------------
// Merged init (2568 blocks): weight cvts, transposes, emb2 bf16.
__global__ __launch_bounds__(256) void k_init(
    const float* __restrict__ Wv, const float* __restrict__ Wvp,
    const float* __restrict__ Wl, const float* __restrict__ Wq,
    const float* __restrict__ Wk, const float* __restrict__ p1w,
    const float* __restrict__ p2w, const float* __restrict__ pca,
    const float* __restrict__ lrf, const float* __restrict__ ac,
    u16* __restrict__ Wlbf, u16* __restrict__ Wqhi, u16* __restrict__ Wqlo,
    u16* __restrict__ Wkhi, u16* __restrict__ Wklo, u16* __restrict__ p1wT,
    u16* __restrict__ p2wbf, u16* __restrict__ pThi, u16* __restrict__ pTlo,
    u16* __restrict__ xThi, u16* __restrict__ xTlo,
    u16* __restrict__ WvT, u16* __restrict__ WvpT, u16* __restrict__ emb2bf)
{
  __shared__ __align__(16) float tl[64 * 65];
  int blk = blockIdx.x, tid = threadIdx.x;
  if (blk < 256) {
    int i = (blk * 256 + tid) * 4;
    float4 v = *(const float4*)(Wl + i);
    u16 o[4] = {f2bf(v.x), f2bf(v.y), f2bf(v.z), f2bf(v.w)};
    *(uint2*)(Wlbf + i) = *(const uint2*)o;
  } else if (blk < 384) {
    int bb = blk - 256;
    const float* s = (bb < 64) ? Wq : Wk;
    u16* dh = (bb < 64) ? Wqhi : Wkhi;
    u16* dl = (bb < 64) ? Wqlo : Wklo;
    int i = ((bb & 63) * 256 + tid) * 4;
    float4 v = *(const float4*)(s + i);
    float vv[4] = {v.x, v.y, v.z, v.w};
    u16 h[4], l[4];
#pragma unroll
    for (int r = 0; r < 4; r++) {
      h[r] = f2bf(vv[r]);
      l[r] = f2bf(vv[r] - bf2f(h[r]));
    }
    *(uint2*)(dh + i) = *(const uint2*)h;
    *(uint2*)(dl + i) = *(const uint2*)l;
  } else if (blk < 388) {
    int l = blk - 384;
    const float* src = p1w + (size_t)l * DQ * DQ;
    u16* dst = p1wT + (size_t)l * DQ * DQ;
#pragma unroll
    for (int i = 0; i < 16; i++) {
      int idx = tid + i * 256;
      int dd = idx >> 6, oo = idx & 63;
      dst[idx] = f2bf(src[oo * DQ + dd]);
    }
  } else if (blk < 392) {
    int l = blk - 388;
    const float* src = p2w + (size_t)l * DQ * DQ;
    u16* dst = p2wbf + (size_t)l * DQ * DQ;
#pragma unroll
    for (int i = 0; i < 16; i++) {
      int idx = tid + i * 256;
      dst[idx] = f2bf(src[idx]);
    }
  } else if (blk < 1416) {
    int bi = blk - 392;
    int nt = bi & 1, y = (bi >> 1) & 7, b = bi >> 4;
    int ct = y & 3, is_lrf = y >> 2;
    const float* x = is_lrf ? lrf : pca;
    u16* hiT = is_lrf ? xThi : pThi;
    u16* loT = is_lrf ? xTlo : pTlo;
    {
      int col = tid & 63, rq = tid >> 6;
      const float* src = x + (size_t)b * CH * NP + (size_t)(ct * 64) * NP + nt * 64;
#pragma unroll
      for (int i = 0; i < 16; i++) {
        int c = rq + i * 4;
        tl[col * 65 + c] = src[(size_t)c * NP + col];
      }
    }
    __syncthreads();
    {
      int cloc = tid & 63, nq = tid >> 6;
#pragma unroll
      for (int i = 0; i < 16; i++) {
        int n = nq + i * 4;
        float v = tl[n * 65 + cloc];
        u16 h = f2bf(v);
        u16 l = f2bf(v - bf2f(h));
        size_t off = ((size_t)b * NP + nt * 64 + n) * CH + ct * 64 + cloc;
        hiT[off] = h;
        loT[off] = l;
      }
    }
  } else if (blk < 1544) {
    // WvT[c_in][c_out] = bf(Wv[c_out][c_in]) (and Wvp)
    int bi = blk - 1416;
    int mat = bi >> 4, t = bi & 15;
    int l = mat & 3;
    const float* src = ((mat < 4) ? Wv : Wvp) + (size_t)l * CH * CH;
    u16* dst = ((mat < 4) ? WvT : WvpT) + (size_t)l * CH * CH;
    int tr = t >> 2, tc = t & 3;
    {
      int col = tid & 63, rq = tid >> 6;
#pragma unroll
      for (int i = 0; i < 16; i++) {
        int co = rq + i * 4;
        tl[col * 65 + co] = src[(size_t)(tr * 64 + co) * CH + tc * 64 + col];
      }
    }
    __syncthreads();
    {
      int cloc = tid & 63, nq = tid >> 6;
#pragma unroll
      for (int i = 0; i < 16; i++) {
        int n = nq + i * 4;
        dst[(size_t)(tc * 64 + n) * CH + tr * 64 + cloc] = f2bf(tl[n * 65 + cloc]);
      }
    }
  } else {
    int bi = blk - 1544;
    int row0 = bi * 8;
    int r = tid >> 5, j = tid & 31;
    int row = row0 + r;
    float a = ac[row];
    float rev = a * ANG_REV * __expf(-(float)j * DIV_STEP);
    emb2bf[(size_t)row * DQ + 2 * j] = f2bf(hw_sin(rev));
    emb2bf[(size_t)row * DQ + 2 * j + 1] = f2bf(hw_cos(rev));
  }
}

// ---------------------------------------------------------------------------
// M[l] = bx*Wl@Wv, M2[l] = (1-bx)*Wl@Wvp, bf16 [c'][c] (k=c contiguous).
__global__ __launch_bounds__(256) void k_mm(
    const u16* __restrict__ WvT, const u16* __restrict__ WvpT,
    const u16* __restrict__ Wlbf, const float* __restrict__ beta_x,
    u16* __restrict__ Mb, u16* __restrict__ M2b)
{
  int tid = threadIdx.x, lane = tid & 63;
  int lm = lane & 15, lk = lane >> 4;
  int tt = blockIdx.x * 4 + (tid >> 6);
  int which = tt >> 8, rest = tt & 255;
  int l = rest >> 6, t = rest & 63;
  int tcp = t >> 3, tcc = t & 7;
  const u16* WT = (which ? WvpT : WvT) + (size_t)l * CH * CH;
  const u16* A0 = WT + ((size_t)(tcc * 32) + lm) * CH + lk * 8;
  const u16* A1 = A0 + 16 * CH;
  const u16* B0 = Wlbf + (size_t)l * CH * CH + ((size_t)(tcp * 32) + lm) * CH + lk * 8;
  const u16* B1 = B0 + 16 * CH;
  f32x4 a00 = {}, a01 = {}, a10 = {}, a11 = {};
#pragma unroll
  for (int ks = 0; ks < 8; ks++) {
    int o = ks * 32;
    sh8 a0 = *(const sh8*)(A0 + o), a1 = *(const sh8*)(A1 + o);
    sh8 b0 = *(const sh8*)(B0 + o), b1 = *(const sh8*)(B1 + o);
    a00 = MFMA(a0, b0, a00);
    a01 = MFMA(a0, b1, a01);
    a10 = MFMA(a1, b0, a10);
    a11 = MFMA(a1, b1, a11);
  }
  float bx = beta_x[l];
  float sc = which ? (1.0f - bx) : bx;
  u16* out = (which ? M2b : Mb) + (size_t)l * CH * CH;
  f32x4 acc[2][2] = {{a00, a01}, {a10, a11}};
#pragma unroll
  for (int i = 0; i < 2; i++)
#pragma unroll
    for (int j = 0; j < 2; j++) {
      int c0 = tcc * 32 + i * 16 + lk * 4;
      int cp = tcp * 32 + j * 16 + lm;
      u16 ov[4];
#pragma unroll
      for (int r = 0; r < 4; r++) ov[r] = f2bf(sc * acc[i][j][r]);
      *(uint2*)&out[(size_t)cp * CH + c0] = *(const uint2*)ov;
    }
}

// ---------------------------------------------------------------------------
#define STAGE_W(dst, src)                                                    \
  _Pragma("unroll")                                                          \
  for (int it = 0; it < 4; it++) {                                           \
    int idx = threadIdx.x + it * 256, row = idx >> 5, ch = idx & 31;         \
    *(uint4*)&dst[row * LROW + ch * 8] =                                     \
        *(const uint4*)(src + row * 256 + ch * 8);                           \
  }

// ---------------------------------------------------------------------------
// [0,512): KP2A[l] = split(Wq[l]@pca + emb2@p2w[l]^T + p2b[l]);
// [512,2560): WlUPA[l][b][n][c'] = bf(M2[l]@pca).
__global__ __launch_bounds__(256) void k_pre2(
    const u16* __restrict__ pThi, const u16* __restrict__ pTlo,
    const u16* __restrict__ Wqhi, const u16* __restrict__ Wqlo,
    const u16* __restrict__ M2b, const u16* __restrict__ p2wbf,
    const u16* __restrict__ emb2bf, const float* __restrict__ p2b,
    u16* __restrict__ KP2hiA, u16* __restrict__ KP2loA, u16* __restrict__ WlUPA)
{
  __shared__ __align__(16) u16 WS[2 * 32 * LROW];
  int tid = threadIdx.x, lane = tid & 63;
  int lm = lane & 15, lk = lane >> 4;
  if (blockIdx.x < 512) {
    int bi = blockIdx.x;
    int l = bi >> 7, rest = bi & 127;
    int dt = rest >> 6, b = rest & 63;
    int nt = tid >> 6;
    u16* WH = WS;
    u16* WL = WS + 32 * LROW;
    {
      const u16* sH = Wqhi + (size_t)l * DQ * CH + (size_t)dt * 32 * CH;
      const u16* sL = Wqlo + (size_t)l * DQ * CH + (size_t)dt * 32 * CH;
      STAGE_W(WH, sH)
      STAGE_W(WL, sL)
    }
    __syncthreads();
    const u16* B0h = pThi + ((size_t)b * NP + nt * 32 + lm) * CH + lk * 8;
    const u16* B1h = B0h + 16 * CH;
    const u16* B0l = pTlo + ((size_t)b * NP + nt * 32 + lm) * CH + lk * 8;
    const u16* B1l = B0l + 16 * CH;
    f32x4 acc[2][2] = {};
#pragma unroll
    for (int kb = 0; kb < 4; kb++) {
      sh8 rb0h[2], rb1h[2], rb0l[2], rb1l[2];
#pragma unroll
      for (int u = 0; u < 2; u++) {
        int o = (kb * 2 + u) * 32;
        rb0h[u] = *(const sh8*)(B0h + o); rb1h[u] = *(const sh8*)(B1h + o);
        rb0l[u] = *(const sh8*)(B0l + o); rb1l[u] = *(const sh8*)(B1l + o);
      }
#pragma unroll
      for (int u = 0; u < 2; u++) {
        int o2 = (kb * 2 + u) * 32 + lk * 8;
        sh8 a0h = *(const sh8*)&WH[lm * LROW + o2];
        sh8 a1h = *(const sh8*)&WH[(16 + lm) * LROW + o2];
        sh8 a0l = *(const sh8*)&WL[lm * LROW + o2];
        sh8 a1l = *(const sh8*)&WL[(16 + lm) * LROW + o2];
        acc[0][0] = MFMA(a0h, rb0h[u], acc[0][0]);
        acc[0][0] = MFMA(a0h, rb0l[u], acc[0][0]);
        acc[0][0] = MFMA(a0l, rb0h[u], acc[0][0]);
        acc[0][1] = MFMA(a0h, rb1h[u], acc[0][1]);
        acc[0][1] = MFMA(a0h, rb1l[u], acc[0][1]);
        acc[0][1] = MFMA(a0l, rb1h[u], acc[0][1]);
        acc[1][0] = MFMA(a1h, rb0h[u], acc[1][0]);
        acc[1][0] = MFMA(a1h, rb0l[u], acc[1][0]);
        acc[1][0] = MFMA(a1l, rb0h[u], acc[1][0]);
        acc[1][1] = MFMA(a1h, rb1h[u], acc[1][1]);
        acc[1][1] = MFMA(a1h, rb1l[u], acc[1][1]);
        acc[1][1] = MFMA(a1l, rb1h[u], acc[1][1]);
      }
    }
    // E2 terms: A = p2w rows (o = dt*32..), B = emb2 rows (m), K = 64
    {
      const u16* A20 = p2wbf + (size_t)l * DQ * DQ + ((size_t)(dt * 32) + lm) * DQ + lk * 8;
      const u16* A21 = A20 + 16 * DQ;
      const u16* B20 = emb2bf + ((size_t)b * NP + nt * 32 + lm) * DQ + lk * 8;
      const u16* B21 = B20 + 16 * DQ;
#pragma unroll
      for (int ks = 0; ks < 2; ks++) {
        int o = ks * 32;
        sh8 a0 = *(const sh8*)(A20 + o), a1 = *(const sh8*)(A21 + o);
        sh8 b0 = *(const sh8*)(B20 + o), b1 = *(const sh8*)(B21 + o);
        acc[0][0] = MFMA(a0, b0, acc[0][0]);
        acc[0][1] = MFMA(a0, b1, acc[0][1]);
        acc[1][0] = MFMA(a1, b0, acc[1][0]);
        acc[1][1] = MFMA(a1, b1, acc[1][1]);
      }
    }
#pragma unroll
    for (int i = 0; i < 2; i++)
#pragma unroll
      for (int j = 0; j < 2; j++) {
        int n = nt * 32 + j * 16 + lm;
        int d0 = dt * 32 + i * 16 + lk * 4;
        size_t off = (((size_t)l * BB + b) * NP + n) * DQ + d0;
        f32x4 v = acc[i][j];
        u16 h[4], lo[4];
#pragma unroll
        for (int r2 = 0; r2 < 4; r2++) {
          float vv = v[r2] + p2b[l * DQ + d0 + r2];
          h[r2] = f2bf(vv);
          lo[r2] = f2bf(vv - bf2f(h[r2]));
        }
        *(uint2*)&KP2hiA[off] = *(const uint2*)h;
        *(uint2*)&KP2loA[off] = *(const uint2*)lo;
      }
  } else {
    int bi = blockIdx.x - 512;
    int l = bi >> 9, rest = bi & 511;
    int ct = rest >> 6, b = rest & 63;
    int nt = tid >> 6;
    {
      const u16* sH = M2b + (size_t)l * CH * CH + (size_t)ct * 32 * CH;
      STAGE_W(WS, sH)
    }
    __syncthreads();
    const u16* X0 = pThi + ((size_t)b * NP + nt * 32 + lm) * CH + lk * 8;
    const u16* X1 = X0 + 16 * CH;
    f32x4 a00 = {}, a01 = {}, a10 = {}, a11 = {};
    // A = M2 rows c' (LDS), B = pca rows n -> D[row=c'][col=n]
#pragma unroll
    for (int kb = 0; kb < 2; kb++) {
      sh8 rx0[4], rx1[4];
#pragma unroll
      for (int u = 0; u < 4; u++) {
        int o = (kb * 4 + u) * 32;
        rx0[u] = *(const sh8*)(X0 + o); rx1[u] = *(const sh8*)(X1 + o);
      }
#pragma unroll
      for (int u = 0; u < 4; u++) {
        int o2 = (kb * 4 + u) * 32 + lk * 8;
        sh8 w0 = *(const sh8*)&WS[lm * LROW + o2];
        sh8 w1 = *(const sh8*)&WS[(16 + lm) * LROW + o2];
        a00 = MFMA(w0, rx0[u], a00);
        a01 = MFMA(w0, rx1[u], a01);
        a10 = MFMA(w1, rx0[u], a10);
        a11 = MFMA(w1, rx1[u], a11);
      }
    }
    f32x4 acc[2][2] = {{a00, a01}, {a10, a11}};
#pragma unroll
    for (int i = 0; i < 2; i++)
#pragma unroll
      for (int j = 0; j < 2; j++) {
        int c0 = ct * 32 + i * 16 + lk * 4;
        int n = nt * 32 + j * 16 + lm;
        u16 ov[4];
#pragma unroll
        for (int r2 = 0; r2 < 4; r2++) ov[r2] = f2bf(acc[i][j][r2]);
        *(uint2*)&WlUPA[(((size_t)l * BB + b) * NP + n) * CH + c0] = *(const uint2*)ov;
      }
  }
}

// ---------------------------------------------------------------------------
// Per-layer QK projections, 512 blocks = 2mat x 2dt x 64b x 2nh; each wave
// handles a 16-row n-tile (2 waves/SIMD occupancy).
__global__ __launch_bounds__(256) void k_qk(
    const u16* __restrict__ xThi, const u16* __restrict__ xTlo,
    const u16* __restrict__ Wqhi, const u16* __restrict__ Wqlo,
    const u16* __restrict__ Wkhi, const u16* __restrict__ Wklo,
    u16* __restrict__ XQhi, u16* __restrict__ XQlo,
    u16* __restrict__ KLThi, u16* __restrict__ KLTlo)
{
  __shared__ __align__(16) u16 WS[2 * 32 * LROW];
  int tid = threadIdx.x, lane = tid & 63, wave = tid >> 6;
  int lm = lane & 15, lk = lane >> 4;
  int bi = blockIdx.x;
  int mat = bi >> 8, r = bi & 255;
  int dt = r >> 7, r2 = r & 127;
  int nh = r2 >> 6, b = r2 & 63;
  u16* WH = WS;
  u16* WL = WS + 32 * LROW;
  {
    const u16* sH = (mat ? Wkhi : Wqhi) + (size_t)dt * 32 * CH;
    const u16* sL = (mat ? Wklo : Wqlo) + (size_t)dt * 32 * CH;
    STAGE_W(WH, sH)
    STAGE_W(WL, sL)
  }
  __syncthreads();
  int n0 = nh * 64 + wave * 16;
  const u16* B0h = xThi + ((size_t)b * NP + n0 + lm) * CH + lk * 8;
  const u16* B0l = xTlo + ((size_t)b * NP + n0 + lm) * CH + lk * 8;
  f32x4 acc[2] = {};
#pragma unroll
  for (int kb = 0; kb < 4; kb++) {
    sh8 rbh[2], rbl[2];
#pragma unroll
    for (int u = 0; u < 2; u++) {
      int o = (kb * 2 + u) * 32;
      rbh[u] = *(const sh8*)(B0h + o);
      rbl[u] = *(const sh8*)(B0l + o);
    }
#pragma unroll
    for (int u = 0; u < 2; u++) {
      int o2 = (kb * 2 + u) * 32 + lk * 8;
      sh8 a0h = *(const sh8*)&WH[lm * LROW + o2];
      sh8 a1h = *(const sh8*)&WH[(16 + lm) * LROW + o2];
      sh8 a0l = *(const sh8*)&WL[lm * LROW + o2];
      sh8 a1l = *(const sh8*)&WL[(16 + lm) * LROW + o2];
      acc[0] = MFMA(a0h, rbh[u], acc[0]);
      acc[0] = MFMA(a0h, rbl[u], acc[0]);
      acc[0] = MFMA(a0l, rbh[u], acc[0]);
      acc[1] = MFMA(a1h, rbh[u], acc[1]);
      acc[1] = MFMA(a1h, rbl[u], acc[1]);
      acc[1] = MFMA(a1l, rbh[u], acc[1]);
    }
  }
  int n = n0 + lm;
#pragma unroll
  for (int i = 0; i < 2; i++) {
    int d0 = dt * 32 + i * 16 + lk * 4;
    size_t off = ((size_t)b * NP + n) * DQ + d0;
    u16 h[4], lo[4];
#pragma unroll
    for (int r3 = 0; r3 < 4; r3++) {
      h[r3] = f2bf(acc[i][r3]);
      lo[r3] = f2bf(acc[i][r3] - bf2f(h[r3]));
    }
    if (mat == 0) {
      *(uint2*)&XQhi[off] = *(const uint2*)h;
      *(uint2*)&XQlo[off] = *(const uint2*)lo;
    } else {
      *(uint2*)&KLThi[off] = *(const uint2*)h;
      *(uint2*)&KLTlo[off] = *(const uint2*)lo;
    }
  }
}

// ---------------------------------------------------------------------------
// Fused attention (256 blocks): energy MFMA + q1-MFMA + c1 + hw-trig bias +
// softmax + P^T bf16 + colsum partials.
__global__ __launch_bounds__(256) void k_att(
    const u16* __restrict__ XQhi, const u16* __restrict__ XQlo,
    const u16* __restrict__ KLThi, const u16* __restrict__ KLTlo,
    const u16* __restrict__ KP2hi, const u16* __restrict__ KP2lo,
    const u16* __restrict__ p1wT, const float* __restrict__ p1b,
    const float* __restrict__ AS, const float* __restrict__ beta_w, int layer,
    u16* __restrict__ PT, float* __restrict__ SCLp)
{
  __shared__ __align__(16) char smem[25856];
  int tid = threadIdx.x;
  int lane = tid & 63;
  int lm = lane & 15, lk = lane >> 4;
  int g = blockIdx.x & 3, b = blockIdx.x >> 2;
  int wave = tid >> 6;
  float* q1sh = (float*)smem;          // [32][66]
  float* c1sh = q1sh + 32 * 66;        // [32]
  float* divs = c1sh + 32;             // [32]
  float* Esh  = divs + 32;             // [32][132]
  if (tid < 32) divs[tid] = __expf(-(float)tid * DIV_STEP);
  float bw = beta_w[layer], obw = 1.0f - bw;
  {
    int mt = wave;
    size_t arow = ((size_t)b * NP + mt * 32 + lm) * DQ + lk * 8;
    size_t brow = ((size_t)b * NP + g * 32 + lm) * DQ + lk * 8;
    const u16* L0h = KLThi + arow;
    const u16* L0l = KLTlo + arow;
    const u16* P0h = KP2hi + arow;
    const u16* P0l = KP2lo + arow;
    const u16* X0h = XQhi + brow;
    const u16* X0l = XQlo + brow;
    sh8 xh[2][2], xl[2][2], lh[2][2], llr[2][2], ph[2][2], pl[2][2];
#pragma unroll
    for (int row = 0; row < 2; row++) {
#pragma unroll
      for (int ks = 0; ks < 2; ks++) {
        int o = row * 16 * DQ + ks * 32;
        xh[row][ks] = *(const sh8*)(X0h + o);
        xl[row][ks] = *(const sh8*)(X0l + o);
        lh[row][ks] = *(const sh8*)(L0h + o);
        llr[row][ks] = *(const sh8*)(L0l + o);
        ph[row][ks] = *(const sh8*)(P0h + o);
        pl[row][ks] = *(const sh8*)(P0l + o);
      }
    }
    f32x4 aL[2][2] = {};
    f32x4 aP[2][2] = {};
#pragma unroll
    for (int ks = 0; ks < 2; ks++) {
#pragma unroll
      for (int i = 0; i < 2; i++) {
#pragma unroll
        for (int j = 0; j < 2; j++) {
          aL[i][j] = MFMA(lh[i][ks], xh[j][ks], aL[i][j]);
          aL[i][j] = MFMA(lh[i][ks], xl[j][ks], aL[i][j]);
          aL[i][j] = MFMA(llr[i][ks], xh[j][ks], aL[i][j]);
          aP[i][j] = MFMA(ph[i][ks], xh[j][ks], aP[i][j]);
          aP[i][j] = MFMA(ph[i][ks], xl[j][ks], aP[i][j]);
          aP[i][j] = MFMA(pl[i][ks], xh[j][ks], aP[i][j]);
        }
      }
    }
#pragma unroll
    for (int i = 0; i < 2; i++)
#pragma unroll
      for (int j = 0; j < 2; j++) {
        int nloc = j * 16 + lm;
        int mloc = mt * 32 + i * 16 + lk * 4;
        float4 v;
        v.x = bw * aL[i][j][0] + obw * aP[i][j][0];
        v.y = bw * aL[i][j][1] + obw * aP[i][j][1];
        v.z = bw * aL[i][j][2] + obw * aP[i][j][2];
        v.w = bw * aL[i][j][3] + obw * aP[i][j][3];
        *(float4*)&Esh[nloc * 132 + mloc] = v;
      }
  }
  if (wave < 2) {
    const u16* A0 = XQhi + ((size_t)b * NP + g * 32 + lm) * DQ + lk * 8;
    const u16* A1 = A0 + 16 * DQ;
    const u16* B0 = p1wT + ((size_t)(wave * 32) + lm) * DQ + lk * 8;
    const u16* B1 = B0 + 16 * DQ;
    f32x4 q[2][2] = {};
#pragma unroll
    for (int ks = 0; ks < 2; ks++) {
      int o = ks * 32;
      sh8 a0 = *(const sh8*)(A0 + o), a1 = *(const sh8*)(A1 + o);
      sh8 b0 = *(const sh8*)(B0 + o), b1 = *(const sh8*)(B1 + o);
      q[0][0] = MFMA(a0, b0, q[0][0]);
      q[0][1] = MFMA(a0, b1, q[0][1]);
      q[1][0] = MFMA(a1, b0, q[1][0]);
      q[1][1] = MFMA(a1, b1, q[1][1]);
    }
#pragma unroll
    for (int i = 0; i < 2; i++)
#pragma unroll
      for (int j = 0; j < 2; j++)
#pragma unroll
        for (int r = 0; r < 4; r++)
          q1sh[(i * 16 + lk * 4 + r) * 66 + wave * 32 + j * 16 + lm] = q[i][j][r];
  }
  {
    int n = tid >> 3, o0 = (tid & 7) * 8;
    const u16* xs = XQhi + ((size_t)b * NP + g * 32 + n) * DQ + o0;
    uint2 w0 = *(const uint2*)xs;
    uint2 w1 = *(const uint2*)(xs + 4);
    const u16* hh = (const u16*)&w0;
    const u16* h2 = (const u16*)&w1;
    float s = 0.0f;
#pragma unroll
    for (int k = 0; k < 4; k++) s = fmaf(bf2f(hh[k]), p1b[o0 + k], s);
#pragma unroll
    for (int k = 0; k < 4; k++) s = fmaf(bf2f(h2[k]), p1b[o0 + 4 + k], s);
    s += __shfl_xor(s, 1);
    s += __shfl_xor(s, 2);
    s += __shfl_xor(s, 4);
    if ((tid & 7) == 0) c1sh[n] = s;
  }
  __syncthreads();
  {
    int n = tid >> 3, mc = (tid & 7) * 16;
    size_t asrow = ((size_t)b * NP + g * 32 + n) * NP + mc;
    float idxv[16], bias[16];
    float c1v = c1sh[n];
#pragma unroll
    for (int k4 = 0; k4 < 4; k4++) {
      float4 a4 = *(const float4*)&AS[asrow + k4 * 4];
      idxv[k4 * 4 + 0] = a4.x * ANG_REV;
      idxv[k4 * 4 + 1] = a4.y * ANG_REV;
      idxv[k4 * 4 + 2] = a4.z * ANG_REV;
      idxv[k4 * 4 + 3] = a4.w * ANG_REV;
    }
#pragma unroll
    for (int k = 0; k < 16; k++) bias[k] = c1v;
    for (int j = 0; j < 32; j++) {
      float dv = divs[j];
      float qs = q1sh[n * 66 + 2 * j], qc = q1sh[n * 66 + 2 * j + 1];
#pragma unroll
      for (int k = 0; k < 16; k++) {
        float rev = idxv[k] * dv;   // |rev| <= 0.61 revolutions
        bias[k] = fmaf(qs, hw_sin(rev), bias[k]);
        bias[k] = fmaf(qc, hw_cos(rev), bias[k]);
      }
    }
    float ev[16], mx = -1e30f;
#pragma unroll
    for (int k = 0; k < 16; k++) {
      ev[k] = Esh[n * 132 + mc + k] + bw * bias[k];
      mx = fmaxf(mx, ev[k]);
    }
    mx = fmaxf(mx, __shfl_xor(mx, 1));
    mx = fmaxf(mx, __shfl_xor(mx, 2));
    mx = fmaxf(mx, __shfl_xor(mx, 4));
    float s = 0.0f;
#pragma unroll
    for (int k = 0; k < 16; k++) {
      ev[k] = __expf(ev[k] - mx);
      s += ev[k];
    }
    s += __shfl_xor(s, 1);
    s += __shfl_xor(s, 2);
    s += __shfl_xor(s, 4);
    float inv = 1.0f / s;
#pragma unroll
    for (int k = 0; k < 16; k++) Esh[n * 132 + mc + k] = ev[k] * inv;
  }
  __syncthreads();
  {
    int m = tid >> 1, nc = (tid & 1) * 16;
    float s = 0.0f;
    u16 tmp[16];
#pragma unroll
    for (int k = 0; k < 16; k++) {
      float v = Esh[(nc + k) * 132 + m];
      s += v;
      tmp[k] = f2bf(v);
    }
    u16* dst = PT + ((size_t)b * NP + m) * NP + g * 32 + nc;
    *(uint4*)&dst[0] = *(const uint4*)&tmp[0];
    *(uint4*)&dst[8] = *(const uint4*)&tmp[8];
    s += __shfl_xor(s, 1);
    if ((tid & 1) == 0) SCLp[((size_t)b * 4 + g) * NP + m] = s;
  }
}

// ---------------------------------------------------------------------------
// Merged value epilogue (512 blocks = 8ct x 64b). Per block:
// phase1: wlu = M@x (+WlUP), afp = Wl@x (K=256, x loaded once, afp in VGPRs);
// phase2: acc2 = wlu @ P (K=128, wlu via LDS overlay); epilogue:
// out = x + gelu(BN(afp - acc2*scl + bl)); writes NEXT-layer xT plane (o).
__global__ __launch_bounds__(256) void k_h4(
    const u16* __restrict__ xThi, const u16* __restrict__ Mb,
    const u16* __restrict__ Wlbf, const u16* __restrict__ WlUP,
    const u16* __restrict__ PT, const float* __restrict__ SCLp,
    const float* __restrict__ bl, const float* __restrict__ bng,
    const float* __restrict__ bnb, const float* __restrict__ xsrc, int xbs,
    float* __restrict__ out, int layer,
    u16* __restrict__ xThi_o, u16* __restrict__ xTlo_o)
{
  __shared__ __align__(16) u16 WS[2 * 32 * LROW];
  int ct = blockIdx.x >> 6, b = blockIdx.x & 63;
  int tid = threadIdx.x, lane = tid & 63, wave = tid >> 6;
  int lm = lane & 15, lk = lane >> 4;
  u16* MT = WS;
  u16* WT = WS + 32 * LROW;
  {
    const u16* sM = Mb + (size_t)ct * 32 * CH;
    const u16* sW = Wlbf + (size_t)ct * 32 * CH;
    STAGE_W(MT, sM)
    STAGE_W(WT, sW)
  }
  __syncthreads();
  // phase 1: both K=256 GEMMs share the x operand load
  const u16* X0 = xThi + ((size_t)b * NP + wave * 32 + lm) * CH + lk * 8;
  const u16* X1 = X0 + 16 * CH;
  f32x4 awl[2][2] = {};
  f32x4 afp[2][2] = {};
#pragma unroll
  for (int kb = 0; kb < 2; kb++) {
    sh8 rx0[4], rx1[4];
#pragma unroll
    for (int u = 0; u < 4; u++) {
      int o = (kb * 4 + u) * 32;
      rx0[u] = *(const sh8*)(X0 + o);
      rx1[u] = *(const sh8*)(X1 + o);
    }
#pragma unroll
    for (int u = 0; u < 4; u++) {
      int o2 = (kb * 4 + u) * 32 + lk * 8;
      sh8 m0 = *(const sh8*)&MT[lm * LROW + o2];
      sh8 m1 = *(const sh8*)&MT[(16 + lm) * LROW + o2];
      sh8 w0 = *(const sh8*)&WT[lm * LROW + o2];
      sh8 w1 = *(const sh8*)&WT[(16 + lm) * LROW + o2];
      awl[0][0] = MFMA(m0, rx0[u], awl[0][0]);
      awl[0][1] = MFMA(m0, rx1[u], awl[0][1]);
      awl[1][0] = MFMA(m1, rx0[u], awl[1][0]);
      awl[1][1] = MFMA(m1, rx1[u], awl[1][1]);
      afp[0][0] = MFMA(w0, rx0[u], afp[0][0]);
      afp[0][1] = MFMA(w0, rx1[u], afp[0][1]);
      afp[1][0] = MFMA(w1, rx0[u], afp[1][0]);
      afp[1][1] = MFMA(w1, rx1[u], afp[1][1]);
    }
  }
  __syncthreads();   // MT reads done everywhere
  u16* wluS = WS;    // overlay: [32 c'][136 n]
#pragma unroll
  for (int i = 0; i < 2; i++)
#pragma unroll
    for (int j = 0; j < 2; j++) {
      int cl = i * 16 + lk * 4;
      int n = wave * 32 + j * 16 + lm;
      uint2 up = *(const uint2*)&WlUP[((size_t)b * NP + n) * CH + ct * 32 + cl];
      const u16* uph = (const u16*)&up;
#pragma unroll
      for (int r = 0; r < 4; r++)
        wluS[(cl + r) * 136 + n] = f2bf(awl[i][j][r] + bf2f(uph[r]));
    }
  __syncthreads();
  // phase 2: acc2 = wlu @ P (K=128 over n); B = PT rows m (wave's 32-range)
  const u16* B0 = PT + ((size_t)b * NP + wave * 32 + lm) * NP + lk * 8;
  const u16* B1 = B0 + 16 * NP;
  f32x4 acc2[2][2] = {};
#pragma unroll
  for (int ks = 0; ks < 4; ks++) {
    int o = ks * 32;
    sh8 b0 = *(const sh8*)(B0 + o);
    sh8 b1 = *(const sh8*)(B1 + o);
    int o2 = ks * 32 + lk * 8;
    sh8 a0 = *(const sh8*)&wluS[lm * 136 + o2];
    sh8 a1 = *(const sh8*)&wluS[(16 + lm) * 136 + o2];
    acc2[0][0] = MFMA(a0, b0, acc2[0][0]);
    acc2[0][1] = MFMA(a0, b1, acc2[0][1]);
    acc2[1][0] = MFMA(a1, b0, acc2[1][0]);
    acc2[1][1] = MFMA(a1, b1, acc2[1][1]);
  }
  const float rbn = 0.999995000037499687f;  // 1/sqrt(1+1e-5)
#pragma unroll
  for (int i = 0; i < 2; i++)
#pragma unroll
    for (int j = 0; j < 2; j++) {
      int m = wave * 32 + j * 16 + lm;
      int cq = ct * 32 + i * 16 + lk * 4;
      const float* sp = SCLp + (size_t)b * 4 * NP + m;
      float scl = 1.0f / (1e-12f + sp[0] + sp[NP] + sp[2 * NP] + sp[3 * NP]);
      u16 hh[4], llv[4];
#pragma unroll
      for (int r = 0; r < 4; r++) {
        int c = cq + r;
        float h = afp[i][j][r] - acc2[i][j][r] * scl + bl[c];
        h = h * rbn * bng[c] + bnb[c];
        float gg = 0.5f * h * (1.0f + erff(h * 0.70710678118654752440f));
        float ov = xsrc[(size_t)b * xbs + (size_t)c * NP + m] + gg;
        out[((size_t)b * 4 * CH + (size_t)layer * CH + c) * NP + m] = ov;
        hh[r] = f2bf(ov);
        llv[r] = f2bf(ov - bf2f(hh[r]));
      }
      size_t xoff = ((size_t)b * NP + m) * CH + cq;
      *(uint2*)&xThi_o[xoff] = *(const uint2*)hh;
      *(uint2*)&xTlo_o[xoff] = *(const uint2*)llv;
    }
}

// ---------------------------------------------------------------------------
extern "C" void kernel_launch(void* const* d_in, const int* in_sizes, int n_in,
                              void* d_out, int out_size, void* d_ws, size_t ws_size,
                              hipStream_t stream)
{
  (void)in_sizes; (void)n_in; (void)out_size; (void)ws_size;
  const float* lrf     = (const float*)d_in[0];
  const float* pca     = (const float*)d_in[1];
  const float* a_self  = (const float*)d_in[2];
  const float* a_cross = (const float*)d_in[3];
  const float* Wq  = (const float*)d_in[4];
  const float* Wk  = (const float*)d_in[5];
  const float* Wv  = (const float*)d_in[6];
  const float* Wvp = (const float*)d_in[7];
  const float* Wl  = (const float*)d_in[8];
  const float* bl  = (const float*)d_in[9];
  const float* bng = (const float*)d_in[10];
  const float* bnb = (const float*)d_in[11];
  const float* p1w = (const float*)d_in[12];
  const float* p1b = (const float*)d_in[13];
  const float* p2w = (const float*)d_in[14];
  const float* p2b = (const float*)d_in[15];
  const float* beta_x = (const float*)d_in[16];
  const float* beta_w = (const float*)d_in[17];
  float* out = (float*)d_out;
  float* ws  = (float*)d_ws;

  // ---- workspace carve ----
  const size_t QKN = (size_t)BB * NP * DQ;        // 524288
  const size_t ENN = (size_t)BB * NP * NP;        // 1048576
  const size_t XCN = (size_t)BB * NP * CH;        // 2097152

  float* SCLp = ws;
  u16* up = (u16*)(SCLp + (size_t)BB * 4 * NP);
  u16* xThiA = up;  up += XCN;   // double-buffered x^T planes
  u16* xTloA = up;  up += XCN;
  u16* xThiB = up;  up += XCN;
  u16* xTloB = up;  up += XCN;
  u16* pThi = up;   up += XCN;
  u16* pTlo = up;   up += XCN;
  u16* XQhi = up;   up += QKN;
  u16* XQlo = up;   up += QKN;
  u16* KLThi = up;  up += QKN;
  u16* KLTlo = up;  up += QKN;
  u16* KP2hiA = up; up += (size_t)NLAYERS * QKN;
  u16* KP2loA = up; up += (size_t)NLAYERS * QKN;
  u16* WlUPA = up;  up += (size_t)NLAYERS * XCN;
  u16* PTbf = up;   up += ENN;
  u16* Wlbf = up;   up += (size_t)NLAYERS * CH * CH;
  u16* WvT = up;    up += (size_t)NLAYERS * CH * CH;
  u16* WvpT = up;   up += (size_t)NLAYERS * CH * CH;
  u16* Mb = up;     up += (size_t)NLAYERS * CH * CH;
  u16* M2b = up;    up += (size_t)NLAYERS * CH * CH;
  u16* Wqhi = up;   up += (size_t)NLAYERS * DQ * CH;
  u16* Wqlo = up;   up += (size_t)NLAYERS * DQ * CH;
  u16* Wkhi = up;   up += (size_t)NLAYERS * DQ * CH;
  u16* Wklo = up;   up += (size_t)NLAYERS * DQ * CH;
  u16* p1wT = up;   up += (size_t)NLAYERS * DQ * DQ;
  u16* p2wbf = up;  up += (size_t)NLAYERS * DQ * DQ;
  u16* emb2bf = up; up += QKN;

  // ---- pre-loop (3 launches) ----
  k_init<<<dim3(2568), 256, 0, stream>>>(
      Wv, Wvp, Wl, Wq, Wk, p1w, p2w, pca, lrf, a_cross,
      Wlbf, Wqhi, Wqlo, Wkhi, Wklo, p1wT, p2wbf,
      pThi, pTlo, xThiA, xTloA, WvT, WvpT, emb2bf);
  k_mm<<<dim3(128), 256, 0, stream>>>(WvT, WvpT, Wlbf, beta_x, Mb, M2b);
  k_pre2<<<dim3(2560), 256, 0, stream>>>(
      pThi, pTlo, Wqhi, Wqlo, M2b, p2wbf, emb2bf, p2b,
      KP2hiA, KP2loA, WlUPA);

  // ---- layer loop (3 launches each) ----
  for (int l = 0; l < NLAYERS; l++) {
    const float* xsrc = (l == 0) ? lrf : (out + (size_t)(l - 1) * CH * NP);
    int xbs = (l == 0) ? CH * NP : 4 * CH * NP;
    u16* xhi_in  = (l & 1) ? xThiB : xThiA;
    u16* xlo_in  = (l & 1) ? xTloB : xTloA;
    u16* xhi_out = (l & 1) ? xThiA : xThiB;
    u16* xlo_out = (l & 1) ? xTloA : xTloB;
    k_qk<<<dim3(512), 256, 0, stream>>>(
        xhi_in, xlo_in,
        Wqhi + (size_t)l * DQ * CH, Wqlo + (size_t)l * DQ * CH,
        Wkhi + (size_t)l * DQ * CH, Wklo + (size_t)l * DQ * CH,
        XQhi, XQlo, KLThi, KLTlo);
    k_att<<<dim3(256), 256, 0, stream>>>(
        XQhi, XQlo, KLThi, KLTlo,
        KP2hiA + (size_t)l * QKN, KP2loA + (size_t)l * QKN,
        p1wT + (size_t)l * DQ * DQ, p1b + (size_t)l * DQ,
        a_self, beta_w, l, PTbf, SCLp);
    k_h4<<<dim3(512), 256, 0, stream>>>(
        xhi_in, Mb + (size_t)l * CH * CH, Wlbf + (size_t)l * CH * CH,
        WlUPA + (size_t)l * XCN, PTbf, SCLp,
        bl + (size_t)l * CH, bng + (size_t)l * CH, bnb + (size_t)l * CH,
        xsrc, xbs, out, l, xhi_out, xlo_out);
  }
}